// Round 2
// baseline (3487.951 us; speedup 1.0000x reference)
//
#include <hip/hip_runtime.h>
#include <stdint.h>

// NystromAttention on MI355X — Round 2: f32 pipeline with bf16 q/k/v storage
// (workspace ~102 MiB, was ~275 MiB -> suspected d_ws overflow crash).
// fp64 Jacobi-SVD pinv with jax rcond truncation semantics.
//
// Shapes (hard-coded from reference): B=2, N=16384, C=512, H=8, hd=64,
// landmarks m=64, seg=256 (no padding).

constexpr int B_   = 2;
constexpr int N_   = 16384;
constexpr int C_   = 512;
constexpr int H_   = 8;
constexpr int HD_  = 64;
constexpr int LM_  = 64;
constexpr int SEG_ = 256;
constexpr int BH_  = 16;     // B*H
constexpr int NCH_ = 16;     // chunks for ker3/kv partials
constexpr int CHLEN_ = 1024; // tokens per chunk
constexpr int NSWEEP_ = 10;  // Jacobi sweeps

// jax pinv default rcond: 10 * max(M,N) * eps(f32) = 640 * 2^-23
#define RCOND_ (640.0 * 1.1920928955078125e-07)

typedef unsigned short ushort4_t __attribute__((ext_vector_type(4)));
typedef unsigned short ushort8_t __attribute__((ext_vector_type(8)));

__device__ inline float bf2f(unsigned short u) {
  union { unsigned int i; float f; } x; x.i = ((unsigned int)u) << 16; return x.f;
}
__device__ inline unsigned short f2bf(float f) {
  union { float f; unsigned int i; } x; x.f = f;
  unsigned int lsb = (x.i >> 16) & 1;
  return (unsigned short)((x.i + 0x7fffu + lsb) >> 16);
}

// ---------------------------------------------------------------------------
// K1: segment means of x -> xbar (B, LM, C).  One block per (b, landmark).
__global__ __launch_bounds__(256) void seg_mean_kernel(const float* __restrict__ x,
                                                       float* __restrict__ xbar) {
  int bl = blockIdx.x;            // b*LM + l
  int b = bl / LM_, l = bl % LM_;
  int t = threadIdx.x;
  int c4 = t & 127;               // float4 column group (512/4 = 128)
  int rh = t >> 7;                // row half: 0 or 1
  const float* xp = x + ((size_t)b * N_ + (size_t)l * SEG_) * C_;
  float4 s = make_float4(0.f, 0.f, 0.f, 0.f);
  for (int r = rh * 128; r < rh * 128 + 128; ++r) {
    float4 v = *(const float4*)(xp + (size_t)r * C_ + c4 * 4);
    s.x += v.x; s.y += v.y; s.z += v.z; s.w += v.w;
  }
  __shared__ float red[2][512];
  *(float4*)&red[rh][c4 * 4] = s;
  __syncthreads();
  if (rh == 0) {
    float4 a = *(float4*)&red[0][c4 * 4];
    float4 c = *(float4*)&red[1][c4 * 4];
    const float invs = 1.0f / SEG_;
    float4 o;
    o.x = (a.x + c.x) * invs; o.y = (a.y + c.y) * invs;
    o.z = (a.z + c.z) * invs; o.w = (a.w + c.w) * invs;
    *(float4*)(xbar + (size_t)bl * C_ + c4 * 4) = o;
  }
}

// ---------------------------------------------------------------------------
// K2: C = A(rows x 512) @ W^T(512 x 512) + bias, optional scale.
// mode 0: f32 out[row][col] plain (row-major, ld=512)
// mode 1: f32 head-split out[((b*H + h)*rpb + n)*64 + d], h = col0/64
// mode 2: bf16 head-split (same layout as mode 1)
__global__ __launch_bounds__(256) void gemm_nt_kernel(const float* __restrict__ A,
                                                      const float* __restrict__ W,
                                                      const float* __restrict__ bias,
                                                      void* __restrict__ out,
                                                      float scale, int mode, int rpb) {
  __shared__ float As[32][68];
  __shared__ float Ws[32][68];
  int row0 = blockIdx.x * 64;
  int col0 = blockIdx.y * 64;
  int tid = threadIdx.x;
  int tm = tid >> 4, tn = tid & 15;
  float acc[4][4] = {};
  for (int k0 = 0; k0 < C_; k0 += 32) {
#pragma unroll
    for (int i = 0; i < 2; ++i) {
      int s = tid + i * 256;
      int r = s >> 3;               // 0..63
      int kg = (s & 7) << 2;        // 0..28
      float4 av = *(const float4*)(A + (size_t)(row0 + r) * C_ + k0 + kg);
      As[kg + 0][r] = av.x; As[kg + 1][r] = av.y;
      As[kg + 2][r] = av.z; As[kg + 3][r] = av.w;
      float4 wv = *(const float4*)(W + (size_t)(col0 + r) * C_ + k0 + kg);
      Ws[kg + 0][r] = wv.x; Ws[kg + 1][r] = wv.y;
      Ws[kg + 2][r] = wv.z; Ws[kg + 3][r] = wv.w;
    }
    __syncthreads();
#pragma unroll
    for (int kk = 0; kk < 32; ++kk) {
      float4 a = *(const float4*)&As[kk][tm * 4];
      float4 b = *(const float4*)&Ws[kk][tn * 4];
      float av[4] = {a.x, a.y, a.z, a.w};
      float bv[4] = {b.x, b.y, b.z, b.w};
#pragma unroll
      for (int i = 0; i < 4; ++i)
#pragma unroll
        for (int j = 0; j < 4; ++j) acc[i][j] += av[i] * bv[j];
    }
    __syncthreads();
  }
#pragma unroll
  for (int i = 0; i < 4; ++i) {
    int row = row0 + tm * 4 + i;
    int d0 = tn * 4;
    float o4[4];
#pragma unroll
    for (int j = 0; j < 4; ++j) o4[j] = (acc[i][j] + bias[col0 + d0 + j]) * scale;
    if (mode == 0) {
      float4 o; o.x = o4[0]; o.y = o4[1]; o.z = o4[2]; o.w = o4[3];
      *(float4*)((float*)out + (size_t)row * C_ + col0 + d0) = o;
    } else {
      int b = row / rpb, n = row % rpb;
      int h = col0 >> 6;
      size_t idx = (((size_t)(b * H_ + h) * rpb) + n) * HD_ + d0;
      if (mode == 1) {
        float4 o; o.x = o4[0]; o.y = o4[1]; o.z = o4[2]; o.w = o4[3];
        *(float4*)((float*)out + idx) = o;
      } else {
        ushort4_t u;
        u[0] = f2bf(o4[0]); u[1] = f2bf(o4[1]); u[2] = f2bf(o4[2]); u[3] = f2bf(o4[3]);
        *(ushort4_t*)((unsigned short*)out + idx) = u;
      }
    }
  }
}

// ---------------------------------------------------------------------------
// K4: ker2 = softmax(q_land @ k_land^T) per (b,h).  64 threads, thread = row.
__global__ __launch_bounds__(64) void ker2_kernel(const float* __restrict__ qland,
                                                  const float* __restrict__ kland,
                                                  float* __restrict__ ker2) {
  int bh = blockIdx.x;
  __shared__ float kl[64][68];
  __shared__ float ql[64][68];
  int t = threadIdx.x;
  for (int i = 0; i < 16; ++i) {
    int s = t + i * 64;               // 1024 float4 slots
    int r = s >> 4, d4 = (s & 15) << 2;
    *(float4*)&kl[r][d4] = *(const float4*)(kland + ((size_t)bh * 64 + r) * 64 + d4);
    *(float4*)&ql[r][d4] = *(const float4*)(qland + ((size_t)bh * 64 + r) * 64 + d4);
  }
  __syncthreads();
  float z[64];
  float se = 0.f;
  for (int j = 0; j < 64; ++j) {
    float acc = 0.f;
#pragma unroll
    for (int d4 = 0; d4 < 64; d4 += 4) {
      float4 qv = *(float4*)&ql[t][d4];
      float4 kv = *(float4*)&kl[j][d4];
      acc += qv.x * kv.x + qv.y * kv.y + qv.z * kv.z + qv.w * kv.w;
    }
    z[j] = expf(acc);
    se += z[j];
  }
  float inv = 1.0f / se;
  for (int j4 = 0; j4 < 64; j4 += 4) {
    float4 o = make_float4(z[j4] * inv, z[j4 + 1] * inv, z[j4 + 2] * inv, z[j4 + 3] * inv);
    *(float4*)(ker2 + ((size_t)bh * 64 + t) * 64 + j4) = o;
  }
}

// ---------------------------------------------------------------------------
// K5: fp64 one-sided Jacobi SVD of ker2 (64x64), jax-rcond-truncated pinv.
// One block (256 threads) per (b,h).
__global__ __launch_bounds__(256) void svd_pinv_kernel(const float* __restrict__ ker2,
                                                       double* __restrict__ pinv) {
  int bh = blockIdx.x;
  __shared__ double Ac[64][66];   // column-major: Ac[col][row]
  __shared__ double Vc[64][66];
  __shared__ double sig2[64];
  __shared__ double smax2s;
  int tid = threadIdx.x;
  for (int i = 0; i < 16; ++i) {
    int s = tid + i * 256;
    int r = s >> 6, c = s & 63;
    Ac[c][r] = (double)ker2[((size_t)bh * 64 + r) * 64 + c];
    Vc[c][r] = (r == c) ? 1.0 : 0.0;
  }
  __syncthreads();
  int g = tid >> 3, t = tid & 3 + 0; t = tid & 7;
  for (int sweep = 0; sweep < NSWEEP_; ++sweep) {
    for (int r = 0; r < 63; ++r) {
      int p, q;
      if (g == 0) { p = 63; q = r; }
      else { p = (r + g) % 63; q = (r - g + 63) % 63; }
      double pa = 0.0, pb = 0.0, pg = 0.0;
#pragma unroll
      for (int j = 0; j < 8; ++j) {
        double xv = Ac[p][t * 8 + j], yv = Ac[q][t * 8 + j];
        pa += xv * xv; pb += yv * yv; pg += xv * yv;
      }
#pragma unroll
      for (int m = 1; m < 8; m <<= 1) {
        pa += __shfl_xor(pa, m); pb += __shfl_xor(pb, m); pg += __shfl_xor(pg, m);
      }
      double cc = 1.0, ss = 0.0;
      if (fabs(pg) > 1e-300 && pa > 0.0 && pb > 0.0) {
        double tau = (pb - pa) / (2.0 * pg);
        double tt = copysign(1.0, tau) / (fabs(tau) + sqrt(1.0 + tau * tau));
        cc = 1.0 / sqrt(1.0 + tt * tt);
        ss = tt * cc;
      }
#pragma unroll
      for (int j = 0; j < 8; ++j) {
        int rr = t * 8 + j;
        double xv = Ac[p][rr], yv = Ac[q][rr];
        Ac[p][rr] = cc * xv - ss * yv;
        Ac[q][rr] = ss * xv + cc * yv;
        double x2 = Vc[p][rr], y2 = Vc[q][rr];
        Vc[p][rr] = cc * x2 - ss * y2;
        Vc[q][rr] = ss * x2 + cc * y2;
      }
      __syncthreads();
    }
  }
  // column squared norms
  {
    int c = tid >> 2, t4 = tid & 3;
    double s2 = 0.0;
    for (int j = 0; j < 16; ++j) { double v = Ac[c][t4 * 16 + j]; s2 += v * v; }
    s2 += __shfl_xor(s2, 1); s2 += __shfl_xor(s2, 2);
    if (t4 == 0) sig2[c] = s2;
  }
  __syncthreads();
  if (tid < 64) {
    double v = sig2[tid];
#pragma unroll
    for (int m = 1; m < 64; m <<= 1) v = fmax(v, __shfl_xor(v, m));
    if (tid == 0) smax2s = v;
  }
  __syncthreads();
  double cutoff2 = smax2s * (RCOND_ * RCOND_);
  int i = tid >> 2, t4 = tid & 3;
  double o[16] = {};
  for (int r = 0; r < 64; ++r) {
    double w = (sig2[r] > cutoff2) ? (1.0 / sig2[r]) : 0.0;
    double vi = Vc[r][i] * w;
#pragma unroll
    for (int j = 0; j < 16; ++j) o[j] += vi * Ac[r][t4 * 16 + j];
  }
  for (int j = 0; j < 16; ++j)
    pinv[((size_t)bh * 64 + i) * 64 + t4 * 16 + j] = o[j];
}

// ---------------------------------------------------------------------------
// K6: partial ker3-softmax-numerator and kv: per (b,h,chunk):
//   pacc[l][d] = sum_n exp(z[l][n]) * v[n][d],  ps[l] = sum_n exp(z[l][n]).
// Logits are tiny (|z| << 1) so no max subtraction needed. k/v are bf16.
__global__ __launch_bounds__(256) void ker3kv_partial_kernel(const float* __restrict__ qland,
                                                             const unsigned short* __restrict__ k4,
                                                             const unsigned short* __restrict__ v4,
                                                             float* __restrict__ pacc,
                                                             float* __restrict__ ps) {
  int bh = blockIdx.y, ch = blockIdx.x;
  __shared__ float ql[64][68];
  __shared__ float ks[64][68];
  __shared__ float vs[64][68];
  int tid = threadIdx.x;
  for (int i = 0; i < 4; ++i) {
    int s = tid + i * 256;
    int r = s >> 4, d4 = (s & 15) << 2;
    *(float4*)&ql[r][d4] = *(const float4*)(qland + ((size_t)bh * 64 + r) * 64 + d4);
  }
  int l = tid >> 2, t = tid & 3;
  float acc[64] = {};
  float ssum = 0.f;
  for (int sub = 0; sub < 16; ++sub) {
    int n0 = ch * CHLEN_ + sub * 64;
    __syncthreads();
#pragma unroll
    for (int i = 0; i < 2; ++i) {
      int s = tid + i * 256;          // 0..511
      int r = s >> 3;                 // 0..63
      int d8 = (s & 7) << 3;          // 0..56
      ushort8_t kb = *(const ushort8_t*)(k4 + ((size_t)bh * N_ + n0 + r) * 64 + d8);
      ushort8_t vb = *(const ushort8_t*)(v4 + ((size_t)bh * N_ + n0 + r) * 64 + d8);
#pragma unroll
      for (int j = 0; j < 8; ++j) {
        ks[r][d8 + j] = bf2f(kb[j]);
        vs[r][d8 + j] = bf2f(vb[j]);
      }
    }
    __syncthreads();
    for (int jj = 0; jj < 16; ++jj) {
      int n = (jj << 2) | t;
      float zz = 0.f;
#pragma unroll
      for (int d4 = 0; d4 < 64; d4 += 4) {
        float4 qv = *(float4*)&ql[l][d4];
        float4 kv = *(float4*)&ks[n][d4];
        zz += qv.x * kv.x + qv.y * kv.y + qv.z * kv.z + qv.w * kv.w;
      }
      float pe = expf(zz);
      ssum += pe;
#pragma unroll
      for (int d4 = 0; d4 < 64; d4 += 4) {
        float4 vv = *(float4*)&vs[n][d4];
        acc[d4 + 0] += pe * vv.x; acc[d4 + 1] += pe * vv.y;
        acc[d4 + 2] += pe * vv.z; acc[d4 + 3] += pe * vv.w;
      }
    }
  }
  ssum += __shfl_xor(ssum, 1); ssum += __shfl_xor(ssum, 2);
#pragma unroll
  for (int d = 0; d < 64; ++d) {
    acc[d] += __shfl_xor(acc[d], 1);
    acc[d] += __shfl_xor(acc[d], 2);
  }
  size_t base = (((size_t)bh * NCH_ + ch) * 64 + l) * 64;
  for (int i = 0; i < 4; ++i) {
    int d = t * 16 + i * 4;
    float4 o = make_float4(acc[d], acc[d + 1], acc[d + 2], acc[d + 3]);
    *(float4*)(pacc + base + d) = o;
  }
  if (t == 0) ps[((size_t)bh * NCH_ + ch) * 64 + l] = ssum;
}

// ---------------------------------------------------------------------------
// K7: combine chunk partials -> kv (B,H,64,64), normalized softmax rows.
__global__ __launch_bounds__(256) void kv_combine_kernel(const float* __restrict__ pacc,
                                                         const float* __restrict__ ps,
                                                         float* __restrict__ kv) {
  int bh = blockIdx.x;
  int tid = threadIdx.x;
  int l = tid >> 2, t = tid & 3;
  float s = 0.f;
  for (int ch = 0; ch < NCH_; ++ch) s += ps[((size_t)bh * NCH_ + ch) * 64 + l];
  float inv = 1.f / s;
  float a[16] = {};
  for (int ch = 0; ch < NCH_; ++ch) {
    size_t base = (((size_t)bh * NCH_ + ch) * 64 + l) * 64 + t * 16;
    for (int i4 = 0; i4 < 16; i4 += 4) {
      float4 v = *(const float4*)(pacc + base + i4);
      a[i4 + 0] += v.x; a[i4 + 1] += v.y; a[i4 + 2] += v.z; a[i4 + 3] += v.w;
    }
  }
  size_t ob = ((size_t)bh * 64 + l) * 64 + t * 16;
  for (int i4 = 0; i4 < 16; i4 += 4) {
    float4 o = make_float4(a[i4] * inv, a[i4 + 1] * inv, a[i4 + 2] * inv, a[i4 + 3] * inv);
    *(float4*)(kv + ob + i4) = o;
  }
}

// ---------------------------------------------------------------------------
// K8: Mmat = pinv @ kv  (fp64 accumulate, f32 out).
__global__ __launch_bounds__(256) void mmat_kernel(const double* __restrict__ pinv,
                                                   const float* __restrict__ kv,
                                                   float* __restrict__ Mmat) {
  int bh = blockIdx.x;
  int tid = threadIdx.x;
  __shared__ float kvs[64][68];
  for (int i = 0; i < 4; ++i) {
    int s = tid + i * 256;
    int r = s >> 4, d4 = (s & 15) << 2;
    *(float4*)&kvs[r][d4] = *(const float4*)(kv + ((size_t)bh * 64 + r) * 64 + d4);
  }
  __syncthreads();
  int l = tid >> 2, t = tid & 3;
  double o[16] = {};
  for (int j = 0; j < 64; ++j) {
    double pv = pinv[((size_t)bh * 64 + l) * 64 + j];
#pragma unroll
    for (int i = 0; i < 16; ++i) o[i] += pv * (double)kvs[j][t * 16 + i];
  }
  size_t ob = ((size_t)bh * 64 + l) * 64 + t * 16;
  for (int i = 0; i < 16; ++i) Mmat[ob + i] = (float)o[i];
}

// ---------------------------------------------------------------------------
// K9: out_heads = softmax(q @ k_land^T) @ Mmat, written to (B,N,C) layout.
// 64 tokens per block; team of 4 threads per token. q is bf16.
__global__ __launch_bounds__(256) void ker1out_kernel(const unsigned short* __restrict__ q4,
                                                      const float* __restrict__ kland,
                                                      const float* __restrict__ Mmat,
                                                      float* __restrict__ outh) {
  int bh = blockIdx.y;
  int tile = blockIdx.x;
  int b = bh >> 3, h = bh & 7;
  __shared__ float kl[64][68];
  __shared__ float Ms[64][68];
  __shared__ float qs[64][68];
  int tid = threadIdx.x;
  int n0 = tile * 64;
  for (int i = 0; i < 4; ++i) {
    int s = tid + i * 256;
    int r = s >> 4, d4 = (s & 15) << 2;
    *(float4*)&kl[r][d4] = *(const float4*)(kland + ((size_t)bh * 64 + r) * 64 + d4);
    *(float4*)&Ms[r][d4] = *(const float4*)(Mmat + ((size_t)bh * 64 + r) * 64 + d4);
  }
#pragma unroll
  for (int i = 0; i < 2; ++i) {
    int s = tid + i * 256;
    int r = s >> 3, d8 = (s & 7) << 3;
    ushort8_t qb = *(const ushort8_t*)(q4 + ((size_t)bh * N_ + n0 + r) * 64 + d8);
#pragma unroll
    for (int j = 0; j < 8; ++j) qs[r][d8 + j] = bf2f(qb[j]);
  }
  __syncthreads();
  int tok = tid >> 2, t = tid & 3;
  float pj[16];
  float psum = 0.f;
#pragma unroll
  for (int jj = 0; jj < 16; ++jj) {
    int j = (jj << 2) | t;     // interleaved to avoid LDS bank conflicts
    float zz = 0.f;
#pragma unroll
    for (int d4 = 0; d4 < 64; d4 += 4) {
      float4 qv = *(float4*)&qs[tok][d4];
      float4 kv = *(float4*)&kl[j][d4];
      zz += qv.x * kv.x + qv.y * kv.y + qv.z * kv.z + qv.w * kv.w;
    }
    pj[jj] = expf(zz);
    psum += pj[jj];
  }
  psum += __shfl_xor(psum, 1); psum += __shfl_xor(psum, 2);
  float oacc[64] = {};
#pragma unroll
  for (int jj = 0; jj < 16; ++jj) {
    int j = (jj << 2) | t;
    float pe = pj[jj];
#pragma unroll
    for (int d4 = 0; d4 < 64; d4 += 4) {
      float4 mv = *(float4*)&Ms[j][d4];
      oacc[d4 + 0] += pe * mv.x; oacc[d4 + 1] += pe * mv.y;
      oacc[d4 + 2] += pe * mv.z; oacc[d4 + 3] += pe * mv.w;
    }
  }
#pragma unroll
  for (int d = 0; d < 64; ++d) {
    oacc[d] += __shfl_xor(oacc[d], 1);
    oacc[d] += __shfl_xor(oacc[d], 2);
  }
  float inv = 1.f / psum;
  size_t obase = ((size_t)b * N_ + n0 + tok) * C_ + h * HD_ + t * 16;
  for (int i4 = 0; i4 < 16; i4 += 4) {
    int d = t * 16 + i4;
    float4 o = make_float4(oacc[d] * inv, oacc[d + 1] * inv, oacc[d + 2] * inv, oacc[d + 3] * inv);
    *(float4*)(outh + obase + i4) = o;
  }
}

// ---------------------------------------------------------------------------
extern "C" void kernel_launch(void* const* d_in, const int* in_sizes, int n_in,
                              void* d_out, int out_size, void* d_ws, size_t ws_size,
                              hipStream_t stream) {
  const float* x  = (const float*)d_in[0];
  const float* wq = (const float*)d_in[1];
  const float* bq = (const float*)d_in[2];
  const float* wk = (const float*)d_in[3];
  const float* bk = (const float*)d_in[4];
  const float* wv = (const float*)d_in[5];
  const float* bv = (const float*)d_in[6];
  const float* wo = (const float*)d_in[7];
  const float* bo = (const float*)d_in[8];
  float* out = (float*)d_out;

  // --- workspace layout (bytes), total ~107 MB ---
  // q4 bf16:  33,554,432
  // k4 bf16:  33,554,432  \ aliased by outh f32 (67,108,864) after ker3kv
  // v4 bf16:  33,554,432  /
  // small f32 region + pinv f64
  char* base = (char*)d_ws;
  const size_t QKV_ELEMS = (size_t)BH_ * N_ * HD_;      // 16,777,216
  unsigned short* q4 = (unsigned short*)base;
  unsigned short* k4 = (unsigned short*)(base + QKV_ELEMS * 2);
  unsigned short* v4 = (unsigned short*)(base + QKV_ELEMS * 4);
  float* outh = (float*)(base + QKV_ELEMS * 2);          // alias k4+v4
  float* p = (float*)(base + QKV_ELEMS * 6);
  float* xbar  = p; p += (size_t)B_ * LM_ * C_;    // 65536
  float* qland = p; p += (size_t)BH_ * LM_ * HD_;  // 65536
  float* kland = p; p += (size_t)BH_ * LM_ * HD_;
  float* ker2  = p; p += (size_t)BH_ * LM_ * LM_;
  float* kvb   = p; p += (size_t)BH_ * LM_ * HD_;
  float* Mmat  = p; p += (size_t)BH_ * LM_ * HD_;
  float* pacc  = p; p += (size_t)BH_ * NCH_ * LM_ * HD_;  // 1,048,576
  float* ps    = p; p += (size_t)BH_ * NCH_ * LM_;        // 16,384
  double* pinv = (double*)p;                              // 8B-aligned

  const float scaleq = 0.125f;  // hd^-0.5

  // landmark path (exact f32, decoupled from big GEMMs)
  seg_mean_kernel<<<B_ * LM_, 256, 0, stream>>>(x, xbar);
  dim3 gl(2, 8);
  gemm_nt_kernel<<<gl, 256, 0, stream>>>(xbar, wq, bq, qland, scaleq, 1, LM_);
  gemm_nt_kernel<<<gl, 256, 0, stream>>>(xbar, wk, bk, kland, 1.0f, 1, LM_);
  ker2_kernel<<<BH_, 64, 0, stream>>>(qland, kland, ker2);
  svd_pinv_kernel<<<BH_, 256, 0, stream>>>(ker2, pinv);

  // projections -> bf16 head-split
  dim3 gp(B_ * N_ / 64, 8);
  gemm_nt_kernel<<<gp, 256, 0, stream>>>(x, wq, bq, q4, scaleq, 2, N_);
  gemm_nt_kernel<<<gp, 256, 0, stream>>>(x, wk, bk, k4, 1.0f, 2, N_);
  gemm_nt_kernel<<<gp, 256, 0, stream>>>(x, wv, bv, v4, 1.0f, 2, N_);

  // ker3 softmax + kv
  dim3 g6(NCH_, BH_);
  ker3kv_partial_kernel<<<g6, 256, 0, stream>>>(qland, k4, v4, pacc, ps);
  kv_combine_kernel<<<BH_, 256, 0, stream>>>(pacc, ps, kvb);

  // M = pinv @ kv
  mmat_kernel<<<BH_, 256, 0, stream>>>(pinv, kvb, Mmat);

  // out_heads = softmax(q k_land^T) @ M  (writes outh, which aliases dead k4/v4)
  dim3 g9(N_ / 64, BH_);
  ker1out_kernel<<<g9, 256, 0, stream>>>(q4, kland, Mmat, outh);

  // final projection
  dim3 g10(B_ * N_ / 64, C_ / 64);
  gemm_nt_kernel<<<g10, 256, 0, stream>>>(outh, wo, bo, out, 1.0f, 0, 1);
}

// Round 3
// 2778.747 us; speedup vs baseline: 1.2552x; 1.2552x over previous
//
#include <hip/hip_runtime.h>
#include <stdint.h>

// NystromAttention MI355X — Round 3:
//  - register-resident single-wave f32 Jacobi SVD (was 1059us, 4-wave fp64 LDS)
//  - bf16 MFMA (16x16x32) for the four 32768x512x512 projections
// Landmark/pinv path stays f32/f64-exact.

constexpr int B_   = 2;
constexpr int N_   = 16384;
constexpr int C_   = 512;
constexpr int H_   = 8;
constexpr int HD_  = 64;
constexpr int LM_  = 64;
constexpr int SEG_ = 256;
constexpr int BH_  = 16;
constexpr int NCH_ = 8;      // chunks for ker3/kv partials
constexpr int CHLEN_ = 2048; // tokens per chunk
constexpr int NSWEEP_ = 8;   // Jacobi sweeps

// jax pinv default rcond: 10 * max(M,N) * eps(f32) = 640 * 2^-23
#define RCOND_ (640.0 * 1.1920928955078125e-07)

typedef unsigned short ushort4_t __attribute__((ext_vector_type(4)));
typedef unsigned short ushort8_t __attribute__((ext_vector_type(8)));
typedef __bf16 bf16x8 __attribute__((ext_vector_type(8)));
typedef float f32x4 __attribute__((ext_vector_type(4)));

__device__ inline float bf2f(unsigned short u) {
  union { unsigned int i; float f; } x; x.i = ((unsigned int)u) << 16; return x.f;
}
__device__ inline unsigned short f2bf(float f) {
  union { float f; unsigned int i; } x; x.f = f;
  unsigned int lsb = (x.i >> 16) & 1;
  return (unsigned short)((x.i + 0x7fffu + lsb) >> 16);
}

// ---------------------------------------------------------------------------
// f32 -> bf16 elementwise convert (for weight matrices)
__global__ __launch_bounds__(256) void cvt_bf16_kernel(const float* __restrict__ src,
                                                       unsigned short* __restrict__ dst,
                                                       int n8) {
  int i = (blockIdx.x * 256 + threadIdx.x);
  if (i >= n8) return;
  const float* s = src + (size_t)i * 8;
  float4 x0 = *(const float4*)(s);
  float4 x1 = *(const float4*)(s + 4);
  ushort8_t u;
  u[0] = f2bf(x0.x); u[1] = f2bf(x0.y); u[2] = f2bf(x0.z); u[3] = f2bf(x0.w);
  u[4] = f2bf(x1.x); u[5] = f2bf(x1.y); u[6] = f2bf(x1.z); u[7] = f2bf(x1.w);
  *(ushort8_t*)(dst + (size_t)i * 8) = u;
}

// ---------------------------------------------------------------------------
// K1: segment means of x -> xbar (B, LM, C).
__global__ __launch_bounds__(256) void seg_mean_kernel(const float* __restrict__ x,
                                                       float* __restrict__ xbar) {
  int bl = blockIdx.x;
  int b = bl / LM_, l = bl % LM_;
  int t = threadIdx.x;
  int c4 = t & 127;
  int rh = t >> 7;
  const float* xp = x + ((size_t)b * N_ + (size_t)l * SEG_) * C_;
  float4 s = make_float4(0.f, 0.f, 0.f, 0.f);
  for (int r = rh * 128; r < rh * 128 + 128; ++r) {
    float4 v = *(const float4*)(xp + (size_t)r * C_ + c4 * 4);
    s.x += v.x; s.y += v.y; s.z += v.z; s.w += v.w;
  }
  __shared__ float red[2][512];
  *(float4*)&red[rh][c4 * 4] = s;
  __syncthreads();
  if (rh == 0) {
    float4 a = *(float4*)&red[0][c4 * 4];
    float4 c = *(float4*)&red[1][c4 * 4];
    const float invs = 1.0f / SEG_;
    float4 o;
    o.x = (a.x + c.x) * invs; o.y = (a.y + c.y) * invs;
    o.z = (a.z + c.z) * invs; o.w = (a.w + c.w) * invs;
    *(float4*)(xbar + (size_t)bl * C_ + c4 * 4) = o;
  }
}

// ---------------------------------------------------------------------------
// f32 VALU GEMM (landmark projections only; 128 rows). mode 1: f32 head-split.
__global__ __launch_bounds__(256) void gemm_nt_kernel(const float* __restrict__ A,
                                                      const float* __restrict__ W,
                                                      const float* __restrict__ bias,
                                                      float* __restrict__ out,
                                                      float scale, int rpb) {
  __shared__ float As[32][68];
  __shared__ float Ws[32][68];
  int row0 = blockIdx.x * 64;
  int col0 = blockIdx.y * 64;
  int tid = threadIdx.x;
  int tm = tid >> 4, tn = tid & 15;
  float acc[4][4] = {};
  for (int k0 = 0; k0 < C_; k0 += 32) {
#pragma unroll
    for (int i = 0; i < 2; ++i) {
      int s = tid + i * 256;
      int r = s >> 3;
      int kg = (s & 7) << 2;
      float4 av = *(const float4*)(A + (size_t)(row0 + r) * C_ + k0 + kg);
      As[kg + 0][r] = av.x; As[kg + 1][r] = av.y;
      As[kg + 2][r] = av.z; As[kg + 3][r] = av.w;
      float4 wv = *(const float4*)(W + (size_t)(col0 + r) * C_ + k0 + kg);
      Ws[kg + 0][r] = wv.x; Ws[kg + 1][r] = wv.y;
      Ws[kg + 2][r] = wv.z; Ws[kg + 3][r] = wv.w;
    }
    __syncthreads();
#pragma unroll
    for (int kk = 0; kk < 32; ++kk) {
      float4 a = *(const float4*)&As[kk][tm * 4];
      float4 b = *(const float4*)&Ws[kk][tn * 4];
      float av[4] = {a.x, a.y, a.z, a.w};
      float bv[4] = {b.x, b.y, b.z, b.w};
#pragma unroll
      for (int i = 0; i < 4; ++i)
#pragma unroll
        for (int j = 0; j < 4; ++j) acc[i][j] += av[i] * bv[j];
    }
    __syncthreads();
  }
#pragma unroll
  for (int i = 0; i < 4; ++i) {
    int row = row0 + tm * 4 + i;
    int d0 = tn * 4;
    float o4[4];
#pragma unroll
    for (int j = 0; j < 4; ++j) o4[j] = (acc[i][j] + bias[col0 + d0 + j]) * scale;
    int b = row / rpb, n = row % rpb;
    int h = col0 >> 6;
    size_t idx = (((size_t)(b * H_ + h) * rpb) + n) * HD_ + d0;
    float4 o; o.x = o4[0]; o.y = o4[1]; o.z = o4[2]; o.w = o4[3];
    *(float4*)(out + idx) = o;
  }
}

// ---------------------------------------------------------------------------
// MFMA GEMM: out = A(f32, Mx512) @ Wb^T(bf16 512x512) + bias, scale.
// 128x128 tile, BK=32, 4 waves, 4x4 frags of mfma_f32_16x16x32_bf16.
// mode 0: f32 out[row][col]; mode 1: bf16 head-split out.
__global__ __launch_bounds__(256) void mfma_gemm_kernel(const float* __restrict__ A,
                                                        const unsigned short* __restrict__ Wb,
                                                        const float* __restrict__ bias,
                                                        void* __restrict__ out,
                                                        float scale, int mode) {
  __shared__ unsigned short Xs[128 * 32];
  __shared__ unsigned short Ws[128 * 32];
  int tid = threadIdx.x;
  int wid = tid >> 6, lane = tid & 63;
  int wr = wid >> 1, wc = wid & 1;
  int row0 = blockIdx.x * 128, col0 = blockIdx.y * 128;
  f32x4 acc[4][4] = {};

  int srow = tid >> 1;               // 0..127
  int sk = (tid & 1) * 16;           // 0 or 16
  const float* apbase = A + (size_t)(row0 + srow) * C_ + sk;
  const unsigned short* wpbase = Wb + (size_t)(col0 + srow) * C_ + sk;
  unsigned short* xdst = &Xs[srow * 32 + sk];
  unsigned short* wdst = &Ws[srow * 32 + sk];

  for (int k0 = 0; k0 < C_; k0 += 32) {
    __syncthreads();
    // A stage: f32 load + convert + ds_write
    float4 x0 = *(const float4*)(apbase + k0);
    float4 x1 = *(const float4*)(apbase + k0 + 4);
    float4 x2 = *(const float4*)(apbase + k0 + 8);
    float4 x3 = *(const float4*)(apbase + k0 + 12);
    ushort8_t u0, u1;
    u0[0] = f2bf(x0.x); u0[1] = f2bf(x0.y); u0[2] = f2bf(x0.z); u0[3] = f2bf(x0.w);
    u0[4] = f2bf(x1.x); u0[5] = f2bf(x1.y); u0[6] = f2bf(x1.z); u0[7] = f2bf(x1.w);
    u1[0] = f2bf(x2.x); u1[1] = f2bf(x2.y); u1[2] = f2bf(x2.z); u1[3] = f2bf(x2.w);
    u1[4] = f2bf(x3.x); u1[5] = f2bf(x3.y); u1[6] = f2bf(x3.z); u1[7] = f2bf(x3.w);
    *(ushort8_t*)(xdst) = u0;
    *(ushort8_t*)(xdst + 8) = u1;
    // W stage: bf16 load + ds_write
    ushort8_t w0 = *(const ushort8_t*)(wpbase + k0);
    ushort8_t w1 = *(const ushort8_t*)(wpbase + k0 + 8);
    *(ushort8_t*)(wdst) = w0;
    *(ushort8_t*)(wdst + 8) = w1;
    __syncthreads();
    // fragments + MFMA
    bf16x8 af[4], bfr[4];
#pragma unroll
    for (int m = 0; m < 4; ++m)
      af[m] = *(bf16x8*)&Xs[(wr * 64 + m * 16 + (lane & 15)) * 32 + (lane >> 4) * 8];
#pragma unroll
    for (int n = 0; n < 4; ++n)
      bfr[n] = *(bf16x8*)&Ws[(wc * 64 + n * 16 + (lane & 15)) * 32 + (lane >> 4) * 8];
#pragma unroll
    for (int m = 0; m < 4; ++m)
#pragma unroll
      for (int n = 0; n < 4; ++n)
        acc[m][n] = __builtin_amdgcn_mfma_f32_16x16x32_bf16(af[m], bfr[n], acc[m][n], 0, 0, 0);
  }

  // epilogue: C/D layout col=lane&15, row=(lane>>4)*4+reg
#pragma unroll
  for (int m = 0; m < 4; ++m) {
    int rbase = row0 + wr * 64 + m * 16 + (lane >> 4) * 4;
#pragma unroll
    for (int n = 0; n < 4; ++n) {
      int c = col0 + wc * 64 + n * 16 + (lane & 15);
      float bc = bias[c];
#pragma unroll
      for (int rg = 0; rg < 4; ++rg) {
        float val = (acc[m][n][rg] + bc) * scale;
        int r = rbase + rg;
        if (mode == 0) {
          ((float*)out)[(size_t)r * C_ + c] = val;
        } else {
          int b = r >> 14, nn = r & 16383, h = c >> 6, d = c & 63;
          ((unsigned short*)out)[(((size_t)(b * H_ + h) * N_) + nn) * HD_ + d] = f2bf(val);
        }
      }
    }
  }
}

// ---------------------------------------------------------------------------
// ker2 = softmax(q_land @ k_land^T) per (b,h).
__global__ __launch_bounds__(64) void ker2_kernel(const float* __restrict__ qland,
                                                  const float* __restrict__ kland,
                                                  float* __restrict__ ker2) {
  int bh = blockIdx.x;
  __shared__ float kl[64][68];
  __shared__ float ql[64][68];
  int t = threadIdx.x;
  for (int i = 0; i < 16; ++i) {
    int s = t + i * 64;
    int r = s >> 4, d4 = (s & 15) << 2;
    *(float4*)&kl[r][d4] = *(const float4*)(kland + ((size_t)bh * 64 + r) * 64 + d4);
    *(float4*)&ql[r][d4] = *(const float4*)(qland + ((size_t)bh * 64 + r) * 64 + d4);
  }
  __syncthreads();
  float z[64];
  float se = 0.f;
  for (int j = 0; j < 64; ++j) {
    float acc = 0.f;
#pragma unroll
    for (int d4 = 0; d4 < 64; d4 += 4) {
      float4 qv = *(float4*)&ql[t][d4];
      float4 kv = *(float4*)&kl[j][d4];
      acc += qv.x * kv.x + qv.y * kv.y + qv.z * kv.z + qv.w * kv.w;
    }
    z[j] = expf(acc);
    se += z[j];
  }
  float inv = 1.0f / se;
  for (int j4 = 0; j4 < 64; j4 += 4) {
    float4 o = make_float4(z[j4] * inv, z[j4 + 1] * inv, z[j4 + 2] * inv, z[j4 + 3] * inv);
    *(float4*)(ker2 + ((size_t)bh * 64 + t) * 64 + j4) = o;
  }
}

// ---------------------------------------------------------------------------
// Register-resident single-wave one-sided Jacobi SVD + rcond-truncated pinv.
// 64 threads; lane = column. XOR-mask pair schedule; no barriers in sweeps.
__global__ __launch_bounds__(64) void svd_pinv_kernel(const float* __restrict__ ker2,
                                                      float* __restrict__ pinv) {
  int bh = blockIdx.x;
  int lane = threadIdx.x;
  float a[64], v[64];
#pragma unroll
  for (int r = 0; r < 64; ++r) a[r] = ker2[((size_t)bh * 64 + r) * 64 + lane];
#pragma unroll
  for (int r = 0; r < 64; ++r) v[r] = (r == lane) ? 1.f : 0.f;

  for (int sweep = 0; sweep < NSWEEP_; ++sweep) {
    for (int mask = 1; mask < 64; ++mask) {
      int partner = lane ^ mask;
      bool lower = lane < partner;
      float o[64];
#pragma unroll
      for (int r = 0; r < 64; ++r) o[r] = __shfl_xor(a[r], mask);
      float alpha = 0.f, beta = 0.f, gamma = 0.f;
#pragma unroll
      for (int r = 0; r < 64; ++r) {
        alpha = fmaf(a[r], a[r], alpha);
        beta  = fmaf(o[r], o[r], beta);
        gamma = fmaf(a[r], o[r], gamma);
      }
      bool need = (gamma * gamma > 1e-14f * alpha * beta);
      if (__any(need)) {
        float ap = lower ? alpha : beta;   // norm^2 of lower-index column
        float aq = lower ? beta : alpha;
        float c = 1.f, s = 0.f;
        if (need) {
          float tau = (aq - ap) / (2.f * gamma);
          float t = copysignf(1.f, tau) / (fabsf(tau) + sqrtf(fmaf(tau, tau, 1.f)));
          c = rsqrtf(fmaf(t, t, 1.f));
          s = t * c;
        }
        float sm = lower ? -s : s;
#pragma unroll
        for (int r = 0; r < 64; ++r) a[r] = fmaf(sm, o[r], c * a[r]);
#pragma unroll
        for (int r = 0; r < 64; ++r) o[r] = __shfl_xor(v[r], mask);
#pragma unroll
        for (int r = 0; r < 64; ++r) v[r] = fmaf(sm, o[r], c * v[r]);
      }
    }
  }

  // sigma^2 (fp64 accumulate), max, truncation weight
  double sig2 = 0.0;
#pragma unroll
  for (int r = 0; r < 64; ++r) sig2 += (double)a[r] * (double)a[r];
  double smax = sig2;
#pragma unroll
  for (int m = 1; m < 64; m <<= 1) smax = fmax(smax, __shfl_xor(smax, m));
  double cutoff2 = smax * (RCOND_ * RCOND_);
  float w = (sig2 > cutoff2) ? (float)(1.0 / sig2) : 0.f;

  // pinv[i][j] = sum_r V[i][r] * w_r * B[j][r]
  __shared__ float was[64][65];
  __shared__ float vs[64][65];
#pragma unroll
  for (int j = 0; j < 64; ++j) was[lane][j] = w * a[j];
#pragma unroll
  for (int j = 0; j < 64; ++j) vs[lane][j] = v[j];
  __syncthreads();
  float accp[64] = {};
  for (int r = 0; r < 64; ++r) {
    float vv = vs[r][lane];
#pragma unroll
    for (int j = 0; j < 64; ++j) accp[j] = fmaf(vv, was[r][j], accp[j]);
  }
#pragma unroll
  for (int j = 0; j < 64; j += 4) {
    float4 ov = make_float4(accp[j], accp[j + 1], accp[j + 2], accp[j + 3]);
    *(float4*)(pinv + ((size_t)bh * 64 + lane) * 64 + j) = ov;
  }
}

// ---------------------------------------------------------------------------
// ker3 softmax-numerator partials + kv. k/v bf16. NCH_=8 chunks of 2048.
__global__ __launch_bounds__(256) void ker3kv_partial_kernel(const float* __restrict__ qland,
                                                             const unsigned short* __restrict__ k4,
                                                             const unsigned short* __restrict__ v4,
                                                             float* __restrict__ pacc,
                                                             float* __restrict__ ps) {
  int bh = blockIdx.y, ch = blockIdx.x;
  __shared__ float ql[64][68];
  __shared__ float ks[64][68];
  __shared__ float vs[64][68];
  int tid = threadIdx.x;
  for (int i = 0; i < 4; ++i) {
    int s = tid + i * 256;
    int r = s >> 4, d4 = (s & 15) << 2;
    *(float4*)&ql[r][d4] = *(const float4*)(qland + ((size_t)bh * 64 + r) * 64 + d4);
  }
  int l = tid >> 2, t = tid & 3;
  float acc[64] = {};
  float ssum = 0.f;
  for (int sub = 0; sub < CHLEN_ / 64; ++sub) {
    int n0 = ch * CHLEN_ + sub * 64;
    __syncthreads();
#pragma unroll
    for (int i = 0; i < 2; ++i) {
      int s = tid + i * 256;
      int r = s >> 3;
      int d8 = (s & 7) << 3;
      ushort8_t kb = *(const ushort8_t*)(k4 + ((size_t)bh * N_ + n0 + r) * 64 + d8);
      ushort8_t vb = *(const ushort8_t*)(v4 + ((size_t)bh * N_ + n0 + r) * 64 + d8);
#pragma unroll
      for (int j = 0; j < 8; ++j) {
        ks[r][d8 + j] = bf2f(kb[j]);
        vs[r][d8 + j] = bf2f(vb[j]);
      }
    }
    __syncthreads();
    for (int jj = 0; jj < 16; ++jj) {
      int n = (jj << 2) | t;
      float zz = 0.f;
#pragma unroll
      for (int d4 = 0; d4 < 64; d4 += 4) {
        float4 qv = *(float4*)&ql[l][d4];
        float4 kv = *(float4*)&ks[n][d4];
        zz += qv.x * kv.x + qv.y * kv.y + qv.z * kv.z + qv.w * kv.w;
      }
      float pe = expf(zz);
      ssum += pe;
#pragma unroll
      for (int d4 = 0; d4 < 64; d4 += 4) {
        float4 vv = *(float4*)&vs[n][d4];
        acc[d4 + 0] += pe * vv.x; acc[d4 + 1] += pe * vv.y;
        acc[d4 + 2] += pe * vv.z; acc[d4 + 3] += pe * vv.w;
      }
    }
  }
  ssum += __shfl_xor(ssum, 1); ssum += __shfl_xor(ssum, 2);
#pragma unroll
  for (int d = 0; d < 64; ++d) {
    acc[d] += __shfl_xor(acc[d], 1);
    acc[d] += __shfl_xor(acc[d], 2);
  }
  size_t base = (((size_t)bh * NCH_ + ch) * 64 + l) * 64;
  for (int i = 0; i < 4; ++i) {
    int d = t * 16 + i * 4;
    float4 o = make_float4(acc[d], acc[d + 1], acc[d + 2], acc[d + 3]);
    *(float4*)(pacc + base + d) = o;
  }
  if (t == 0) ps[((size_t)bh * NCH_ + ch) * 64 + l] = ssum;
}

// ---------------------------------------------------------------------------
__global__ __launch_bounds__(256) void kv_combine_kernel(const float* __restrict__ pacc,
                                                         const float* __restrict__ ps,
                                                         float* __restrict__ kv) {
  int bh = blockIdx.x;
  int tid = threadIdx.x;
  int l = tid >> 2, t = tid & 3;
  float s = 0.f;
  for (int ch = 0; ch < NCH_; ++ch) s += ps[((size_t)bh * NCH_ + ch) * 64 + l];
  float inv = 1.f / s;
  float a[16] = {};
  for (int ch = 0; ch < NCH_; ++ch) {
    size_t base = (((size_t)bh * NCH_ + ch) * 64 + l) * 64 + t * 16;
    for (int i4 = 0; i4 < 16; i4 += 4) {
      float4 v = *(const float4*)(pacc + base + i4);
      a[i4 + 0] += v.x; a[i4 + 1] += v.y; a[i4 + 2] += v.z; a[i4 + 3] += v.w;
    }
  }
  size_t ob = ((size_t)bh * 64 + l) * 64 + t * 16;
  for (int i4 = 0; i4 < 16; i4 += 4) {
    float4 o = make_float4(a[i4] * inv, a[i4 + 1] * inv, a[i4 + 2] * inv, a[i4 + 3] * inv);
    *(float4*)(kv + ob + i4) = o;
  }
}

// ---------------------------------------------------------------------------
// Mmat = pinv(f32) @ kv (fp64 accumulate).
__global__ __launch_bounds__(256) void mmat_kernel(const float* __restrict__ pinv,
                                                   const float* __restrict__ kv,
                                                   float* __restrict__ Mmat) {
  int bh = blockIdx.x;
  int tid = threadIdx.x;
  __shared__ float kvs[64][68];
  for (int i = 0; i < 4; ++i) {
    int s = tid + i * 256;
    int r = s >> 4, d4 = (s & 15) << 2;
    *(float4*)&kvs[r][d4] = *(const float4*)(kv + ((size_t)bh * 64 + r) * 64 + d4);
  }
  __syncthreads();
  int l = tid >> 2, t = tid & 3;
  double o[16] = {};
  for (int j = 0; j < 64; ++j) {
    double pv = (double)pinv[((size_t)bh * 64 + l) * 64 + j];
#pragma unroll
    for (int i = 0; i < 16; ++i) o[i] += pv * (double)kvs[j][t * 16 + i];
  }
  size_t ob = ((size_t)bh * 64 + l) * 64 + t * 16;
  for (int i = 0; i < 16; ++i) Mmat[ob + i] = (float)o[i];
}

// ---------------------------------------------------------------------------
// out_heads = softmax(q @ k_land^T) @ Mmat -> (B,N,C) f32. q bf16.
__global__ __launch_bounds__(256) void ker1out_kernel(const unsigned short* __restrict__ q4,
                                                      const float* __restrict__ kland,
                                                      const float* __restrict__ Mmat,
                                                      float* __restrict__ outh) {
  int bh = blockIdx.y;
  int tile = blockIdx.x;
  int b = bh >> 3, h = bh & 7;
  __shared__ float kl[64][68];
  __shared__ float Ms[64][68];
  __shared__ float qs[64][68];
  int tid = threadIdx.x;
  int n0 = tile * 64;
  for (int i = 0; i < 4; ++i) {
    int s = tid + i * 256;
    int r = s >> 4, d4 = (s & 15) << 2;
    *(float4*)&kl[r][d4] = *(const float4*)(kland + ((size_t)bh * 64 + r) * 64 + d4);
    *(float4*)&Ms[r][d4] = *(const float4*)(Mmat + ((size_t)bh * 64 + r) * 64 + d4);
  }
#pragma unroll
  for (int i = 0; i < 2; ++i) {
    int s = tid + i * 256;
    int r = s >> 3, d8 = (s & 7) << 3;
    ushort8_t qb = *(const ushort8_t*)(q4 + ((size_t)bh * N_ + n0 + r) * 64 + d8);
#pragma unroll
    for (int j = 0; j < 8; ++j) qs[r][d8 + j] = bf2f(qb[j]);
  }
  __syncthreads();
  int tok = tid >> 2, t = tid & 3;
  float pj[16];
  float psum = 0.f;
#pragma unroll
  for (int jj = 0; jj < 16; ++jj) {
    int j = (jj << 2) | t;
    float zz = 0.f;
#pragma unroll
    for (int d4 = 0; d4 < 64; d4 += 4) {
      float4 qv = *(float4*)&qs[tok][d4];
      float4 kv = *(float4*)&kl[j][d4];
      zz += qv.x * kv.x + qv.y * kv.y + qv.z * kv.z + qv.w * kv.w;
    }
    pj[jj] = expf(zz);
    psum += pj[jj];
  }
  psum += __shfl_xor(psum, 1); psum += __shfl_xor(psum, 2);
  float oacc[64] = {};
#pragma unroll
  for (int jj = 0; jj < 16; ++jj) {
    int j = (jj << 2) | t;
    float pe = pj[jj];
#pragma unroll
    for (int d4 = 0; d4 < 64; d4 += 4) {
      float4 mv = *(float4*)&Ms[j][d4];
      oacc[d4 + 0] += pe * mv.x; oacc[d4 + 1] += pe * mv.y;
      oacc[d4 + 2] += pe * mv.z; oacc[d4 + 3] += pe * mv.w;
    }
  }
#pragma unroll
  for (int d = 0; d < 64; ++d) {
    oacc[d] += __shfl_xor(oacc[d], 1);
    oacc[d] += __shfl_xor(oacc[d], 2);
  }
  float inv = 1.f / psum;
  size_t obase = ((size_t)b * N_ + n0 + tok) * C_ + h * HD_ + t * 16;
  for (int i4 = 0; i4 < 16; i4 += 4) {
    int d = t * 16 + i4;
    float4 o = make_float4(oacc[d] * inv, oacc[d + 1] * inv, oacc[d + 2] * inv, oacc[d + 3] * inv);
    *(float4*)(outh + obase + i4) = o;
  }
}

// ---------------------------------------------------------------------------
extern "C" void kernel_launch(void* const* d_in, const int* in_sizes, int n_in,
                              void* d_out, int out_size, void* d_ws, size_t ws_size,
                              hipStream_t stream) {
  const float* x  = (const float*)d_in[0];
  const float* wq = (const float*)d_in[1];
  const float* bq = (const float*)d_in[2];
  const float* wk = (const float*)d_in[3];
  const float* bk = (const float*)d_in[4];
  const float* wv = (const float*)d_in[5];
  const float* bv = (const float*)d_in[6];
  const float* wo = (const float*)d_in[7];
  const float* bo = (const float*)d_in[8];
  float* out = (float*)d_out;

  // workspace (~106.6 MB): q4/k4/v4 bf16; outh f32 aliases k4+v4 (dead after ker3kv)
  char* base = (char*)d_ws;
  const size_t QKV = (size_t)BH_ * N_ * HD_;   // 16,777,216 elems
  unsigned short* q4 = (unsigned short*)base;
  unsigned short* k4 = (unsigned short*)(base + QKV * 2);
  unsigned short* v4 = (unsigned short*)(base + QKV * 4);
  float* outh = (float*)(base + QKV * 2);       // alias k4+v4
  char* sp = base + QKV * 6;
  unsigned short* wqb = (unsigned short*)sp; sp += (size_t)C_ * C_ * 2;
  unsigned short* wkb = (unsigned short*)sp; sp += (size_t)C_ * C_ * 2;
  unsigned short* wvb = (unsigned short*)sp; sp += (size_t)C_ * C_ * 2;
  unsigned short* wob = (unsigned short*)sp; sp += (size_t)C_ * C_ * 2;
  float* p = (float*)sp;
  float* xbar  = p; p += (size_t)B_ * LM_ * C_;
  float* qland = p; p += (size_t)BH_ * LM_ * HD_;
  float* kland = p; p += (size_t)BH_ * LM_ * HD_;
  float* ker2  = p; p += (size_t)BH_ * LM_ * LM_;
  float* kvb   = p; p += (size_t)BH_ * LM_ * HD_;
  float* Mmat  = p; p += (size_t)BH_ * LM_ * HD_;
  float* pacc  = p; p += (size_t)BH_ * NCH_ * LM_ * HD_;
  float* ps    = p; p += (size_t)BH_ * NCH_ * LM_;
  float* pinv  = p; p += (size_t)BH_ * LM_ * LM_;

  const float scaleq = 0.125f;  // hd^-0.5
  const int W8 = (C_ * C_) / 8; // 32768 ushort8 groups per W

  // weight converts
  cvt_bf16_kernel<<<W8 / 256, 256, 0, stream>>>(wq, wqb, W8);
  cvt_bf16_kernel<<<W8 / 256, 256, 0, stream>>>(wk, wkb, W8);
  cvt_bf16_kernel<<<W8 / 256, 256, 0, stream>>>(wv, wvb, W8);
  cvt_bf16_kernel<<<W8 / 256, 256, 0, stream>>>(wo, wob, W8);

  // landmark path (f32-exact)
  seg_mean_kernel<<<B_ * LM_, 256, 0, stream>>>(x, xbar);
  dim3 gl(2, 8);
  gemm_nt_kernel<<<gl, 256, 0, stream>>>(xbar, wq, bq, qland, scaleq, LM_);
  gemm_nt_kernel<<<gl, 256, 0, stream>>>(xbar, wk, bk, kland, 1.0f, LM_);
  ker2_kernel<<<BH_, 64, 0, stream>>>(qland, kland, ker2);
  svd_pinv_kernel<<<BH_, 64, 0, stream>>>(ker2, pinv);

  // projections (bf16 MFMA) -> bf16 head-split
  dim3 gp(B_ * N_ / 128, C_ / 128);
  mfma_gemm_kernel<<<gp, 256, 0, stream>>>(x, wqb, bq, q4, scaleq, 1);
  mfma_gemm_kernel<<<gp, 256, 0, stream>>>(x, wkb, bk, k4, 1.0f, 1);
  mfma_gemm_kernel<<<gp, 256, 0, stream>>>(x, wvb, bv, v4, 1.0f, 1);

  // ker3 softmax + kv
  dim3 g6(NCH_, BH_);
  ker3kv_partial_kernel<<<g6, 256, 0, stream>>>(qland, k4, v4, pacc, ps);
  kv_combine_kernel<<<BH_, 256, 0, stream>>>(pacc, ps, kvb);
  mmat_kernel<<<BH_, 256, 0, stream>>>(pinv, kvb, Mmat);

  // out_heads (writes outh = dead k4/v4 alias)
  dim3 g9(N_ / 64, BH_);
  ker1out_kernel<<<g9, 256, 0, stream>>>(q4, kland, Mmat, outh);

  // final projection (bf16 MFMA) -> f32 out
  mfma_gemm_kernel<<<gp, 256, 0, stream>>>(outh, wob, bo, out, 1.0f, 0);
}

// Round 5
// 1302.161 us; speedup vs baseline: 2.6786x; 2.1340x over previous
//
#include <hip/hip_runtime.h>
#include <stdint.h>

// NystromAttention MI355X — Round 5: deviation-form softmax MFMA sweeps.
// ker3kv: P-1 in bf16 + exact ones*V colsum; qland hi/lo for QK logits.
// ker1out: (P/S - 1/64) in bf16 + exact fp64 col-mean-of-M bias; M hi/lo.
// Landmark/ker2/pinv path stays f32/f64-exact.

constexpr int B_   = 2;
constexpr int N_   = 16384;
constexpr int C_   = 512;
constexpr int H_   = 8;
constexpr int HD_  = 64;
constexpr int LM_  = 64;
constexpr int SEG_ = 256;
constexpr int BH_  = 16;
constexpr int NCH_ = 16;     // ker3kv chunks; 4 waves/chunk -> 64 partials per bh
constexpr int NPART_ = 64;
constexpr int NSWEEP_ = 8;   // Jacobi sweeps

#define RCOND_ (640.0 * 1.1920928955078125e-07)

typedef unsigned short ushort4_t __attribute__((ext_vector_type(4)));
typedef unsigned short ushort8_t __attribute__((ext_vector_type(8)));
typedef __bf16 bf16x8 __attribute__((ext_vector_type(8)));
typedef float f32x4 __attribute__((ext_vector_type(4)));

__device__ inline float bf2f(unsigned short u) {
  union { unsigned int i; float f; } x; x.i = ((unsigned int)u) << 16; return x.f;
}
__device__ inline unsigned short f2bf(float f) {
  union { float f; unsigned int i; } x; x.f = f;
  unsigned int lsb = (x.i >> 16) & 1;
  return (unsigned short)((x.i + 0x7fffu + lsb) >> 16);
}
__device__ inline bf16x8 ld_bf8(const unsigned short* p) { return *(const bf16x8*)p; }

// ---------------------------------------------------------------------------
__global__ __launch_bounds__(256) void cvt_bf16_kernel(const float* __restrict__ src,
                                                       unsigned short* __restrict__ dst,
                                                       int n8) {
  int i = (blockIdx.x * 256 + threadIdx.x);
  if (i >= n8) return;
  const float* s = src + (size_t)i * 8;
  float4 x0 = *(const float4*)(s);
  float4 x1 = *(const float4*)(s + 4);
  ushort8_t u;
  u[0] = f2bf(x0.x); u[1] = f2bf(x0.y); u[2] = f2bf(x0.z); u[3] = f2bf(x0.w);
  u[4] = f2bf(x1.x); u[5] = f2bf(x1.y); u[6] = f2bf(x1.z); u[7] = f2bf(x1.w);
  *(ushort8_t*)(dst + (size_t)i * 8) = u;
}

// f32 -> bf16 hi/lo pair
__global__ __launch_bounds__(256) void cvt_bf16_pair_kernel(const float* __restrict__ src,
                                                            unsigned short* __restrict__ hi,
                                                            unsigned short* __restrict__ lo,
                                                            int n) {
  int i = blockIdx.x * 256 + threadIdx.x;
  if (i >= n) return;
  float f = src[i];
  unsigned short h = f2bf(f);
  float rem = f - bf2f(h);
  hi[i] = h; lo[i] = f2bf(rem);
}

// ---------------------------------------------------------------------------
__global__ __launch_bounds__(256) void seg_mean_kernel(const float* __restrict__ x,
                                                       float* __restrict__ xbar) {
  int bl = blockIdx.x;
  int b = bl / LM_, l = bl % LM_;
  int t = threadIdx.x;
  int c4 = t & 127;
  int rh = t >> 7;
  const float* xp = x + ((size_t)b * N_ + (size_t)l * SEG_) * C_;
  float4 s = make_float4(0.f, 0.f, 0.f, 0.f);
  for (int r = rh * 128; r < rh * 128 + 128; ++r) {
    float4 v = *(const float4*)(xp + (size_t)r * C_ + c4 * 4);
    s.x += v.x; s.y += v.y; s.z += v.z; s.w += v.w;
  }
  __shared__ float red[2][512];
  *(float4*)&red[rh][c4 * 4] = s;
  __syncthreads();
  if (rh == 0) {
    float4 a = *(float4*)&red[0][c4 * 4];
    float4 c = *(float4*)&red[1][c4 * 4];
    const float invs = 1.0f / SEG_;
    float4 o;
    o.x = (a.x + c.x) * invs; o.y = (a.y + c.y) * invs;
    o.z = (a.z + c.z) * invs; o.w = (a.w + c.w) * invs;
    *(float4*)(xbar + (size_t)bl * C_ + c4 * 4) = o;
  }
}

// ---------------------------------------------------------------------------
// f32 VALU GEMM for landmark projections (128 rows): f32 head-split out.
__global__ __launch_bounds__(256) void gemm_nt_kernel(const float* __restrict__ A,
                                                      const float* __restrict__ W,
                                                      const float* __restrict__ bias,
                                                      float* __restrict__ out,
                                                      float scale, int rpb) {
  __shared__ float As[32][68];
  __shared__ float Ws[32][68];
  int row0 = blockIdx.x * 64;
  int col0 = blockIdx.y * 64;
  int tid = threadIdx.x;
  int tm = tid >> 4, tn = tid & 15;
  float acc[4][4] = {};
  for (int k0 = 0; k0 < C_; k0 += 32) {
#pragma unroll
    for (int i = 0; i < 2; ++i) {
      int s = tid + i * 256;
      int r = s >> 3;
      int kg = (s & 7) << 2;
      float4 av = *(const float4*)(A + (size_t)(row0 + r) * C_ + k0 + kg);
      As[kg + 0][r] = av.x; As[kg + 1][r] = av.y;
      As[kg + 2][r] = av.z; As[kg + 3][r] = av.w;
      float4 wv = *(const float4*)(W + (size_t)(col0 + r) * C_ + k0 + kg);
      Ws[kg + 0][r] = wv.x; Ws[kg + 1][r] = wv.y;
      Ws[kg + 2][r] = wv.z; Ws[kg + 3][r] = wv.w;
    }
    __syncthreads();
#pragma unroll
    for (int kk = 0; kk < 32; ++kk) {
      float4 a = *(const float4*)&As[kk][tm * 4];
      float4 b = *(const float4*)&Ws[kk][tn * 4];
      float av[4] = {a.x, a.y, a.z, a.w};
      float bv[4] = {b.x, b.y, b.z, b.w};
#pragma unroll
      for (int i = 0; i < 4; ++i)
#pragma unroll
        for (int j = 0; j < 4; ++j) acc[i][j] += av[i] * bv[j];
    }
    __syncthreads();
  }
#pragma unroll
  for (int i = 0; i < 4; ++i) {
    int row = row0 + tm * 4 + i;
    int d0 = tn * 4;
    float o4[4];
#pragma unroll
    for (int j = 0; j < 4; ++j) o4[j] = (acc[i][j] + bias[col0 + d0 + j]) * scale;
    int b = row / rpb, n = row % rpb;
    int h = col0 >> 6;
    size_t idx = (((size_t)(b * H_ + h) * rpb) + n) * HD_ + d0;
    float4 o; o.x = o4[0]; o.y = o4[1]; o.z = o4[2]; o.w = o4[3];
    *(float4*)(out + idx) = o;
  }
}

// ---------------------------------------------------------------------------
// MFMA GEMM: out = A(Mx512) @ Wb^T(bf16 512x512) + bias, scale.
// amode 0: A f32; amode 1: A bf16.
// omode 0: f32 out[row][col]; omode 1: bf16 head-split; omode 2: bf16 vt.
__global__ __launch_bounds__(256) void mfma_gemm_kernel(const void* __restrict__ A,
                                                        const unsigned short* __restrict__ Wb,
                                                        const float* __restrict__ bias,
                                                        void* __restrict__ out,
                                                        float scale, int amode, int omode) {
  __shared__ __align__(16) unsigned short Xs[128 * 32];
  __shared__ __align__(16) unsigned short Ws[128 * 32];
  int tid = threadIdx.x;
  int wid = tid >> 6, lane = tid & 63;
  int wr = wid >> 1, wc = wid & 1;
  int row0 = blockIdx.x * 128, col0 = blockIdx.y * 128;
  f32x4 acc[4][4] = {};

  int srow = tid >> 1;               // 0..127
  int sk = (tid & 1) * 16;           // 0 or 16
  const unsigned short* wpbase = Wb + (size_t)(col0 + srow) * C_ + sk;
  unsigned short* xdst = &Xs[srow * 32 + sk];
  unsigned short* wdst = &Ws[srow * 32 + sk];

  for (int k0 = 0; k0 < C_; k0 += 32) {
    __syncthreads();
    if (amode == 0) {
      const float* apbase = (const float*)A + (size_t)(row0 + srow) * C_ + sk;
      float4 x0 = *(const float4*)(apbase + k0);
      float4 x1 = *(const float4*)(apbase + k0 + 4);
      float4 x2 = *(const float4*)(apbase + k0 + 8);
      float4 x3 = *(const float4*)(apbase + k0 + 12);
      ushort8_t u0, u1;
      u0[0] = f2bf(x0.x); u0[1] = f2bf(x0.y); u0[2] = f2bf(x0.z); u0[3] = f2bf(x0.w);
      u0[4] = f2bf(x1.x); u0[5] = f2bf(x1.y); u0[6] = f2bf(x1.z); u0[7] = f2bf(x1.w);
      u1[0] = f2bf(x2.x); u1[1] = f2bf(x2.y); u1[2] = f2bf(x2.z); u1[3] = f2bf(x2.w);
      u1[4] = f2bf(x3.x); u1[5] = f2bf(x3.y); u1[6] = f2bf(x3.z); u1[7] = f2bf(x3.w);
      *(ushort8_t*)(xdst) = u0;
      *(ushort8_t*)(xdst + 8) = u1;
    } else {
      const unsigned short* apbase = (const unsigned short*)A + (size_t)(row0 + srow) * C_ + sk;
      ushort8_t a0 = *(const ushort8_t*)(apbase + k0);
      ushort8_t a1 = *(const ushort8_t*)(apbase + k0 + 8);
      *(ushort8_t*)(xdst) = a0;
      *(ushort8_t*)(xdst + 8) = a1;
    }
    ushort8_t w0 = *(const ushort8_t*)(wpbase + k0);
    ushort8_t w1 = *(const ushort8_t*)(wpbase + k0 + 8);
    *(ushort8_t*)(wdst) = w0;
    *(ushort8_t*)(wdst + 8) = w1;
    __syncthreads();
    bf16x8 af[4], bfr[4];
#pragma unroll
    for (int m = 0; m < 4; ++m)
      af[m] = *(bf16x8*)&Xs[(wr * 64 + m * 16 + (lane & 15)) * 32 + (lane >> 4) * 8];
#pragma unroll
    for (int n = 0; n < 4; ++n)
      bfr[n] = *(bf16x8*)&Ws[(wc * 64 + n * 16 + (lane & 15)) * 32 + (lane >> 4) * 8];
#pragma unroll
    for (int m = 0; m < 4; ++m)
#pragma unroll
      for (int n = 0; n < 4; ++n)
        acc[m][n] = __builtin_amdgcn_mfma_f32_16x16x32_bf16(af[m], bfr[n], acc[m][n], 0, 0, 0);
  }

#pragma unroll
  for (int m = 0; m < 4; ++m) {
    int rbase = row0 + wr * 64 + m * 16 + (lane >> 4) * 4;
#pragma unroll
    for (int n = 0; n < 4; ++n) {
      int c = col0 + wc * 64 + n * 16 + (lane & 15);
      float bc = bias[c];
      if (omode == 2) {
        int b = rbase >> 14, nn = rbase & 16383;
        int h = c >> 6, d = c & 63;
        ushort4_t u;
#pragma unroll
        for (int rg = 0; rg < 4; ++rg) u[rg] = f2bf((acc[m][n][rg] + bc) * scale);
        *(ushort4_t*)((unsigned short*)out + ((size_t)(b * H_ + h) * HD_ + d) * N_ + nn) = u;
      } else {
#pragma unroll
        for (int rg = 0; rg < 4; ++rg) {
          float val = (acc[m][n][rg] + bc) * scale;
          int r = rbase + rg;
          if (omode == 0) {
            ((float*)out)[(size_t)r * C_ + c] = val;
          } else {
            int b = r >> 14, nn = r & 16383, h = c >> 6, d = c & 63;
            ((unsigned short*)out)[(((size_t)(b * H_ + h) * N_) + nn) * HD_ + d] = f2bf(val);
          }
        }
      }
    }
  }
}

// ---------------------------------------------------------------------------
__global__ __launch_bounds__(64) void ker2_kernel(const float* __restrict__ qland,
                                                  const float* __restrict__ kland,
                                                  float* __restrict__ ker2) {
  int bh = blockIdx.x;
  __shared__ float kl[64][68];
  __shared__ float ql[64][68];
  int t = threadIdx.x;
  for (int i = 0; i < 16; ++i) {
    int s = t + i * 64;
    int r = s >> 4, d4 = (s & 15) << 2;
    *(float4*)&kl[r][d4] = *(const float4*)(kland + ((size_t)bh * 64 + r) * 64 + d4);
    *(float4*)&ql[r][d4] = *(const float4*)(qland + ((size_t)bh * 64 + r) * 64 + d4);
  }
  __syncthreads();
  float z[64];
  float se = 0.f;
  for (int j = 0; j < 64; ++j) {
    float acc = 0.f;
#pragma unroll
    for (int d4 = 0; d4 < 64; d4 += 4) {
      float4 qv = *(float4*)&ql[t][d4];
      float4 kv = *(float4*)&kl[j][d4];
      acc += qv.x * kv.x + qv.y * kv.y + qv.z * kv.z + qv.w * kv.w;
    }
    z[j] = expf(acc);
    se += z[j];
  }
  float inv = 1.0f / se;
  for (int j4 = 0; j4 < 64; j4 += 4) {
    float4 o = make_float4(z[j4] * inv, z[j4 + 1] * inv, z[j4 + 2] * inv, z[j4 + 3] * inv);
    *(float4*)(ker2 + ((size_t)bh * 64 + t) * 64 + j4) = o;
  }
}

// ---------------------------------------------------------------------------
// Register-resident single-wave one-sided Jacobi SVD + rcond-truncated pinv.
__global__ __launch_bounds__(64) void svd_pinv_kernel(const float* __restrict__ ker2,
                                                      float* __restrict__ pinv) {
  int bh = blockIdx.x;
  int lane = threadIdx.x;
  float a[64], v[64];
#pragma unroll
  for (int r = 0; r < 64; ++r) a[r] = ker2[((size_t)bh * 64 + r) * 64 + lane];
#pragma unroll
  for (int r = 0; r < 64; ++r) v[r] = (r == lane) ? 1.f : 0.f;

  for (int sweep = 0; sweep < NSWEEP_; ++sweep) {
    for (int mask = 1; mask < 64; ++mask) {
      int partner = lane ^ mask;
      bool lower = lane < partner;
      float o[64];
#pragma unroll
      for (int r = 0; r < 64; ++r) o[r] = __shfl_xor(a[r], mask);
      float alpha = 0.f, beta = 0.f, gamma = 0.f;
#pragma unroll
      for (int r = 0; r < 64; ++r) {
        alpha = fmaf(a[r], a[r], alpha);
        beta  = fmaf(o[r], o[r], beta);
        gamma = fmaf(a[r], o[r], gamma);
      }
      bool need = (gamma * gamma > 1e-14f * alpha * beta);
      if (__any(need)) {
        float ap = lower ? alpha : beta;
        float aq = lower ? beta : alpha;
        float c = 1.f, s = 0.f;
        if (need) {
          float tau = (aq - ap) / (2.f * gamma);
          float t = copysignf(1.f, tau) / (fabsf(tau) + sqrtf(fmaf(tau, tau, 1.f)));
          c = rsqrtf(fmaf(t, t, 1.f));
          s = t * c;
        }
        float sm = lower ? -s : s;
#pragma unroll
        for (int r = 0; r < 64; ++r) a[r] = fmaf(sm, o[r], c * a[r]);
#pragma unroll
        for (int r = 0; r < 64; ++r) o[r] = __shfl_xor(v[r], mask);
#pragma unroll
        for (int r = 0; r < 64; ++r) v[r] = fmaf(sm, o[r], c * v[r]);
      }
    }
  }

  double sig2 = 0.0;
#pragma unroll
  for (int r = 0; r < 64; ++r) sig2 += (double)a[r] * (double)a[r];
  double smax = sig2;
#pragma unroll
  for (int m = 1; m < 64; m <<= 1) smax = fmax(smax, __shfl_xor(smax, m));
  double cutoff2 = smax * (RCOND_ * RCOND_);
  float w = (sig2 > cutoff2) ? (float)(1.0 / sig2) : 0.f;

  __shared__ float was[64][65];
  __shared__ float vs[64][65];
#pragma unroll
  for (int j = 0; j < 64; ++j) was[lane][j] = w * a[j];
#pragma unroll
  for (int j = 0; j < 64; ++j) vs[lane][j] = v[j];
  __syncthreads();
  float accp[64] = {};
  for (int r = 0; r < 64; ++r) {
    float vv = vs[r][lane];
#pragma unroll
    for (int j = 0; j < 64; ++j) accp[j] = fmaf(vv, was[r][j], accp[j]);
  }
#pragma unroll
  for (int j = 0; j < 64; j += 4) {
    float4 ov = make_float4(accp[j], accp[j + 1], accp[j + 2], accp[j + 3]);
    *(float4*)(pinv + ((size_t)bh * 64 + lane) * 64 + j) = ov;
  }
}

// ---------------------------------------------------------------------------
// ker3+kv partials via MFMA in DEVIATION form.
// S-logits: (qh+ql) hi/lo qland vs bf16 K. P-1 stored bf16; ones*V colsum exact.
__global__ __launch_bounds__(256, 1) void ker3kv_mfma_kernel(
    const unsigned short* __restrict__ qlh,
    const unsigned short* __restrict__ qll,
    const unsigned short* __restrict__ k4,
    const unsigned short* __restrict__ vt,
    float* __restrict__ pacc,    // [bh][part][64][64] dev part
    float* __restrict__ pacc0,   // [bh][part][64] colsum of V over part tokens
    float* __restrict__ ps) {    // [bh][part][64] sum of (P-1)
  int bh = blockIdx.y, ch = blockIdx.x;
  int tid = threadIdx.x, w = tid >> 6, lane = tid & 63;
  int part = ch * 4 + w;
  int lrow = lane & 15, lgrp = lane >> 4;
  __shared__ __align__(16) unsigned short Pl[4][64 * 72];
  unsigned short* myP = &Pl[w][0];

  bf16x8 qah[4][2], qal[4][2];
#pragma unroll
  for (int mf = 0; mf < 4; ++mf)
#pragma unroll
    for (int ks = 0; ks < 2; ++ks) {
      size_t off = ((size_t)bh * 64 + mf * 16 + lrow) * 64 + ks * 32 + lgrp * 8;
      qah[mf][ks] = ld_bf8(qlh + off);
      qal[mf][ks] = ld_bf8(qll + off);
    }
  bf16x8 onesf;
#pragma unroll
  for (int j = 0; j < 8; ++j) onesf[j] = (__bf16)1.0f;

  f32x4 kvacc[4][4] = {};
  f32x4 oneacc[4] = {};
  f32x4 ssum[4] = {};

  for (int sub = 0; sub < 4; ++sub) {
    int n0 = ch * 1024 + w * 256 + sub * 64;
    f32x4 sacc[4][4] = {};
#pragma unroll
    for (int ks = 0; ks < 2; ++ks) {
#pragma unroll
      for (int nf = 0; nf < 4; ++nf) {
        bf16x8 kb = ld_bf8(k4 + ((size_t)bh * N_ + n0 + nf * 16 + lrow) * 64 + ks * 32 + lgrp * 8);
#pragma unroll
        for (int mf = 0; mf < 4; ++mf) {
          sacc[mf][nf] = __builtin_amdgcn_mfma_f32_16x16x32_bf16(qah[mf][ks], kb, sacc[mf][nf], 0, 0, 0);
          sacc[mf][nf] = __builtin_amdgcn_mfma_f32_16x16x32_bf16(qal[mf][ks], kb, sacc[mf][nf], 0, 0, 0);
        }
      }
    }
#pragma unroll
    for (int mf = 0; mf < 4; ++mf) {
#pragma unroll
      for (int nf = 0; nf < 4; ++nf) {
#pragma unroll
        for (int r = 0; r < 4; ++r) {
          float pd = expf(sacc[mf][nf][r]) - 1.0f;   // P - 1, |.| <~ 0.1
          ssum[mf][r] += pd;
          myP[(mf * 16 + lgrp * 4 + r) * 72 + nf * 16 + lrow] = f2bf(pd);
        }
      }
    }
#pragma unroll
    for (int ks = 0; ks < 2; ++ks) {
      bf16x8 pa[4];
#pragma unroll
      for (int mf = 0; mf < 4; ++mf)
        pa[mf] = ld_bf8(myP + (mf * 16 + lrow) * 72 + ks * 32 + lgrp * 8);
#pragma unroll
      for (int nf = 0; nf < 4; ++nf) {
        bf16x8 vb = ld_bf8(vt + ((size_t)bh * 64 + nf * 16 + lrow) * N_ + n0 + ks * 32 + lgrp * 8);
#pragma unroll
        for (int mf = 0; mf < 4; ++mf)
          kvacc[mf][nf] = __builtin_amdgcn_mfma_f32_16x16x32_bf16(pa[mf], vb, kvacc[mf][nf], 0, 0, 0);
        oneacc[nf] = __builtin_amdgcn_mfma_f32_16x16x32_bf16(onesf, vb, oneacc[nf], 0, 0, 0);
      }
    }
  }
#pragma unroll
  for (int mf = 0; mf < 4; ++mf)
#pragma unroll
    for (int m = 1; m < 16; m <<= 1)
#pragma unroll
      for (int r = 0; r < 4; ++r) ssum[mf][r] += __shfl_xor(ssum[mf][r], m);

  size_t pb = (((size_t)bh * NPART_ + part) * 64) * 64;
#pragma unroll
  for (int mf = 0; mf < 4; ++mf)
#pragma unroll
    for (int nf = 0; nf < 4; ++nf)
#pragma unroll
      for (int r = 0; r < 4; ++r)
        pacc[pb + (size_t)(mf * 16 + lgrp * 4 + r) * 64 + nf * 16 + lrow] = kvacc[mf][nf][r];
  if (lrow == 0) {
#pragma unroll
    for (int mf = 0; mf < 4; ++mf)
#pragma unroll
      for (int r = 0; r < 4; ++r)
        ps[((size_t)bh * NPART_ + part) * 64 + mf * 16 + lgrp * 4 + r] = ssum[mf][r];
  }
  if (lgrp == 0) {
#pragma unroll
    for (int nf = 0; nf < 4; ++nf)
      pacc0[((size_t)bh * NPART_ + part) * 64 + nf * 16 + lrow] = oneacc[nf][0];
  }
}

// ---------------------------------------------------------------------------
// kv = (colsumV + sum dev partials) / (16384 + sum (P-1)). Grid (4, BH_).
__global__ __launch_bounds__(256) void kv_combine_kernel(const float* __restrict__ pacc,
                                                         const float* __restrict__ pacc0,
                                                         const float* __restrict__ ps,
                                                         float* __restrict__ kv) {
  int bh = blockIdx.y;
  int lm = blockIdx.x * 16 + (threadIdx.x >> 4);
  int d4 = (threadIdx.x & 15) * 4;
  float s = 16384.f;
  for (int part = 0; part < NPART_; ++part) s += ps[((size_t)bh * NPART_ + part) * 64 + lm];
  float4 a = make_float4(0.f, 0.f, 0.f, 0.f);
  for (int part = 0; part < NPART_; ++part) {
    float4 c0 = *(const float4*)&pacc0[((size_t)bh * NPART_ + part) * 64 + d4];
    float4 v = *(const float4*)&pacc[(((size_t)bh * NPART_ + part) * 64 + lm) * 64 + d4];
    a.x += c0.x + v.x; a.y += c0.y + v.y; a.z += c0.z + v.z; a.w += c0.w + v.w;
  }
  float inv = 1.f / s;
  float4 o = make_float4(a.x * inv, a.y * inv, a.z * inv, a.w * inv);
  *(float4*)(kv + ((size_t)bh * 64 + lm) * 64 + d4) = o;
}

// ---------------------------------------------------------------------------
// M = pinv @ kv (fp64) -> bf16 hi/lo transposed Mt[d][l], plus exact
// msum[d] = (1/64) sum_l M[l][d] (f64 via pinv column sums).
__global__ __launch_bounds__(256) void mmat_kernel(const float* __restrict__ pinv,
                                                   const float* __restrict__ kv,
                                                   unsigned short* __restrict__ mtbh,
                                                   unsigned short* __restrict__ mtbl,
                                                   float* __restrict__ msum) {
  int bh = blockIdx.x;
  int tid = threadIdx.x;
  __shared__ float kvs[64][68];
  __shared__ double pcsd[64];
  for (int i = 0; i < 4; ++i) {
    int s = tid + i * 256;
    int r = s >> 4, d4 = (s & 15) << 2;
    *(float4*)&kvs[r][d4] = *(const float4*)(kv + ((size_t)bh * 64 + r) * 64 + d4);
  }
  if (tid < 64) {
    double s = 0.0;
    for (int l = 0; l < 64; ++l) s += (double)pinv[((size_t)bh * 64 + l) * 64 + tid];
    pcsd[tid] = s;
  }
  __syncthreads();
  int l = tid >> 2, t = tid & 3;
  double o[16] = {};
  for (int j = 0; j < 64; ++j) {
    double pv = (double)pinv[((size_t)bh * 64 + l) * 64 + j];
#pragma unroll
    for (int i = 0; i < 16; ++i) o[i] += pv * (double)kvs[j][t * 16 + i];
  }
#pragma unroll
  for (int i = 0; i < 16; ++i) {
    float f = (float)o[i];
    unsigned short hi = f2bf(f);
    float lo = f - bf2f(hi);
    int d = t * 16 + i;
    mtbh[((size_t)bh * 64 + d) * 64 + l] = hi;
    mtbl[((size_t)bh * 64 + d) * 64 + l] = f2bf(lo);
  }
  if (tid < 64) {
    double m = 0.0;
    for (int j = 0; j < 64; ++j) m += pcsd[j] * (double)kvs[j][tid];
    msum[(size_t)bh * 64 + tid] = (float)(m * (1.0 / 64.0));
  }
}

// ---------------------------------------------------------------------------
// out_heads = softmax(q kl^T) @ M via MFMA, deviation form:
// out = msum[d] + sum_l (P/S - 1/64) * M[l][d].  Writes bf16 outh (B,N,C).
__global__ __launch_bounds__(256, 1) void ker1out_mfma_kernel(
    const unsigned short* __restrict__ q4,
    const unsigned short* __restrict__ klb,
    const unsigned short* __restrict__ mtbh,
    const unsigned short* __restrict__ mtbl,
    const float* __restrict__ msum,
    unsigned short* __restrict__ outh) {
  int bh = blockIdx.y, tile = blockIdx.x;
  int b = bh >> 3, h = bh & 7;
  int tid = threadIdx.x, w = tid >> 6, lane = tid & 63;
  int lrow = lane & 15, lgrp = lane >> 4;
  int tok0 = tile * 256 + w * 64;
  __shared__ __align__(16) unsigned short Pl[4][64 * 72];
  unsigned short* myP = &Pl[w][0];

  f32x4 sacc[4][4] = {};
#pragma unroll
  for (int ks = 0; ks < 2; ++ks) {
    bf16x8 kb[4];
#pragma unroll
    for (int nf = 0; nf < 4; ++nf)
      kb[nf] = ld_bf8(klb + ((size_t)bh * 64 + nf * 16 + lrow) * 64 + ks * 32 + lgrp * 8);
#pragma unroll
    for (int mf = 0; mf < 4; ++mf) {
      bf16x8 qa = ld_bf8(q4 + ((size_t)bh * N_ + tok0 + mf * 16 + lrow) * 64 + ks * 32 + lgrp * 8);
#pragma unroll
      for (int nf = 0; nf < 4; ++nf)
        sacc[mf][nf] = __builtin_amdgcn_mfma_f32_16x16x32_bf16(qa, kb[nf], sacc[mf][nf], 0, 0, 0);
    }
  }
  f32x4 ssum[4] = {};
#pragma unroll
  for (int mf = 0; mf < 4; ++mf)
#pragma unroll
    for (int nf = 0; nf < 4; ++nf)
#pragma unroll
      for (int r = 0; r < 4; ++r) {
        sacc[mf][nf][r] = expf(sacc[mf][nf][r]);
        ssum[mf][r] += sacc[mf][nf][r];
      }
#pragma unroll
  for (int mf = 0; mf < 4; ++mf)
#pragma unroll
    for (int m = 1; m < 16; m <<= 1)
#pragma unroll
      for (int r = 0; r < 4; ++r) ssum[mf][r] += __shfl_xor(ssum[mf][r], m);
#pragma unroll
  for (int mf = 0; mf < 4; ++mf) {
    f32x4 inv;
#pragma unroll
    for (int r = 0; r < 4; ++r) inv[r] = 1.f / ssum[mf][r];
#pragma unroll
    for (int nf = 0; nf < 4; ++nf)
#pragma unroll
      for (int r = 0; r < 4; ++r) {
        float pdev = fmaf(sacc[mf][nf][r], inv[r], -0.015625f);  // P/S - 1/64
        myP[(mf * 16 + lgrp * 4 + r) * 72 + nf * 16 + lrow] = f2bf(pdev);
      }
  }

  f32x4 oacc[4][4] = {};
#pragma unroll
  for (int ks = 0; ks < 2; ++ks) {
    bf16x8 pa[4];
#pragma unroll
    for (int mf = 0; mf < 4; ++mf)
      pa[mf] = ld_bf8(myP + (mf * 16 + lrow) * 72 + ks * 32 + lgrp * 8);
#pragma unroll
    for (int nf = 0; nf < 4; ++nf) {
      bf16x8 mh = ld_bf8(mtbh + ((size_t)bh * 64 + nf * 16 + lrow) * 64 + ks * 32 + lgrp * 8);
      bf16x8 ml = ld_bf8(mtbl + ((size_t)bh * 64 + nf * 16 + lrow) * 64 + ks * 32 + lgrp * 8);
#pragma unroll
      for (int mf = 0; mf < 4; ++mf) {
        oacc[mf][nf] = __builtin_amdgcn_mfma_f32_16x16x32_bf16(pa[mf], mh, oacc[mf][nf], 0, 0, 0);
        oacc[mf][nf] = __builtin_amdgcn_mfma_f32_16x16x32_bf16(pa[mf], ml, oacc[mf][nf], 0, 0, 0);
      }
    }
  }
#pragma unroll
  for (int nf = 0; nf < 4; ++nf) {
    float ms = msum[(size_t)bh * 64 + nf * 16 + lrow];
#pragma unroll
    for (int mf = 0; mf < 4; ++mf)
#pragma unroll
      for (int r = 0; r < 4; ++r) {
        int tok = tok0 + mf * 16 + lgrp * 4 + r;
        int d = nf * 16 + lrow;
        outh[((size_t)b * N_ + tok) * C_ + h * HD_ + d] = f2bf(oacc[mf][nf][r] + ms);
      }
  }
}

// ---------------------------------------------------------------------------
extern "C" void kernel_launch(void* const* d_in, const int* in_sizes, int n_in,
                              void* d_out, int out_size, void* d_ws, size_t ws_size,
                              hipStream_t stream) {
  const float* x  = (const float*)d_in[0];
  const float* wq = (const float*)d_in[1];
  const float* bq = (const float*)d_in[2];
  const float* wk = (const float*)d_in[3];
  const float* bk = (const float*)d_in[4];
  const float* wv = (const float*)d_in[5];
  const float* bv = (const float*)d_in[6];
  const float* wo = (const float*)d_in[7];
  const float* bo = (const float*)d_in[8];
  float* out = (float*)d_out;

  char* base = (char*)d_ws;
  const size_t QKV = (size_t)BH_ * N_ * HD_;   // 16,777,216 elems
  unsigned short* q4 = (unsigned short*)base;                 // 32MB
  unsigned short* k4 = (unsigned short*)(base + QKV * 2);     // 32MB
  unsigned short* vt = (unsigned short*)(base + QKV * 4);     // 32MB
  unsigned short* outh = (unsigned short*)(base + QKV * 2);   // alias k4 (dead after ker3kv)
  char* sp = base + QKV * 6;
  float* pacc  = (float*)sp; sp += (size_t)BH_ * NPART_ * 64 * 64 * 4;  // 16.78MB
  float* pacc0 = (float*)sp; sp += (size_t)BH_ * NPART_ * 64 * 4;
  float* ps    = (float*)sp; sp += (size_t)BH_ * NPART_ * 64 * 4;
  unsigned short* wqb = (unsigned short*)sp; sp += (size_t)C_ * C_ * 2;
  unsigned short* wkb = (unsigned short*)sp; sp += (size_t)C_ * C_ * 2;
  unsigned short* wvb = (unsigned short*)sp; sp += (size_t)C_ * C_ * 2;
  unsigned short* wob = (unsigned short*)sp; sp += (size_t)C_ * C_ * 2;
  float* xbar  = (float*)sp; sp += (size_t)B_ * LM_ * C_ * 4;
  float* qland = (float*)sp; sp += (size_t)BH_ * LM_ * HD_ * 4;
  float* kland = (float*)sp; sp += (size_t)BH_ * LM_ * HD_ * 4;
  unsigned short* qlbh = (unsigned short*)sp; sp += (size_t)BH_ * LM_ * HD_ * 2;
  unsigned short* qlbl = (unsigned short*)sp; sp += (size_t)BH_ * LM_ * HD_ * 2;
  unsigned short* klb  = (unsigned short*)sp; sp += (size_t)BH_ * LM_ * HD_ * 2;
  float* ker2  = (float*)sp; sp += (size_t)BH_ * LM_ * LM_ * 4;
  float* pinv  = (float*)sp; sp += (size_t)BH_ * LM_ * LM_ * 4;
  float* kvb   = (float*)sp; sp += (size_t)BH_ * LM_ * HD_ * 4;
  unsigned short* mtbh = (unsigned short*)sp; sp += (size_t)BH_ * LM_ * HD_ * 2;
  unsigned short* mtbl = (unsigned short*)sp; sp += (size_t)BH_ * LM_ * HD_ * 2;
  float* msum  = (float*)sp; sp += (size_t)BH_ * HD_ * 4;

  const float scaleq = 0.125f;
  const int W8 = (C_ * C_) / 8;
  const int L = BH_ * LM_ * HD_;
  const int L8 = L / 8;

  cvt_bf16_kernel<<<W8 / 256, 256, 0, stream>>>(wq, wqb, W8);
  cvt_bf16_kernel<<<W8 / 256, 256, 0, stream>>>(wk, wkb, W8);
  cvt_bf16_kernel<<<W8 / 256, 256, 0, stream>>>(wv, wvb, W8);
  cvt_bf16_kernel<<<W8 / 256, 256, 0, stream>>>(wo, wob, W8);

  // landmark path (f32-exact)
  seg_mean_kernel<<<B_ * LM_, 256, 0, stream>>>(x, xbar);
  dim3 gl(2, 8);
  gemm_nt_kernel<<<gl, 256, 0, stream>>>(xbar, wq, bq, qland, scaleq, LM_);
  gemm_nt_kernel<<<gl, 256, 0, stream>>>(xbar, wk, bk, kland, 1.0f, LM_);
  cvt_bf16_pair_kernel<<<L / 256, 256, 0, stream>>>(qland, qlbh, qlbl, L);
  cvt_bf16_kernel<<<L8 / 256, 256, 0, stream>>>(kland, klb, L8);
  ker2_kernel<<<BH_, 64, 0, stream>>>(qland, kland, ker2);
  svd_pinv_kernel<<<BH_, 64, 0, stream>>>(ker2, pinv);

  // projections
  dim3 gp(B_ * N_ / 128, C_ / 128);
  mfma_gemm_kernel<<<gp, 256, 0, stream>>>(x, wqb, bq, q4, scaleq, 0, 1);
  mfma_gemm_kernel<<<gp, 256, 0, stream>>>(x, wkb, bk, k4, 1.0f, 0, 1);
  mfma_gemm_kernel<<<gp, 256, 0, stream>>>(x, wvb, bv, vt, 1.0f, 0, 2);

  // ker3 + kv (MFMA, deviation form)
  dim3 g6(NCH_, BH_);
  ker3kv_mfma_kernel<<<g6, 256, 0, stream>>>(qlbh, qlbl, k4, vt, pacc, pacc0, ps);
  dim3 g7(4, BH_);
  kv_combine_kernel<<<g7, 256, 0, stream>>>(pacc, pacc0, ps, kvb);
  mmat_kernel<<<BH_, 256, 0, stream>>>(pinv, kvb, mtbh, mtbl, msum);

  // out_heads (MFMA, deviation form) -> bf16 outh (aliases dead k4)
  dim3 g9(N_ / 256, BH_);
  ker1out_mfma_kernel<<<g9, 256, 0, stream>>>(q4, klb, mtbh, mtbl, msum, outh);

  // final projection (bf16 A) -> f32 out
  mfma_gemm_kernel<<<gp, 256, 0, stream>>>(outh, wob, bo, out, 1.0f, 1, 0);
}

// Round 6
// 1149.318 us; speedup vs baseline: 3.0348x; 1.1330x over previous
//
#include <hip/hip_runtime.h>
#include <stdint.h>

// NystromAttention MI355X — Round 6: fast single-wave Jacobi SVD
// (launch_bounds(64,1) to unspill; incremental column norms; split dot chains;
//  sweep early-exit). Rest identical to round 5 (passed, 1302us).

constexpr int B_   = 2;
constexpr int N_   = 16384;
constexpr int C_   = 512;
constexpr int H_   = 8;
constexpr int HD_  = 64;
constexpr int LM_  = 64;
constexpr int SEG_ = 256;
constexpr int BH_  = 16;
constexpr int NCH_ = 16;     // ker3kv chunks; 4 waves/chunk -> 64 partials per bh
constexpr int NPART_ = 64;
constexpr int NSWEEP_ = 8;   // max Jacobi sweeps (early exit when converged)

#define RCOND_ (640.0 * 1.1920928955078125e-07)

typedef unsigned short ushort4_t __attribute__((ext_vector_type(4)));
typedef unsigned short ushort8_t __attribute__((ext_vector_type(8)));
typedef __bf16 bf16x8 __attribute__((ext_vector_type(8)));
typedef float f32x4 __attribute__((ext_vector_type(4)));

__device__ inline float bf2f(unsigned short u) {
  union { unsigned int i; float f; } x; x.i = ((unsigned int)u) << 16; return x.f;
}
__device__ inline unsigned short f2bf(float f) {
  union { float f; unsigned int i; } x; x.f = f;
  unsigned int lsb = (x.i >> 16) & 1;
  return (unsigned short)((x.i + 0x7fffu + lsb) >> 16);
}
__device__ inline bf16x8 ld_bf8(const unsigned short* p) { return *(const bf16x8*)p; }

// ---------------------------------------------------------------------------
__global__ __launch_bounds__(256) void cvt_bf16_kernel(const float* __restrict__ src,
                                                       unsigned short* __restrict__ dst,
                                                       int n8) {
  int i = (blockIdx.x * 256 + threadIdx.x);
  if (i >= n8) return;
  const float* s = src + (size_t)i * 8;
  float4 x0 = *(const float4*)(s);
  float4 x1 = *(const float4*)(s + 4);
  ushort8_t u;
  u[0] = f2bf(x0.x); u[1] = f2bf(x0.y); u[2] = f2bf(x0.z); u[3] = f2bf(x0.w);
  u[4] = f2bf(x1.x); u[5] = f2bf(x1.y); u[6] = f2bf(x1.z); u[7] = f2bf(x1.w);
  *(ushort8_t*)(dst + (size_t)i * 8) = u;
}

// f32 -> bf16 hi/lo pair
__global__ __launch_bounds__(256) void cvt_bf16_pair_kernel(const float* __restrict__ src,
                                                            unsigned short* __restrict__ hi,
                                                            unsigned short* __restrict__ lo,
                                                            int n) {
  int i = blockIdx.x * 256 + threadIdx.x;
  if (i >= n) return;
  float f = src[i];
  unsigned short h = f2bf(f);
  float rem = f - bf2f(h);
  hi[i] = h; lo[i] = f2bf(rem);
}

// ---------------------------------------------------------------------------
__global__ __launch_bounds__(256) void seg_mean_kernel(const float* __restrict__ x,
                                                       float* __restrict__ xbar) {
  int bl = blockIdx.x;
  int b = bl / LM_, l = bl % LM_;
  int t = threadIdx.x;
  int c4 = t & 127;
  int rh = t >> 7;
  const float* xp = x + ((size_t)b * N_ + (size_t)l * SEG_) * C_;
  float4 s = make_float4(0.f, 0.f, 0.f, 0.f);
  for (int r = rh * 128; r < rh * 128 + 128; ++r) {
    float4 v = *(const float4*)(xp + (size_t)r * C_ + c4 * 4);
    s.x += v.x; s.y += v.y; s.z += v.z; s.w += v.w;
  }
  __shared__ float red[2][512];
  *(float4*)&red[rh][c4 * 4] = s;
  __syncthreads();
  if (rh == 0) {
    float4 a = *(float4*)&red[0][c4 * 4];
    float4 c = *(float4*)&red[1][c4 * 4];
    const float invs = 1.0f / SEG_;
    float4 o;
    o.x = (a.x + c.x) * invs; o.y = (a.y + c.y) * invs;
    o.z = (a.z + c.z) * invs; o.w = (a.w + c.w) * invs;
    *(float4*)(xbar + (size_t)bl * C_ + c4 * 4) = o;
  }
}

// ---------------------------------------------------------------------------
// f32 VALU GEMM for landmark projections (128 rows): f32 head-split out.
__global__ __launch_bounds__(256) void gemm_nt_kernel(const float* __restrict__ A,
                                                      const float* __restrict__ W,
                                                      const float* __restrict__ bias,
                                                      float* __restrict__ out,
                                                      float scale, int rpb) {
  __shared__ float As[32][68];
  __shared__ float Ws[32][68];
  int row0 = blockIdx.x * 64;
  int col0 = blockIdx.y * 64;
  int tid = threadIdx.x;
  int tm = tid >> 4, tn = tid & 15;
  float acc[4][4] = {};
  for (int k0 = 0; k0 < C_; k0 += 32) {
#pragma unroll
    for (int i = 0; i < 2; ++i) {
      int s = tid + i * 256;
      int r = s >> 3;
      int kg = (s & 7) << 2;
      float4 av = *(const float4*)(A + (size_t)(row0 + r) * C_ + k0 + kg);
      As[kg + 0][r] = av.x; As[kg + 1][r] = av.y;
      As[kg + 2][r] = av.z; As[kg + 3][r] = av.w;
      float4 wv = *(const float4*)(W + (size_t)(col0 + r) * C_ + k0 + kg);
      Ws[kg + 0][r] = wv.x; Ws[kg + 1][r] = wv.y;
      Ws[kg + 2][r] = wv.z; Ws[kg + 3][r] = wv.w;
    }
    __syncthreads();
#pragma unroll
    for (int kk = 0; kk < 32; ++kk) {
      float4 a = *(const float4*)&As[kk][tm * 4];
      float4 b = *(const float4*)&Ws[kk][tn * 4];
      float av[4] = {a.x, a.y, a.z, a.w};
      float bv[4] = {b.x, b.y, b.z, b.w};
#pragma unroll
      for (int i = 0; i < 4; ++i)
#pragma unroll
        for (int j = 0; j < 4; ++j) acc[i][j] += av[i] * bv[j];
    }
    __syncthreads();
  }
#pragma unroll
  for (int i = 0; i < 4; ++i) {
    int row = row0 + tm * 4 + i;
    int d0 = tn * 4;
    float o4[4];
#pragma unroll
    for (int j = 0; j < 4; ++j) o4[j] = (acc[i][j] + bias[col0 + d0 + j]) * scale;
    int b = row / rpb, n = row % rpb;
    int h = col0 >> 6;
    size_t idx = (((size_t)(b * H_ + h) * rpb) + n) * HD_ + d0;
    float4 o; o.x = o4[0]; o.y = o4[1]; o.z = o4[2]; o.w = o4[3];
    *(float4*)(out + idx) = o;
  }
}

// ---------------------------------------------------------------------------
// MFMA GEMM: out = A(Mx512) @ Wb^T(bf16 512x512) + bias, scale.
// amode 0: A f32; amode 1: A bf16.
// omode 0: f32 out[row][col]; omode 1: bf16 head-split; omode 2: bf16 vt.
__global__ __launch_bounds__(256) void mfma_gemm_kernel(const void* __restrict__ A,
                                                        const unsigned short* __restrict__ Wb,
                                                        const float* __restrict__ bias,
                                                        void* __restrict__ out,
                                                        float scale, int amode, int omode) {
  __shared__ __align__(16) unsigned short Xs[128 * 32];
  __shared__ __align__(16) unsigned short Ws[128 * 32];
  int tid = threadIdx.x;
  int wid = tid >> 6, lane = tid & 63;
  int wr = wid >> 1, wc = wid & 1;
  int row0 = blockIdx.x * 128, col0 = blockIdx.y * 128;
  f32x4 acc[4][4] = {};

  int srow = tid >> 1;               // 0..127
  int sk = (tid & 1) * 16;           // 0 or 16
  const unsigned short* wpbase = Wb + (size_t)(col0 + srow) * C_ + sk;
  unsigned short* xdst = &Xs[srow * 32 + sk];
  unsigned short* wdst = &Ws[srow * 32 + sk];

  for (int k0 = 0; k0 < C_; k0 += 32) {
    __syncthreads();
    if (amode == 0) {
      const float* apbase = (const float*)A + (size_t)(row0 + srow) * C_ + sk;
      float4 x0 = *(const float4*)(apbase + k0);
      float4 x1 = *(const float4*)(apbase + k0 + 4);
      float4 x2 = *(const float4*)(apbase + k0 + 8);
      float4 x3 = *(const float4*)(apbase + k0 + 12);
      ushort8_t u0, u1;
      u0[0] = f2bf(x0.x); u0[1] = f2bf(x0.y); u0[2] = f2bf(x0.z); u0[3] = f2bf(x0.w);
      u0[4] = f2bf(x1.x); u0[5] = f2bf(x1.y); u0[6] = f2bf(x1.z); u0[7] = f2bf(x1.w);
      u1[0] = f2bf(x2.x); u1[1] = f2bf(x2.y); u1[2] = f2bf(x2.z); u1[3] = f2bf(x2.w);
      u1[4] = f2bf(x3.x); u1[5] = f2bf(x3.y); u1[6] = f2bf(x3.z); u1[7] = f2bf(x3.w);
      *(ushort8_t*)(xdst) = u0;
      *(ushort8_t*)(xdst + 8) = u1;
    } else {
      const unsigned short* apbase = (const unsigned short*)A + (size_t)(row0 + srow) * C_ + sk;
      ushort8_t a0 = *(const ushort8_t*)(apbase + k0);
      ushort8_t a1 = *(const ushort8_t*)(apbase + k0 + 8);
      *(ushort8_t*)(xdst) = a0;
      *(ushort8_t*)(xdst + 8) = a1;
    }
    ushort8_t w0 = *(const ushort8_t*)(wpbase + k0);
    ushort8_t w1 = *(const ushort8_t*)(wpbase + k0 + 8);
    *(ushort8_t*)(wdst) = w0;
    *(ushort8_t*)(wdst + 8) = w1;
    __syncthreads();
    bf16x8 af[4], bfr[4];
#pragma unroll
    for (int m = 0; m < 4; ++m)
      af[m] = *(bf16x8*)&Xs[(wr * 64 + m * 16 + (lane & 15)) * 32 + (lane >> 4) * 8];
#pragma unroll
    for (int n = 0; n < 4; ++n)
      bfr[n] = *(bf16x8*)&Ws[(wc * 64 + n * 16 + (lane & 15)) * 32 + (lane >> 4) * 8];
#pragma unroll
    for (int m = 0; m < 4; ++m)
#pragma unroll
      for (int n = 0; n < 4; ++n)
        acc[m][n] = __builtin_amdgcn_mfma_f32_16x16x32_bf16(af[m], bfr[n], acc[m][n], 0, 0, 0);
  }

#pragma unroll
  for (int m = 0; m < 4; ++m) {
    int rbase = row0 + wr * 64 + m * 16 + (lane >> 4) * 4;
#pragma unroll
    for (int n = 0; n < 4; ++n) {
      int c = col0 + wc * 64 + n * 16 + (lane & 15);
      float bc = bias[c];
      if (omode == 2) {
        int b = rbase >> 14, nn = rbase & 16383;
        int h = c >> 6, d = c & 63;
        ushort4_t u;
#pragma unroll
        for (int rg = 0; rg < 4; ++rg) u[rg] = f2bf((acc[m][n][rg] + bc) * scale);
        *(ushort4_t*)((unsigned short*)out + ((size_t)(b * H_ + h) * HD_ + d) * N_ + nn) = u;
      } else {
#pragma unroll
        for (int rg = 0; rg < 4; ++rg) {
          float val = (acc[m][n][rg] + bc) * scale;
          int r = rbase + rg;
          if (omode == 0) {
            ((float*)out)[(size_t)r * C_ + c] = val;
          } else {
            int b = r >> 14, nn = r & 16383, h = c >> 6, d = c & 63;
            ((unsigned short*)out)[(((size_t)(b * H_ + h) * N_) + nn) * HD_ + d] = f2bf(val);
          }
        }
      }
    }
  }
}

// ---------------------------------------------------------------------------
__global__ __launch_bounds__(64) void ker2_kernel(const float* __restrict__ qland,
                                                  const float* __restrict__ kland,
                                                  float* __restrict__ ker2) {
  int bh = blockIdx.x;
  __shared__ float kl[64][68];
  __shared__ float ql[64][68];
  int t = threadIdx.x;
  for (int i = 0; i < 16; ++i) {
    int s = t + i * 64;
    int r = s >> 4, d4 = (s & 15) << 2;
    *(float4*)&kl[r][d4] = *(const float4*)(kland + ((size_t)bh * 64 + r) * 64 + d4);
    *(float4*)&ql[r][d4] = *(const float4*)(qland + ((size_t)bh * 64 + r) * 64 + d4);
  }
  __syncthreads();
  float z[64];
  float se = 0.f;
  for (int j = 0; j < 64; ++j) {
    float acc = 0.f;
#pragma unroll
    for (int d4 = 0; d4 < 64; d4 += 4) {
      float4 qv = *(float4*)&ql[t][d4];
      float4 kv = *(float4*)&kl[j][d4];
      acc += qv.x * kv.x + qv.y * kv.y + qv.z * kv.z + qv.w * kv.w;
    }
    z[j] = expf(acc);
    se += z[j];
  }
  float inv = 1.0f / se;
  for (int j4 = 0; j4 < 64; j4 += 4) {
    float4 o = make_float4(z[j4] * inv, z[j4 + 1] * inv, z[j4 + 2] * inv, z[j4 + 3] * inv);
    *(float4*)(ker2 + ((size_t)bh * 64 + t) * 64 + j4) = o;
  }
}

// ---------------------------------------------------------------------------
// Register-resident single-wave one-sided Jacobi SVD + rcond-truncated pinv.
// launch_bounds(64,1): full VGPR budget (a[64]+v[64]+o[64] in regs, no spill).
// Column norms maintained incrementally; exact recompute at sweep start.
__global__ __launch_bounds__(64, 1) void svd_pinv_kernel(const float* __restrict__ ker2,
                                                         float* __restrict__ pinv) {
  int bh = blockIdx.x;
  int lane = threadIdx.x;
  float a[64], v[64];
#pragma unroll
  for (int r = 0; r < 64; ++r) a[r] = ker2[((size_t)bh * 64 + r) * 64 + lane];
#pragma unroll
  for (int r = 0; r < 64; ++r) v[r] = (r == lane) ? 1.f : 0.f;

  for (int sweep = 0; sweep < NSWEEP_; ++sweep) {
    // exact column norm^2 (fix incremental drift), 4-way split chains
    float al0 = 0.f, al1 = 0.f, al2 = 0.f, al3 = 0.f;
#pragma unroll
    for (int r = 0; r < 64; r += 4) {
      al0 = fmaf(a[r], a[r], al0);
      al1 = fmaf(a[r + 1], a[r + 1], al1);
      al2 = fmaf(a[r + 2], a[r + 2], al2);
      al3 = fmaf(a[r + 3], a[r + 3], al3);
    }
    float alpha = (al0 + al1) + (al2 + al3);
    bool sweep_rot = false;
    for (int mask = 1; mask < 64; ++mask) {
      bool lower = lane < (lane ^ mask);
      float o[64];
#pragma unroll
      for (int r = 0; r < 64; ++r) o[r] = __shfl_xor(a[r], mask);
      float g0 = 0.f, g1 = 0.f, g2 = 0.f, g3 = 0.f;
#pragma unroll
      for (int r = 0; r < 64; r += 4) {
        g0 = fmaf(a[r], o[r], g0);
        g1 = fmaf(a[r + 1], o[r + 1], g1);
        g2 = fmaf(a[r + 2], o[r + 2], g2);
        g3 = fmaf(a[r + 3], o[r + 3], g3);
      }
      float gamma = (g0 + g1) + (g2 + g3);   // bitwise-equal on both pair lanes
      float beta = __shfl_xor(alpha, mask);
      bool need = (gamma * gamma > 1e-14f * alpha * beta);
      if (__any(need)) {
        sweep_rot = true;
        float ap = lower ? alpha : beta;
        float aq = lower ? beta : alpha;
        float c = 1.f, s = 0.f;
        if (need) {
          float tau = (aq - ap) / (2.f * gamma);
          float t = copysignf(1.f, tau) / (fabsf(tau) + sqrtf(fmaf(tau, tau, 1.f)));
          c = rsqrtf(fmaf(t, t, 1.f));
          s = t * c;
        }
        float sm = lower ? -s : s;
#pragma unroll
        for (int r = 0; r < 64; ++r) a[r] = fmaf(sm, o[r], c * a[r]);
#pragma unroll
        for (int r = 0; r < 64; ++r) {
          float ov = __shfl_xor(v[r], mask);
          v[r] = fmaf(sm, ov, c * v[r]);
        }
        // alpha' = c^2 a + s^2 b + sgn*2csg  (sgn = lower ? -1 : +1)
        float twocsg = 2.f * c * s * gamma;
        alpha = fmaf(c * c, alpha, fmaf(s * s, beta, lower ? -twocsg : twocsg));
      }
    }
    if (!sweep_rot) break;
  }

  double sig2 = 0.0;
#pragma unroll
  for (int r = 0; r < 64; ++r) sig2 += (double)a[r] * (double)a[r];
  double smax = sig2;
#pragma unroll
  for (int m = 1; m < 64; m <<= 1) smax = fmax(smax, __shfl_xor(smax, m));
  double cutoff2 = smax * (RCOND_ * RCOND_);
  float w = (sig2 > cutoff2) ? (float)(1.0 / sig2) : 0.f;

  __shared__ float was[64][65];
  __shared__ float vs[64][65];
#pragma unroll
  for (int j = 0; j < 64; ++j) was[lane][j] = w * a[j];
#pragma unroll
  for (int j = 0; j < 64; ++j) vs[lane][j] = v[j];
  __syncthreads();
  float accp[64] = {};
  for (int r = 0; r < 64; ++r) {
    float vv = vs[r][lane];
#pragma unroll
    for (int j = 0; j < 64; ++j) accp[j] = fmaf(vv, was[r][j], accp[j]);
  }
#pragma unroll
  for (int j = 0; j < 64; j += 4) {
    float4 ov = make_float4(accp[j], accp[j + 1], accp[j + 2], accp[j + 3]);
    *(float4*)(pinv + ((size_t)bh * 64 + lane) * 64 + j) = ov;
  }
}

// ---------------------------------------------------------------------------
// ker3+kv partials via MFMA in DEVIATION form.
// S-logits: (qh+ql) hi/lo qland vs bf16 K. P-1 stored bf16; ones*V colsum exact.
__global__ __launch_bounds__(256, 1) void ker3kv_mfma_kernel(
    const unsigned short* __restrict__ qlh,
    const unsigned short* __restrict__ qll,
    const unsigned short* __restrict__ k4,
    const unsigned short* __restrict__ vt,
    float* __restrict__ pacc,    // [bh][part][64][64] dev part
    float* __restrict__ pacc0,   // [bh][part][64] colsum of V over part tokens
    float* __restrict__ ps) {    // [bh][part][64] sum of (P-1)
  int bh = blockIdx.y, ch = blockIdx.x;
  int tid = threadIdx.x, w = tid >> 6, lane = tid & 63;
  int part = ch * 4 + w;
  int lrow = lane & 15, lgrp = lane >> 4;
  __shared__ __align__(16) unsigned short Pl[4][64 * 72];
  unsigned short* myP = &Pl[w][0];

  bf16x8 qah[4][2], qal[4][2];
#pragma unroll
  for (int mf = 0; mf < 4; ++mf)
#pragma unroll
    for (int ks = 0; ks < 2; ++ks) {
      size_t off = ((size_t)bh * 64 + mf * 16 + lrow) * 64 + ks * 32 + lgrp * 8;
      qah[mf][ks] = ld_bf8(qlh + off);
      qal[mf][ks] = ld_bf8(qll + off);
    }
  bf16x8 onesf;
#pragma unroll
  for (int j = 0; j < 8; ++j) onesf[j] = (__bf16)1.0f;

  f32x4 kvacc[4][4] = {};
  f32x4 oneacc[4] = {};
  f32x4 ssum[4] = {};

  for (int sub = 0; sub < 4; ++sub) {
    int n0 = ch * 1024 + w * 256 + sub * 64;
    f32x4 sacc[4][4] = {};
#pragma unroll
    for (int ks = 0; ks < 2; ++ks) {
#pragma unroll
      for (int nf = 0; nf < 4; ++nf) {
        bf16x8 kb = ld_bf8(k4 + ((size_t)bh * N_ + n0 + nf * 16 + lrow) * 64 + ks * 32 + lgrp * 8);
#pragma unroll
        for (int mf = 0; mf < 4; ++mf) {
          sacc[mf][nf] = __builtin_amdgcn_mfma_f32_16x16x32_bf16(qah[mf][ks], kb, sacc[mf][nf], 0, 0, 0);
          sacc[mf][nf] = __builtin_amdgcn_mfma_f32_16x16x32_bf16(qal[mf][ks], kb, sacc[mf][nf], 0, 0, 0);
        }
      }
    }
#pragma unroll
    for (int mf = 0; mf < 4; ++mf) {
#pragma unroll
      for (int nf = 0; nf < 4; ++nf) {
#pragma unroll
        for (int r = 0; r < 4; ++r) {
          float pd = expf(sacc[mf][nf][r]) - 1.0f;   // P - 1, |.| <~ 0.1
          ssum[mf][r] += pd;
          myP[(mf * 16 + lgrp * 4 + r) * 72 + nf * 16 + lrow] = f2bf(pd);
        }
      }
    }
#pragma unroll
    for (int ks = 0; ks < 2; ++ks) {
      bf16x8 pa[4];
#pragma unroll
      for (int mf = 0; mf < 4; ++mf)
        pa[mf] = ld_bf8(myP + (mf * 16 + lrow) * 72 + ks * 32 + lgrp * 8);
#pragma unroll
      for (int nf = 0; nf < 4; ++nf) {
        bf16x8 vb = ld_bf8(vt + ((size_t)bh * 64 + nf * 16 + lrow) * N_ + n0 + ks * 32 + lgrp * 8);
#pragma unroll
        for (int mf = 0; mf < 4; ++mf)
          kvacc[mf][nf] = __builtin_amdgcn_mfma_f32_16x16x32_bf16(pa[mf], vb, kvacc[mf][nf], 0, 0, 0);
        oneacc[nf] = __builtin_amdgcn_mfma_f32_16x16x32_bf16(onesf, vb, oneacc[nf], 0, 0, 0);
      }
    }
  }
#pragma unroll
  for (int mf = 0; mf < 4; ++mf)
#pragma unroll
    for (int m = 1; m < 16; m <<= 1)
#pragma unroll
      for (int r = 0; r < 4; ++r) ssum[mf][r] += __shfl_xor(ssum[mf][r], m);

  size_t pb = (((size_t)bh * NPART_ + part) * 64) * 64;
#pragma unroll
  for (int mf = 0; mf < 4; ++mf)
#pragma unroll
    for (int nf = 0; nf < 4; ++nf)
#pragma unroll
      for (int r = 0; r < 4; ++r)
        pacc[pb + (size_t)(mf * 16 + lgrp * 4 + r) * 64 + nf * 16 + lrow] = kvacc[mf][nf][r];
  if (lrow == 0) {
#pragma unroll
    for (int mf = 0; mf < 4; ++mf)
#pragma unroll
      for (int r = 0; r < 4; ++r)
        ps[((size_t)bh * NPART_ + part) * 64 + mf * 16 + lgrp * 4 + r] = ssum[mf][r];
  }
  if (lgrp == 0) {
#pragma unroll
    for (int nf = 0; nf < 4; ++nf)
      pacc0[((size_t)bh * NPART_ + part) * 64 + nf * 16 + lrow] = oneacc[nf][0];
  }
}

// ---------------------------------------------------------------------------
// kv = (colsumV + sum dev partials) / (16384 + sum (P-1)). Grid (4, BH_).
__global__ __launch_bounds__(256) void kv_combine_kernel(const float* __restrict__ pacc,
                                                         const float* __restrict__ pacc0,
                                                         const float* __restrict__ ps,
                                                         float* __restrict__ kv) {
  int bh = blockIdx.y;
  int lm = blockIdx.x * 16 + (threadIdx.x >> 4);
  int d4 = (threadIdx.x & 15) * 4;
  float s = 16384.f;
  for (int part = 0; part < NPART_; ++part) s += ps[((size_t)bh * NPART_ + part) * 64 + lm];
  float4 a = make_float4(0.f, 0.f, 0.f, 0.f);
  for (int part = 0; part < NPART_; ++part) {
    float4 c0 = *(const float4*)&pacc0[((size_t)bh * NPART_ + part) * 64 + d4];
    float4 v = *(const float4*)&pacc[(((size_t)bh * NPART_ + part) * 64 + lm) * 64 + d4];
    a.x += c0.x + v.x; a.y += c0.y + v.y; a.z += c0.z + v.z; a.w += c0.w + v.w;
  }
  float inv = 1.f / s;
  float4 o = make_float4(a.x * inv, a.y * inv, a.z * inv, a.w * inv);
  *(float4*)(kv + ((size_t)bh * 64 + lm) * 64 + d4) = o;
}

// ---------------------------------------------------------------------------
// M = pinv @ kv (fp64) -> bf16 hi/lo transposed Mt[d][l], plus exact
// msum[d] = (1/64) sum_l M[l][d] (f64 via pinv column sums).
__global__ __launch_bounds__(256) void mmat_kernel(const float* __restrict__ pinv,
                                                   const float* __restrict__ kv,
                                                   unsigned short* __restrict__ mtbh,
                                                   unsigned short* __restrict__ mtbl,
                                                   float* __restrict__ msum) {
  int bh = blockIdx.x;
  int tid = threadIdx.x;
  __shared__ float kvs[64][68];
  __shared__ double pcsd[64];
  for (int i = 0; i < 4; ++i) {
    int s = tid + i * 256;
    int r = s >> 4, d4 = (s & 15) << 2;
    *(float4*)&kvs[r][d4] = *(const float4*)(kv + ((size_t)bh * 64 + r) * 64 + d4);
  }
  if (tid < 64) {
    double s = 0.0;
    for (int l = 0; l < 64; ++l) s += (double)pinv[((size_t)bh * 64 + l) * 64 + tid];
    pcsd[tid] = s;
  }
  __syncthreads();
  int l = tid >> 2, t = tid & 3;
  double o[16] = {};
  for (int j = 0; j < 64; ++j) {
    double pv = (double)pinv[((size_t)bh * 64 + l) * 64 + j];
#pragma unroll
    for (int i = 0; i < 16; ++i) o[i] += pv * (double)kvs[j][t * 16 + i];
  }
#pragma unroll
  for (int i = 0; i < 16; ++i) {
    float f = (float)o[i];
    unsigned short hi = f2bf(f);
    float lo = f - bf2f(hi);
    int d = t * 16 + i;
    mtbh[((size_t)bh * 64 + d) * 64 + l] = hi;
    mtbl[((size_t)bh * 64 + d) * 64 + l] = f2bf(lo);
  }
  if (tid < 64) {
    double m = 0.0;
    for (int j = 0; j < 64; ++j) m += pcsd[j] * (double)kvs[j][tid];
    msum[(size_t)bh * 64 + tid] = (float)(m * (1.0 / 64.0));
  }
}

// ---------------------------------------------------------------------------
// out_heads = softmax(q kl^T) @ M via MFMA, deviation form:
// out = msum[d] + sum_l (P/S - 1/64) * M[l][d].  Writes bf16 outh (B,N,C).
__global__ __launch_bounds__(256, 1) void ker1out_mfma_kernel(
    const unsigned short* __restrict__ q4,
    const unsigned short* __restrict__ klb,
    const unsigned short* __restrict__ mtbh,
    const unsigned short* __restrict__ mtbl,
    const float* __restrict__ msum,
    unsigned short* __restrict__ outh) {
  int bh = blockIdx.y, tile = blockIdx.x;
  int b = bh >> 3, h = bh & 7;
  int tid = threadIdx.x, w = tid >> 6, lane = tid & 63;
  int lrow = lane & 15, lgrp = lane >> 4;
  int tok0 = tile * 256 + w * 64;
  __shared__ __align__(16) unsigned short Pl[4][64 * 72];
  unsigned short* myP = &Pl[w][0];

  f32x4 sacc[4][4] = {};
#pragma unroll
  for (int ks = 0; ks < 2; ++ks) {
    bf16x8 kb[4];
#pragma unroll
    for (int nf = 0; nf < 4; ++nf)
      kb[nf] = ld_bf8(klb + ((size_t)bh * 64 + nf * 16 + lrow) * 64 + ks * 32 + lgrp * 8);
#pragma unroll
    for (int mf = 0; mf < 4; ++mf) {
      bf16x8 qa = ld_bf8(q4 + ((size_t)bh * N_ + tok0 + mf * 16 + lrow) * 64 + ks * 32 + lgrp * 8);
#pragma unroll
      for (int nf = 0; nf < 4; ++nf)
        sacc[mf][nf] = __builtin_amdgcn_mfma_f32_16x16x32_bf16(qa, kb[nf], sacc[mf][nf], 0, 0, 0);
    }
  }
  f32x4 ssum[4] = {};
#pragma unroll
  for (int mf = 0; mf < 4; ++mf)
#pragma unroll
    for (int nf = 0; nf < 4; ++nf)
#pragma unroll
      for (int r = 0; r < 4; ++r) {
        sacc[mf][nf][r] = expf(sacc[mf][nf][r]);
        ssum[mf][r] += sacc[mf][nf][r];
      }
#pragma unroll
  for (int mf = 0; mf < 4; ++mf)
#pragma unroll
    for (int m = 1; m < 16; m <<= 1)
#pragma unroll
      for (int r = 0; r < 4; ++r) ssum[mf][r] += __shfl_xor(ssum[mf][r], m);
#pragma unroll
  for (int mf = 0; mf < 4; ++mf) {
    f32x4 inv;
#pragma unroll
    for (int r = 0; r < 4; ++r) inv[r] = 1.f / ssum[mf][r];
#pragma unroll
    for (int nf = 0; nf < 4; ++nf)
#pragma unroll
      for (int r = 0; r < 4; ++r) {
        float pdev = fmaf(sacc[mf][nf][r], inv[r], -0.015625f);  // P/S - 1/64
        myP[(mf * 16 + lgrp * 4 + r) * 72 + nf * 16 + lrow] = f2bf(pdev);
      }
  }

  f32x4 oacc[4][4] = {};
#pragma unroll
  for (int ks = 0; ks < 2; ++ks) {
    bf16x8 pa[4];
#pragma unroll
    for (int mf = 0; mf < 4; ++mf)
      pa[mf] = ld_bf8(myP + (mf * 16 + lrow) * 72 + ks * 32 + lgrp * 8);
#pragma unroll
    for (int nf = 0; nf < 4; ++nf) {
      bf16x8 mh = ld_bf8(mtbh + ((size_t)bh * 64 + nf * 16 + lrow) * 64 + ks * 32 + lgrp * 8);
      bf16x8 ml = ld_bf8(mtbl + ((size_t)bh * 64 + nf * 16 + lrow) * 64 + ks * 32 + lgrp * 8);
#pragma unroll
      for (int mf = 0; mf < 4; ++mf) {
        oacc[mf][nf] = __builtin_amdgcn_mfma_f32_16x16x32_bf16(pa[mf], mh, oacc[mf][nf], 0, 0, 0);
        oacc[mf][nf] = __builtin_amdgcn_mfma_f32_16x16x32_bf16(pa[mf], ml, oacc[mf][nf], 0, 0, 0);
      }
    }
  }
#pragma unroll
  for (int nf = 0; nf < 4; ++nf) {
    float ms = msum[(size_t)bh * 64 + nf * 16 + lrow];
#pragma unroll
    for (int mf = 0; mf < 4; ++mf)
#pragma unroll
      for (int r = 0; r < 4; ++r) {
        int tok = tok0 + mf * 16 + lgrp * 4 + r;
        int d = nf * 16 + lrow;
        outh[((size_t)b * N_ + tok) * C_ + h * HD_ + d] = f2bf(oacc[mf][nf][r] + ms);
      }
  }
}

// ---------------------------------------------------------------------------
extern "C" void kernel_launch(void* const* d_in, const int* in_sizes, int n_in,
                              void* d_out, int out_size, void* d_ws, size_t ws_size,
                              hipStream_t stream) {
  const float* x  = (const float*)d_in[0];
  const float* wq = (const float*)d_in[1];
  const float* bq = (const float*)d_in[2];
  const float* wk = (const float*)d_in[3];
  const float* bk = (const float*)d_in[4];
  const float* wv = (const float*)d_in[5];
  const float* bv = (const float*)d_in[6];
  const float* wo = (const float*)d_in[7];
  const float* bo = (const float*)d_in[8];
  float* out = (float*)d_out;

  char* base = (char*)d_ws;
  const size_t QKV = (size_t)BH_ * N_ * HD_;   // 16,777,216 elems
  unsigned short* q4 = (unsigned short*)base;                 // 32MB
  unsigned short* k4 = (unsigned short*)(base + QKV * 2);     // 32MB
  unsigned short* vt = (unsigned short*)(base + QKV * 4);     // 32MB
  unsigned short* outh = (unsigned short*)(base + QKV * 2);   // alias k4 (dead after ker3kv)
  char* sp = base + QKV * 6;
  float* pacc  = (float*)sp; sp += (size_t)BH_ * NPART_ * 64 * 64 * 4;  // 16.78MB
  float* pacc0 = (float*)sp; sp += (size_t)BH_ * NPART_ * 64 * 4;
  float* ps    = (float*)sp; sp += (size_t)BH_ * NPART_ * 64 * 4;
  unsigned short* wqb = (unsigned short*)sp; sp += (size_t)C_ * C_ * 2;
  unsigned short* wkb = (unsigned short*)sp; sp += (size_t)C_ * C_ * 2;
  unsigned short* wvb = (unsigned short*)sp; sp += (size_t)C_ * C_ * 2;
  unsigned short* wob = (unsigned short*)sp; sp += (size_t)C_ * C_ * 2;
  float* xbar  = (float*)sp; sp += (size_t)B_ * LM_ * C_ * 4;
  float* qland = (float*)sp; sp += (size_t)BH_ * LM_ * HD_ * 4;
  float* kland = (float*)sp; sp += (size_t)BH_ * LM_ * HD_ * 4;
  unsigned short* qlbh = (unsigned short*)sp; sp += (size_t)BH_ * LM_ * HD_ * 2;
  unsigned short* qlbl = (unsigned short*)sp; sp += (size_t)BH_ * LM_ * HD_ * 2;
  unsigned short* klb  = (unsigned short*)sp; sp += (size_t)BH_ * LM_ * HD_ * 2;
  float* ker2  = (float*)sp; sp += (size_t)BH_ * LM_ * LM_ * 4;
  float* pinv  = (float*)sp; sp += (size_t)BH_ * LM_ * LM_ * 4;
  float* kvb   = (float*)sp; sp += (size_t)BH_ * LM_ * HD_ * 4;
  unsigned short* mtbh = (unsigned short*)sp; sp += (size_t)BH_ * LM_ * HD_ * 2;
  unsigned short* mtbl = (unsigned short*)sp; sp += (size_t)BH_ * LM_ * HD_ * 2;
  float* msum  = (float*)sp; sp += (size_t)BH_ * HD_ * 4;

  const float scaleq = 0.125f;
  const int W8 = (C_ * C_) / 8;
  const int L = BH_ * LM_ * HD_;
  const int L8 = L / 8;

  cvt_bf16_kernel<<<W8 / 256, 256, 0, stream>>>(wq, wqb, W8);
  cvt_bf16_kernel<<<W8 / 256, 256, 0, stream>>>(wk, wkb, W8);
  cvt_bf16_kernel<<<W8 / 256, 256, 0, stream>>>(wv, wvb, W8);
  cvt_bf16_kernel<<<W8 / 256, 256, 0, stream>>>(wo, wob, W8);

  // landmark path (f32-exact)
  seg_mean_kernel<<<B_ * LM_, 256, 0, stream>>>(x, xbar);
  dim3 gl(2, 8);
  gemm_nt_kernel<<<gl, 256, 0, stream>>>(xbar, wq, bq, qland, scaleq, LM_);
  gemm_nt_kernel<<<gl, 256, 0, stream>>>(xbar, wk, bk, kland, 1.0f, LM_);
  cvt_bf16_pair_kernel<<<L / 256, 256, 0, stream>>>(qland, qlbh, qlbl, L);
  cvt_bf16_kernel<<<L8 / 256, 256, 0, stream>>>(kland, klb, L8);
  ker2_kernel<<<BH_, 64, 0, stream>>>(qland, kland, ker2);
  svd_pinv_kernel<<<BH_, 64, 0, stream>>>(ker2, pinv);

  // projections
  dim3 gp(B_ * N_ / 128, C_ / 128);
  mfma_gemm_kernel<<<gp, 256, 0, stream>>>(x, wqb, bq, q4, scaleq, 0, 1);
  mfma_gemm_kernel<<<gp, 256, 0, stream>>>(x, wkb, bk, k4, 1.0f, 0, 1);
  mfma_gemm_kernel<<<gp, 256, 0, stream>>>(x, wvb, bv, vt, 1.0f, 0, 2);

  // ker3 + kv (MFMA, deviation form)
  dim3 g6(NCH_, BH_);
  ker3kv_mfma_kernel<<<g6, 256, 0, stream>>>(qlbh, qlbl, k4, vt, pacc, pacc0, ps);
  dim3 g7(4, BH_);
  kv_combine_kernel<<<g7, 256, 0, stream>>>(pacc, pacc0, ps, kvb);
  mmat_kernel<<<BH_, 256, 0, stream>>>(pinv, kvb, mtbh, mtbl, msum);

  // out_heads (MFMA, deviation form) -> bf16 outh (aliases dead k4)
  dim3 g9(N_ / 256, BH_);
  ker1out_mfma_kernel<<<g9, 256, 0, stream>>>(q4, klb, mtbh, mtbl, msum, outh);

  // final projection (bf16 A) -> f32 out
  mfma_gemm_kernel<<<gp, 256, 0, stream>>>(outh, wob, bo, out, 1.0f, 1, 0);
}

// Round 7
// 733.210 us; speedup vs baseline: 4.7571x; 1.5675x over previous
//
#include <hip/hip_runtime.h>
#include <stdint.h>

// NystromAttention MI355X — Round 7: 4-wave row-split Jacobi SVD (a[16]/v[16]
// per thread, intra-wave shuffles, 1 barrier/rotation, fp64 sigma/cutoff).
// Rest identical to round 6 (passed, absmax 6.1e-5).

constexpr int B_   = 2;
constexpr int N_   = 16384;
constexpr int C_   = 512;
constexpr int H_   = 8;
constexpr int HD_  = 64;
constexpr int LM_  = 64;
constexpr int SEG_ = 256;
constexpr int BH_  = 16;
constexpr int NCH_ = 16;     // ker3kv chunks; 4 waves/chunk -> 64 partials per bh
constexpr int NPART_ = 64;
constexpr int NSWEEP_ = 8;   // max Jacobi sweeps (early exit when converged)

#define RCOND_ (640.0 * 1.1920928955078125e-07)

typedef unsigned short ushort4_t __attribute__((ext_vector_type(4)));
typedef unsigned short ushort8_t __attribute__((ext_vector_type(8)));
typedef __bf16 bf16x8 __attribute__((ext_vector_type(8)));
typedef float f32x4 __attribute__((ext_vector_type(4)));

__device__ inline float bf2f(unsigned short u) {
  union { unsigned int i; float f; } x; x.i = ((unsigned int)u) << 16; return x.f;
}
__device__ inline unsigned short f2bf(float f) {
  union { float f; unsigned int i; } x; x.f = f;
  unsigned int lsb = (x.i >> 16) & 1;
  return (unsigned short)((x.i + 0x7fffu + lsb) >> 16);
}
__device__ inline bf16x8 ld_bf8(const unsigned short* p) { return *(const bf16x8*)p; }

// ---------------------------------------------------------------------------
__global__ __launch_bounds__(256) void cvt_bf16_kernel(const float* __restrict__ src,
                                                       unsigned short* __restrict__ dst,
                                                       int n8) {
  int i = (blockIdx.x * 256 + threadIdx.x);
  if (i >= n8) return;
  const float* s = src + (size_t)i * 8;
  float4 x0 = *(const float4*)(s);
  float4 x1 = *(const float4*)(s + 4);
  ushort8_t u;
  u[0] = f2bf(x0.x); u[1] = f2bf(x0.y); u[2] = f2bf(x0.z); u[3] = f2bf(x0.w);
  u[4] = f2bf(x1.x); u[5] = f2bf(x1.y); u[6] = f2bf(x1.z); u[7] = f2bf(x1.w);
  *(ushort8_t*)(dst + (size_t)i * 8) = u;
}

// f32 -> bf16 hi/lo pair
__global__ __launch_bounds__(256) void cvt_bf16_pair_kernel(const float* __restrict__ src,
                                                            unsigned short* __restrict__ hi,
                                                            unsigned short* __restrict__ lo,
                                                            int n) {
  int i = blockIdx.x * 256 + threadIdx.x;
  if (i >= n) return;
  float f = src[i];
  unsigned short h = f2bf(f);
  float rem = f - bf2f(h);
  hi[i] = h; lo[i] = f2bf(rem);
}

// ---------------------------------------------------------------------------
__global__ __launch_bounds__(256) void seg_mean_kernel(const float* __restrict__ x,
                                                       float* __restrict__ xbar) {
  int bl = blockIdx.x;
  int b = bl / LM_, l = bl % LM_;
  int t = threadIdx.x;
  int c4 = t & 127;
  int rh = t >> 7;
  const float* xp = x + ((size_t)b * N_ + (size_t)l * SEG_) * C_;
  float4 s = make_float4(0.f, 0.f, 0.f, 0.f);
  for (int r = rh * 128; r < rh * 128 + 128; ++r) {
    float4 v = *(const float4*)(xp + (size_t)r * C_ + c4 * 4);
    s.x += v.x; s.y += v.y; s.z += v.z; s.w += v.w;
  }
  __shared__ float red[2][512];
  *(float4*)&red[rh][c4 * 4] = s;
  __syncthreads();
  if (rh == 0) {
    float4 a = *(float4*)&red[0][c4 * 4];
    float4 c = *(float4*)&red[1][c4 * 4];
    const float invs = 1.0f / SEG_;
    float4 o;
    o.x = (a.x + c.x) * invs; o.y = (a.y + c.y) * invs;
    o.z = (a.z + c.z) * invs; o.w = (a.w + c.w) * invs;
    *(float4*)(xbar + (size_t)bl * C_ + c4 * 4) = o;
  }
}

// ---------------------------------------------------------------------------
// f32 VALU GEMM for landmark projections (128 rows): f32 head-split out.
__global__ __launch_bounds__(256) void gemm_nt_kernel(const float* __restrict__ A,
                                                      const float* __restrict__ W,
                                                      const float* __restrict__ bias,
                                                      float* __restrict__ out,
                                                      float scale, int rpb) {
  __shared__ float As[32][68];
  __shared__ float Ws[32][68];
  int row0 = blockIdx.x * 64;
  int col0 = blockIdx.y * 64;
  int tid = threadIdx.x;
  int tm = tid >> 4, tn = tid & 15;
  float acc[4][4] = {};
  for (int k0 = 0; k0 < C_; k0 += 32) {
#pragma unroll
    for (int i = 0; i < 2; ++i) {
      int s = tid + i * 256;
      int r = s >> 3;
      int kg = (s & 7) << 2;
      float4 av = *(const float4*)(A + (size_t)(row0 + r) * C_ + k0 + kg);
      As[kg + 0][r] = av.x; As[kg + 1][r] = av.y;
      As[kg + 2][r] = av.z; As[kg + 3][r] = av.w;
      float4 wv = *(const float4*)(W + (size_t)(col0 + r) * C_ + k0 + kg);
      Ws[kg + 0][r] = wv.x; Ws[kg + 1][r] = wv.y;
      Ws[kg + 2][r] = wv.z; Ws[kg + 3][r] = wv.w;
    }
    __syncthreads();
#pragma unroll
    for (int kk = 0; kk < 32; ++kk) {
      float4 a = *(const float4*)&As[kk][tm * 4];
      float4 b = *(const float4*)&Ws[kk][tn * 4];
      float av[4] = {a.x, a.y, a.z, a.w};
      float bv[4] = {b.x, b.y, b.z, b.w};
#pragma unroll
      for (int i = 0; i < 4; ++i)
#pragma unroll
        for (int j = 0; j < 4; ++j) acc[i][j] += av[i] * bv[j];
    }
    __syncthreads();
  }
#pragma unroll
  for (int i = 0; i < 4; ++i) {
    int row = row0 + tm * 4 + i;
    int d0 = tn * 4;
    float o4[4];
#pragma unroll
    for (int j = 0; j < 4; ++j) o4[j] = (acc[i][j] + bias[col0 + d0 + j]) * scale;
    int b = row / rpb, n = row % rpb;
    int h = col0 >> 6;
    size_t idx = (((size_t)(b * H_ + h) * rpb) + n) * HD_ + d0;
    float4 o; o.x = o4[0]; o.y = o4[1]; o.z = o4[2]; o.w = o4[3];
    *(float4*)(out + idx) = o;
  }
}

// ---------------------------------------------------------------------------
// MFMA GEMM: out = A(Mx512) @ Wb^T(bf16 512x512) + bias, scale.
// amode 0: A f32; amode 1: A bf16.
// omode 0: f32 out[row][col]; omode 1: bf16 head-split; omode 2: bf16 vt.
__global__ __launch_bounds__(256) void mfma_gemm_kernel(const void* __restrict__ A,
                                                        const unsigned short* __restrict__ Wb,
                                                        const float* __restrict__ bias,
                                                        void* __restrict__ out,
                                                        float scale, int amode, int omode) {
  __shared__ __align__(16) unsigned short Xs[128 * 32];
  __shared__ __align__(16) unsigned short Ws[128 * 32];
  int tid = threadIdx.x;
  int wid = tid >> 6, lane = tid & 63;
  int wr = wid >> 1, wc = wid & 1;
  int row0 = blockIdx.x * 128, col0 = blockIdx.y * 128;
  f32x4 acc[4][4] = {};

  int srow = tid >> 1;               // 0..127
  int sk = (tid & 1) * 16;           // 0 or 16
  const unsigned short* wpbase = Wb + (size_t)(col0 + srow) * C_ + sk;
  unsigned short* xdst = &Xs[srow * 32 + sk];
  unsigned short* wdst = &Ws[srow * 32 + sk];

  for (int k0 = 0; k0 < C_; k0 += 32) {
    __syncthreads();
    if (amode == 0) {
      const float* apbase = (const float*)A + (size_t)(row0 + srow) * C_ + sk;
      float4 x0 = *(const float4*)(apbase + k0);
      float4 x1 = *(const float4*)(apbase + k0 + 4);
      float4 x2 = *(const float4*)(apbase + k0 + 8);
      float4 x3 = *(const float4*)(apbase + k0 + 12);
      ushort8_t u0, u1;
      u0[0] = f2bf(x0.x); u0[1] = f2bf(x0.y); u0[2] = f2bf(x0.z); u0[3] = f2bf(x0.w);
      u0[4] = f2bf(x1.x); u0[5] = f2bf(x1.y); u0[6] = f2bf(x1.z); u0[7] = f2bf(x1.w);
      u1[0] = f2bf(x2.x); u1[1] = f2bf(x2.y); u1[2] = f2bf(x2.z); u1[3] = f2bf(x2.w);
      u1[4] = f2bf(x3.x); u1[5] = f2bf(x3.y); u1[6] = f2bf(x3.z); u1[7] = f2bf(x3.w);
      *(ushort8_t*)(xdst) = u0;
      *(ushort8_t*)(xdst + 8) = u1;
    } else {
      const unsigned short* apbase = (const unsigned short*)A + (size_t)(row0 + srow) * C_ + sk;
      ushort8_t a0 = *(const ushort8_t*)(apbase + k0);
      ushort8_t a1 = *(const ushort8_t*)(apbase + k0 + 8);
      *(ushort8_t*)(xdst) = a0;
      *(ushort8_t*)(xdst + 8) = a1;
    }
    ushort8_t w0 = *(const ushort8_t*)(wpbase + k0);
    ushort8_t w1 = *(const ushort8_t*)(wpbase + k0 + 8);
    *(ushort8_t*)(wdst) = w0;
    *(ushort8_t*)(wdst + 8) = w1;
    __syncthreads();
    bf16x8 af[4], bfr[4];
#pragma unroll
    for (int m = 0; m < 4; ++m)
      af[m] = *(bf16x8*)&Xs[(wr * 64 + m * 16 + (lane & 15)) * 32 + (lane >> 4) * 8];
#pragma unroll
    for (int n = 0; n < 4; ++n)
      bfr[n] = *(bf16x8*)&Ws[(wc * 64 + n * 16 + (lane & 15)) * 32 + (lane >> 4) * 8];
#pragma unroll
    for (int m = 0; m < 4; ++m)
#pragma unroll
      for (int n = 0; n < 4; ++n)
        acc[m][n] = __builtin_amdgcn_mfma_f32_16x16x32_bf16(af[m], bfr[n], acc[m][n], 0, 0, 0);
  }

#pragma unroll
  for (int m = 0; m < 4; ++m) {
    int rbase = row0 + wr * 64 + m * 16 + (lane >> 4) * 4;
#pragma unroll
    for (int n = 0; n < 4; ++n) {
      int c = col0 + wc * 64 + n * 16 + (lane & 15);
      float bc = bias[c];
      if (omode == 2) {
        int b = rbase >> 14, nn = rbase & 16383;
        int h = c >> 6, d = c & 63;
        ushort4_t u;
#pragma unroll
        for (int rg = 0; rg < 4; ++rg) u[rg] = f2bf((acc[m][n][rg] + bc) * scale);
        *(ushort4_t*)((unsigned short*)out + ((size_t)(b * H_ + h) * HD_ + d) * N_ + nn) = u;
      } else {
#pragma unroll
        for (int rg = 0; rg < 4; ++rg) {
          float val = (acc[m][n][rg] + bc) * scale;
          int r = rbase + rg;
          if (omode == 0) {
            ((float*)out)[(size_t)r * C_ + c] = val;
          } else {
            int b = r >> 14, nn = r & 16383, h = c >> 6, d = c & 63;
            ((unsigned short*)out)[(((size_t)(b * H_ + h) * N_) + nn) * HD_ + d] = f2bf(val);
          }
        }
      }
    }
  }
}

// ---------------------------------------------------------------------------
__global__ __launch_bounds__(64) void ker2_kernel(const float* __restrict__ qland,
                                                  const float* __restrict__ kland,
                                                  float* __restrict__ ker2) {
  int bh = blockIdx.x;
  __shared__ float kl[64][68];
  __shared__ float ql[64][68];
  int t = threadIdx.x;
  for (int i = 0; i < 16; ++i) {
    int s = t + i * 64;
    int r = s >> 4, d4 = (s & 15) << 2;
    *(float4*)&kl[r][d4] = *(const float4*)(kland + ((size_t)bh * 64 + r) * 64 + d4);
    *(float4*)&ql[r][d4] = *(const float4*)(qland + ((size_t)bh * 64 + r) * 64 + d4);
  }
  __syncthreads();
  float z[64];
  float se = 0.f;
  for (int j = 0; j < 64; ++j) {
    float acc = 0.f;
#pragma unroll
    for (int d4 = 0; d4 < 64; d4 += 4) {
      float4 qv = *(float4*)&ql[t][d4];
      float4 kv = *(float4*)&kl[j][d4];
      acc += qv.x * kv.x + qv.y * kv.y + qv.z * kv.z + qv.w * kv.w;
    }
    z[j] = expf(acc);
    se += z[j];
  }
  float inv = 1.0f / se;
  for (int j4 = 0; j4 < 64; j4 += 4) {
    float4 o = make_float4(z[j4] * inv, z[j4 + 1] * inv, z[j4 + 2] * inv, z[j4 + 3] * inv);
    *(float4*)(ker2 + ((size_t)bh * 64 + t) * 64 + j4) = o;
  }
}

// ---------------------------------------------------------------------------
// 4-wave row-split one-sided Jacobi SVD + rcond-truncated pinv.
// 256 threads: wave w owns rows 16w..16w+15; lane = column. Partner columns
// fetched by intra-wave shfl_xor; gamma via LDS 4-way reduce (1 barrier/rot).
__global__ __launch_bounds__(256, 1) void svd_pinv_kernel(const float* __restrict__ ker2,
                                                          float* __restrict__ pinv) {
  int bh = blockIdx.x;
  int tid = threadIdx.x;
  int w = tid >> 6, lane = tid & 63;
  __shared__ float pg[2][4][64];    // gamma partials, double-buffered
  __shared__ float pa4[4][64];      // alpha partials
  __shared__ double ps2[4][64];     // sigma^2 partials (fp64)
  __shared__ float vsL[64][65];     // V columns
  __shared__ float wasL[64][65];    // w * B columns

  float a[16], v[16];
#pragma unroll
  for (int k = 0; k < 16; ++k)
    a[k] = ker2[((size_t)bh * 64 + w * 16 + k) * 64 + lane];
#pragma unroll
  for (int k = 0; k < 16; ++k) v[k] = (w * 16 + k == lane) ? 1.f : 0.f;

  for (int sweep = 0; sweep < NSWEEP_; ++sweep) {
    float p0 = 0.f, p1 = 0.f;
#pragma unroll
    for (int k = 0; k < 16; k += 2) { p0 = fmaf(a[k], a[k], p0); p1 = fmaf(a[k + 1], a[k + 1], p1); }
    pa4[w][lane] = p0 + p1;
    __syncthreads();
    float alpha = (pa4[0][lane] + pa4[1][lane]) + (pa4[2][lane] + pa4[3][lane]);
    bool sweep_rot = false;
    for (int mask = 1; mask < 64; ++mask) {
      int buf = mask & 1;
      bool lower = lane < (lane ^ mask);
      float o[16], ov[16];
#pragma unroll
      for (int k = 0; k < 16; ++k) o[k] = __shfl_xor(a[k], mask);
#pragma unroll
      for (int k = 0; k < 16; ++k) ov[k] = __shfl_xor(v[k], mask);
      float g0 = 0.f, g1 = 0.f;
#pragma unroll
      for (int k = 0; k < 16; k += 2) { g0 = fmaf(a[k], o[k], g0); g1 = fmaf(a[k + 1], o[k + 1], g1); }
      pg[buf][w][lane] = g0 + g1;
      __syncthreads();
      float gamma = (pg[buf][0][lane] + pg[buf][1][lane]) + (pg[buf][2][lane] + pg[buf][3][lane]);
      float beta = __shfl_xor(alpha, mask);
      bool need = (gamma * gamma > 1e-14f * alpha * beta);
      if (__any(need)) {
        sweep_rot = true;
        float ap = lower ? alpha : beta;
        float aq = lower ? beta : alpha;
        float c = 1.f, s = 0.f;
        if (need) {
          float tau = (aq - ap) / (2.f * gamma);
          float t = copysignf(1.f, tau) / (fabsf(tau) + sqrtf(fmaf(tau, tau, 1.f)));
          c = rsqrtf(fmaf(t, t, 1.f));
          s = t * c;
        }
        float sm = lower ? -s : s;
#pragma unroll
        for (int k = 0; k < 16; ++k) a[k] = fmaf(sm, o[k], c * a[k]);
#pragma unroll
        for (int k = 0; k < 16; ++k) v[k] = fmaf(sm, ov[k], c * v[k]);
        float twocsg = 2.f * c * s * gamma;
        alpha = fmaf(c * c, alpha, fmaf(s * s, beta, lower ? -twocsg : twocsg));
      }
    }
    if (!sweep_rot) break;
  }

  // sigma^2 per column (fp64), max over columns, truncation weight
  double psig = 0.0;
#pragma unroll
  for (int k = 0; k < 16; ++k) psig += (double)a[k] * (double)a[k];
  ps2[w][lane] = psig;
  __syncthreads();
  double sig2 = (ps2[0][lane] + ps2[1][lane]) + (ps2[2][lane] + ps2[3][lane]);
  double smax = sig2;
#pragma unroll
  for (int m = 1; m < 64; m <<= 1) smax = fmax(smax, __shfl_xor(smax, m));
  double cutoff2 = smax * (RCOND_ * RCOND_);
  float wgt = (sig2 > cutoff2) ? (float)(1.0 / sig2) : 0.f;

  // scatter: vsL[col][row] = V[row][col]; wasL[col][row] = w_col * B[row][col]
#pragma unroll
  for (int k = 0; k < 16; ++k) {
    vsL[lane][w * 16 + k] = v[k];
    wasL[lane][w * 16 + k] = wgt * a[k];
  }
  __syncthreads();
  // pinv[i][j] = sum_r V[i][r] * w_r * B[j][r] = sum_r vsL[r][i] * wasL[r][j]
  int i = tid >> 2;
  int j0 = (tid & 3) * 16;
  float acc[16] = {};
  for (int r = 0; r < 64; ++r) {
    float vv = vsL[r][i];
#pragma unroll
    for (int jj = 0; jj < 16; ++jj) acc[jj] = fmaf(vv, wasL[r][j0 + jj], acc[jj]);
  }
#pragma unroll
  for (int jj = 0; jj < 16; jj += 4) {
    float4 ovv = make_float4(acc[jj], acc[jj + 1], acc[jj + 2], acc[jj + 3]);
    *(float4*)(pinv + ((size_t)bh * 64 + i) * 64 + j0 + jj) = ovv;
  }
}

// ---------------------------------------------------------------------------
// ker3+kv partials via MFMA in DEVIATION form.
// S-logits: (qh+ql) hi/lo qland vs bf16 K. P-1 stored bf16; ones*V colsum exact.
__global__ __launch_bounds__(256, 1) void ker3kv_mfma_kernel(
    const unsigned short* __restrict__ qlh,
    const unsigned short* __restrict__ qll,
    const unsigned short* __restrict__ k4,
    const unsigned short* __restrict__ vt,
    float* __restrict__ pacc,    // [bh][part][64][64] dev part
    float* __restrict__ pacc0,   // [bh][part][64] colsum of V over part tokens
    float* __restrict__ ps) {    // [bh][part][64] sum of (P-1)
  int bh = blockIdx.y, ch = blockIdx.x;
  int tid = threadIdx.x, w = tid >> 6, lane = tid & 63;
  int part = ch * 4 + w;
  int lrow = lane & 15, lgrp = lane >> 4;
  __shared__ __align__(16) unsigned short Pl[4][64 * 72];
  unsigned short* myP = &Pl[w][0];

  bf16x8 qah[4][2], qal[4][2];
#pragma unroll
  for (int mf = 0; mf < 4; ++mf)
#pragma unroll
    for (int ks = 0; ks < 2; ++ks) {
      size_t off = ((size_t)bh * 64 + mf * 16 + lrow) * 64 + ks * 32 + lgrp * 8;
      qah[mf][ks] = ld_bf8(qlh + off);
      qal[mf][ks] = ld_bf8(qll + off);
    }
  bf16x8 onesf;
#pragma unroll
  for (int j = 0; j < 8; ++j) onesf[j] = (__bf16)1.0f;

  f32x4 kvacc[4][4] = {};
  f32x4 oneacc[4] = {};
  f32x4 ssum[4] = {};

  for (int sub = 0; sub < 4; ++sub) {
    int n0 = ch * 1024 + w * 256 + sub * 64;
    f32x4 sacc[4][4] = {};
#pragma unroll
    for (int ks = 0; ks < 2; ++ks) {
#pragma unroll
      for (int nf = 0; nf < 4; ++nf) {
        bf16x8 kb = ld_bf8(k4 + ((size_t)bh * N_ + n0 + nf * 16 + lrow) * 64 + ks * 32 + lgrp * 8);
#pragma unroll
        for (int mf = 0; mf < 4; ++mf) {
          sacc[mf][nf] = __builtin_amdgcn_mfma_f32_16x16x32_bf16(qah[mf][ks], kb, sacc[mf][nf], 0, 0, 0);
          sacc[mf][nf] = __builtin_amdgcn_mfma_f32_16x16x32_bf16(qal[mf][ks], kb, sacc[mf][nf], 0, 0, 0);
        }
      }
    }
#pragma unroll
    for (int mf = 0; mf < 4; ++mf) {
#pragma unroll
      for (int nf = 0; nf < 4; ++nf) {
#pragma unroll
        for (int r = 0; r < 4; ++r) {
          float pd = expf(sacc[mf][nf][r]) - 1.0f;   // P - 1, |.| <~ 0.1
          ssum[mf][r] += pd;
          myP[(mf * 16 + lgrp * 4 + r) * 72 + nf * 16 + lrow] = f2bf(pd);
        }
      }
    }
#pragma unroll
    for (int ks = 0; ks < 2; ++ks) {
      bf16x8 pa[4];
#pragma unroll
      for (int mf = 0; mf < 4; ++mf)
        pa[mf] = ld_bf8(myP + (mf * 16 + lrow) * 72 + ks * 32 + lgrp * 8);
#pragma unroll
      for (int nf = 0; nf < 4; ++nf) {
        bf16x8 vb = ld_bf8(vt + ((size_t)bh * 64 + nf * 16 + lrow) * N_ + n0 + ks * 32 + lgrp * 8);
#pragma unroll
        for (int mf = 0; mf < 4; ++mf)
          kvacc[mf][nf] = __builtin_amdgcn_mfma_f32_16x16x32_bf16(pa[mf], vb, kvacc[mf][nf], 0, 0, 0);
        oneacc[nf] = __builtin_amdgcn_mfma_f32_16x16x32_bf16(onesf, vb, oneacc[nf], 0, 0, 0);
      }
    }
  }
#pragma unroll
  for (int mf = 0; mf < 4; ++mf)
#pragma unroll
    for (int m = 1; m < 16; m <<= 1)
#pragma unroll
      for (int r = 0; r < 4; ++r) ssum[mf][r] += __shfl_xor(ssum[mf][r], m);

  size_t pb = (((size_t)bh * NPART_ + part) * 64) * 64;
#pragma unroll
  for (int mf = 0; mf < 4; ++mf)
#pragma unroll
    for (int nf = 0; nf < 4; ++nf)
#pragma unroll
      for (int r = 0; r < 4; ++r)
        pacc[pb + (size_t)(mf * 16 + lgrp * 4 + r) * 64 + nf * 16 + lrow] = kvacc[mf][nf][r];
  if (lrow == 0) {
#pragma unroll
    for (int mf = 0; mf < 4; ++mf)
#pragma unroll
      for (int r = 0; r < 4; ++r)
        ps[((size_t)bh * NPART_ + part) * 64 + mf * 16 + lgrp * 4 + r] = ssum[mf][r];
  }
  if (lgrp == 0) {
#pragma unroll
    for (int nf = 0; nf < 4; ++nf)
      pacc0[((size_t)bh * NPART_ + part) * 64 + nf * 16 + lrow] = oneacc[nf][0];
  }
}

// ---------------------------------------------------------------------------
// kv = (colsumV + sum dev partials) / (16384 + sum (P-1)). Grid (4, BH_).
__global__ __launch_bounds__(256) void kv_combine_kernel(const float* __restrict__ pacc,
                                                         const float* __restrict__ pacc0,
                                                         const float* __restrict__ ps,
                                                         float* __restrict__ kv) {
  int bh = blockIdx.y;
  int lm = blockIdx.x * 16 + (threadIdx.x >> 4);
  int d4 = (threadIdx.x & 15) * 4;
  float s = 16384.f;
  for (int part = 0; part < NPART_; ++part) s += ps[((size_t)bh * NPART_ + part) * 64 + lm];
  float4 a = make_float4(0.f, 0.f, 0.f, 0.f);
  for (int part = 0; part < NPART_; ++part) {
    float4 c0 = *(const float4*)&pacc0[((size_t)bh * NPART_ + part) * 64 + d4];
    float4 v = *(const float4*)&pacc[(((size_t)bh * NPART_ + part) * 64 + lm) * 64 + d4];
    a.x += c0.x + v.x; a.y += c0.y + v.y; a.z += c0.z + v.z; a.w += c0.w + v.w;
  }
  float inv = 1.f / s;
  float4 o = make_float4(a.x * inv, a.y * inv, a.z * inv, a.w * inv);
  *(float4*)(kv + ((size_t)bh * 64 + lm) * 64 + d4) = o;
}

// ---------------------------------------------------------------------------
// M = pinv @ kv (fp64) -> bf16 hi/lo transposed Mt[d][l], plus exact
// msum[d] = (1/64) sum_l M[l][d] (f64 via pinv column sums).
__global__ __launch_bounds__(256) void mmat_kernel(const float* __restrict__ pinv,
                                                   const float* __restrict__ kv,
                                                   unsigned short* __restrict__ mtbh,
                                                   unsigned short* __restrict__ mtbl,
                                                   float* __restrict__ msum) {
  int bh = blockIdx.x;
  int tid = threadIdx.x;
  __shared__ float kvs[64][68];
  __shared__ double pcsd[64];
  for (int i = 0; i < 4; ++i) {
    int s = tid + i * 256;
    int r = s >> 4, d4 = (s & 15) << 2;
    *(float4*)&kvs[r][d4] = *(const float4*)(kv + ((size_t)bh * 64 + r) * 64 + d4);
  }
  if (tid < 64) {
    double s = 0.0;
    for (int l = 0; l < 64; ++l) s += (double)pinv[((size_t)bh * 64 + l) * 64 + tid];
    pcsd[tid] = s;
  }
  __syncthreads();
  int l = tid >> 2, t = tid & 3;
  double o[16] = {};
  for (int j = 0; j < 64; ++j) {
    double pv = (double)pinv[((size_t)bh * 64 + l) * 64 + j];
#pragma unroll
    for (int i = 0; i < 16; ++i) o[i] += pv * (double)kvs[j][t * 16 + i];
  }
#pragma unroll
  for (int i = 0; i < 16; ++i) {
    float f = (float)o[i];
    unsigned short hi = f2bf(f);
    float lo = f - bf2f(hi);
    int d = t * 16 + i;
    mtbh[((size_t)bh * 64 + d) * 64 + l] = hi;
    mtbl[((size_t)bh * 64 + d) * 64 + l] = f2bf(lo);
  }
  if (tid < 64) {
    double m = 0.0;
    for (int j = 0; j < 64; ++j) m += pcsd[j] * (double)kvs[j][tid];
    msum[(size_t)bh * 64 + tid] = (float)(m * (1.0 / 64.0));
  }
}

// ---------------------------------------------------------------------------
// out_heads = softmax(q kl^T) @ M via MFMA, deviation form:
// out = msum[d] + sum_l (P/S - 1/64) * M[l][d].  Writes bf16 outh (B,N,C).
__global__ __launch_bounds__(256, 1) void ker1out_mfma_kernel(
    const unsigned short* __restrict__ q4,
    const unsigned short* __restrict__ klb,
    const unsigned short* __restrict__ mtbh,
    const unsigned short* __restrict__ mtbl,
    const float* __restrict__ msum,
    unsigned short* __restrict__ outh) {
  int bh = blockIdx.y, tile = blockIdx.x;
  int b = bh >> 3, h = bh & 7;
  int tid = threadIdx.x, w = tid >> 6, lane = tid & 63;
  int lrow = lane & 15, lgrp = lane >> 4;
  int tok0 = tile * 256 + w * 64;
  __shared__ __align__(16) unsigned short Pl[4][64 * 72];
  unsigned short* myP = &Pl[w][0];

  f32x4 sacc[4][4] = {};
#pragma unroll
  for (int ks = 0; ks < 2; ++ks) {
    bf16x8 kb[4];
#pragma unroll
    for (int nf = 0; nf < 4; ++nf)
      kb[nf] = ld_bf8(klb + ((size_t)bh * 64 + nf * 16 + lrow) * 64 + ks * 32 + lgrp * 8);
#pragma unroll
    for (int mf = 0; mf < 4; ++mf) {
      bf16x8 qa = ld_bf8(q4 + ((size_t)bh * N_ + tok0 + mf * 16 + lrow) * 64 + ks * 32 + lgrp * 8);
#pragma unroll
      for (int nf = 0; nf < 4; ++nf)
        sacc[mf][nf] = __builtin_amdgcn_mfma_f32_16x16x32_bf16(qa, kb[nf], sacc[mf][nf], 0, 0, 0);
    }
  }
  f32x4 ssum[4] = {};
#pragma unroll
  for (int mf = 0; mf < 4; ++mf)
#pragma unroll
    for (int nf = 0; nf < 4; ++nf)
#pragma unroll
      for (int r = 0; r < 4; ++r) {
        sacc[mf][nf][r] = expf(sacc[mf][nf][r]);
        ssum[mf][r] += sacc[mf][nf][r];
      }
#pragma unroll
  for (int mf = 0; mf < 4; ++mf)
#pragma unroll
    for (int m = 1; m < 16; m <<= 1)
#pragma unroll
      for (int r = 0; r < 4; ++r) ssum[mf][r] += __shfl_xor(ssum[mf][r], m);
#pragma unroll
  for (int mf = 0; mf < 4; ++mf) {
    f32x4 inv;
#pragma unroll
    for (int r = 0; r < 4; ++r) inv[r] = 1.f / ssum[mf][r];
#pragma unroll
    for (int nf = 0; nf < 4; ++nf)
#pragma unroll
      for (int r = 0; r < 4; ++r) {
        float pdev = fmaf(sacc[mf][nf][r], inv[r], -0.015625f);  // P/S - 1/64
        myP[(mf * 16 + lgrp * 4 + r) * 72 + nf * 16 + lrow] = f2bf(pdev);
      }
  }

  f32x4 oacc[4][4] = {};
#pragma unroll
  for (int ks = 0; ks < 2; ++ks) {
    bf16x8 pa[4];
#pragma unroll
    for (int mf = 0; mf < 4; ++mf)
      pa[mf] = ld_bf8(myP + (mf * 16 + lrow) * 72 + ks * 32 + lgrp * 8);
#pragma unroll
    for (int nf = 0; nf < 4; ++nf) {
      bf16x8 mh = ld_bf8(mtbh + ((size_t)bh * 64 + nf * 16 + lrow) * 64 + ks * 32 + lgrp * 8);
      bf16x8 ml = ld_bf8(mtbl + ((size_t)bh * 64 + nf * 16 + lrow) * 64 + ks * 32 + lgrp * 8);
#pragma unroll
      for (int mf = 0; mf < 4; ++mf) {
        oacc[mf][nf] = __builtin_amdgcn_mfma_f32_16x16x32_bf16(pa[mf], mh, oacc[mf][nf], 0, 0, 0);
        oacc[mf][nf] = __builtin_amdgcn_mfma_f32_16x16x32_bf16(pa[mf], ml, oacc[mf][nf], 0, 0, 0);
      }
    }
  }
#pragma unroll
  for (int nf = 0; nf < 4; ++nf) {
    float ms = msum[(size_t)bh * 64 + nf * 16 + lrow];
#pragma unroll
    for (int mf = 0; mf < 4; ++mf)
#pragma unroll
      for (int r = 0; r < 4; ++r) {
        int tok = tok0 + mf * 16 + lgrp * 4 + r;
        int d = nf * 16 + lrow;
        outh[((size_t)b * N_ + tok) * C_ + h * HD_ + d] = f2bf(oacc[mf][nf][r] + ms);
      }
  }
}

// ---------------------------------------------------------------------------
extern "C" void kernel_launch(void* const* d_in, const int* in_sizes, int n_in,
                              void* d_out, int out_size, void* d_ws, size_t ws_size,
                              hipStream_t stream) {
  const float* x  = (const float*)d_in[0];
  const float* wq = (const float*)d_in[1];
  const float* bq = (const float*)d_in[2];
  const float* wk = (const float*)d_in[3];
  const float* bk = (const float*)d_in[4];
  const float* wv = (const float*)d_in[5];
  const float* bv = (const float*)d_in[6];
  const float* wo = (const float*)d_in[7];
  const float* bo = (const float*)d_in[8];
  float* out = (float*)d_out;

  char* base = (char*)d_ws;
  const size_t QKV = (size_t)BH_ * N_ * HD_;   // 16,777,216 elems
  unsigned short* q4 = (unsigned short*)base;                 // 32MB
  unsigned short* k4 = (unsigned short*)(base + QKV * 2);     // 32MB
  unsigned short* vt = (unsigned short*)(base + QKV * 4);     // 32MB
  unsigned short* outh = (unsigned short*)(base + QKV * 2);   // alias k4 (dead after ker3kv)
  char* sp = base + QKV * 6;
  float* pacc  = (float*)sp; sp += (size_t)BH_ * NPART_ * 64 * 64 * 4;  // 16.78MB
  float* pacc0 = (float*)sp; sp += (size_t)BH_ * NPART_ * 64 * 4;
  float* ps    = (float*)sp; sp += (size_t)BH_ * NPART_ * 64 * 4;
  unsigned short* wqb = (unsigned short*)sp; sp += (size_t)C_ * C_ * 2;
  unsigned short* wkb = (unsigned short*)sp; sp += (size_t)C_ * C_ * 2;
  unsigned short* wvb = (unsigned short*)sp; sp += (size_t)C_ * C_ * 2;
  unsigned short* wob = (unsigned short*)sp; sp += (size_t)C_ * C_ * 2;
  float* xbar  = (float*)sp; sp += (size_t)B_ * LM_ * C_ * 4;
  float* qland = (float*)sp; sp += (size_t)BH_ * LM_ * HD_ * 4;
  float* kland = (float*)sp; sp += (size_t)BH_ * LM_ * HD_ * 4;
  unsigned short* qlbh = (unsigned short*)sp; sp += (size_t)BH_ * LM_ * HD_ * 2;
  unsigned short* qlbl = (unsigned short*)sp; sp += (size_t)BH_ * LM_ * HD_ * 2;
  unsigned short* klb  = (unsigned short*)sp; sp += (size_t)BH_ * LM_ * HD_ * 2;
  float* ker2  = (float*)sp; sp += (size_t)BH_ * LM_ * LM_ * 4;
  float* pinv  = (float*)sp; sp += (size_t)BH_ * LM_ * LM_ * 4;
  float* kvb   = (float*)sp; sp += (size_t)BH_ * LM_ * HD_ * 4;
  unsigned short* mtbh = (unsigned short*)sp; sp += (size_t)BH_ * LM_ * HD_ * 2;
  unsigned short* mtbl = (unsigned short*)sp; sp += (size_t)BH_ * LM_ * HD_ * 2;
  float* msum  = (float*)sp; sp += (size_t)BH_ * HD_ * 4;

  const float scaleq = 0.125f;
  const int W8 = (C_ * C_) / 8;
  const int L = BH_ * LM_ * HD_;
  const int L8 = L / 8;

  cvt_bf16_kernel<<<W8 / 256, 256, 0, stream>>>(wq, wqb, W8);
  cvt_bf16_kernel<<<W8 / 256, 256, 0, stream>>>(wk, wkb, W8);
  cvt_bf16_kernel<<<W8 / 256, 256, 0, stream>>>(wv, wvb, W8);
  cvt_bf16_kernel<<<W8 / 256, 256, 0, stream>>>(wo, wob, W8);

  // landmark path (f32-exact)
  seg_mean_kernel<<<B_ * LM_, 256, 0, stream>>>(x, xbar);
  dim3 gl(2, 8);
  gemm_nt_kernel<<<gl, 256, 0, stream>>>(xbar, wq, bq, qland, scaleq, LM_);
  gemm_nt_kernel<<<gl, 256, 0, stream>>>(xbar, wk, bk, kland, 1.0f, LM_);
  cvt_bf16_pair_kernel<<<L / 256, 256, 0, stream>>>(qland, qlbh, qlbl, L);
  cvt_bf16_kernel<<<L8 / 256, 256, 0, stream>>>(kland, klb, L8);
  ker2_kernel<<<BH_, 64, 0, stream>>>(qland, kland, ker2);
  svd_pinv_kernel<<<BH_, 256, 0, stream>>>(ker2, pinv);

  // projections
  dim3 gp(B_ * N_ / 128, C_ / 128);
  mfma_gemm_kernel<<<gp, 256, 0, stream>>>(x, wqb, bq, q4, scaleq, 0, 1);
  mfma_gemm_kernel<<<gp, 256, 0, stream>>>(x, wkb, bk, k4, 1.0f, 0, 1);
  mfma_gemm_kernel<<<gp, 256, 0, stream>>>(x, wvb, bv, vt, 1.0f, 0, 2);

  // ker3 + kv (MFMA, deviation form)
  dim3 g6(NCH_, BH_);
  ker3kv_mfma_kernel<<<g6, 256, 0, stream>>>(qlbh, qlbl, k4, vt, pacc, pacc0, ps);
  dim3 g7(4, BH_);
  kv_combine_kernel<<<g7, 256, 0, stream>>>(pacc, pacc0, ps, kvb);
  mmat_kernel<<<BH_, 256, 0, stream>>>(pinv, kvb, mtbh, mtbl, msum);

  // out_heads (MFMA, deviation form) -> bf16 outh (aliases dead k4)
  dim3 g9(N_ / 256, BH_);
  ker1out_mfma_kernel<<<g9, 256, 0, stream>>>(q4, klb, mtbh, mtbl, msum, outh);

  // final projection (bf16 A) -> f32 out
  mfma_gemm_kernel<<<gp, 256, 0, stream>>>(outh, wob, bo, out, 1.0f, 1, 0);
}

// Round 8
// 649.197 us; speedup vs baseline: 5.3727x; 1.1294x over previous
//
#include <hip/hip_runtime.h>
#include <stdint.h>

// NystromAttention MI355X — Round 8: fuse {q,k,v projections + SVD} into one
// kernel (SVD blocks first -> overlap 337us SVD with ~190us of GEMMs);
// SVD round tweaks (hoisted beta shuffle, ov post-barrier, 1e-12 threshold);
// W converted f32->bf16 in staging (drops 4 cvt kernels).
// Rest identical to round 7 (passed, absmax 6.1e-5).

constexpr int B_   = 2;
constexpr int N_   = 16384;
constexpr int C_   = 512;
constexpr int H_   = 8;
constexpr int HD_  = 64;
constexpr int LM_  = 64;
constexpr int SEG_ = 256;
constexpr int BH_  = 16;
constexpr int NCH_ = 16;
constexpr int NPART_ = 64;
constexpr int NSWEEP_ = 8;

#define RCOND_ (640.0 * 1.1920928955078125e-07)

typedef unsigned short ushort4_t __attribute__((ext_vector_type(4)));
typedef unsigned short ushort8_t __attribute__((ext_vector_type(8)));
typedef __bf16 bf16x8 __attribute__((ext_vector_type(8)));
typedef float f32x4 __attribute__((ext_vector_type(4)));

__device__ inline float bf2f(unsigned short u) {
  union { unsigned int i; float f; } x; x.i = ((unsigned int)u) << 16; return x.f;
}
__device__ inline unsigned short f2bf(float f) {
  union { float f; unsigned int i; } x; x.f = f;
  unsigned int lsb = (x.i >> 16) & 1;
  return (unsigned short)((x.i + 0x7fffu + lsb) >> 16);
}
__device__ inline bf16x8 ld_bf8(const unsigned short* p) { return *(const bf16x8*)p; }

// ---------------------------------------------------------------------------
__global__ __launch_bounds__(256) void cvt_bf16_kernel(const float* __restrict__ src,
                                                       unsigned short* __restrict__ dst,
                                                       int n8) {
  int i = (blockIdx.x * 256 + threadIdx.x);
  if (i >= n8) return;
  const float* s = src + (size_t)i * 8;
  float4 x0 = *(const float4*)(s);
  float4 x1 = *(const float4*)(s + 4);
  ushort8_t u;
  u[0] = f2bf(x0.x); u[1] = f2bf(x0.y); u[2] = f2bf(x0.z); u[3] = f2bf(x0.w);
  u[4] = f2bf(x1.x); u[5] = f2bf(x1.y); u[6] = f2bf(x1.z); u[7] = f2bf(x1.w);
  *(ushort8_t*)(dst + (size_t)i * 8) = u;
}

__global__ __launch_bounds__(256) void cvt_bf16_pair_kernel(const float* __restrict__ src,
                                                            unsigned short* __restrict__ hi,
                                                            unsigned short* __restrict__ lo,
                                                            int n) {
  int i = blockIdx.x * 256 + threadIdx.x;
  if (i >= n) return;
  float f = src[i];
  unsigned short h = f2bf(f);
  float rem = f - bf2f(h);
  hi[i] = h; lo[i] = f2bf(rem);
}

// ---------------------------------------------------------------------------
__global__ __launch_bounds__(256) void seg_mean_kernel(const float* __restrict__ x,
                                                       float* __restrict__ xbar) {
  int bl = blockIdx.x;
  int b = bl / LM_, l = bl % LM_;
  int t = threadIdx.x;
  int c4 = t & 127;
  int rh = t >> 7;
  const float* xp = x + ((size_t)b * N_ + (size_t)l * SEG_) * C_;
  float4 s = make_float4(0.f, 0.f, 0.f, 0.f);
  for (int r = rh * 128; r < rh * 128 + 128; ++r) {
    float4 v = *(const float4*)(xp + (size_t)r * C_ + c4 * 4);
    s.x += v.x; s.y += v.y; s.z += v.z; s.w += v.w;
  }
  __shared__ float red[2][512];
  *(float4*)&red[rh][c4 * 4] = s;
  __syncthreads();
  if (rh == 0) {
    float4 a = *(float4*)&red[0][c4 * 4];
    float4 c = *(float4*)&red[1][c4 * 4];
    const float invs = 1.0f / SEG_;
    float4 o;
    o.x = (a.x + c.x) * invs; o.y = (a.y + c.y) * invs;
    o.z = (a.z + c.z) * invs; o.w = (a.w + c.w) * invs;
    *(float4*)(xbar + (size_t)bl * C_ + c4 * 4) = o;
  }
}

// ---------------------------------------------------------------------------
// f32 VALU GEMM for landmark projections (128 rows): f32 head-split out.
__global__ __launch_bounds__(256) void gemm_nt_kernel(const float* __restrict__ A,
                                                      const float* __restrict__ W,
                                                      const float* __restrict__ bias,
                                                      float* __restrict__ out,
                                                      float scale, int rpb) {
  __shared__ float As[32][68];
  __shared__ float Ws[32][68];
  int row0 = blockIdx.x * 64;
  int col0 = blockIdx.y * 64;
  int tid = threadIdx.x;
  int tm = tid >> 4, tn = tid & 15;
  float acc[4][4] = {};
  for (int k0 = 0; k0 < C_; k0 += 32) {
#pragma unroll
    for (int i = 0; i < 2; ++i) {
      int s = tid + i * 256;
      int r = s >> 3;
      int kg = (s & 7) << 2;
      float4 av = *(const float4*)(A + (size_t)(row0 + r) * C_ + k0 + kg);
      As[kg + 0][r] = av.x; As[kg + 1][r] = av.y;
      As[kg + 2][r] = av.z; As[kg + 3][r] = av.w;
      float4 wv = *(const float4*)(W + (size_t)(col0 + r) * C_ + k0 + kg);
      Ws[kg + 0][r] = wv.x; Ws[kg + 1][r] = wv.y;
      Ws[kg + 2][r] = wv.z; Ws[kg + 3][r] = wv.w;
    }
    __syncthreads();
#pragma unroll
    for (int kk = 0; kk < 32; ++kk) {
      float4 a = *(const float4*)&As[kk][tm * 4];
      float4 b = *(const float4*)&Ws[kk][tn * 4];
      float av[4] = {a.x, a.y, a.z, a.w};
      float bv[4] = {b.x, b.y, b.z, b.w};
#pragma unroll
      for (int i = 0; i < 4; ++i)
#pragma unroll
        for (int j = 0; j < 4; ++j) acc[i][j] += av[i] * bv[j];
    }
    __syncthreads();
  }
#pragma unroll
  for (int i = 0; i < 4; ++i) {
    int row = row0 + tm * 4 + i;
    int d0 = tn * 4;
    float o4[4];
#pragma unroll
    for (int j = 0; j < 4; ++j) o4[j] = (acc[i][j] + bias[col0 + d0 + j]) * scale;
    int b = row / rpb, n = row % rpb;
    int h = col0 >> 6;
    size_t idx = (((size_t)(b * H_ + h) * rpb) + n) * HD_ + d0;
    float4 o; o.x = o4[0]; o.y = o4[1]; o.z = o4[2]; o.w = o4[3];
    *(float4*)(out + idx) = o;
  }
}

// ---------------------------------------------------------------------------
// MFMA GEMM body. A: f32 (amode 0) or bf16 (amode 1). W: f32, converted in
// staging. omode 0: f32 out[row][col]; 1: bf16 head-split; 2: bf16 vt.
__device__ __forceinline__ void mfma_gemm_body(const void* __restrict__ A,
                                               const float* __restrict__ W,
                                               const float* __restrict__ bias,
                                               void* __restrict__ out,
                                               float scale, int amode, int omode,
                                               int row0, int col0,
                                               unsigned short* Xs, unsigned short* Ws,
                                               int tid) {
  int wid = tid >> 6, lane = tid & 63;
  int wr = wid >> 1, wc = wid & 1;
  f32x4 acc[4][4] = {};
  int srow = tid >> 1;               // 0..127
  int sk = (tid & 1) * 16;           // 0 or 16
  const float* wpbase = W + (size_t)(col0 + srow) * C_ + sk;
  unsigned short* xdst = &Xs[srow * 32 + sk];
  unsigned short* wdst = &Ws[srow * 32 + sk];

  for (int k0 = 0; k0 < C_; k0 += 32) {
    __syncthreads();
    if (amode == 0) {
      const float* apbase = (const float*)A + (size_t)(row0 + srow) * C_ + sk;
      float4 x0 = *(const float4*)(apbase + k0);
      float4 x1 = *(const float4*)(apbase + k0 + 4);
      float4 x2 = *(const float4*)(apbase + k0 + 8);
      float4 x3 = *(const float4*)(apbase + k0 + 12);
      ushort8_t u0, u1;
      u0[0] = f2bf(x0.x); u0[1] = f2bf(x0.y); u0[2] = f2bf(x0.z); u0[3] = f2bf(x0.w);
      u0[4] = f2bf(x1.x); u0[5] = f2bf(x1.y); u0[6] = f2bf(x1.z); u0[7] = f2bf(x1.w);
      u1[0] = f2bf(x2.x); u1[1] = f2bf(x2.y); u1[2] = f2bf(x2.z); u1[3] = f2bf(x2.w);
      u1[4] = f2bf(x3.x); u1[5] = f2bf(x3.y); u1[6] = f2bf(x3.z); u1[7] = f2bf(x3.w);
      *(ushort8_t*)(xdst) = u0;
      *(ushort8_t*)(xdst + 8) = u1;
    } else {
      const unsigned short* apbase = (const unsigned short*)A + (size_t)(row0 + srow) * C_ + sk;
      ushort8_t a0 = *(const ushort8_t*)(apbase + k0);
      ushort8_t a1 = *(const ushort8_t*)(apbase + k0 + 8);
      *(ushort8_t*)(xdst) = a0;
      *(ushort8_t*)(xdst + 8) = a1;
    }
    {
      float4 w0 = *(const float4*)(wpbase + k0);
      float4 w1 = *(const float4*)(wpbase + k0 + 4);
      float4 w2 = *(const float4*)(wpbase + k0 + 8);
      float4 w3 = *(const float4*)(wpbase + k0 + 12);
      ushort8_t u0, u1;
      u0[0] = f2bf(w0.x); u0[1] = f2bf(w0.y); u0[2] = f2bf(w0.z); u0[3] = f2bf(w0.w);
      u0[4] = f2bf(w1.x); u0[5] = f2bf(w1.y); u0[6] = f2bf(w1.z); u0[7] = f2bf(w1.w);
      u1[0] = f2bf(w2.x); u1[1] = f2bf(w2.y); u1[2] = f2bf(w2.z); u1[3] = f2bf(w2.w);
      u1[4] = f2bf(w3.x); u1[5] = f2bf(w3.y); u1[6] = f2bf(w3.z); u1[7] = f2bf(w3.w);
      *(ushort8_t*)(wdst) = u0;
      *(ushort8_t*)(wdst + 8) = u1;
    }
    __syncthreads();
    bf16x8 af[4], bfr[4];
#pragma unroll
    for (int m = 0; m < 4; ++m)
      af[m] = *(bf16x8*)&Xs[(wr * 64 + m * 16 + (lane & 15)) * 32 + (lane >> 4) * 8];
#pragma unroll
    for (int n = 0; n < 4; ++n)
      bfr[n] = *(bf16x8*)&Ws[(wc * 64 + n * 16 + (lane & 15)) * 32 + (lane >> 4) * 8];
#pragma unroll
    for (int m = 0; m < 4; ++m)
#pragma unroll
      for (int n = 0; n < 4; ++n)
        acc[m][n] = __builtin_amdgcn_mfma_f32_16x16x32_bf16(af[m], bfr[n], acc[m][n], 0, 0, 0);
  }

#pragma unroll
  for (int m = 0; m < 4; ++m) {
    int rbase = row0 + wr * 64 + m * 16 + (lane >> 4) * 4;
#pragma unroll
    for (int n = 0; n < 4; ++n) {
      int c = col0 + wc * 64 + n * 16 + (lane & 15);
      float bc = bias[c];
      if (omode == 2) {
        int b = rbase >> 14, nn = rbase & 16383;
        int h = c >> 6, d = c & 63;
        ushort4_t u;
#pragma unroll
        for (int rg = 0; rg < 4; ++rg) u[rg] = f2bf((acc[m][n][rg] + bc) * scale);
        *(ushort4_t*)((unsigned short*)out + ((size_t)(b * H_ + h) * HD_ + d) * N_ + nn) = u;
      } else {
#pragma unroll
        for (int rg = 0; rg < 4; ++rg) {
          float val = (acc[m][n][rg] + bc) * scale;
          int r = rbase + rg;
          if (omode == 0) {
            ((float*)out)[(size_t)r * C_ + c] = val;
          } else {
            int b = r >> 14, nn = r & 16383, h = c >> 6, d = c & 63;
            ((unsigned short*)out)[(((size_t)(b * H_ + h) * N_) + nn) * HD_ + d] = f2bf(val);
          }
        }
      }
    }
  }
}

// ---------------------------------------------------------------------------
// 4-wave row-split Jacobi SVD body (see R7), tuned:
//  - beta shuffle hoisted to round start (off the post-barrier critical path)
//  - ov shuffles moved after the barrier (overlap c/s transcendentals)
//  - rotation threshold 1e-12 (cos<=1e-6): early exit can fire
__device__ void svd_body(const float* __restrict__ ker2, float* __restrict__ pinv,
                         int bh, char* smemraw, int tid) {
  float (*pg)[4][64] = (float(*)[4][64])(smemraw);          // 2048 B
  float (*pa4)[64]   = (float(*)[64])(smemraw + 2048);      // 1024 B
  double (*ps2)[64]  = (double(*)[64])(smemraw + 3072);     // 2048 B
  float (*vsL)[65]   = (float(*)[65])(smemraw + 5120);      // 16640 B
  float (*wasL)[65]  = (float(*)[65])(smemraw + 21760);     // 16640 B -> 38400

  int w = tid >> 6, lane = tid & 63;
  float a[16], v[16];
#pragma unroll
  for (int k = 0; k < 16; ++k)
    a[k] = ker2[((size_t)bh * 64 + w * 16 + k) * 64 + lane];
#pragma unroll
  for (int k = 0; k < 16; ++k) v[k] = (w * 16 + k == lane) ? 1.f : 0.f;

  for (int sweep = 0; sweep < NSWEEP_; ++sweep) {
    float p0 = 0.f, p1 = 0.f;
#pragma unroll
    for (int k = 0; k < 16; k += 2) { p0 = fmaf(a[k], a[k], p0); p1 = fmaf(a[k + 1], a[k + 1], p1); }
    pa4[w][lane] = p0 + p1;
    __syncthreads();
    float alpha = (pa4[0][lane] + pa4[1][lane]) + (pa4[2][lane] + pa4[3][lane]);
    bool sweep_rot = false;
    for (int mask = 1; mask < 64; ++mask) {
      int buf = mask & 1;
      bool lower = lane < (lane ^ mask);
      float beta = __shfl_xor(alpha, mask);   // hoisted: issues with o-shuffles
      float o[16];
#pragma unroll
      for (int k = 0; k < 16; ++k) o[k] = __shfl_xor(a[k], mask);
      float g0 = 0.f, g1 = 0.f;
#pragma unroll
      for (int k = 0; k < 16; k += 2) { g0 = fmaf(a[k], o[k], g0); g1 = fmaf(a[k + 1], o[k + 1], g1); }
      pg[buf][w][lane] = g0 + g1;
      __syncthreads();
      float gamma = (pg[buf][0][lane] + pg[buf][1][lane]) + (pg[buf][2][lane] + pg[buf][3][lane]);
      bool need = (gamma * gamma > 1e-12f * alpha * beta);
      if (__any(need)) {
        sweep_rot = true;
        float ov[16];
#pragma unroll
        for (int k = 0; k < 16; ++k) ov[k] = __shfl_xor(v[k], mask);  // overlaps c/s
        float ap = lower ? alpha : beta;
        float aq = lower ? beta : alpha;
        float c = 1.f, s = 0.f;
        if (need) {
          float tau = (aq - ap) / (2.f * gamma);
          float t = copysignf(1.f, tau) / (fabsf(tau) + sqrtf(fmaf(tau, tau, 1.f)));
          c = rsqrtf(fmaf(t, t, 1.f));
          s = t * c;
        }
        float sm = lower ? -s : s;
#pragma unroll
        for (int k = 0; k < 16; ++k) a[k] = fmaf(sm, o[k], c * a[k]);
#pragma unroll
        for (int k = 0; k < 16; ++k) v[k] = fmaf(sm, ov[k], c * v[k]);
        float twocsg = 2.f * c * s * gamma;
        alpha = fmaf(c * c, alpha, fmaf(s * s, beta, lower ? -twocsg : twocsg));
      }
    }
    if (!sweep_rot) break;
  }

  double psig = 0.0;
#pragma unroll
  for (int k = 0; k < 16; ++k) psig += (double)a[k] * (double)a[k];
  ps2[w][lane] = psig;
  __syncthreads();
  double sig2 = (ps2[0][lane] + ps2[1][lane]) + (ps2[2][lane] + ps2[3][lane]);
  double smax = sig2;
#pragma unroll
  for (int m = 1; m < 64; m <<= 1) smax = fmax(smax, __shfl_xor(smax, m));
  double cutoff2 = smax * (RCOND_ * RCOND_);
  float wgt = (sig2 > cutoff2) ? (float)(1.0 / sig2) : 0.f;

#pragma unroll
  for (int k = 0; k < 16; ++k) {
    vsL[lane][w * 16 + k] = v[k];
    wasL[lane][w * 16 + k] = wgt * a[k];
  }
  __syncthreads();
  int i = tid >> 2;
  int j0 = (tid & 3) * 16;
  float acc[16] = {};
  for (int r = 0; r < 64; ++r) {
    float vv = vsL[r][i];
#pragma unroll
    for (int jj = 0; jj < 16; ++jj) acc[jj] = fmaf(vv, wasL[r][j0 + jj], acc[jj]);
  }
#pragma unroll
  for (int jj = 0; jj < 16; jj += 4) {
    float4 ovv = make_float4(acc[jj], acc[jj + 1], acc[jj + 2], acc[jj + 3]);
    *(float4*)(pinv + ((size_t)bh * 64 + i) * 64 + j0 + jj) = ovv;
  }
}

// ---------------------------------------------------------------------------
// Fused: blocks 0..15 = SVD (dispatch-first so it starts immediately);
// blocks 16..3087 = the three projection GEMMs (1024 each).
__global__ __launch_bounds__(256) void fused_proj_svd_kernel(
    const float* __restrict__ x,
    const float* __restrict__ wq, const float* __restrict__ bq,
    const float* __restrict__ wk, const float* __restrict__ bk,
    const float* __restrict__ wv, const float* __restrict__ bv,
    unsigned short* __restrict__ q4, unsigned short* __restrict__ k4,
    unsigned short* __restrict__ vt,
    const float* __restrict__ ker2, float* __restrict__ pinv) {
  __shared__ __align__(16) char smem[38400];
  int tid = threadIdx.x;
  int blk = blockIdx.x;
  if (blk < 16) { svd_body(ker2, pinv, blk, smem, tid); return; }
  int g = blk - 16;
  int which = g >> 10;
  int sub = g & 1023;
  int row0 = (sub >> 2) * 128;
  int col0 = (sub & 3) * 128;
  unsigned short* Xs = (unsigned short*)smem;
  unsigned short* Ws = Xs + 128 * 32;
  if (which == 0)
    mfma_gemm_body(x, wq, bq, q4, 0.125f, 0, 1, row0, col0, Xs, Ws, tid);
  else if (which == 1)
    mfma_gemm_body(x, wk, bk, k4, 1.0f, 0, 1, row0, col0, Xs, Ws, tid);
  else
    mfma_gemm_body(x, wv, bv, vt, 1.0f, 0, 2, row0, col0, Xs, Ws, tid);
}

// Final projection: outh(bf16) @ wo^T + bo -> f32 out.
__global__ __launch_bounds__(256) void oproj_kernel(const unsigned short* __restrict__ outh,
                                                    const float* __restrict__ wo,
                                                    const float* __restrict__ bo,
                                                    float* __restrict__ out) {
  __shared__ __align__(16) unsigned short Xs[128 * 32];
  __shared__ __align__(16) unsigned short Ws[128 * 32];
  mfma_gemm_body(outh, wo, bo, out, 1.0f, 1, 0, blockIdx.x * 128, blockIdx.y * 128,
                 Xs, Ws, threadIdx.x);
}

// ---------------------------------------------------------------------------
__global__ __launch_bounds__(64) void ker2_kernel(const float* __restrict__ qland,
                                                  const float* __restrict__ kland,
                                                  float* __restrict__ ker2) {
  int bh = blockIdx.x;
  __shared__ float kl[64][68];
  __shared__ float ql[64][68];
  int t = threadIdx.x;
  for (int i = 0; i < 16; ++i) {
    int s = t + i * 64;
    int r = s >> 4, d4 = (s & 15) << 2;
    *(float4*)&kl[r][d4] = *(const float4*)(kland + ((size_t)bh * 64 + r) * 64 + d4);
    *(float4*)&ql[r][d4] = *(const float4*)(qland + ((size_t)bh * 64 + r) * 64 + d4);
  }
  __syncthreads();
  float z[64];
  float se = 0.f;
  for (int j = 0; j < 64; ++j) {
    float acc = 0.f;
#pragma unroll
    for (int d4 = 0; d4 < 64; d4 += 4) {
      float4 qv = *(float4*)&ql[t][d4];
      float4 kv = *(float4*)&kl[j][d4];
      acc += qv.x * kv.x + qv.y * kv.y + qv.z * kv.z + qv.w * kv.w;
    }
    z[j] = expf(acc);
    se += z[j];
  }
  float inv = 1.0f / se;
  for (int j4 = 0; j4 < 64; j4 += 4) {
    float4 o = make_float4(z[j4] * inv, z[j4 + 1] * inv, z[j4 + 2] * inv, z[j4 + 3] * inv);
    *(float4*)(ker2 + ((size_t)bh * 64 + t) * 64 + j4) = o;
  }
}

// ---------------------------------------------------------------------------
// ker3+kv partials via MFMA in DEVIATION form (see R5-R7).
__global__ __launch_bounds__(256, 1) void ker3kv_mfma_kernel(
    const unsigned short* __restrict__ qlh,
    const unsigned short* __restrict__ qll,
    const unsigned short* __restrict__ k4,
    const unsigned short* __restrict__ vt,
    float* __restrict__ pacc,
    float* __restrict__ pacc0,
    float* __restrict__ ps) {
  int bh = blockIdx.y, ch = blockIdx.x;
  int tid = threadIdx.x, w = tid >> 6, lane = tid & 63;
  int part = ch * 4 + w;
  int lrow = lane & 15, lgrp = lane >> 4;
  __shared__ __align__(16) unsigned short Pl[4][64 * 72];
  unsigned short* myP = &Pl[w][0];

  bf16x8 qah[4][2], qal[4][2];
#pragma unroll
  for (int mf = 0; mf < 4; ++mf)
#pragma unroll
    for (int ks = 0; ks < 2; ++ks) {
      size_t off = ((size_t)bh * 64 + mf * 16 + lrow) * 64 + ks * 32 + lgrp * 8;
      qah[mf][ks] = ld_bf8(qlh + off);
      qal[mf][ks] = ld_bf8(qll + off);
    }
  bf16x8 onesf;
#pragma unroll
  for (int j = 0; j < 8; ++j) onesf[j] = (__bf16)1.0f;

  f32x4 kvacc[4][4] = {};
  f32x4 oneacc[4] = {};
  f32x4 ssum[4] = {};

  for (int sub = 0; sub < 4; ++sub) {
    int n0 = ch * 1024 + w * 256 + sub * 64;
    f32x4 sacc[4][4] = {};
#pragma unroll
    for (int ks = 0; ks < 2; ++ks) {
#pragma unroll
      for (int nf = 0; nf < 4; ++nf) {
        bf16x8 kb = ld_bf8(k4 + ((size_t)bh * N_ + n0 + nf * 16 + lrow) * 64 + ks * 32 + lgrp * 8);
#pragma unroll
        for (int mf = 0; mf < 4; ++mf) {
          sacc[mf][nf] = __builtin_amdgcn_mfma_f32_16x16x32_bf16(qah[mf][ks], kb, sacc[mf][nf], 0, 0, 0);
          sacc[mf][nf] = __builtin_amdgcn_mfma_f32_16x16x32_bf16(qal[mf][ks], kb, sacc[mf][nf], 0, 0, 0);
        }
      }
    }
#pragma unroll
    for (int mf = 0; mf < 4; ++mf) {
#pragma unroll
      for (int nf = 0; nf < 4; ++nf) {
#pragma unroll
        for (int r = 0; r < 4; ++r) {
          float pd = expf(sacc[mf][nf][r]) - 1.0f;
          ssum[mf][r] += pd;
          myP[(mf * 16 + lgrp * 4 + r) * 72 + nf * 16 + lrow] = f2bf(pd);
        }
      }
    }
#pragma unroll
    for (int ks = 0; ks < 2; ++ks) {
      bf16x8 pa[4];
#pragma unroll
      for (int mf = 0; mf < 4; ++mf)
        pa[mf] = ld_bf8(myP + (mf * 16 + lrow) * 72 + ks * 32 + lgrp * 8);
#pragma unroll
      for (int nf = 0; nf < 4; ++nf) {
        bf16x8 vb = ld_bf8(vt + ((size_t)bh * 64 + nf * 16 + lrow) * N_ + n0 + ks * 32 + lgrp * 8);
#pragma unroll
        for (int mf = 0; mf < 4; ++mf)
          kvacc[mf][nf] = __builtin_amdgcn_mfma_f32_16x16x32_bf16(pa[mf], vb, kvacc[mf][nf], 0, 0, 0);
        oneacc[nf] = __builtin_amdgcn_mfma_f32_16x16x32_bf16(onesf, vb, oneacc[nf], 0, 0, 0);
      }
    }
  }
#pragma unroll
  for (int mf = 0; mf < 4; ++mf)
#pragma unroll
    for (int m = 1; m < 16; m <<= 1)
#pragma unroll
      for (int r = 0; r < 4; ++r) ssum[mf][r] += __shfl_xor(ssum[mf][r], m);

  size_t pb = (((size_t)bh * NPART_ + part) * 64) * 64;
#pragma unroll
  for (int mf = 0; mf < 4; ++mf)
#pragma unroll
    for (int nf = 0; nf < 4; ++nf)
#pragma unroll
      for (int r = 0; r < 4; ++r)
        pacc[pb + (size_t)(mf * 16 + lgrp * 4 + r) * 64 + nf * 16 + lrow] = kvacc[mf][nf][r];
  if (lrow == 0) {
#pragma unroll
    for (int mf = 0; mf < 4; ++mf)
#pragma unroll
      for (int r = 0; r < 4; ++r)
        ps[((size_t)bh * NPART_ + part) * 64 + mf * 16 + lgrp * 4 + r] = ssum[mf][r];
  }
  if (lgrp == 0) {
#pragma unroll
    for (int nf = 0; nf < 4; ++nf)
      pacc0[((size_t)bh * NPART_ + part) * 64 + nf * 16 + lrow] = oneacc[nf][0];
  }
}

// ---------------------------------------------------------------------------
__global__ __launch_bounds__(256) void kv_combine_kernel(const float* __restrict__ pacc,
                                                         const float* __restrict__ pacc0,
                                                         const float* __restrict__ ps,
                                                         float* __restrict__ kv) {
  int bh = blockIdx.y;
  int lm = blockIdx.x * 16 + (threadIdx.x >> 4);
  int d4 = (threadIdx.x & 15) * 4;
  float s = 16384.f;
  for (int part = 0; part < NPART_; ++part) s += ps[((size_t)bh * NPART_ + part) * 64 + lm];
  float4 a = make_float4(0.f, 0.f, 0.f, 0.f);
  for (int part = 0; part < NPART_; ++part) {
    float4 c0 = *(const float4*)&pacc0[((size_t)bh * NPART_ + part) * 64 + d4];
    float4 v = *(const float4*)&pacc[(((size_t)bh * NPART_ + part) * 64 + lm) * 64 + d4];
    a.x += c0.x + v.x; a.y += c0.y + v.y; a.z += c0.z + v.z; a.w += c0.w + v.w;
  }
  float inv = 1.f / s;
  float4 o = make_float4(a.x * inv, a.y * inv, a.z * inv, a.w * inv);
  *(float4*)(kv + ((size_t)bh * 64 + lm) * 64 + d4) = o;
}

// ---------------------------------------------------------------------------
__global__ __launch_bounds__(256) void mmat_kernel(const float* __restrict__ pinv,
                                                   const float* __restrict__ kv,
                                                   unsigned short* __restrict__ mtbh,
                                                   unsigned short* __restrict__ mtbl,
                                                   float* __restrict__ msum) {
  int bh = blockIdx.x;
  int tid = threadIdx.x;
  __shared__ float kvs[64][68];
  __shared__ double pcsd[64];
  for (int i = 0; i < 4; ++i) {
    int s = tid + i * 256;
    int r = s >> 4, d4 = (s & 15) << 2;
    *(float4*)&kvs[r][d4] = *(const float4*)(kv + ((size_t)bh * 64 + r) * 64 + d4);
  }
  if (tid < 64) {
    double s = 0.0;
    for (int l = 0; l < 64; ++l) s += (double)pinv[((size_t)bh * 64 + l) * 64 + tid];
    pcsd[tid] = s;
  }
  __syncthreads();
  int l = tid >> 2, t = tid & 3;
  double o[16] = {};
  for (int j = 0; j < 64; ++j) {
    double pv = (double)pinv[((size_t)bh * 64 + l) * 64 + j];
#pragma unroll
    for (int i = 0; i < 16; ++i) o[i] += pv * (double)kvs[j][t * 16 + i];
  }
#pragma unroll
  for (int i = 0; i < 16; ++i) {
    float f = (float)o[i];
    unsigned short hi = f2bf(f);
    float lo = f - bf2f(hi);
    int d = t * 16 + i;
    mtbh[((size_t)bh * 64 + d) * 64 + l] = hi;
    mtbl[((size_t)bh * 64 + d) * 64 + l] = f2bf(lo);
  }
  if (tid < 64) {
    double m = 0.0;
    for (int j = 0; j < 64; ++j) m += pcsd[j] * (double)kvs[j][tid];
    msum[(size_t)bh * 64 + tid] = (float)(m * (1.0 / 64.0));
  }
}

// ---------------------------------------------------------------------------
__global__ __launch_bounds__(256, 1) void ker1out_mfma_kernel(
    const unsigned short* __restrict__ q4,
    const unsigned short* __restrict__ klb,
    const unsigned short* __restrict__ mtbh,
    const unsigned short* __restrict__ mtbl,
    const float* __restrict__ msum,
    unsigned short* __restrict__ outh) {
  int bh = blockIdx.y, tile = blockIdx.x;
  int b = bh >> 3, h = bh & 7;
  int tid = threadIdx.x, w = tid >> 6, lane = tid & 63;
  int lrow = lane & 15, lgrp = lane >> 4;
  int tok0 = tile * 256 + w * 64;
  __shared__ __align__(16) unsigned short Pl[4][64 * 72];
  unsigned short* myP = &Pl[w][0];

  f32x4 sacc[4][4] = {};
#pragma unroll
  for (int ks = 0; ks < 2; ++ks) {
    bf16x8 kb[4];
#pragma unroll
    for (int nf = 0; nf < 4; ++nf)
      kb[nf] = ld_bf8(klb + ((size_t)bh * 64 + nf * 16 + lrow) * 64 + ks * 32 + lgrp * 8);
#pragma unroll
    for (int mf = 0; mf < 4; ++mf) {
      bf16x8 qa = ld_bf8(q4 + ((size_t)bh * N_ + tok0 + mf * 16 + lrow) * 64 + ks * 32 + lgrp * 8);
#pragma unroll
      for (int nf = 0; nf < 4; ++nf)
        sacc[mf][nf] = __builtin_amdgcn_mfma_f32_16x16x32_bf16(qa, kb[nf], sacc[mf][nf], 0, 0, 0);
    }
  }
  f32x4 ssum[4] = {};
#pragma unroll
  for (int mf = 0; mf < 4; ++mf)
#pragma unroll
    for (int nf = 0; nf < 4; ++nf)
#pragma unroll
      for (int r = 0; r < 4; ++r) {
        sacc[mf][nf][r] = expf(sacc[mf][nf][r]);
        ssum[mf][r] += sacc[mf][nf][r];
      }
#pragma unroll
  for (int mf = 0; mf < 4; ++mf)
#pragma unroll
    for (int m = 1; m < 16; m <<= 1)
#pragma unroll
      for (int r = 0; r < 4; ++r) ssum[mf][r] += __shfl_xor(ssum[mf][r], m);
#pragma unroll
  for (int mf = 0; mf < 4; ++mf) {
    f32x4 inv;
#pragma unroll
    for (int r = 0; r < 4; ++r) inv[r] = 1.f / ssum[mf][r];
#pragma unroll
    for (int nf = 0; nf < 4; ++nf)
#pragma unroll
      for (int r = 0; r < 4; ++r) {
        float pdev = fmaf(sacc[mf][nf][r], inv[r], -0.015625f);
        myP[(mf * 16 + lgrp * 4 + r) * 72 + nf * 16 + lrow] = f2bf(pdev);
      }
  }

  f32x4 oacc[4][4] = {};
#pragma unroll
  for (int ks = 0; ks < 2; ++ks) {
    bf16x8 pa[4];
#pragma unroll
    for (int mf = 0; mf < 4; ++mf)
      pa[mf] = ld_bf8(myP + (mf * 16 + lrow) * 72 + ks * 32 + lgrp * 8);
#pragma unroll
    for (int nf = 0; nf < 4; ++nf) {
      bf16x8 mh = ld_bf8(mtbh + ((size_t)bh * 64 + nf * 16 + lrow) * 64 + ks * 32 + lgrp * 8);
      bf16x8 ml = ld_bf8(mtbl + ((size_t)bh * 64 + nf * 16 + lrow) * 64 + ks * 32 + lgrp * 8);
#pragma unroll
      for (int mf = 0; mf < 4; ++mf) {
        oacc[mf][nf] = __builtin_amdgcn_mfma_f32_16x16x32_bf16(pa[mf], mh, oacc[mf][nf], 0, 0, 0);
        oacc[mf][nf] = __builtin_amdgcn_mfma_f32_16x16x32_bf16(pa[mf], ml, oacc[mf][nf], 0, 0, 0);
      }
    }
  }
#pragma unroll
  for (int nf = 0; nf < 4; ++nf) {
    float ms = msum[(size_t)bh * 64 + nf * 16 + lrow];
#pragma unroll
    for (int mf = 0; mf < 4; ++mf)
#pragma unroll
      for (int r = 0; r < 4; ++r) {
        int tok = tok0 + mf * 16 + lgrp * 4 + r;
        int d = nf * 16 + lrow;
        outh[((size_t)b * N_ + tok) * C_ + h * HD_ + d] = f2bf(oacc[mf][nf][r] + ms);
      }
  }
}

// ---------------------------------------------------------------------------
extern "C" void kernel_launch(void* const* d_in, const int* in_sizes, int n_in,
                              void* d_out, int out_size, void* d_ws, size_t ws_size,
                              hipStream_t stream) {
  const float* x  = (const float*)d_in[0];
  const float* wq = (const float*)d_in[1];
  const float* bq = (const float*)d_in[2];
  const float* wk = (const float*)d_in[3];
  const float* bk = (const float*)d_in[4];
  const float* wv = (const float*)d_in[5];
  const float* bv = (const float*)d_in[6];
  const float* wo = (const float*)d_in[7];
  const float* bo = (const float*)d_in[8];
  float* out = (float*)d_out;

  char* base = (char*)d_ws;
  const size_t QKV = (size_t)BH_ * N_ * HD_;   // 16,777,216 elems
  unsigned short* q4 = (unsigned short*)base;                 // 32MB
  unsigned short* k4 = (unsigned short*)(base + QKV * 2);     // 32MB
  unsigned short* vt = (unsigned short*)(base + QKV * 4);     // 32MB
  unsigned short* outh = (unsigned short*)(base + QKV * 2);   // alias k4 (dead after ker3kv)
  char* sp = base + QKV * 6;
  float* pacc  = (float*)sp; sp += (size_t)BH_ * NPART_ * 64 * 64 * 4;  // 16.78MB
  float* pacc0 = (float*)sp; sp += (size_t)BH_ * NPART_ * 64 * 4;
  float* ps    = (float*)sp; sp += (size_t)BH_ * NPART_ * 64 * 4;
  float* xbar  = (float*)sp; sp += (size_t)B_ * LM_ * C_ * 4;
  float* qland = (float*)sp; sp += (size_t)BH_ * LM_ * HD_ * 4;
  float* kland = (float*)sp; sp += (size_t)BH_ * LM_ * HD_ * 4;
  unsigned short* qlbh = (unsigned short*)sp; sp += (size_t)BH_ * LM_ * HD_ * 2;
  unsigned short* qlbl = (unsigned short*)sp; sp += (size_t)BH_ * LM_ * HD_ * 2;
  unsigned short* klb  = (unsigned short*)sp; sp += (size_t)BH_ * LM_ * HD_ * 2;
  float* ker2  = (float*)sp; sp += (size_t)BH_ * LM_ * LM_ * 4;
  float* pinv  = (float*)sp; sp += (size_t)BH_ * LM_ * LM_ * 4;
  float* kvb   = (float*)sp; sp += (size_t)BH_ * LM_ * HD_ * 4;
  unsigned short* mtbh = (unsigned short*)sp; sp += (size_t)BH_ * LM_ * HD_ * 2;
  unsigned short* mtbl = (unsigned short*)sp; sp += (size_t)BH_ * LM_ * HD_ * 2;
  float* msum  = (float*)sp; sp += (size_t)BH_ * HD_ * 4;

  const float scaleq = 0.125f;
  const int L = BH_ * LM_ * HD_;
  const int L8 = L / 8;

  // landmark path (f32-exact)
  seg_mean_kernel<<<B_ * LM_, 256, 0, stream>>>(x, xbar);
  dim3 gl(2, 8);
  gemm_nt_kernel<<<gl, 256, 0, stream>>>(xbar, wq, bq, qland, scaleq, LM_);
  gemm_nt_kernel<<<gl, 256, 0, stream>>>(xbar, wk, bk, kland, 1.0f, LM_);
  cvt_bf16_pair_kernel<<<L / 256, 256, 0, stream>>>(qland, qlbh, qlbl, L);
  cvt_bf16_kernel<<<L8 / 256, 256, 0, stream>>>(kland, klb, L8);
  ker2_kernel<<<BH_, 64, 0, stream>>>(qland, kland, ker2);

  // fused: SVD (blocks 0..15) + q/k/v projections (blocks 16..3087)
  fused_proj_svd_kernel<<<16 + 3 * 1024, 256, 0, stream>>>(
      x, wq, bq, wk, bk, wv, bv, q4, k4, vt, ker2, pinv);

  // ker3 + kv (MFMA, deviation form)
  dim3 g6(NCH_, BH_);
  ker3kv_mfma_kernel<<<g6, 256, 0, stream>>>(qlbh, qlbl, k4, vt, pacc, pacc0, ps);
  dim3 g7(4, BH_);
  kv_combine_kernel<<<g7, 256, 0, stream>>>(pacc, pacc0, ps, kvb);
  mmat_kernel<<<BH_, 256, 0, stream>>>(pinv, kvb, mtbh, mtbl, msum);

  // out_heads (MFMA, deviation form) -> bf16 outh (aliases dead k4)
  dim3 g9(N_ / 256, BH_);
  ker1out_mfma_kernel<<<g9, 256, 0, stream>>>(q4, klb, mtbh, mtbl, msum, outh);

  // final projection
  dim3 g10(B_ * N_ / 128, C_ / 128);
  oproj_kernel<<<g10, 256, 0, stream>>>(outh, wo, bo, out);
}

// Round 9
// 595.053 us; speedup vs baseline: 5.8616x; 1.0910x over previous
//
#include <hip/hip_runtime.h>
#include <stdint.h>

// NystromAttention MI355X — Round 9:
//  - SVD phase-split: 5 sweeps fused with proj GEMMs, 3 sweeps + pinv fused
//    with ker3kv (state via global asave/vsave) -> absorbs ker3kv's window.
//  - oproj (serial tail) DMA-staged via global_load_lds with preconverted wob.
// All numerics identical to round 8 (passed, absmax 6.1e-5).

constexpr int B_   = 2;
constexpr int N_   = 16384;
constexpr int C_   = 512;
constexpr int H_   = 8;
constexpr int HD_  = 64;
constexpr int LM_  = 64;
constexpr int SEG_ = 256;
constexpr int BH_  = 16;
constexpr int NCH_ = 16;
constexpr int NPART_ = 64;
constexpr int SW1_ = 5;   // sweeps in phase 1
constexpr int SW2_ = 3;   // sweeps in phase 2

#define RCOND_ (640.0 * 1.1920928955078125e-07)

typedef unsigned short ushort4_t __attribute__((ext_vector_type(4)));
typedef unsigned short ushort8_t __attribute__((ext_vector_type(8)));
typedef __bf16 bf16x8 __attribute__((ext_vector_type(8)));
typedef float f32x4 __attribute__((ext_vector_type(4)));

__device__ inline float bf2f(unsigned short u) {
  union { unsigned int i; float f; } x; x.i = ((unsigned int)u) << 16; return x.f;
}
__device__ inline unsigned short f2bf(float f) {
  union { float f; unsigned int i; } x; x.f = f;
  unsigned int lsb = (x.i >> 16) & 1;
  return (unsigned short)((x.i + 0x7fffu + lsb) >> 16);
}
__device__ inline bf16x8 ld_bf8(const unsigned short* p) { return *(const bf16x8*)p; }

__device__ __forceinline__ void gload_lds16(const unsigned short* gsrc, unsigned short* ldst) {
  __builtin_amdgcn_global_load_lds((const __attribute__((address_space(1))) void*)gsrc,
                                   (__attribute__((address_space(3))) void*)ldst, 16, 0, 0);
}

// ---------------------------------------------------------------------------
__global__ __launch_bounds__(256) void cvt_bf16_kernel(const float* __restrict__ src,
                                                       unsigned short* __restrict__ dst,
                                                       int n8) {
  int i = (blockIdx.x * 256 + threadIdx.x);
  if (i >= n8) return;
  const float* s = src + (size_t)i * 8;
  float4 x0 = *(const float4*)(s);
  float4 x1 = *(const float4*)(s + 4);
  ushort8_t u;
  u[0] = f2bf(x0.x); u[1] = f2bf(x0.y); u[2] = f2bf(x0.z); u[3] = f2bf(x0.w);
  u[4] = f2bf(x1.x); u[5] = f2bf(x1.y); u[6] = f2bf(x1.z); u[7] = f2bf(x1.w);
  *(ushort8_t*)(dst + (size_t)i * 8) = u;
}

__global__ __launch_bounds__(256) void cvt_bf16_pair_kernel(const float* __restrict__ src,
                                                            unsigned short* __restrict__ hi,
                                                            unsigned short* __restrict__ lo,
                                                            int n) {
  int i = blockIdx.x * 256 + threadIdx.x;
  if (i >= n) return;
  float f = src[i];
  unsigned short h = f2bf(f);
  float rem = f - bf2f(h);
  hi[i] = h; lo[i] = f2bf(rem);
}

// ---------------------------------------------------------------------------
__global__ __launch_bounds__(256) void seg_mean_kernel(const float* __restrict__ x,
                                                       float* __restrict__ xbar) {
  int bl = blockIdx.x;
  int b = bl / LM_, l = bl % LM_;
  int t = threadIdx.x;
  int c4 = t & 127;
  int rh = t >> 7;
  const float* xp = x + ((size_t)b * N_ + (size_t)l * SEG_) * C_;
  float4 s = make_float4(0.f, 0.f, 0.f, 0.f);
  for (int r = rh * 128; r < rh * 128 + 128; ++r) {
    float4 v = *(const float4*)(xp + (size_t)r * C_ + c4 * 4);
    s.x += v.x; s.y += v.y; s.z += v.z; s.w += v.w;
  }
  __shared__ float red[2][512];
  *(float4*)&red[rh][c4 * 4] = s;
  __syncthreads();
  if (rh == 0) {
    float4 a = *(float4*)&red[0][c4 * 4];
    float4 c = *(float4*)&red[1][c4 * 4];
    const float invs = 1.0f / SEG_;
    float4 o;
    o.x = (a.x + c.x) * invs; o.y = (a.y + c.y) * invs;
    o.z = (a.z + c.z) * invs; o.w = (a.w + c.w) * invs;
    *(float4*)(xbar + (size_t)bl * C_ + c4 * 4) = o;
  }
}

// ---------------------------------------------------------------------------
// f32 VALU GEMM for landmark projections (128 rows): f32 head-split out.
__global__ __launch_bounds__(256) void gemm_nt_kernel(const float* __restrict__ A,
                                                      const float* __restrict__ W,
                                                      const float* __restrict__ bias,
                                                      float* __restrict__ out,
                                                      float scale, int rpb) {
  __shared__ float As[32][68];
  __shared__ float Ws[32][68];
  int row0 = blockIdx.x * 64;
  int col0 = blockIdx.y * 64;
  int tid = threadIdx.x;
  int tm = tid >> 4, tn = tid & 15;
  float acc[4][4] = {};
  for (int k0 = 0; k0 < C_; k0 += 32) {
#pragma unroll
    for (int i = 0; i < 2; ++i) {
      int s = tid + i * 256;
      int r = s >> 3;
      int kg = (s & 7) << 2;
      float4 av = *(const float4*)(A + (size_t)(row0 + r) * C_ + k0 + kg);
      As[kg + 0][r] = av.x; As[kg + 1][r] = av.y;
      As[kg + 2][r] = av.z; As[kg + 3][r] = av.w;
      float4 wv = *(const float4*)(W + (size_t)(col0 + r) * C_ + k0 + kg);
      Ws[kg + 0][r] = wv.x; Ws[kg + 1][r] = wv.y;
      Ws[kg + 2][r] = wv.z; Ws[kg + 3][r] = wv.w;
    }
    __syncthreads();
#pragma unroll
    for (int kk = 0; kk < 32; ++kk) {
      float4 a = *(const float4*)&As[kk][tm * 4];
      float4 b = *(const float4*)&Ws[kk][tn * 4];
      float av[4] = {a.x, a.y, a.z, a.w};
      float bv[4] = {b.x, b.y, b.z, b.w};
#pragma unroll
      for (int i = 0; i < 4; ++i)
#pragma unroll
        for (int j = 0; j < 4; ++j) acc[i][j] += av[i] * bv[j];
    }
    __syncthreads();
  }
#pragma unroll
  for (int i = 0; i < 4; ++i) {
    int row = row0 + tm * 4 + i;
    int d0 = tn * 4;
    float o4[4];
#pragma unroll
    for (int j = 0; j < 4; ++j) o4[j] = (acc[i][j] + bias[col0 + d0 + j]) * scale;
    int b = row / rpb, n = row % rpb;
    int h = col0 >> 6;
    size_t idx = (((size_t)(b * H_ + h) * rpb) + n) * HD_ + d0;
    float4 o; o.x = o4[0]; o.y = o4[1]; o.z = o4[2]; o.w = o4[3];
    *(float4*)(out + idx) = o;
  }
}

// ---------------------------------------------------------------------------
// Reg-staged MFMA GEMM body (A f32, W f32 converted in staging).
// omode 1: bf16 head-split; omode 2: bf16 vt.
__device__ __forceinline__ void mfma_gemm_body(const float* __restrict__ A,
                                               const float* __restrict__ W,
                                               const float* __restrict__ bias,
                                               unsigned short* __restrict__ out,
                                               float scale, int omode,
                                               int row0, int col0,
                                               unsigned short* Xs, unsigned short* Ws,
                                               int tid) {
  int wid = tid >> 6, lane = tid & 63;
  int wr = wid >> 1, wc = wid & 1;
  f32x4 acc[4][4] = {};
  int srow = tid >> 1;
  int sk = (tid & 1) * 16;
  const float* wpbase = W + (size_t)(col0 + srow) * C_ + sk;
  const float* apbase = A + (size_t)(row0 + srow) * C_ + sk;
  unsigned short* xdst = &Xs[srow * 32 + sk];
  unsigned short* wdst = &Ws[srow * 32 + sk];

  for (int k0 = 0; k0 < C_; k0 += 32) {
    __syncthreads();
    {
      float4 x0 = *(const float4*)(apbase + k0);
      float4 x1 = *(const float4*)(apbase + k0 + 4);
      float4 x2 = *(const float4*)(apbase + k0 + 8);
      float4 x3 = *(const float4*)(apbase + k0 + 12);
      ushort8_t u0, u1;
      u0[0] = f2bf(x0.x); u0[1] = f2bf(x0.y); u0[2] = f2bf(x0.z); u0[3] = f2bf(x0.w);
      u0[4] = f2bf(x1.x); u0[5] = f2bf(x1.y); u0[6] = f2bf(x1.z); u0[7] = f2bf(x1.w);
      u1[0] = f2bf(x2.x); u1[1] = f2bf(x2.y); u1[2] = f2bf(x2.z); u1[3] = f2bf(x2.w);
      u1[4] = f2bf(x3.x); u1[5] = f2bf(x3.y); u1[6] = f2bf(x3.z); u1[7] = f2bf(x3.w);
      *(ushort8_t*)(xdst) = u0;
      *(ushort8_t*)(xdst + 8) = u1;
    }
    {
      float4 w0 = *(const float4*)(wpbase + k0);
      float4 w1 = *(const float4*)(wpbase + k0 + 4);
      float4 w2 = *(const float4*)(wpbase + k0 + 8);
      float4 w3 = *(const float4*)(wpbase + k0 + 12);
      ushort8_t u0, u1;
      u0[0] = f2bf(w0.x); u0[1] = f2bf(w0.y); u0[2] = f2bf(w0.z); u0[3] = f2bf(w0.w);
      u0[4] = f2bf(w1.x); u0[5] = f2bf(w1.y); u0[6] = f2bf(w1.z); u0[7] = f2bf(w1.w);
      u1[0] = f2bf(w2.x); u1[1] = f2bf(w2.y); u1[2] = f2bf(w2.z); u1[3] = f2bf(w2.w);
      u1[4] = f2bf(w3.x); u1[5] = f2bf(w3.y); u1[6] = f2bf(w3.z); u1[7] = f2bf(w3.w);
      *(ushort8_t*)(wdst) = u0;
      *(ushort8_t*)(wdst + 8) = u1;
    }
    __syncthreads();
    bf16x8 af[4], bfr[4];
#pragma unroll
    for (int m = 0; m < 4; ++m)
      af[m] = *(bf16x8*)&Xs[(wr * 64 + m * 16 + (lane & 15)) * 32 + (lane >> 4) * 8];
#pragma unroll
    for (int n = 0; n < 4; ++n)
      bfr[n] = *(bf16x8*)&Ws[(wc * 64 + n * 16 + (lane & 15)) * 32 + (lane >> 4) * 8];
#pragma unroll
    for (int m = 0; m < 4; ++m)
#pragma unroll
      for (int n = 0; n < 4; ++n)
        acc[m][n] = __builtin_amdgcn_mfma_f32_16x16x32_bf16(af[m], bfr[n], acc[m][n], 0, 0, 0);
  }

#pragma unroll
  for (int m = 0; m < 4; ++m) {
    int rbase = row0 + wr * 64 + m * 16 + (lane >> 4) * 4;
#pragma unroll
    for (int n = 0; n < 4; ++n) {
      int c = col0 + wc * 64 + n * 16 + (lane & 15);
      float bc = bias[c];
      if (omode == 2) {
        int b = rbase >> 14, nn = rbase & 16383;
        int h = c >> 6, d = c & 63;
        ushort4_t u;
#pragma unroll
        for (int rg = 0; rg < 4; ++rg) u[rg] = f2bf((acc[m][n][rg] + bc) * scale);
        *(ushort4_t*)(out + ((size_t)(b * H_ + h) * HD_ + d) * N_ + nn) = u;
      } else {
#pragma unroll
        for (int rg = 0; rg < 4; ++rg) {
          float val = (acc[m][n][rg] + bc) * scale;
          int r = rbase + rg;
          int b = r >> 14, nn = r & 16383, h = c >> 6, d = c & 63;
          out[(((size_t)(b * H_ + h) * N_) + nn) * HD_ + d] = f2bf(val);
        }
      }
    }
  }
}

// ---------------------------------------------------------------------------
// SVD sweep loop (4-wave row-split, shared by both phases).
__device__ __forceinline__ void svd_sweeps(float a[16], float v[16], char* smemraw,
                                           int w, int lane, int nsweeps) {
  float (*pg)[4][64] = (float(*)[4][64])(smemraw);          // 2048 B
  float (*pa4)[64]   = (float(*)[64])(smemraw + 2048);      // 1024 B
  for (int sweep = 0; sweep < nsweeps; ++sweep) {
    float p0 = 0.f, p1 = 0.f;
#pragma unroll
    for (int k = 0; k < 16; k += 2) { p0 = fmaf(a[k], a[k], p0); p1 = fmaf(a[k + 1], a[k + 1], p1); }
    pa4[w][lane] = p0 + p1;
    __syncthreads();
    float alpha = (pa4[0][lane] + pa4[1][lane]) + (pa4[2][lane] + pa4[3][lane]);
    for (int mask = 1; mask < 64; ++mask) {
      int buf = mask & 1;
      bool lower = lane < (lane ^ mask);
      float beta = __shfl_xor(alpha, mask);
      float o[16];
#pragma unroll
      for (int k = 0; k < 16; ++k) o[k] = __shfl_xor(a[k], mask);
      float g0 = 0.f, g1 = 0.f;
#pragma unroll
      for (int k = 0; k < 16; k += 2) { g0 = fmaf(a[k], o[k], g0); g1 = fmaf(a[k + 1], o[k + 1], g1); }
      pg[buf][w][lane] = g0 + g1;
      __syncthreads();
      float gamma = (pg[buf][0][lane] + pg[buf][1][lane]) + (pg[buf][2][lane] + pg[buf][3][lane]);
      bool need = (gamma * gamma > 1e-12f * alpha * beta);
      if (__any(need)) {
        float ov[16];
#pragma unroll
        for (int k = 0; k < 16; ++k) ov[k] = __shfl_xor(v[k], mask);
        float ap = lower ? alpha : beta;
        float aq = lower ? beta : alpha;
        float c = 1.f, s = 0.f;
        if (need) {
          float tau = (aq - ap) / (2.f * gamma);
          float t = copysignf(1.f, tau) / (fabsf(tau) + sqrtf(fmaf(tau, tau, 1.f)));
          c = rsqrtf(fmaf(t, t, 1.f));
          s = t * c;
        }
        float sm = lower ? -s : s;
#pragma unroll
        for (int k = 0; k < 16; ++k) a[k] = fmaf(sm, o[k], c * a[k]);
#pragma unroll
        for (int k = 0; k < 16; ++k) v[k] = fmaf(sm, ov[k], c * v[k]);
        float twocsg = 2.f * c * s * gamma;
        alpha = fmaf(c * c, alpha, fmaf(s * s, beta, lower ? -twocsg : twocsg));
      }
    }
  }
}

// Phase 1: load ker2, SW1_ sweeps, save state.
__device__ void svd_phase1(const float* __restrict__ ker2,
                           float* __restrict__ asave, float* __restrict__ vsave,
                           int bh, char* smemraw, int tid) {
  int w = tid >> 6, lane = tid & 63;
  float a[16], v[16];
#pragma unroll
  for (int k = 0; k < 16; ++k)
    a[k] = ker2[((size_t)bh * 64 + w * 16 + k) * 64 + lane];
#pragma unroll
  for (int k = 0; k < 16; ++k) v[k] = (w * 16 + k == lane) ? 1.f : 0.f;
  svd_sweeps(a, v, smemraw, w, lane, SW1_);
#pragma unroll
  for (int k = 0; k < 16; ++k) {
    asave[((size_t)bh * 64 + w * 16 + k) * 64 + lane] = a[k];
    vsave[((size_t)bh * 64 + w * 16 + k) * 64 + lane] = v[k];
  }
}

// Phase 2: load state, SW2_ sweeps, sigma/cutoff + pinv.
__device__ void svd_phase2(const float* __restrict__ asave, const float* __restrict__ vsave,
                           float* __restrict__ pinv, int bh, char* smemraw, int tid) {
  double (*ps2)[64]  = (double(*)[64])(smemraw + 3072);     // 2048 B
  float (*vsL)[65]   = (float(*)[65])(smemraw + 5120);      // 16640 B
  float (*wasL)[65]  = (float(*)[65])(smemraw + 21760);     // 16640 B
  int w = tid >> 6, lane = tid & 63;
  float a[16], v[16];
#pragma unroll
  for (int k = 0; k < 16; ++k) {
    a[k] = asave[((size_t)bh * 64 + w * 16 + k) * 64 + lane];
    v[k] = vsave[((size_t)bh * 64 + w * 16 + k) * 64 + lane];
  }
  svd_sweeps(a, v, smemraw, w, lane, SW2_);

  double psig = 0.0;
#pragma unroll
  for (int k = 0; k < 16; ++k) psig += (double)a[k] * (double)a[k];
  ps2[w][lane] = psig;
  __syncthreads();
  double sig2 = (ps2[0][lane] + ps2[1][lane]) + (ps2[2][lane] + ps2[3][lane]);
  double smax = sig2;
#pragma unroll
  for (int m = 1; m < 64; m <<= 1) smax = fmax(smax, __shfl_xor(smax, m));
  double cutoff2 = smax * (RCOND_ * RCOND_);
  float wgt = (sig2 > cutoff2) ? (float)(1.0 / sig2) : 0.f;

#pragma unroll
  for (int k = 0; k < 16; ++k) {
    vsL[lane][w * 16 + k] = v[k];
    wasL[lane][w * 16 + k] = wgt * a[k];
  }
  __syncthreads();
  int i = tid >> 2;
  int j0 = (tid & 3) * 16;
  float acc[16] = {};
  for (int r = 0; r < 64; ++r) {
    float vv = vsL[r][i];
#pragma unroll
    for (int jj = 0; jj < 16; ++jj) acc[jj] = fmaf(vv, wasL[r][j0 + jj], acc[jj]);
  }
#pragma unroll
  for (int jj = 0; jj < 16; jj += 4) {
    float4 ovv = make_float4(acc[jj], acc[jj + 1], acc[jj + 2], acc[jj + 3]);
    *(float4*)(pinv + ((size_t)bh * 64 + i) * 64 + j0 + jj) = ovv;
  }
}

// ---------------------------------------------------------------------------
// Fused 1: blocks 0..15 = SVD phase 1; 16..3087 = q/k/v projections.
__global__ __launch_bounds__(256) void fused1_kernel(
    const float* __restrict__ x,
    const float* __restrict__ wq, const float* __restrict__ bq,
    const float* __restrict__ wk, const float* __restrict__ bk,
    const float* __restrict__ wv, const float* __restrict__ bv,
    unsigned short* __restrict__ q4, unsigned short* __restrict__ k4,
    unsigned short* __restrict__ vt,
    const float* __restrict__ ker2,
    float* __restrict__ asave, float* __restrict__ vsave) {
  __shared__ __align__(16) char smem[16384];
  int tid = threadIdx.x;
  int blk = blockIdx.x;
  if (blk < 16) { svd_phase1(ker2, asave, vsave, blk, smem, tid); return; }
  int g = blk - 16;
  int which = g >> 10;
  int sub = g & 1023;
  int row0 = (sub >> 2) * 128;
  int col0 = (sub & 3) * 128;
  unsigned short* Xs = (unsigned short*)smem;
  unsigned short* Ws = Xs + 128 * 32;
  if (which == 0)
    mfma_gemm_body(x, wq, bq, q4, 0.125f, 1, row0, col0, Xs, Ws, tid);
  else if (which == 1)
    mfma_gemm_body(x, wk, bk, k4, 1.0f, 1, row0, col0, Xs, Ws, tid);
  else
    mfma_gemm_body(x, wv, bv, vt, 1.0f, 2, row0, col0, Xs, Ws, tid);
}

// ---------------------------------------------------------------------------
// ker3+kv body (deviation form, MFMA) — unchanged math from R8.
__device__ void ker3kv_body(const unsigned short* __restrict__ qlh,
                            const unsigned short* __restrict__ qll,
                            const unsigned short* __restrict__ k4,
                            const unsigned short* __restrict__ vt,
                            float* __restrict__ pacc,
                            float* __restrict__ pacc0,
                            float* __restrict__ ps,
                            int bh, int ch, char* smemraw, int tid) {
  int w = tid >> 6, lane = tid & 63;
  int part = ch * 4 + w;
  int lrow = lane & 15, lgrp = lane >> 4;
  unsigned short* myP = (unsigned short*)smemraw + w * 64 * 72;

  bf16x8 qah[4][2], qal[4][2];
#pragma unroll
  for (int mf = 0; mf < 4; ++mf)
#pragma unroll
    for (int ks = 0; ks < 2; ++ks) {
      size_t off = ((size_t)bh * 64 + mf * 16 + lrow) * 64 + ks * 32 + lgrp * 8;
      qah[mf][ks] = ld_bf8(qlh + off);
      qal[mf][ks] = ld_bf8(qll + off);
    }
  bf16x8 onesf;
#pragma unroll
  for (int j = 0; j < 8; ++j) onesf[j] = (__bf16)1.0f;

  f32x4 kvacc[4][4] = {};
  f32x4 oneacc[4] = {};
  f32x4 ssum[4] = {};

  for (int sub = 0; sub < 4; ++sub) {
    int n0 = ch * 1024 + w * 256 + sub * 64;
    f32x4 sacc[4][4] = {};
#pragma unroll
    for (int ks = 0; ks < 2; ++ks) {
#pragma unroll
      for (int nf = 0; nf < 4; ++nf) {
        bf16x8 kb = ld_bf8(k4 + ((size_t)bh * N_ + n0 + nf * 16 + lrow) * 64 + ks * 32 + lgrp * 8);
#pragma unroll
        for (int mf = 0; mf < 4; ++mf) {
          sacc[mf][nf] = __builtin_amdgcn_mfma_f32_16x16x32_bf16(qah[mf][ks], kb, sacc[mf][nf], 0, 0, 0);
          sacc[mf][nf] = __builtin_amdgcn_mfma_f32_16x16x32_bf16(qal[mf][ks], kb, sacc[mf][nf], 0, 0, 0);
        }
      }
    }
#pragma unroll
    for (int mf = 0; mf < 4; ++mf) {
#pragma unroll
      for (int nf = 0; nf < 4; ++nf) {
#pragma unroll
        for (int r = 0; r < 4; ++r) {
          float pd = expf(sacc[mf][nf][r]) - 1.0f;
          ssum[mf][r] += pd;
          myP[(mf * 16 + lgrp * 4 + r) * 72 + nf * 16 + lrow] = f2bf(pd);
        }
      }
    }
#pragma unroll
    for (int ks = 0; ks < 2; ++ks) {
      bf16x8 pa[4];
#pragma unroll
      for (int mf = 0; mf < 4; ++mf)
        pa[mf] = ld_bf8(myP + (mf * 16 + lrow) * 72 + ks * 32 + lgrp * 8);
#pragma unroll
      for (int nf = 0; nf < 4; ++nf) {
        bf16x8 vb = ld_bf8(vt + ((size_t)bh * 64 + nf * 16 + lrow) * N_ + n0 + ks * 32 + lgrp * 8);
#pragma unroll
        for (int mf = 0; mf < 4; ++mf)
          kvacc[mf][nf] = __builtin_amdgcn_mfma_f32_16x16x32_bf16(pa[mf], vb, kvacc[mf][nf], 0, 0, 0);
        oneacc[nf] = __builtin_amdgcn_mfma_f32_16x16x32_bf16(onesf, vb, oneacc[nf], 0, 0, 0);
      }
    }
  }
#pragma unroll
  for (int mf = 0; mf < 4; ++mf)
#pragma unroll
    for (int m = 1; m < 16; m <<= 1)
#pragma unroll
      for (int r = 0; r < 4; ++r) ssum[mf][r] += __shfl_xor(ssum[mf][r], m);

  size_t pb = (((size_t)bh * NPART_ + part) * 64) * 64;
#pragma unroll
  for (int mf = 0; mf < 4; ++mf)
#pragma unroll
    for (int nf = 0; nf < 4; ++nf)
#pragma unroll
      for (int r = 0; r < 4; ++r)
        pacc[pb + (size_t)(mf * 16 + lgrp * 4 + r) * 64 + nf * 16 + lrow] = kvacc[mf][nf][r];
  if (lrow == 0) {
#pragma unroll
    for (int mf = 0; mf < 4; ++mf)
#pragma unroll
      for (int r = 0; r < 4; ++r)
        ps[((size_t)bh * NPART_ + part) * 64 + mf * 16 + lgrp * 4 + r] = ssum[mf][r];
  }
  if (lgrp == 0) {
#pragma unroll
    for (int nf = 0; nf < 4; ++nf)
      pacc0[((size_t)bh * NPART_ + part) * 64 + nf * 16 + lrow] = oneacc[nf][0];
  }
}

// Fused 2: blocks 0..15 = SVD phase 2 (+pinv); 16..271 = ker3kv.
__global__ __launch_bounds__(256, 1) void fused2_kernel(
    const unsigned short* __restrict__ qlh,
    const unsigned short* __restrict__ qll,
    const unsigned short* __restrict__ k4,
    const unsigned short* __restrict__ vt,
    float* __restrict__ pacc, float* __restrict__ pacc0, float* __restrict__ ps,
    const float* __restrict__ asave, const float* __restrict__ vsave,
    float* __restrict__ pinv) {
  __shared__ __align__(16) char smem[38400];
  int tid = threadIdx.x;
  int blk = blockIdx.x;
  if (blk < 16) { svd_phase2(asave, vsave, pinv, blk, smem, tid); return; }
  int g = blk - 16;
  int bh = g >> 4, ch = g & 15;
  ker3kv_body(qlh, qll, k4, vt, pacc, pacc0, ps, bh, ch, smem, tid);
}

// ---------------------------------------------------------------------------
__global__ __launch_bounds__(64) void ker2_kernel(const float* __restrict__ qland,
                                                  const float* __restrict__ kland,
                                                  float* __restrict__ ker2) {
  int bh = blockIdx.x;
  __shared__ float kl[64][68];
  __shared__ float ql[64][68];
  int t = threadIdx.x;
  for (int i = 0; i < 16; ++i) {
    int s = t + i * 64;
    int r = s >> 4, d4 = (s & 15) << 2;
    *(float4*)&kl[r][d4] = *(const float4*)(kland + ((size_t)bh * 64 + r) * 64 + d4);
    *(float4*)&ql[r][d4] = *(const float4*)(qland + ((size_t)bh * 64 + r) * 64 + d4);
  }
  __syncthreads();
  float z[64];
  float se = 0.f;
  for (int j = 0; j < 64; ++j) {
    float acc = 0.f;
#pragma unroll
    for (int d4 = 0; d4 < 64; d4 += 4) {
      float4 qv = *(float4*)&ql[t][d4];
      float4 kv = *(float4*)&kl[j][d4];
      acc += qv.x * kv.x + qv.y * kv.y + qv.z * kv.z + qv.w * kv.w;
    }
    z[j] = expf(acc);
    se += z[j];
  }
  float inv = 1.0f / se;
  for (int j4 = 0; j4 < 64; j4 += 4) {
    float4 o = make_float4(z[j4] * inv, z[j4 + 1] * inv, z[j4 + 2] * inv, z[j4 + 3] * inv);
    *(float4*)(ker2 + ((size_t)bh * 64 + t) * 64 + j4) = o;
  }
}

// ---------------------------------------------------------------------------
__global__ __launch_bounds__(256) void kv_combine_kernel(const float* __restrict__ pacc,
                                                         const float* __restrict__ pacc0,
                                                         const float* __restrict__ ps,
                                                         float* __restrict__ kv) {
  int bh = blockIdx.y;
  int lm = blockIdx.x * 16 + (threadIdx.x >> 4);
  int d4 = (threadIdx.x & 15) * 4;
  float s = 16384.f;
  for (int part = 0; part < NPART_; ++part) s += ps[((size_t)bh * NPART_ + part) * 64 + lm];
  float4 a = make_float4(0.f, 0.f, 0.f, 0.f);
  for (int part = 0; part < NPART_; ++part) {
    float4 c0 = *(const float4*)&pacc0[((size_t)bh * NPART_ + part) * 64 + d4];
    float4 v = *(const float4*)&pacc[(((size_t)bh * NPART_ + part) * 64 + lm) * 64 + d4];
    a.x += c0.x + v.x; a.y += c0.y + v.y; a.z += c0.z + v.z; a.w += c0.w + v.w;
  }
  float inv = 1.f / s;
  float4 o = make_float4(a.x * inv, a.y * inv, a.z * inv, a.w * inv);
  *(float4*)(kv + ((size_t)bh * 64 + lm) * 64 + d4) = o;
}

// ---------------------------------------------------------------------------
__global__ __launch_bounds__(256) void mmat_kernel(const float* __restrict__ pinv,
                                                   const float* __restrict__ kv,
                                                   unsigned short* __restrict__ mtbh,
                                                   unsigned short* __restrict__ mtbl,
                                                   float* __restrict__ msum) {
  int bh = blockIdx.x;
  int tid = threadIdx.x;
  __shared__ float kvs[64][68];
  __shared__ double pcsd[64];
  for (int i = 0; i < 4; ++i) {
    int s = tid + i * 256;
    int r = s >> 4, d4 = (s & 15) << 2;
    *(float4*)&kvs[r][d4] = *(const float4*)(kv + ((size_t)bh * 64 + r) * 64 + d4);
  }
  if (tid < 64) {
    double s = 0.0;
    for (int l = 0; l < 64; ++l) s += (double)pinv[((size_t)bh * 64 + l) * 64 + tid];
    pcsd[tid] = s;
  }
  __syncthreads();
  int l = tid >> 2, t = tid & 3;
  double o[16] = {};
  for (int j = 0; j < 64; ++j) {
    double pv = (double)pinv[((size_t)bh * 64 + l) * 64 + j];
#pragma unroll
    for (int i = 0; i < 16; ++i) o[i] += pv * (double)kvs[j][t * 16 + i];
  }
#pragma unroll
  for (int i = 0; i < 16; ++i) {
    float f = (float)o[i];
    unsigned short hi = f2bf(f);
    float lo = f - bf2f(hi);
    int d = t * 16 + i;
    mtbh[((size_t)bh * 64 + d) * 64 + l] = hi;
    mtbl[((size_t)bh * 64 + d) * 64 + l] = f2bf(lo);
  }
  if (tid < 64) {
    double m = 0.0;
    for (int j = 0; j < 64; ++j) m += pcsd[j] * (double)kvs[j][tid];
    msum[(size_t)bh * 64 + tid] = (float)(m * (1.0 / 64.0));
  }
}

// ---------------------------------------------------------------------------
__global__ __launch_bounds__(256, 1) void ker1out_mfma_kernel(
    const unsigned short* __restrict__ q4,
    const unsigned short* __restrict__ klb,
    const unsigned short* __restrict__ mtbh,
    const unsigned short* __restrict__ mtbl,
    const float* __restrict__ msum,
    unsigned short* __restrict__ outh) {
  int bh = blockIdx.y, tile = blockIdx.x;
  int b = bh >> 3, h = bh & 7;
  int tid = threadIdx.x, w = tid >> 6, lane = tid & 63;
  int lrow = lane & 15, lgrp = lane >> 4;
  int tok0 = tile * 256 + w * 64;
  __shared__ __align__(16) unsigned short Pl[4][64 * 72];
  unsigned short* myP = &Pl[w][0];

  f32x4 sacc[4][4] = {};
#pragma unroll
  for (int ks = 0; ks < 2; ++ks) {
    bf16x8 kb[4];
#pragma unroll
    for (int nf = 0; nf < 4; ++nf)
      kb[nf] = ld_bf8(klb + ((size_t)bh * 64 + nf * 16 + lrow) * 64 + ks * 32 + lgrp * 8);
#pragma unroll
    for (int mf = 0; mf < 4; ++mf) {
      bf16x8 qa = ld_bf8(q4 + ((size_t)bh * N_ + tok0 + mf * 16 + lrow) * 64 + ks * 32 + lgrp * 8);
#pragma unroll
      for (int nf = 0; nf < 4; ++nf)
        sacc[mf][nf] = __builtin_amdgcn_mfma_f32_16x16x32_bf16(qa, kb[nf], sacc[mf][nf], 0, 0, 0);
    }
  }
  f32x4 ssum[4] = {};
#pragma unroll
  for (int mf = 0; mf < 4; ++mf)
#pragma unroll
    for (int nf = 0; nf < 4; ++nf)
#pragma unroll
      for (int r = 0; r < 4; ++r) {
        sacc[mf][nf][r] = expf(sacc[mf][nf][r]);
        ssum[mf][r] += sacc[mf][nf][r];
      }
#pragma unroll
  for (int mf = 0; mf < 4; ++mf)
#pragma unroll
    for (int m = 1; m < 16; m <<= 1)
#pragma unroll
      for (int r = 0; r < 4; ++r) ssum[mf][r] += __shfl_xor(ssum[mf][r], m);
#pragma unroll
  for (int mf = 0; mf < 4; ++mf) {
    f32x4 inv;
#pragma unroll
    for (int r = 0; r < 4; ++r) inv[r] = 1.f / ssum[mf][r];
#pragma unroll
    for (int nf = 0; nf < 4; ++nf)
#pragma unroll
      for (int r = 0; r < 4; ++r) {
        float pdev = fmaf(sacc[mf][nf][r], inv[r], -0.015625f);
        myP[(mf * 16 + lgrp * 4 + r) * 72 + nf * 16 + lrow] = f2bf(pdev);
      }
  }

  f32x4 oacc[4][4] = {};
#pragma unroll
  for (int ks = 0; ks < 2; ++ks) {
    bf16x8 pa[4];
#pragma unroll
    for (int mf = 0; mf < 4; ++mf)
      pa[mf] = ld_bf8(myP + (mf * 16 + lrow) * 72 + ks * 32 + lgrp * 8);
#pragma unroll
    for (int nf = 0; nf < 4; ++nf) {
      bf16x8 mh = ld_bf8(mtbh + ((size_t)bh * 64 + nf * 16 + lrow) * 64 + ks * 32 + lgrp * 8);
      bf16x8 ml = ld_bf8(mtbl + ((size_t)bh * 64 + nf * 16 + lrow) * 64 + ks * 32 + lgrp * 8);
#pragma unroll
      for (int mf = 0; mf < 4; ++mf) {
        oacc[mf][nf] = __builtin_amdgcn_mfma_f32_16x16x32_bf16(pa[mf], mh, oacc[mf][nf], 0, 0, 0);
        oacc[mf][nf] = __builtin_amdgcn_mfma_f32_16x16x32_bf16(pa[mf], ml, oacc[mf][nf], 0, 0, 0);
      }
    }
  }
#pragma unroll
  for (int nf = 0; nf < 4; ++nf) {
    float ms = msum[(size_t)bh * 64 + nf * 16 + lrow];
#pragma unroll
    for (int mf = 0; mf < 4; ++mf)
#pragma unroll
      for (int r = 0; r < 4; ++r) {
        int tok = tok0 + mf * 16 + lgrp * 4 + r;
        int d = nf * 16 + lrow;
        outh[((size_t)b * N_ + tok) * C_ + h * HD_ + d] = f2bf(oacc[mf][nf][r] + ms);
      }
  }
}

// ---------------------------------------------------------------------------
// Final projection (serial tail): outh(bf16) @ wob^T(bf16) + bo -> f32 out.
// DMA-staged via global_load_lds (both operands bf16).
__global__ __launch_bounds__(256) void oproj_kernel(const unsigned short* __restrict__ outh,
                                                    const unsigned short* __restrict__ wob,
                                                    const float* __restrict__ bo,
                                                    float* __restrict__ out) {
  __shared__ __align__(16) unsigned short Xs[128 * 32];
  __shared__ __align__(16) unsigned short Ws[128 * 32];
  int tid = threadIdx.x;
  int w = tid >> 6, lane = tid & 63;
  int wr = w >> 1, wc = w & 1;
  int row0 = blockIdx.x * 128, col0 = blockIdx.y * 128;
  f32x4 acc[4][4] = {};

  for (int k0 = 0; k0 < C_; k0 += 32) {
    __syncthreads();
#pragma unroll
    for (int i = 0; i < 2; ++i) {
      // X rows w*32+i*16 .. +16: lane L -> row +L/4, 16B chunk L%4 (LDS linear)
      const unsigned short* gx = outh + (size_t)(row0 + w * 32 + i * 16 + (lane >> 2)) * C_ + k0 + (lane & 3) * 8;
      gload_lds16(gx, &Xs[(w * 32 + i * 16) * 32]);
      const unsigned short* gw = wob + (size_t)(col0 + w * 32 + i * 16 + (lane >> 2)) * C_ + k0 + (lane & 3) * 8;
      gload_lds16(gw, &Ws[(w * 32 + i * 16) * 32]);
    }
    __syncthreads();
    bf16x8 af[4], bfr[4];
#pragma unroll
    for (int m = 0; m < 4; ++m)
      af[m] = *(bf16x8*)&Xs[(wr * 64 + m * 16 + (lane & 15)) * 32 + (lane >> 4) * 8];
#pragma unroll
    for (int n = 0; n < 4; ++n)
      bfr[n] = *(bf16x8*)&Ws[(wc * 64 + n * 16 + (lane & 15)) * 32 + (lane >> 4) * 8];
#pragma unroll
    for (int m = 0; m < 4; ++m)
#pragma unroll
      for (int n = 0; n < 4; ++n)
        acc[m][n] = __builtin_amdgcn_mfma_f32_16x16x32_bf16(af[m], bfr[n], acc[m][n], 0, 0, 0);
  }

#pragma unroll
  for (int m = 0; m < 4; ++m) {
    int rbase = row0 + wr * 64 + m * 16 + (lane >> 4) * 4;
#pragma unroll
    for (int n = 0; n < 4; ++n) {
      int c = col0 + wc * 64 + n * 16 + (lane & 15);
      float bc = bo[c];
#pragma unroll
      for (int rg = 0; rg < 4; ++rg)
        out[(size_t)(rbase + rg) * C_ + c] = acc[m][n][rg] + bc;
    }
  }
}

// ---------------------------------------------------------------------------
extern "C" void kernel_launch(void* const* d_in, const int* in_sizes, int n_in,
                              void* d_out, int out_size, void* d_ws, size_t ws_size,
                              hipStream_t stream) {
  const float* x  = (const float*)d_in[0];
  const float* wq = (const float*)d_in[1];
  const float* bq = (const float*)d_in[2];
  const float* wk = (const float*)d_in[3];
  const float* bk = (const float*)d_in[4];
  const float* wv = (const float*)d_in[5];
  const float* bv = (const float*)d_in[6];
  const float* wo = (const float*)d_in[7];
  const float* bo = (const float*)d_in[8];
  float* out = (float*)d_out;

  char* base = (char*)d_ws;
  const size_t QKV = (size_t)BH_ * N_ * HD_;
  unsigned short* q4 = (unsigned short*)base;                 // 32MB
  unsigned short* k4 = (unsigned short*)(base + QKV * 2);     // 32MB
  unsigned short* vt = (unsigned short*)(base + QKV * 4);     // 32MB
  unsigned short* outh = (unsigned short*)(base + QKV * 2);   // alias k4 (dead after ker3kv)
  char* sp = base + QKV * 6;
  float* pacc  = (float*)sp; sp += (size_t)BH_ * NPART_ * 64 * 64 * 4;  // 16.78MB
  float* pacc0 = (float*)sp; sp += (size_t)BH_ * NPART_ * 64 * 4;
  float* ps    = (float*)sp; sp += (size_t)BH_ * NPART_ * 64 * 4;
  float* xbar  = (float*)sp; sp += (size_t)B_ * LM_ * C_ * 4;
  float* qland = (float*)sp; sp += (size_t)BH_ * LM_ * HD_ * 4;
  float* kland = (float*)sp; sp += (size_t)BH_ * LM_ * HD_ * 4;
  unsigned short* qlbh = (unsigned short*)sp; sp += (size_t)BH_ * LM_ * HD_ * 2;
  unsigned short* qlbl = (unsigned short*)sp; sp += (size_t)BH_ * LM_ * HD_ * 2;
  unsigned short* klb  = (unsigned short*)sp; sp += (size_t)BH_ * LM_ * HD_ * 2;
  float* ker2  = (float*)sp; sp += (size_t)BH_ * LM_ * LM_ * 4;
  float* pinv  = (float*)sp; sp += (size_t)BH_ * LM_ * LM_ * 4;
  float* kvb   = (float*)sp; sp += (size_t)BH_ * LM_ * HD_ * 4;
  unsigned short* mtbh = (unsigned short*)sp; sp += (size_t)BH_ * LM_ * HD_ * 2;
  unsigned short* mtbl = (unsigned short*)sp; sp += (size_t)BH_ * LM_ * HD_ * 2;
  float* msum  = (float*)sp; sp += (size_t)BH_ * HD_ * 4;
  float* asave = (float*)sp; sp += (size_t)BH_ * LM_ * LM_ * 4;   // 256KB
  float* vsave = (float*)sp; sp += (size_t)BH_ * LM_ * LM_ * 4;   // 256KB
  unsigned short* wob = (unsigned short*)sp; sp += (size_t)C_ * C_ * 2;  // 512KB

  const float scaleq = 0.125f;
  const int L = BH_ * LM_ * HD_;
  const int L8 = L / 8;
  const int W8 = (C_ * C_) / 8;

  // wo -> bf16 (needed only by the serial-tail oproj)
  cvt_bf16_kernel<<<W8 / 256, 256, 0, stream>>>(wo, wob, W8);

  // landmark path (f32-exact)
  seg_mean_kernel<<<B_ * LM_, 256, 0, stream>>>(x, xbar);
  dim3 gl(2, 8);
  gemm_nt_kernel<<<gl, 256, 0, stream>>>(xbar, wq, bq, qland, scaleq, LM_);
  gemm_nt_kernel<<<gl, 256, 0, stream>>>(xbar, wk, bk, kland, 1.0f, LM_);
  cvt_bf16_pair_kernel<<<L / 256, 256, 0, stream>>>(qland, qlbh, qlbl, L);
  cvt_bf16_kernel<<<L8 / 256, 256, 0, stream>>>(kland, klb, L8);
  ker2_kernel<<<BH_, 64, 0, stream>>>(qland, kland, ker2);

  // fused 1: SVD phase 1 (blocks 0..15) + q/k/v projections
  fused1_kernel<<<16 + 3 * 1024, 256, 0, stream>>>(
      x, wq, bq, wk, bk, wv, bv, q4, k4, vt, ker2, asave, vsave);

  // fused 2: SVD phase 2 + pinv (blocks 0..15) + ker3kv (256 blocks)
  fused2_kernel<<<16 + NCH_ * BH_, 256, 0, stream>>>(
      qlbh, qlbl, k4, vt, pacc, pacc0, ps, asave, vsave, pinv);

  // combine + M
  dim3 g7(4, BH_);
  kv_combine_kernel<<<g7, 256, 0, stream>>>(pacc, pacc0, ps, kvb);
  mmat_kernel<<<BH_, 256, 0, stream>>>(pinv, kvb, mtbh, mtbl, msum);

  // out_heads -> bf16 outh (aliases dead k4)
  dim3 g9(N_ / 256, BH_);
  ker1out_mfma_kernel<<<g9, 256, 0, stream>>>(q4, klb, mtbh, mtbl, msum, outh);

  // final projection (DMA-staged bf16 GEMM)
  dim3 g10(B_ * N_ / 128, C_ / 128);
  oproj_kernel<<<g10, 256, 0, stream>>>(outh, wob, bo, out);
}

// Round 10
// 591.040 us; speedup vs baseline: 5.9014x; 1.0068x over previous
//
#include <hip/hip_runtime.h>
#include <stdint.h>

// NystromAttention MI355X — Round 10: s_setprio(3) on SVD waves (both fused
// phases) to stop CU-scheduler starvation of the 504-round latency chain;
// fold qland/kland bf16 converts into ker2; merge landmark GEMMs.
// All numerics identical to round 9 (passed, absmax 6.1e-5).

constexpr int B_   = 2;
constexpr int N_   = 16384;
constexpr int C_   = 512;
constexpr int H_   = 8;
constexpr int HD_  = 64;
constexpr int LM_  = 64;
constexpr int SEG_ = 256;
constexpr int BH_  = 16;
constexpr int NCH_ = 16;
constexpr int NPART_ = 64;
constexpr int SW1_ = 5;   // sweeps in phase 1
constexpr int SW2_ = 3;   // sweeps in phase 2

#define RCOND_ (640.0 * 1.1920928955078125e-07)

typedef unsigned short ushort4_t __attribute__((ext_vector_type(4)));
typedef unsigned short ushort8_t __attribute__((ext_vector_type(8)));
typedef __bf16 bf16x8 __attribute__((ext_vector_type(8)));
typedef float f32x4 __attribute__((ext_vector_type(4)));

__device__ inline float bf2f(unsigned short u) {
  union { unsigned int i; float f; } x; x.i = ((unsigned int)u) << 16; return x.f;
}
__device__ inline unsigned short f2bf(float f) {
  union { float f; unsigned int i; } x; x.f = f;
  unsigned int lsb = (x.i >> 16) & 1;
  return (unsigned short)((x.i + 0x7fffu + lsb) >> 16);
}
__device__ inline bf16x8 ld_bf8(const unsigned short* p) { return *(const bf16x8*)p; }

__device__ __forceinline__ void gload_lds16(const unsigned short* gsrc, unsigned short* ldst) {
  __builtin_amdgcn_global_load_lds((const __attribute__((address_space(1))) void*)gsrc,
                                   (__attribute__((address_space(3))) void*)ldst, 16, 0, 0);
}

// ---------------------------------------------------------------------------
__global__ __launch_bounds__(256) void cvt_bf16_kernel(const float* __restrict__ src,
                                                       unsigned short* __restrict__ dst,
                                                       int n8) {
  int i = (blockIdx.x * 256 + threadIdx.x);
  if (i >= n8) return;
  const float* s = src + (size_t)i * 8;
  float4 x0 = *(const float4*)(s);
  float4 x1 = *(const float4*)(s + 4);
  ushort8_t u;
  u[0] = f2bf(x0.x); u[1] = f2bf(x0.y); u[2] = f2bf(x0.z); u[3] = f2bf(x0.w);
  u[4] = f2bf(x1.x); u[5] = f2bf(x1.y); u[6] = f2bf(x1.z); u[7] = f2bf(x1.w);
  *(ushort8_t*)(dst + (size_t)i * 8) = u;
}

// ---------------------------------------------------------------------------
__global__ __launch_bounds__(256) void seg_mean_kernel(const float* __restrict__ x,
                                                       float* __restrict__ xbar) {
  int bl = blockIdx.x;
  int b = bl / LM_, l = bl % LM_;
  int t = threadIdx.x;
  int c4 = t & 127;
  int rh = t >> 7;
  const float* xp = x + ((size_t)b * N_ + (size_t)l * SEG_) * C_;
  float4 s = make_float4(0.f, 0.f, 0.f, 0.f);
  for (int r = rh * 128; r < rh * 128 + 128; ++r) {
    float4 v = *(const float4*)(xp + (size_t)r * C_ + c4 * 4);
    s.x += v.x; s.y += v.y; s.z += v.z; s.w += v.w;
  }
  __shared__ float red[2][512];
  *(float4*)&red[rh][c4 * 4] = s;
  __syncthreads();
  if (rh == 0) {
    float4 a = *(float4*)&red[0][c4 * 4];
    float4 c = *(float4*)&red[1][c4 * 4];
    const float invs = 1.0f / SEG_;
    float4 o;
    o.x = (a.x + c.x) * invs; o.y = (a.y + c.y) * invs;
    o.z = (a.z + c.z) * invs; o.w = (a.w + c.w) * invs;
    *(float4*)(xbar + (size_t)bl * C_ + c4 * 4) = o;
  }
}

// ---------------------------------------------------------------------------
// f32 VALU GEMM body for landmark projections (128 rows): f32 head-split out.
__device__ void gemm_nt_body(const float* __restrict__ A,
                             const float* __restrict__ W,
                             const float* __restrict__ bias,
                             float* __restrict__ out,
                             float scale, int rpb, int row0, int col0,
                             float (*As)[68], float (*Ws)[68], int tid) {
  int tm = tid >> 4, tn = tid & 15;
  float acc[4][4] = {};
  for (int k0 = 0; k0 < C_; k0 += 32) {
#pragma unroll
    for (int i = 0; i < 2; ++i) {
      int s = tid + i * 256;
      int r = s >> 3;
      int kg = (s & 7) << 2;
      float4 av = *(const float4*)(A + (size_t)(row0 + r) * C_ + k0 + kg);
      As[kg + 0][r] = av.x; As[kg + 1][r] = av.y;
      As[kg + 2][r] = av.z; As[kg + 3][r] = av.w;
      float4 wv = *(const float4*)(W + (size_t)(col0 + r) * C_ + k0 + kg);
      Ws[kg + 0][r] = wv.x; Ws[kg + 1][r] = wv.y;
      Ws[kg + 2][r] = wv.z; Ws[kg + 3][r] = wv.w;
    }
    __syncthreads();
#pragma unroll
    for (int kk = 0; kk < 32; ++kk) {
      float4 a = *(const float4*)&As[kk][tm * 4];
      float4 b = *(const float4*)&Ws[kk][tn * 4];
      float av[4] = {a.x, a.y, a.z, a.w};
      float bv[4] = {b.x, b.y, b.z, b.w};
#pragma unroll
      for (int i = 0; i < 4; ++i)
#pragma unroll
        for (int j = 0; j < 4; ++j) acc[i][j] += av[i] * bv[j];
    }
    __syncthreads();
  }
#pragma unroll
  for (int i = 0; i < 4; ++i) {
    int row = row0 + tm * 4 + i;
    int d0 = tn * 4;
    float o4[4];
#pragma unroll
    for (int j = 0; j < 4; ++j) o4[j] = (acc[i][j] + bias[col0 + d0 + j]) * scale;
    int b = row / rpb, n = row % rpb;
    int h = col0 >> 6;
    size_t idx = (((size_t)(b * H_ + h) * rpb) + n) * HD_ + d0;
    float4 o; o.x = o4[0]; o.y = o4[1]; o.z = o4[2]; o.w = o4[3];
    *(float4*)(out + idx) = o;
  }
}

// Merged landmark projections: grid (4, 8); blockIdx.x>>1 = {q,k}.
__global__ __launch_bounds__(256) void land_gemm_kernel(const float* __restrict__ xbar,
                                                        const float* __restrict__ wq,
                                                        const float* __restrict__ bq,
                                                        const float* __restrict__ wk,
                                                        const float* __restrict__ bk,
                                                        float* __restrict__ qland,
                                                        float* __restrict__ kland) {
  __shared__ float As[32][68];
  __shared__ float Ws[32][68];
  int which = blockIdx.x >> 1;
  int row0 = (blockIdx.x & 1) * 64;
  int col0 = blockIdx.y * 64;
  if (which == 0)
    gemm_nt_body(xbar, wq, bq, qland, 0.125f, LM_, row0, col0, As, Ws, threadIdx.x);
  else
    gemm_nt_body(xbar, wk, bk, kland, 1.0f, LM_, row0, col0, As, Ws, threadIdx.x);
}

// ---------------------------------------------------------------------------
// Reg-staged MFMA GEMM body (A f32, W f32 converted in staging).
// omode 1: bf16 head-split; omode 2: bf16 vt.
__device__ __forceinline__ void mfma_gemm_body(const float* __restrict__ A,
                                               const float* __restrict__ W,
                                               const float* __restrict__ bias,
                                               unsigned short* __restrict__ out,
                                               float scale, int omode,
                                               int row0, int col0,
                                               unsigned short* Xs, unsigned short* Ws,
                                               int tid) {
  int wid = tid >> 6, lane = tid & 63;
  int wr = wid >> 1, wc = wid & 1;
  f32x4 acc[4][4] = {};
  int srow = tid >> 1;
  int sk = (tid & 1) * 16;
  const float* wpbase = W + (size_t)(col0 + srow) * C_ + sk;
  const float* apbase = A + (size_t)(row0 + srow) * C_ + sk;
  unsigned short* xdst = &Xs[srow * 32 + sk];
  unsigned short* wdst = &Ws[srow * 32 + sk];

  for (int k0 = 0; k0 < C_; k0 += 32) {
    __syncthreads();
    {
      float4 x0 = *(const float4*)(apbase + k0);
      float4 x1 = *(const float4*)(apbase + k0 + 4);
      float4 x2 = *(const float4*)(apbase + k0 + 8);
      float4 x3 = *(const float4*)(apbase + k0 + 12);
      ushort8_t u0, u1;
      u0[0] = f2bf(x0.x); u0[1] = f2bf(x0.y); u0[2] = f2bf(x0.z); u0[3] = f2bf(x0.w);
      u0[4] = f2bf(x1.x); u0[5] = f2bf(x1.y); u0[6] = f2bf(x1.z); u0[7] = f2bf(x1.w);
      u1[0] = f2bf(x2.x); u1[1] = f2bf(x2.y); u1[2] = f2bf(x2.z); u1[3] = f2bf(x2.w);
      u1[4] = f2bf(x3.x); u1[5] = f2bf(x3.y); u1[6] = f2bf(x3.z); u1[7] = f2bf(x3.w);
      *(ushort8_t*)(xdst) = u0;
      *(ushort8_t*)(xdst + 8) = u1;
    }
    {
      float4 w0 = *(const float4*)(wpbase + k0);
      float4 w1 = *(const float4*)(wpbase + k0 + 4);
      float4 w2 = *(const float4*)(wpbase + k0 + 8);
      float4 w3 = *(const float4*)(wpbase + k0 + 12);
      ushort8_t u0, u1;
      u0[0] = f2bf(w0.x); u0[1] = f2bf(w0.y); u0[2] = f2bf(w0.z); u0[3] = f2bf(w0.w);
      u0[4] = f2bf(w1.x); u0[5] = f2bf(w1.y); u0[6] = f2bf(w1.z); u0[7] = f2bf(w1.w);
      u1[0] = f2bf(w2.x); u1[1] = f2bf(w2.y); u1[2] = f2bf(w2.z); u1[3] = f2bf(w2.w);
      u1[4] = f2bf(w3.x); u1[5] = f2bf(w3.y); u1[6] = f2bf(w3.z); u1[7] = f2bf(w3.w);
      *(ushort8_t*)(wdst) = u0;
      *(ushort8_t*)(wdst + 8) = u1;
    }
    __syncthreads();
    bf16x8 af[4], bfr[4];
#pragma unroll
    for (int m = 0; m < 4; ++m)
      af[m] = *(bf16x8*)&Xs[(wr * 64 + m * 16 + (lane & 15)) * 32 + (lane >> 4) * 8];
#pragma unroll
    for (int n = 0; n < 4; ++n)
      bfr[n] = *(bf16x8*)&Ws[(wc * 64 + n * 16 + (lane & 15)) * 32 + (lane >> 4) * 8];
#pragma unroll
    for (int m = 0; m < 4; ++m)
#pragma unroll
      for (int n = 0; n < 4; ++n)
        acc[m][n] = __builtin_amdgcn_mfma_f32_16x16x32_bf16(af[m], bfr[n], acc[m][n], 0, 0, 0);
  }

#pragma unroll
  for (int m = 0; m < 4; ++m) {
    int rbase = row0 + wr * 64 + m * 16 + (lane >> 4) * 4;
#pragma unroll
    for (int n = 0; n < 4; ++n) {
      int c = col0 + wc * 64 + n * 16 + (lane & 15);
      float bc = bias[c];
      if (omode == 2) {
        int b = rbase >> 14, nn = rbase & 16383;
        int h = c >> 6, d = c & 63;
        ushort4_t u;
#pragma unroll
        for (int rg = 0; rg < 4; ++rg) u[rg] = f2bf((acc[m][n][rg] + bc) * scale);
        *(ushort4_t*)(out + ((size_t)(b * H_ + h) * HD_ + d) * N_ + nn) = u;
      } else {
#pragma unroll
        for (int rg = 0; rg < 4; ++rg) {
          float val = (acc[m][n][rg] + bc) * scale;
          int r = rbase + rg;
          int b = r >> 14, nn = r & 16383, h = c >> 6, d = c & 63;
          out[(((size_t)(b * H_ + h) * N_) + nn) * HD_ + d] = f2bf(val);
        }
      }
    }
  }
}

// ---------------------------------------------------------------------------
// SVD sweep loop (4-wave row-split, shared by both phases).
__device__ __forceinline__ void svd_sweeps(float a[16], float v[16], char* smemraw,
                                           int w, int lane, int nsweeps) {
  float (*pg)[4][64] = (float(*)[4][64])(smemraw);          // 2048 B
  float (*pa4)[64]   = (float(*)[64])(smemraw + 2048);      // 1024 B
  for (int sweep = 0; sweep < nsweeps; ++sweep) {
    float p0 = 0.f, p1 = 0.f;
#pragma unroll
    for (int k = 0; k < 16; k += 2) { p0 = fmaf(a[k], a[k], p0); p1 = fmaf(a[k + 1], a[k + 1], p1); }
    pa4[w][lane] = p0 + p1;
    __syncthreads();
    float alpha = (pa4[0][lane] + pa4[1][lane]) + (pa4[2][lane] + pa4[3][lane]);
    for (int mask = 1; mask < 64; ++mask) {
      int buf = mask & 1;
      bool lower = lane < (lane ^ mask);
      float beta = __shfl_xor(alpha, mask);
      float o[16];
#pragma unroll
      for (int k = 0; k < 16; ++k) o[k] = __shfl_xor(a[k], mask);
      float g0 = 0.f, g1 = 0.f;
#pragma unroll
      for (int k = 0; k < 16; k += 2) { g0 = fmaf(a[k], o[k], g0); g1 = fmaf(a[k + 1], o[k + 1], g1); }
      pg[buf][w][lane] = g0 + g1;
      __syncthreads();
      float gamma = (pg[buf][0][lane] + pg[buf][1][lane]) + (pg[buf][2][lane] + pg[buf][3][lane]);
      bool need = (gamma * gamma > 1e-12f * alpha * beta);
      if (__any(need)) {
        float ov[16];
#pragma unroll
        for (int k = 0; k < 16; ++k) ov[k] = __shfl_xor(v[k], mask);
        float ap = lower ? alpha : beta;
        float aq = lower ? beta : alpha;
        float c = 1.f, s = 0.f;
        if (need) {
          float tau = (aq - ap) / (2.f * gamma);
          float t = copysignf(1.f, tau) / (fabsf(tau) + sqrtf(fmaf(tau, tau, 1.f)));
          c = rsqrtf(fmaf(t, t, 1.f));
          s = t * c;
        }
        float sm = lower ? -s : s;
#pragma unroll
        for (int k = 0; k < 16; ++k) a[k] = fmaf(sm, o[k], c * a[k]);
#pragma unroll
        for (int k = 0; k < 16; ++k) v[k] = fmaf(sm, ov[k], c * v[k]);
        float twocsg = 2.f * c * s * gamma;
        alpha = fmaf(c * c, alpha, fmaf(s * s, beta, lower ? -twocsg : twocsg));
      }
    }
  }
}

// Phase 1: load ker2, SW1_ sweeps, save state. High wave priority.
__device__ void svd_phase1(const float* __restrict__ ker2,
                           float* __restrict__ asave, float* __restrict__ vsave,
                           int bh, char* smemraw, int tid) {
  __builtin_amdgcn_s_setprio(3);
  int w = tid >> 6, lane = tid & 63;
  float a[16], v[16];
#pragma unroll
  for (int k = 0; k < 16; ++k)
    a[k] = ker2[((size_t)bh * 64 + w * 16 + k) * 64 + lane];
#pragma unroll
  for (int k = 0; k < 16; ++k) v[k] = (w * 16 + k == lane) ? 1.f : 0.f;
  svd_sweeps(a, v, smemraw, w, lane, SW1_);
#pragma unroll
  for (int k = 0; k < 16; ++k) {
    asave[((size_t)bh * 64 + w * 16 + k) * 64 + lane] = a[k];
    vsave[((size_t)bh * 64 + w * 16 + k) * 64 + lane] = v[k];
  }
  __builtin_amdgcn_s_setprio(0);
}

// Phase 2: load state, SW2_ sweeps, sigma/cutoff + pinv. High wave priority.
__device__ void svd_phase2(const float* __restrict__ asave, const float* __restrict__ vsave,
                           float* __restrict__ pinv, int bh, char* smemraw, int tid) {
  __builtin_amdgcn_s_setprio(3);
  double (*ps2)[64]  = (double(*)[64])(smemraw + 3072);     // 2048 B
  float (*vsL)[65]   = (float(*)[65])(smemraw + 5120);      // 16640 B
  float (*wasL)[65]  = (float(*)[65])(smemraw + 21760);     // 16640 B
  int w = tid >> 6, lane = tid & 63;
  float a[16], v[16];
#pragma unroll
  for (int k = 0; k < 16; ++k) {
    a[k] = asave[((size_t)bh * 64 + w * 16 + k) * 64 + lane];
    v[k] = vsave[((size_t)bh * 64 + w * 16 + k) * 64 + lane];
  }
  svd_sweeps(a, v, smemraw, w, lane, SW2_);

  double psig = 0.0;
#pragma unroll
  for (int k = 0; k < 16; ++k) psig += (double)a[k] * (double)a[k];
  ps2[w][lane] = psig;
  __syncthreads();
  double sig2 = (ps2[0][lane] + ps2[1][lane]) + (ps2[2][lane] + ps2[3][lane]);
  double smax = sig2;
#pragma unroll
  for (int m = 1; m < 64; m <<= 1) smax = fmax(smax, __shfl_xor(smax, m));
  double cutoff2 = smax * (RCOND_ * RCOND_);
  float wgt = (sig2 > cutoff2) ? (float)(1.0 / sig2) : 0.f;

#pragma unroll
  for (int k = 0; k < 16; ++k) {
    vsL[lane][w * 16 + k] = v[k];
    wasL[lane][w * 16 + k] = wgt * a[k];
  }
  __syncthreads();
  int i = tid >> 2;
  int j0 = (tid & 3) * 16;
  float acc[16] = {};
  for (int r = 0; r < 64; ++r) {
    float vv = vsL[r][i];
#pragma unroll
    for (int jj = 0; jj < 16; ++jj) acc[jj] = fmaf(vv, wasL[r][j0 + jj], acc[jj]);
  }
#pragma unroll
  for (int jj = 0; jj < 16; jj += 4) {
    float4 ovv = make_float4(acc[jj], acc[jj + 1], acc[jj + 2], acc[jj + 3]);
    *(float4*)(pinv + ((size_t)bh * 64 + i) * 64 + j0 + jj) = ovv;
  }
  __builtin_amdgcn_s_setprio(0);
}

// ---------------------------------------------------------------------------
// Fused 1: blocks 0..15 = SVD phase 1; 16..3087 = q/k/v projections.
__global__ __launch_bounds__(256) void fused1_kernel(
    const float* __restrict__ x,
    const float* __restrict__ wq, const float* __restrict__ bq,
    const float* __restrict__ wk, const float* __restrict__ bk,
    const float* __restrict__ wv, const float* __restrict__ bv,
    unsigned short* __restrict__ q4, unsigned short* __restrict__ k4,
    unsigned short* __restrict__ vt,
    const float* __restrict__ ker2,
    float* __restrict__ asave, float* __restrict__ vsave) {
  __shared__ __align__(16) char smem[16384];
  int tid = threadIdx.x;
  int blk = blockIdx.x;
  if (blk < 16) { svd_phase1(ker2, asave, vsave, blk, smem, tid); return; }
  int g = blk - 16;
  int which = g >> 10;
  int sub = g & 1023;
  int row0 = (sub >> 2) * 128;
  int col0 = (sub & 3) * 128;
  unsigned short* Xs = (unsigned short*)smem;
  unsigned short* Ws = Xs + 128 * 32;
  if (which == 0)
    mfma_gemm_body(x, wq, bq, q4, 0.125f, 1, row0, col0, Xs, Ws, tid);
  else if (which == 1)
    mfma_gemm_body(x, wk, bk, k4, 1.0f, 1, row0, col0, Xs, Ws, tid);
  else
    mfma_gemm_body(x, wv, bv, vt, 1.0f, 2, row0, col0, Xs, Ws, tid);
}

// ---------------------------------------------------------------------------
// ker3+kv body (deviation form, MFMA) — unchanged math.
__device__ void ker3kv_body(const unsigned short* __restrict__ qlh,
                            const unsigned short* __restrict__ qll,
                            const unsigned short* __restrict__ k4,
                            const unsigned short* __restrict__ vt,
                            float* __restrict__ pacc,
                            float* __restrict__ pacc0,
                            float* __restrict__ ps,
                            int bh, int ch, char* smemraw, int tid) {
  int w = tid >> 6, lane = tid & 63;
  int part = ch * 4 + w;
  int lrow = lane & 15, lgrp = lane >> 4;
  unsigned short* myP = (unsigned short*)smemraw + w * 64 * 72;

  bf16x8 qah[4][2], qal[4][2];
#pragma unroll
  for (int mf = 0; mf < 4; ++mf)
#pragma unroll
    for (int ks = 0; ks < 2; ++ks) {
      size_t off = ((size_t)bh * 64 + mf * 16 + lrow) * 64 + ks * 32 + lgrp * 8;
      qah[mf][ks] = ld_bf8(qlh + off);
      qal[mf][ks] = ld_bf8(qll + off);
    }
  bf16x8 onesf;
#pragma unroll
  for (int j = 0; j < 8; ++j) onesf[j] = (__bf16)1.0f;

  f32x4 kvacc[4][4] = {};
  f32x4 oneacc[4] = {};
  f32x4 ssum[4] = {};

  for (int sub = 0; sub < 4; ++sub) {
    int n0 = ch * 1024 + w * 256 + sub * 64;
    f32x4 sacc[4][4] = {};
#pragma unroll
    for (int ks = 0; ks < 2; ++ks) {
#pragma unroll
      for (int nf = 0; nf < 4; ++nf) {
        bf16x8 kb = ld_bf8(k4 + ((size_t)bh * N_ + n0 + nf * 16 + lrow) * 64 + ks * 32 + lgrp * 8);
#pragma unroll
        for (int mf = 0; mf < 4; ++mf) {
          sacc[mf][nf] = __builtin_amdgcn_mfma_f32_16x16x32_bf16(qah[mf][ks], kb, sacc[mf][nf], 0, 0, 0);
          sacc[mf][nf] = __builtin_amdgcn_mfma_f32_16x16x32_bf16(qal[mf][ks], kb, sacc[mf][nf], 0, 0, 0);
        }
      }
    }
#pragma unroll
    for (int mf = 0; mf < 4; ++mf) {
#pragma unroll
      for (int nf = 0; nf < 4; ++nf) {
#pragma unroll
        for (int r = 0; r < 4; ++r) {
          float pd = expf(sacc[mf][nf][r]) - 1.0f;
          ssum[mf][r] += pd;
          myP[(mf * 16 + lgrp * 4 + r) * 72 + nf * 16 + lrow] = f2bf(pd);
        }
      }
    }
#pragma unroll
    for (int ks = 0; ks < 2; ++ks) {
      bf16x8 pa[4];
#pragma unroll
      for (int mf = 0; mf < 4; ++mf)
        pa[mf] = ld_bf8(myP + (mf * 16 + lrow) * 72 + ks * 32 + lgrp * 8);
#pragma unroll
      for (int nf = 0; nf < 4; ++nf) {
        bf16x8 vb = ld_bf8(vt + ((size_t)bh * 64 + nf * 16 + lrow) * N_ + n0 + ks * 32 + lgrp * 8);
#pragma unroll
        for (int mf = 0; mf < 4; ++mf)
          kvacc[mf][nf] = __builtin_amdgcn_mfma_f32_16x16x32_bf16(pa[mf], vb, kvacc[mf][nf], 0, 0, 0);
        oneacc[nf] = __builtin_amdgcn_mfma_f32_16x16x32_bf16(onesf, vb, oneacc[nf], 0, 0, 0);
      }
    }
  }
#pragma unroll
  for (int mf = 0; mf < 4; ++mf)
#pragma unroll
    for (int m = 1; m < 16; m <<= 1)
#pragma unroll
      for (int r = 0; r < 4; ++r) ssum[mf][r] += __shfl_xor(ssum[mf][r], m);

  size_t pb = (((size_t)bh * NPART_ + part) * 64) * 64;
#pragma unroll
  for (int mf = 0; mf < 4; ++mf)
#pragma unroll
    for (int nf = 0; nf < 4; ++nf)
#pragma unroll
      for (int r = 0; r < 4; ++r)
        pacc[pb + (size_t)(mf * 16 + lgrp * 4 + r) * 64 + nf * 16 + lrow] = kvacc[mf][nf][r];
  if (lrow == 0) {
#pragma unroll
    for (int mf = 0; mf < 4; ++mf)
#pragma unroll
      for (int r = 0; r < 4; ++r)
        ps[((size_t)bh * NPART_ + part) * 64 + mf * 16 + lgrp * 4 + r] = ssum[mf][r];
  }
  if (lgrp == 0) {
#pragma unroll
    for (int nf = 0; nf < 4; ++nf)
      pacc0[((size_t)bh * NPART_ + part) * 64 + nf * 16 + lrow] = oneacc[nf][0];
  }
}

// Fused 2: blocks 0..15 = SVD phase 2 (+pinv); 16..271 = ker3kv.
__global__ __launch_bounds__(256, 1) void fused2_kernel(
    const unsigned short* __restrict__ qlh,
    const unsigned short* __restrict__ qll,
    const unsigned short* __restrict__ k4,
    const unsigned short* __restrict__ vt,
    float* __restrict__ pacc, float* __restrict__ pacc0, float* __restrict__ ps,
    const float* __restrict__ asave, const float* __restrict__ vsave,
    float* __restrict__ pinv) {
  __shared__ __align__(16) char smem[38400];
  int tid = threadIdx.x;
  int blk = blockIdx.x;
  if (blk < 16) { svd_phase2(asave, vsave, pinv, blk, smem, tid); return; }
  int g = blk - 16;
  int bh = g >> 4, ch = g & 15;
  ker3kv_body(qlh, qll, k4, vt, pacc, pacc0, ps, bh, ch, smem, tid);
}

// ---------------------------------------------------------------------------
// ker2 = softmax(qland klandT) per bh; also emits qland hi/lo and kland bf16.
__global__ __launch_bounds__(64) void ker2_kernel(const float* __restrict__ qland,
                                                  const float* __restrict__ kland,
                                                  float* __restrict__ ker2,
                                                  unsigned short* __restrict__ qlbh,
                                                  unsigned short* __restrict__ qlbl,
                                                  unsigned short* __restrict__ klb) {
  int bh = blockIdx.x;
  __shared__ float kl[64][68];
  __shared__ float ql[64][68];
  int t = threadIdx.x;
  for (int i = 0; i < 16; ++i) {
    int s = t + i * 64;
    int r = s >> 4, d4 = (s & 15) << 2;
    *(float4*)&kl[r][d4] = *(const float4*)(kland + ((size_t)bh * 64 + r) * 64 + d4);
    *(float4*)&ql[r][d4] = *(const float4*)(qland + ((size_t)bh * 64 + r) * 64 + d4);
  }
  __syncthreads();
  // bf16 conversions (row t)
  {
    size_t rb = ((size_t)bh * 64 + t) * 64;
    ushort8_t uh, ul, uk;
    for (int j0 = 0; j0 < 64; j0 += 8) {
#pragma unroll
      for (int j = 0; j < 8; ++j) {
        float qf = ql[t][j0 + j];
        unsigned short h = f2bf(qf);
        uh[j] = h;
        ul[j] = f2bf(qf - bf2f(h));
        uk[j] = f2bf(kl[t][j0 + j]);
      }
      *(ushort8_t*)(qlbh + rb + j0) = uh;
      *(ushort8_t*)(qlbl + rb + j0) = ul;
      *(ushort8_t*)(klb + rb + j0) = uk;
    }
  }
  float z[64];
  float se = 0.f;
  for (int j = 0; j < 64; ++j) {
    float acc = 0.f;
#pragma unroll
    for (int d4 = 0; d4 < 64; d4 += 4) {
      float4 qv = *(float4*)&ql[t][d4];
      float4 kv = *(float4*)&kl[j][d4];
      acc += qv.x * kv.x + qv.y * kv.y + qv.z * kv.z + qv.w * kv.w;
    }
    z[j] = expf(acc);
    se += z[j];
  }
  float inv = 1.0f / se;
  for (int j4 = 0; j4 < 64; j4 += 4) {
    float4 o = make_float4(z[j4] * inv, z[j4 + 1] * inv, z[j4 + 2] * inv, z[j4 + 3] * inv);
    *(float4*)(ker2 + ((size_t)bh * 64 + t) * 64 + j4) = o;
  }
}

// ---------------------------------------------------------------------------
__global__ __launch_bounds__(256) void kv_combine_kernel(const float* __restrict__ pacc,
                                                         const float* __restrict__ pacc0,
                                                         const float* __restrict__ ps,
                                                         float* __restrict__ kv) {
  int bh = blockIdx.y;
  int lm = blockIdx.x * 16 + (threadIdx.x >> 4);
  int d4 = (threadIdx.x & 15) * 4;
  float s = 16384.f;
  for (int part = 0; part < NPART_; ++part) s += ps[((size_t)bh * NPART_ + part) * 64 + lm];
  float4 a = make_float4(0.f, 0.f, 0.f, 0.f);
  for (int part = 0; part < NPART_; ++part) {
    float4 c0 = *(const float4*)&pacc0[((size_t)bh * NPART_ + part) * 64 + d4];
    float4 v = *(const float4*)&pacc[(((size_t)bh * NPART_ + part) * 64 + lm) * 64 + d4];
    a.x += c0.x + v.x; a.y += c0.y + v.y; a.z += c0.z + v.z; a.w += c0.w + v.w;
  }
  float inv = 1.f / s;
  float4 o = make_float4(a.x * inv, a.y * inv, a.z * inv, a.w * inv);
  *(float4*)(kv + ((size_t)bh * 64 + lm) * 64 + d4) = o;
}

// ---------------------------------------------------------------------------
__global__ __launch_bounds__(256) void mmat_kernel(const float* __restrict__ pinv,
                                                   const float* __restrict__ kv,
                                                   unsigned short* __restrict__ mtbh,
                                                   unsigned short* __restrict__ mtbl,
                                                   float* __restrict__ msum) {
  int bh = blockIdx.x;
  int tid = threadIdx.x;
  __shared__ float kvs[64][68];
  __shared__ double pcsd[64];
  for (int i = 0; i < 4; ++i) {
    int s = tid + i * 256;
    int r = s >> 4, d4 = (s & 15) << 2;
    *(float4*)&kvs[r][d4] = *(const float4*)(kv + ((size_t)bh * 64 + r) * 64 + d4);
  }
  if (tid < 64) {
    double s = 0.0;
    for (int l = 0; l < 64; ++l) s += (double)pinv[((size_t)bh * 64 + l) * 64 + tid];
    pcsd[tid] = s;
  }
  __syncthreads();
  int l = tid >> 2, t = tid & 3;
  double o[16] = {};
  for (int j = 0; j < 64; ++j) {
    double pv = (double)pinv[((size_t)bh * 64 + l) * 64 + j];
#pragma unroll
    for (int i = 0; i < 16; ++i) o[i] += pv * (double)kvs[j][t * 16 + i];
  }
#pragma unroll
  for (int i = 0; i < 16; ++i) {
    float f = (float)o[i];
    unsigned short hi = f2bf(f);
    float lo = f - bf2f(hi);
    int d = t * 16 + i;
    mtbh[((size_t)bh * 64 + d) * 64 + l] = hi;
    mtbl[((size_t)bh * 64 + d) * 64 + l] = f2bf(lo);
  }
  if (tid < 64) {
    double m = 0.0;
    for (int j = 0; j < 64; ++j) m += pcsd[j] * (double)kvs[j][tid];
    msum[(size_t)bh * 64 + tid] = (float)(m * (1.0 / 64.0));
  }
}

// ---------------------------------------------------------------------------
__global__ __launch_bounds__(256, 1) void ker1out_mfma_kernel(
    const unsigned short* __restrict__ q4,
    const unsigned short* __restrict__ klb,
    const unsigned short* __restrict__ mtbh,
    const unsigned short* __restrict__ mtbl,
    const float* __restrict__ msum,
    unsigned short* __restrict__ outh) {
  int bh = blockIdx.y, tile = blockIdx.x;
  int b = bh >> 3, h = bh & 7;
  int tid = threadIdx.x, w = tid >> 6, lane = tid & 63;
  int lrow = lane & 15, lgrp = lane >> 4;
  int tok0 = tile * 256 + w * 64;
  __shared__ __align__(16) unsigned short Pl[4][64 * 72];
  unsigned short* myP = &Pl[w][0];

  f32x4 sacc[4][4] = {};
#pragma unroll
  for (int ks = 0; ks < 2; ++ks) {
    bf16x8 kb[4];
#pragma unroll
    for (int nf = 0; nf < 4; ++nf)
      kb[nf] = ld_bf8(klb + ((size_t)bh * 64 + nf * 16 + lrow) * 64 + ks * 32 + lgrp * 8);
#pragma unroll
    for (int mf = 0; mf < 4; ++mf) {
      bf16x8 qa = ld_bf8(q4 + ((size_t)bh * N_ + tok0 + mf * 16 + lrow) * 64 + ks * 32 + lgrp * 8);
#pragma unroll
      for (int nf = 0; nf < 4; ++nf)
        sacc[mf][nf] = __builtin_amdgcn_mfma_f32_16x16x32_bf16(qa, kb[nf], sacc[mf][nf], 0, 0, 0);
    }
  }
  f32x4 ssum[4] = {};
#pragma unroll
  for (int mf = 0; mf < 4; ++mf)
#pragma unroll
    for (int nf = 0; nf < 4; ++nf)
#pragma unroll
      for (int r = 0; r < 4; ++r) {
        sacc[mf][nf][r] = expf(sacc[mf][nf][r]);
        ssum[mf][r] += sacc[mf][nf][r];
      }
#pragma unroll
  for (int mf = 0; mf < 4; ++mf)
#pragma unroll
    for (int m = 1; m < 16; m <<= 1)
#pragma unroll
      for (int r = 0; r < 4; ++r) ssum[mf][r] += __shfl_xor(ssum[mf][r], m);
#pragma unroll
  for (int mf = 0; mf < 4; ++mf) {
    f32x4 inv;
#pragma unroll
    for (int r = 0; r < 4; ++r) inv[r] = 1.f / ssum[mf][r];
#pragma unroll
    for (int nf = 0; nf < 4; ++nf)
#pragma unroll
      for (int r = 0; r < 4; ++r) {
        float pdev = fmaf(sacc[mf][nf][r], inv[r], -0.015625f);
        myP[(mf * 16 + lgrp * 4 + r) * 72 + nf * 16 + lrow] = f2bf(pdev);
      }
  }

  f32x4 oacc[4][4] = {};
#pragma unroll
  for (int ks = 0; ks < 2; ++ks) {
    bf16x8 pa[4];
#pragma unroll
    for (int mf = 0; mf < 4; ++mf)
      pa[mf] = ld_bf8(myP + (mf * 16 + lrow) * 72 + ks * 32 + lgrp * 8);
#pragma unroll
    for (int nf = 0; nf < 4; ++nf) {
      bf16x8 mh = ld_bf8(mtbh + ((size_t)bh * 64 + nf * 16 + lrow) * 64 + ks * 32 + lgrp * 8);
      bf16x8 ml = ld_bf8(mtbl + ((size_t)bh * 64 + nf * 16 + lrow) * 64 + ks * 32 + lgrp * 8);
#pragma unroll
      for (int mf = 0; mf < 4; ++mf) {
        oacc[mf][nf] = __builtin_amdgcn_mfma_f32_16x16x32_bf16(pa[mf], mh, oacc[mf][nf], 0, 0, 0);
        oacc[mf][nf] = __builtin_amdgcn_mfma_f32_16x16x32_bf16(pa[mf], ml, oacc[mf][nf], 0, 0, 0);
      }
    }
  }
#pragma unroll
  for (int nf = 0; nf < 4; ++nf) {
    float ms = msum[(size_t)bh * 64 + nf * 16 + lrow];
#pragma unroll
    for (int mf = 0; mf < 4; ++mf)
#pragma unroll
      for (int r = 0; r < 4; ++r) {
        int tok = tok0 + mf * 16 + lgrp * 4 + r;
        int d = nf * 16 + lrow;
        outh[((size_t)b * N_ + tok) * C_ + h * HD_ + d] = f2bf(oacc[mf][nf][r] + ms);
      }
  }
}

// ---------------------------------------------------------------------------
// Final projection (serial tail): outh(bf16) @ wob^T(bf16) + bo -> f32 out.
// DMA-staged via global_load_lds (both operands bf16).
__global__ __launch_bounds__(256) void oproj_kernel(const unsigned short* __restrict__ outh,
                                                    const unsigned short* __restrict__ wob,
                                                    const float* __restrict__ bo,
                                                    float* __restrict__ out) {
  __shared__ __align__(16) unsigned short Xs[128 * 32];
  __shared__ __align__(16) unsigned short Ws[128 * 32];
  int tid = threadIdx.x;
  int w = tid >> 6, lane = tid & 63;
  int wr = w >> 1, wc = w & 1;
  int row0 = blockIdx.x * 128, col0 = blockIdx.y * 128;
  f32x4 acc[4][4] = {};

  for (int k0 = 0; k0 < C_; k0 += 32) {
    __syncthreads();
#pragma unroll
    for (int i = 0; i < 2; ++i) {
      const unsigned short* gx = outh + (size_t)(row0 + w * 32 + i * 16 + (lane >> 2)) * C_ + k0 + (lane & 3) * 8;
      gload_lds16(gx, &Xs[(w * 32 + i * 16) * 32]);
      const unsigned short* gw = wob + (size_t)(col0 + w * 32 + i * 16 + (lane >> 2)) * C_ + k0 + (lane & 3) * 8;
      gload_lds16(gw, &Ws[(w * 32 + i * 16) * 32]);
    }
    __syncthreads();
    bf16x8 af[4], bfr[4];
#pragma unroll
    for (int m = 0; m < 4; ++m)
      af[m] = *(bf16x8*)&Xs[(wr * 64 + m * 16 + (lane & 15)) * 32 + (lane >> 4) * 8];
#pragma unroll
    for (int n = 0; n < 4; ++n)
      bfr[n] = *(bf16x8*)&Ws[(wc * 64 + n * 16 + (lane & 15)) * 32 + (lane >> 4) * 8];
#pragma unroll
    for (int m = 0; m < 4; ++m)
#pragma unroll
      for (int n = 0; n < 4; ++n)
        acc[m][n] = __builtin_amdgcn_mfma_f32_16x16x32_bf16(af[m], bfr[n], acc[m][n], 0, 0, 0);
  }

#pragma unroll
  for (int m = 0; m < 4; ++m) {
    int rbase = row0 + wr * 64 + m * 16 + (lane >> 4) * 4;
#pragma unroll
    for (int n = 0; n < 4; ++n) {
      int c = col0 + wc * 64 + n * 16 + (lane & 15);
      float bc = bo[c];
#pragma unroll
      for (int rg = 0; rg < 4; ++rg)
        out[(size_t)(rbase + rg) * C_ + c] = acc[m][n][rg] + bc;
    }
  }
}

// ---------------------------------------------------------------------------
extern "C" void kernel_launch(void* const* d_in, const int* in_sizes, int n_in,
                              void* d_out, int out_size, void* d_ws, size_t ws_size,
                              hipStream_t stream) {
  const float* x  = (const float*)d_in[0];
  const float* wq = (const float*)d_in[1];
  const float* bq = (const float*)d_in[2];
  const float* wk = (const float*)d_in[3];
  const float* bk = (const float*)d_in[4];
  const float* wv = (const float*)d_in[5];
  const float* bv = (const float*)d_in[6];
  const float* wo = (const float*)d_in[7];
  const float* bo = (const float*)d_in[8];
  float* out = (float*)d_out;

  char* base = (char*)d_ws;
  const size_t QKV = (size_t)BH_ * N_ * HD_;
  unsigned short* q4 = (unsigned short*)base;                 // 32MB
  unsigned short* k4 = (unsigned short*)(base + QKV * 2);     // 32MB
  unsigned short* vt = (unsigned short*)(base + QKV * 4);     // 32MB
  unsigned short* outh = (unsigned short*)(base + QKV * 2);   // alias k4 (dead after ker3kv)
  char* sp = base + QKV * 6;
  float* pacc  = (float*)sp; sp += (size_t)BH_ * NPART_ * 64 * 64 * 4;  // 16.78MB
  float* pacc0 = (float*)sp; sp += (size_t)BH_ * NPART_ * 64 * 4;
  float* ps    = (float*)sp; sp += (size_t)BH_ * NPART_ * 64 * 4;
  float* xbar  = (float*)sp; sp += (size_t)B_ * LM_ * C_ * 4;
  float* qland = (float*)sp; sp += (size_t)BH_ * LM_ * HD_ * 4;
  float* kland = (float*)sp; sp += (size_t)BH_ * LM_ * HD_ * 4;
  unsigned short* qlbh = (unsigned short*)sp; sp += (size_t)BH_ * LM_ * HD_ * 2;
  unsigned short* qlbl = (unsigned short*)sp; sp += (size_t)BH_ * LM_ * HD_ * 2;
  unsigned short* klb  = (unsigned short*)sp; sp += (size_t)BH_ * LM_ * HD_ * 2;
  float* ker2  = (float*)sp; sp += (size_t)BH_ * LM_ * LM_ * 4;
  float* pinv  = (float*)sp; sp += (size_t)BH_ * LM_ * LM_ * 4;
  float* kvb   = (float*)sp; sp += (size_t)BH_ * LM_ * HD_ * 4;
  unsigned short* mtbh = (unsigned short*)sp; sp += (size_t)BH_ * LM_ * HD_ * 2;
  unsigned short* mtbl = (unsigned short*)sp; sp += (size_t)BH_ * LM_ * HD_ * 2;
  float* msum  = (float*)sp; sp += (size_t)BH_ * HD_ * 4;
  float* asave = (float*)sp; sp += (size_t)BH_ * LM_ * LM_ * 4;   // 256KB
  float* vsave = (float*)sp; sp += (size_t)BH_ * LM_ * LM_ * 4;   // 256KB
  unsigned short* wob = (unsigned short*)sp; sp += (size_t)C_ * C_ * 2;  // 512KB

  const int W8 = (C_ * C_) / 8;

  // wo -> bf16 (needed only by the serial-tail oproj)
  cvt_bf16_kernel<<<W8 / 256, 256, 0, stream>>>(wo, wob, W8);

  // landmark path (f32-exact)
  seg_mean_kernel<<<B_ * LM_, 256, 0, stream>>>(x, xbar);
  dim3 gl(4, 8);
  land_gemm_kernel<<<gl, 256, 0, stream>>>(xbar, wq, bq, wk, bk, qland, kland);
  ker2_kernel<<<BH_, 64, 0, stream>>>(qland, kland, ker2, qlbh, qlbl, klb);

  // fused 1: SVD phase 1 (blocks 0..15, prio 3) + q/k/v projections
  fused1_kernel<<<16 + 3 * 1024, 256, 0, stream>>>(
      x, wq, bq, wk, bk, wv, bv, q4, k4, vt, ker2, asave, vsave);

  // fused 2: SVD phase 2 + pinv (blocks 0..15, prio 3) + ker3kv (256 blocks)
  fused2_kernel<<<16 + NCH_ * BH_, 256, 0, stream>>>(
      qlbh, qlbl, k4, vt, pacc, pacc0, ps, asave, vsave, pinv);

  // combine + M
  dim3 g7(4, BH_);
  kv_combine_kernel<<<g7, 256, 0, stream>>>(pacc, pacc0, ps, kvb);
  mmat_kernel<<<BH_, 256, 0, stream>>>(pinv, kvb, mtbh, mtbl, msum);

  // out_heads -> bf16 outh (aliases dead k4)
  dim3 g9(N_ / 256, BH_);
  ker1out_mfma_kernel<<<g9, 256, 0, stream>>>(q4, klb, mtbh, mtbl, msum, outh);

  // final projection (DMA-staged bf16 GEMM)
  dim3 g10(B_ * N_ / 128, C_ / 128);
  oproj_kernel<<<g10, 256, 0, stream>>>(outh, wob, bo, out);
}

// Round 13
// 569.416 us; speedup vs baseline: 6.1255x; 1.0380x over previous
//
#include <hip/hip_runtime.h>
#include <stdint.h>

// NystromAttention MI355X — Round 13: fix svd_phase1 LDS staging loop bound
// (16 -> 4 iterations; the 16-iter version clobbered klS with qland rows
// 64..127, making ker2 garbage -> identical 9.3e-3 failures in R11/R12
// regardless of sweep count). Sweeps stay 5+3. Rest identical to R12.

constexpr int B_   = 2;
constexpr int N_   = 16384;
constexpr int C_   = 512;
constexpr int H_   = 8;
constexpr int HD_  = 64;
constexpr int LM_  = 64;
constexpr int SEG_ = 256;
constexpr int BH_  = 16;
constexpr int NCH_ = 16;
constexpr int NPART_ = 64;
constexpr int SW1_ = 5;   // sweeps in phase 1
constexpr int SW2_ = 3;   // sweeps in phase 2  (total 8 = R10-passing config)

#define RCOND_ (640.0 * 1.1920928955078125e-07)

typedef unsigned short ushort4_t __attribute__((ext_vector_type(4)));
typedef unsigned short ushort8_t __attribute__((ext_vector_type(8)));
typedef __bf16 bf16x8 __attribute__((ext_vector_type(8)));
typedef float f32x4 __attribute__((ext_vector_type(4)));

__device__ inline float bf2f(unsigned short u) {
  union { unsigned int i; float f; } x; x.i = ((unsigned int)u) << 16; return x.f;
}
__device__ inline unsigned short f2bf(float f) {
  union { float f; unsigned int i; } x; x.f = f;
  unsigned int lsb = (x.i >> 16) & 1;
  return (unsigned short)((x.i + 0x7fffu + lsb) >> 16);
}
__device__ inline bf16x8 ld_bf8(const unsigned short* p) { return *(const bf16x8*)p; }

__device__ __forceinline__ void gload_lds16(const unsigned short* gsrc, unsigned short* ldst) {
  __builtin_amdgcn_global_load_lds((const __attribute__((address_space(1))) void*)gsrc,
                                   (__attribute__((address_space(3))) void*)ldst, 16, 0, 0);
}

// ---------------------------------------------------------------------------
__global__ __launch_bounds__(256) void cvt_bf16_kernel(const float* __restrict__ src,
                                                       unsigned short* __restrict__ dst,
                                                       int n8) {
  int i = (blockIdx.x * 256 + threadIdx.x);
  if (i >= n8) return;
  const float* s = src + (size_t)i * 8;
  float4 x0 = *(const float4*)(s);
  float4 x1 = *(const float4*)(s + 4);
  ushort8_t u;
  u[0] = f2bf(x0.x); u[1] = f2bf(x0.y); u[2] = f2bf(x0.z); u[3] = f2bf(x0.w);
  u[4] = f2bf(x1.x); u[5] = f2bf(x1.y); u[6] = f2bf(x1.z); u[7] = f2bf(x1.w);
  *(ushort8_t*)(dst + (size_t)i * 8) = u;
}

// ---------------------------------------------------------------------------
__global__ __launch_bounds__(256) void seg_mean_kernel(const float* __restrict__ x,
                                                       float* __restrict__ xbar) {
  int bl = blockIdx.x;
  int b = bl / LM_, l = bl % LM_;
  int t = threadIdx.x;
  int c4 = t & 127;
  int rh = t >> 7;
  const float* xp = x + ((size_t)b * N_ + (size_t)l * SEG_) * C_;
  float4 s = make_float4(0.f, 0.f, 0.f, 0.f);
  for (int r = rh * 128; r < rh * 128 + 128; ++r) {
    float4 v = *(const float4*)(xp + (size_t)r * C_ + c4 * 4);
    s.x += v.x; s.y += v.y; s.z += v.z; s.w += v.w;
  }
  __shared__ float red[2][512];
  *(float4*)&red[rh][c4 * 4] = s;
  __syncthreads();
  if (rh == 0) {
    float4 a = *(float4*)&red[0][c4 * 4];
    float4 c = *(float4*)&red[1][c4 * 4];
    const float invs = 1.0f / SEG_;
    float4 o;
    o.x = (a.x + c.x) * invs; o.y = (a.y + c.y) * invs;
    o.z = (a.z + c.z) * invs; o.w = (a.w + c.w) * invs;
    *(float4*)(xbar + (size_t)bl * C_ + c4 * 4) = o;
  }
}

// ---------------------------------------------------------------------------
// Merged landmark projections (f32 VALU GEMM, 128 rows) with bf16 epilogue:
// which==0 -> qland f32 + qlbh/qlbl;  which==1 -> kland f32 + klb.
__global__ __launch_bounds__(256) void land_gemm_kernel(const float* __restrict__ xbar,
                                                        const float* __restrict__ wq,
                                                        const float* __restrict__ bq,
                                                        const float* __restrict__ wk,
                                                        const float* __restrict__ bk,
                                                        float* __restrict__ qland,
                                                        float* __restrict__ kland,
                                                        unsigned short* __restrict__ qlbh,
                                                        unsigned short* __restrict__ qlbl,
                                                        unsigned short* __restrict__ klb) {
  __shared__ float As[32][68];
  __shared__ float Ws[32][68];
  int which = blockIdx.x >> 1;
  int row0 = (blockIdx.x & 1) * 64;
  int col0 = blockIdx.y * 64;
  const float* A = xbar;
  const float* W = which ? wk : wq;
  const float* bias = which ? bk : bq;
  float scale = which ? 1.0f : 0.125f;
  float* out = which ? kland : qland;
  int tid = threadIdx.x;
  int tm = tid >> 4, tn = tid & 15;
  float acc[4][4] = {};
  for (int k0 = 0; k0 < C_; k0 += 32) {
#pragma unroll
    for (int i = 0; i < 2; ++i) {
      int s = tid + i * 256;
      int r = s >> 3;
      int kg = (s & 7) << 2;
      float4 av = *(const float4*)(A + (size_t)(row0 + r) * C_ + k0 + kg);
      As[kg + 0][r] = av.x; As[kg + 1][r] = av.y;
      As[kg + 2][r] = av.z; As[kg + 3][r] = av.w;
      float4 wv = *(const float4*)(W + (size_t)(col0 + r) * C_ + k0 + kg);
      Ws[kg + 0][r] = wv.x; Ws[kg + 1][r] = wv.y;
      Ws[kg + 2][r] = wv.z; Ws[kg + 3][r] = wv.w;
    }
    __syncthreads();
#pragma unroll
    for (int kk = 0; kk < 32; ++kk) {
      float4 a = *(const float4*)&As[kk][tm * 4];
      float4 b = *(const float4*)&Ws[kk][tn * 4];
      float av[4] = {a.x, a.y, a.z, a.w};
      float bv[4] = {b.x, b.y, b.z, b.w};
#pragma unroll
      for (int i = 0; i < 4; ++i)
#pragma unroll
        for (int j = 0; j < 4; ++j) acc[i][j] += av[i] * bv[j];
    }
    __syncthreads();
  }
#pragma unroll
  for (int i = 0; i < 4; ++i) {
    int row = row0 + tm * 4 + i;
    int d0 = tn * 4;
    float o4[4];
#pragma unroll
    for (int j = 0; j < 4; ++j) o4[j] = (acc[i][j] + bias[col0 + d0 + j]) * scale;
    int b = row / LM_, n = row % LM_;
    int h = col0 >> 6;
    size_t idx = (((size_t)(b * H_ + h) * LM_) + n) * HD_ + d0;
    float4 o; o.x = o4[0]; o.y = o4[1]; o.z = o4[2]; o.w = o4[3];
    *(float4*)(out + idx) = o;
    if (which == 0) {
      ushort4_t uh, ul;
#pragma unroll
      for (int j = 0; j < 4; ++j) {
        unsigned short hbits = f2bf(o4[j]);
        uh[j] = hbits;
        ul[j] = f2bf(o4[j] - bf2f(hbits));
      }
      *(ushort4_t*)(qlbh + idx) = uh;
      *(ushort4_t*)(qlbl + idx) = ul;
    } else {
      ushort4_t uk;
#pragma unroll
      for (int j = 0; j < 4; ++j) uk[j] = f2bf(o4[j]);
      *(ushort4_t*)(klb + idx) = uk;
    }
  }
}

// ---------------------------------------------------------------------------
// Reg-staged MFMA GEMM body (A f32, W f32 converted in staging).
// omode 1: bf16 head-split; omode 2: bf16 vt.
__device__ __forceinline__ void mfma_gemm_body(const float* __restrict__ A,
                                               const float* __restrict__ W,
                                               const float* __restrict__ bias,
                                               unsigned short* __restrict__ out,
                                               float scale, int omode,
                                               int row0, int col0,
                                               unsigned short* Xs, unsigned short* Ws,
                                               int tid) {
  int wid = tid >> 6, lane = tid & 63;
  int wr = wid >> 1, wc = wid & 1;
  f32x4 acc[4][4] = {};
  int srow = tid >> 1;
  int sk = (tid & 1) * 16;
  const float* wpbase = W + (size_t)(col0 + srow) * C_ + sk;
  const float* apbase = A + (size_t)(row0 + srow) * C_ + sk;
  unsigned short* xdst = &Xs[srow * 32 + sk];
  unsigned short* wdst = &Ws[srow * 32 + sk];

  for (int k0 = 0; k0 < C_; k0 += 32) {
    __syncthreads();
    {
      float4 x0 = *(const float4*)(apbase + k0);
      float4 x1 = *(const float4*)(apbase + k0 + 4);
      float4 x2 = *(const float4*)(apbase + k0 + 8);
      float4 x3 = *(const float4*)(apbase + k0 + 12);
      ushort8_t u0, u1;
      u0[0] = f2bf(x0.x); u0[1] = f2bf(x0.y); u0[2] = f2bf(x0.z); u0[3] = f2bf(x0.w);
      u0[4] = f2bf(x1.x); u0[5] = f2bf(x1.y); u0[6] = f2bf(x1.z); u0[7] = f2bf(x1.w);
      u1[0] = f2bf(x2.x); u1[1] = f2bf(x2.y); u1[2] = f2bf(x2.z); u1[3] = f2bf(x2.w);
      u1[4] = f2bf(x3.x); u1[5] = f2bf(x3.y); u1[6] = f2bf(x3.z); u1[7] = f2bf(x3.w);
      *(ushort8_t*)(xdst) = u0;
      *(ushort8_t*)(xdst + 8) = u1;
    }
    {
      float4 w0 = *(const float4*)(wpbase + k0);
      float4 w1 = *(const float4*)(wpbase + k0 + 4);
      float4 w2 = *(const float4*)(wpbase + k0 + 8);
      float4 w3 = *(const float4*)(wpbase + k0 + 12);
      ushort8_t u0, u1;
      u0[0] = f2bf(w0.x); u0[1] = f2bf(w0.y); u0[2] = f2bf(w0.z); u0[3] = f2bf(w0.w);
      u0[4] = f2bf(w1.x); u0[5] = f2bf(w1.y); u0[6] = f2bf(w1.z); u0[7] = f2bf(w1.w);
      u1[0] = f2bf(w2.x); u1[1] = f2bf(w2.y); u1[2] = f2bf(w2.z); u1[3] = f2bf(w2.w);
      u1[4] = f2bf(w3.x); u1[5] = f2bf(w3.y); u1[6] = f2bf(w3.z); u1[7] = f2bf(w3.w);
      *(ushort8_t*)(wdst) = u0;
      *(ushort8_t*)(wdst + 8) = u1;
    }
    __syncthreads();
    bf16x8 af[4], bfr[4];
#pragma unroll
    for (int m = 0; m < 4; ++m)
      af[m] = *(bf16x8*)&Xs[(wr * 64 + m * 16 + (lane & 15)) * 32 + (lane >> 4) * 8];
#pragma unroll
    for (int n = 0; n < 4; ++n)
      bfr[n] = *(bf16x8*)&Ws[(wc * 64 + n * 16 + (lane & 15)) * 32 + (lane >> 4) * 8];
#pragma unroll
    for (int m = 0; m < 4; ++m)
#pragma unroll
      for (int n = 0; n < 4; ++n)
        acc[m][n] = __builtin_amdgcn_mfma_f32_16x16x32_bf16(af[m], bfr[n], acc[m][n], 0, 0, 0);
  }

#pragma unroll
  for (int m = 0; m < 4; ++m) {
    int rbase = row0 + wr * 64 + m * 16 + (lane >> 4) * 4;
#pragma unroll
    for (int n = 0; n < 4; ++n) {
      int c = col0 + wc * 64 + n * 16 + (lane & 15);
      float bc = bias[c];
      if (omode == 2) {
        int b = rbase >> 14, nn = rbase & 16383;
        int h = c >> 6, d = c & 63;
        ushort4_t u;
#pragma unroll
        for (int rg = 0; rg < 4; ++rg) u[rg] = f2bf((acc[m][n][rg] + bc) * scale);
        *(ushort4_t*)(out + ((size_t)(b * H_ + h) * HD_ + d) * N_ + nn) = u;
      } else {
#pragma unroll
        for (int rg = 0; rg < 4; ++rg) {
          float val = (acc[m][n][rg] + bc) * scale;
          int r = rbase + rg;
          int b = r >> 14, nn = r & 16383, h = c >> 6, d = c & 63;
          out[(((size_t)(b * H_ + h) * N_) + nn) * HD_ + d] = f2bf(val);
        }
      }
    }
  }
}

// ---------------------------------------------------------------------------
// SVD sweep loop (4-wave row-split, shared by both phases).
__device__ __forceinline__ void svd_sweeps(float a[16], float v[16], char* smemraw,
                                           int w, int lane, int nsweeps) {
  float (*pg)[4][64] = (float(*)[4][64])(smemraw);          // 2048 B
  float (*pa4)[64]   = (float(*)[64])(smemraw + 2048);      // 1024 B
  for (int sweep = 0; sweep < nsweeps; ++sweep) {
    float p0 = 0.f, p1 = 0.f;
#pragma unroll
    for (int k = 0; k < 16; k += 2) { p0 = fmaf(a[k], a[k], p0); p1 = fmaf(a[k + 1], a[k + 1], p1); }
    pa4[w][lane] = p0 + p1;
    __syncthreads();
    float alpha = (pa4[0][lane] + pa4[1][lane]) + (pa4[2][lane] + pa4[3][lane]);
    for (int mask = 1; mask < 64; ++mask) {
      int buf = mask & 1;
      bool lower = lane < (lane ^ mask);
      float beta = __shfl_xor(alpha, mask);
      float o[16];
#pragma unroll
      for (int k = 0; k < 16; ++k) o[k] = __shfl_xor(a[k], mask);
      float g0 = 0.f, g1 = 0.f;
#pragma unroll
      for (int k = 0; k < 16; k += 2) { g0 = fmaf(a[k], o[k], g0); g1 = fmaf(a[k + 1], o[k + 1], g1); }
      pg[buf][w][lane] = g0 + g1;
      __syncthreads();
      float gamma = (pg[buf][0][lane] + pg[buf][1][lane]) + (pg[buf][2][lane] + pg[buf][3][lane]);
      bool need = (gamma * gamma > 1e-12f * alpha * beta);
      if (__any(need)) {
        float ov[16];
#pragma unroll
        for (int k = 0; k < 16; ++k) ov[k] = __shfl_xor(v[k], mask);
        float ap = lower ? alpha : beta;
        float aq = lower ? beta : alpha;
        float c = 1.f, s = 0.f;
        if (need) {
          float tau = (aq - ap) / (2.f * gamma);
          float t = copysignf(1.f, tau) / (fabsf(tau) + sqrtf(fmaf(tau, tau, 1.f)));
          c = rsqrtf(fmaf(t, t, 1.f));
          s = t * c;
        }
        float sm = lower ? -s : s;
#pragma unroll
        for (int k = 0; k < 16; ++k) a[k] = fmaf(sm, o[k], c * a[k]);
#pragma unroll
        for (int k = 0; k < 16; ++k) v[k] = fmaf(sm, ov[k], c * v[k]);
        float twocsg = 2.f * c * s * gamma;
        alpha = fmaf(c * c, alpha, fmaf(s * s, beta, lower ? -twocsg : twocsg));
      }
    }
  }
}

// Phase 1: compute ker2 in-LDS from qland/kland, SW1_ sweeps, save state.
__device__ void svd_phase1(const float* __restrict__ qland, const float* __restrict__ kland,
                           float* __restrict__ asave, float* __restrict__ vsave,
                           int bh, char* smemraw, int tid) {
  __builtin_amdgcn_s_setprio(3);
  float (*qlS)[65] = (float(*)[65])(smemraw);             // 16640 B
  float (*klS)[65] = (float(*)[65])(smemraw + 16640);     // 16640 B -> 33280
  // 64 rows x 16 float4-groups = 1024 slots / 256 threads = 4 iterations.
  for (int i = 0; i < 4; ++i) {
    int s = tid + i * 256;
    int r = s >> 4, d4 = (s & 15) << 2;
    *(float4*)&qlS[r][d4] = *(const float4*)(qland + ((size_t)bh * 64 + r) * 64 + d4);
    *(float4*)&klS[r][d4] = *(const float4*)(kland + ((size_t)bh * 64 + r) * 64 + d4);
  }
  __syncthreads();
  int w = tid >> 6, lane = tid & 63;
  float a[16], v[16];
#pragma unroll
  for (int k = 0; k < 16; ++k) {
    int row = w * 16 + k;
    float acc = 0.f;
#pragma unroll
    for (int d4 = 0; d4 < 64; d4 += 4) {
      float4 qv = *(float4*)&qlS[row][d4];
      float4 kv = *(float4*)&klS[lane][d4];
      acc += qv.x * kv.x + qv.y * kv.y + qv.z * kv.z + qv.w * kv.w;
    }
    float e = expf(acc);
    float rs = e;
#pragma unroll
    for (int m = 1; m < 64; m <<= 1) rs += __shfl_xor(rs, m);
    a[k] = e * (1.f / rs);
  }
#pragma unroll
  for (int k = 0; k < 16; ++k) v[k] = (w * 16 + k == lane) ? 1.f : 0.f;
  __syncthreads();   // qlS/klS dead; pg/pa4 overlay safe
  svd_sweeps(a, v, smemraw, w, lane, SW1_);
#pragma unroll
  for (int k = 0; k < 16; ++k) {
    asave[((size_t)bh * 64 + w * 16 + k) * 64 + lane] = a[k];
    vsave[((size_t)bh * 64 + w * 16 + k) * 64 + lane] = v[k];
  }
  __builtin_amdgcn_s_setprio(0);
}

// Phase 2: load state, SW2_ sweeps, sigma/cutoff + pinv.
__device__ void svd_phase2(const float* __restrict__ asave, const float* __restrict__ vsave,
                           float* __restrict__ pinv, int bh, char* smemraw, int tid) {
  __builtin_amdgcn_s_setprio(3);
  double (*ps2)[64]  = (double(*)[64])(smemraw + 3072);     // 2048 B
  float (*vsL)[65]   = (float(*)[65])(smemraw + 5120);      // 16640 B
  float (*wasL)[65]  = (float(*)[65])(smemraw + 21760);     // 16640 B
  int w = tid >> 6, lane = tid & 63;
  float a[16], v[16];
#pragma unroll
  for (int k = 0; k < 16; ++k) {
    a[k] = asave[((size_t)bh * 64 + w * 16 + k) * 64 + lane];
    v[k] = vsave[((size_t)bh * 64 + w * 16 + k) * 64 + lane];
  }
  svd_sweeps(a, v, smemraw, w, lane, SW2_);

  double psig = 0.0;
#pragma unroll
  for (int k = 0; k < 16; ++k) psig += (double)a[k] * (double)a[k];
  ps2[w][lane] = psig;
  __syncthreads();
  double sig2 = (ps2[0][lane] + ps2[1][lane]) + (ps2[2][lane] + ps2[3][lane]);
  double smax = sig2;
#pragma unroll
  for (int m = 1; m < 64; m <<= 1) smax = fmax(smax, __shfl_xor(smax, m));
  double cutoff2 = smax * (RCOND_ * RCOND_);
  float wgt = (sig2 > cutoff2) ? (float)(1.0 / sig2) : 0.f;

#pragma unroll
  for (int k = 0; k < 16; ++k) {
    vsL[lane][w * 16 + k] = v[k];
    wasL[lane][w * 16 + k] = wgt * a[k];
  }
  __syncthreads();
  int i = tid >> 2;
  int j0 = (tid & 3) * 16;
  float acc[16] = {};
  for (int r = 0; r < 64; ++r) {
    float vv = vsL[r][i];
#pragma unroll
    for (int jj = 0; jj < 16; ++jj) acc[jj] = fmaf(vv, wasL[r][j0 + jj], acc[jj]);
  }
#pragma unroll
  for (int jj = 0; jj < 16; jj += 4) {
    float4 ovv = make_float4(acc[jj], acc[jj + 1], acc[jj + 2], acc[jj + 3]);
    *(float4*)(pinv + ((size_t)bh * 64 + i) * 64 + j0 + jj) = ovv;
  }
  __builtin_amdgcn_s_setprio(0);
}

// ---------------------------------------------------------------------------
// Fused 1: blocks 0..15 = SVD phase 1 (incl. ker2); 16..3087 = projections.
__global__ __launch_bounds__(256) void fused1_kernel(
    const float* __restrict__ x,
    const float* __restrict__ wq, const float* __restrict__ bq,
    const float* __restrict__ wk, const float* __restrict__ bk,
    const float* __restrict__ wv, const float* __restrict__ bv,
    unsigned short* __restrict__ q4, unsigned short* __restrict__ k4,
    unsigned short* __restrict__ vt,
    const float* __restrict__ qland, const float* __restrict__ kland,
    float* __restrict__ asave, float* __restrict__ vsave) {
  __shared__ __align__(16) char smem[33280];
  int tid = threadIdx.x;
  int blk = blockIdx.x;
  if (blk < 16) { svd_phase1(qland, kland, asave, vsave, blk, smem, tid); return; }
  int g = blk - 16;
  int which = g >> 10;
  int sub = g & 1023;
  int row0 = (sub >> 2) * 128;
  int col0 = (sub & 3) * 128;
  unsigned short* Xs = (unsigned short*)smem;
  unsigned short* Ws = Xs + 128 * 32;
  if (which == 0)
    mfma_gemm_body(x, wq, bq, q4, 0.125f, 1, row0, col0, Xs, Ws, tid);
  else if (which == 1)
    mfma_gemm_body(x, wk, bk, k4, 1.0f, 1, row0, col0, Xs, Ws, tid);
  else
    mfma_gemm_body(x, wv, bv, vt, 1.0f, 2, row0, col0, Xs, Ws, tid);
}

// ---------------------------------------------------------------------------
// ker3+kv body (deviation form, MFMA) — unchanged math.
__device__ void ker3kv_body(const unsigned short* __restrict__ qlh,
                            const unsigned short* __restrict__ qll,
                            const unsigned short* __restrict__ k4,
                            const unsigned short* __restrict__ vt,
                            float* __restrict__ pacc,
                            float* __restrict__ pacc0,
                            float* __restrict__ ps,
                            int bh, int ch, char* smemraw, int tid) {
  int w = tid >> 6, lane = tid & 63;
  int part = ch * 4 + w;
  int lrow = lane & 15, lgrp = lane >> 4;
  unsigned short* myP = (unsigned short*)smemraw + w * 64 * 72;

  bf16x8 qah[4][2], qal[4][2];
#pragma unroll
  for (int mf = 0; mf < 4; ++mf)
#pragma unroll
    for (int ks = 0; ks < 2; ++ks) {
      size_t off = ((size_t)bh * 64 + mf * 16 + lrow) * 64 + ks * 32 + lgrp * 8;
      qah[mf][ks] = ld_bf8(qlh + off);
      qal[mf][ks] = ld_bf8(qll + off);
    }
  bf16x8 onesf;
#pragma unroll
  for (int j = 0; j < 8; ++j) onesf[j] = (__bf16)1.0f;

  f32x4 kvacc[4][4] = {};
  f32x4 oneacc[4] = {};
  f32x4 ssum[4] = {};

  for (int sub = 0; sub < 4; ++sub) {
    int n0 = ch * 1024 + w * 256 + sub * 64;
    f32x4 sacc[4][4] = {};
#pragma unroll
    for (int ks = 0; ks < 2; ++ks) {
#pragma unroll
      for (int nf = 0; nf < 4; ++nf) {
        bf16x8 kb = ld_bf8(k4 + ((size_t)bh * N_ + n0 + nf * 16 + lrow) * 64 + ks * 32 + lgrp * 8);
#pragma unroll
        for (int mf = 0; mf < 4; ++mf) {
          sacc[mf][nf] = __builtin_amdgcn_mfma_f32_16x16x32_bf16(qah[mf][ks], kb, sacc[mf][nf], 0, 0, 0);
          sacc[mf][nf] = __builtin_amdgcn_mfma_f32_16x16x32_bf16(qal[mf][ks], kb, sacc[mf][nf], 0, 0, 0);
        }
      }
    }
#pragma unroll
    for (int mf = 0; mf < 4; ++mf) {
#pragma unroll
      for (int nf = 0; nf < 4; ++nf) {
#pragma unroll
        for (int r = 0; r < 4; ++r) {
          float pd = expf(sacc[mf][nf][r]) - 1.0f;
          ssum[mf][r] += pd;
          myP[(mf * 16 + lgrp * 4 + r) * 72 + nf * 16 + lrow] = f2bf(pd);
        }
      }
    }
#pragma unroll
    for (int ks = 0; ks < 2; ++ks) {
      bf16x8 pa[4];
#pragma unroll
      for (int mf = 0; mf < 4; ++mf)
        pa[mf] = ld_bf8(myP + (mf * 16 + lrow) * 72 + ks * 32 + lgrp * 8);
#pragma unroll
      for (int nf = 0; nf < 4; ++nf) {
        bf16x8 vb = ld_bf8(vt + ((size_t)bh * 64 + nf * 16 + lrow) * N_ + n0 + ks * 32 + lgrp * 8);
#pragma unroll
        for (int mf = 0; mf < 4; ++mf)
          kvacc[mf][nf] = __builtin_amdgcn_mfma_f32_16x16x32_bf16(pa[mf], vb, kvacc[mf][nf], 0, 0, 0);
        oneacc[nf] = __builtin_amdgcn_mfma_f32_16x16x32_bf16(onesf, vb, oneacc[nf], 0, 0, 0);
      }
    }
  }
#pragma unroll
  for (int mf = 0; mf < 4; ++mf)
#pragma unroll
    for (int m = 1; m < 16; m <<= 1)
#pragma unroll
      for (int r = 0; r < 4; ++r) ssum[mf][r] += __shfl_xor(ssum[mf][r], m);

  size_t pb = (((size_t)bh * NPART_ + part) * 64) * 64;
#pragma unroll
  for (int mf = 0; mf < 4; ++mf)
#pragma unroll
    for (int nf = 0; nf < 4; ++nf)
#pragma unroll
      for (int r = 0; r < 4; ++r)
        pacc[pb + (size_t)(mf * 16 + lgrp * 4 + r) * 64 + nf * 16 + lrow] = kvacc[mf][nf][r];
  if (lrow == 0) {
#pragma unroll
    for (int mf = 0; mf < 4; ++mf)
#pragma unroll
      for (int r = 0; r < 4; ++r)
        ps[((size_t)bh * NPART_ + part) * 64 + mf * 16 + lgrp * 4 + r] = ssum[mf][r];
  }
  if (lgrp == 0) {
#pragma unroll
    for (int nf = 0; nf < 4; ++nf)
      pacc0[((size_t)bh * NPART_ + part) * 64 + nf * 16 + lrow] = oneacc[nf][0];
  }
}

// Fused 2: blocks 0..15 = SVD phase 2 (+pinv); 16..271 = ker3kv.
__global__ __launch_bounds__(256, 1) void fused2_kernel(
    const unsigned short* __restrict__ qlh,
    const unsigned short* __restrict__ qll,
    const unsigned short* __restrict__ k4,
    const unsigned short* __restrict__ vt,
    float* __restrict__ pacc, float* __restrict__ pacc0, float* __restrict__ ps,
    const float* __restrict__ asave, const float* __restrict__ vsave,
    float* __restrict__ pinv) {
  __shared__ __align__(16) char smem[38400];
  int tid = threadIdx.x;
  int blk = blockIdx.x;
  if (blk < 16) { svd_phase2(asave, vsave, pinv, blk, smem, tid); return; }
  int g = blk - 16;
  int bh = g >> 4, ch = g & 15;
  ker3kv_body(qlh, qll, k4, vt, pacc, pacc0, ps, bh, ch, smem, tid);
}

// ---------------------------------------------------------------------------
__global__ __launch_bounds__(256) void kv_combine_kernel(const float* __restrict__ pacc,
                                                         const float* __restrict__ pacc0,
                                                         const float* __restrict__ ps,
                                                         float* __restrict__ kv) {
  int bh = blockIdx.y;
  int lm = blockIdx.x * 16 + (threadIdx.x >> 4);
  int d4 = (threadIdx.x & 15) * 4;
  float s = 16384.f;
  for (int part = 0; part < NPART_; ++part) s += ps[((size_t)bh * NPART_ + part) * 64 + lm];
  float4 a = make_float4(0.f, 0.f, 0.f, 0.f);
  for (int part = 0; part < NPART_; ++part) {
    float4 c0 = *(const float4*)&pacc0[((size_t)bh * NPART_ + part) * 64 + d4];
    float4 v = *(const float4*)&pacc[(((size_t)bh * NPART_ + part) * 64 + lm) * 64 + d4];
    a.x += c0.x + v.x; a.y += c0.y + v.y; a.z += c0.z + v.z; a.w += c0.w + v.w;
  }
  float inv = 1.f / s;
  float4 o = make_float4(a.x * inv, a.y * inv, a.z * inv, a.w * inv);
  *(float4*)(kv + ((size_t)bh * 64 + lm) * 64 + d4) = o;
}

// ---------------------------------------------------------------------------
__global__ __launch_bounds__(256) void mmat_kernel(const float* __restrict__ pinv,
                                                   const float* __restrict__ kv,
                                                   unsigned short* __restrict__ mtbh,
                                                   unsigned short* __restrict__ mtbl,
                                                   float* __restrict__ msum) {
  int bh = blockIdx.x;
  int tid = threadIdx.x;
  __shared__ float kvs[64][68];
  __shared__ double pcsd[64];
  for (int i = 0; i < 4; ++i) {
    int s = tid + i * 256;
    int r = s >> 4, d4 = (s & 15) << 2;
    *(float4*)&kvs[r][d4] = *(const float4*)(kv + ((size_t)bh * 64 + r) * 64 + d4);
  }
  if (tid < 64) {
    double s = 0.0;
    for (int l = 0; l < 64; ++l) s += (double)pinv[((size_t)bh * 64 + l) * 64 + tid];
    pcsd[tid] = s;
  }
  __syncthreads();
  int l = tid >> 2, t = tid & 3;
  double o[16] = {};
  for (int j = 0; j < 64; ++j) {
    double pv = (double)pinv[((size_t)bh * 64 + l) * 64 + j];
#pragma unroll
    for (int i = 0; i < 16; ++i) o[i] += pv * (double)kvs[j][t * 16 + i];
  }
#pragma unroll
  for (int i = 0; i < 16; ++i) {
    float f = (float)o[i];
    unsigned short hi = f2bf(f);
    float lo = f - bf2f(hi);
    int d = t * 16 + i;
    mtbh[((size_t)bh * 64 + d) * 64 + l] = hi;
    mtbl[((size_t)bh * 64 + d) * 64 + l] = f2bf(lo);
  }
  if (tid < 64) {
    double m = 0.0;
    for (int j = 0; j < 64; ++j) m += pcsd[j] * (double)kvs[j][tid];
    msum[(size_t)bh * 64 + tid] = (float)(m * (1.0 / 64.0));
  }
}

// ---------------------------------------------------------------------------
__global__ __launch_bounds__(256, 1) void ker1out_mfma_kernel(
    const unsigned short* __restrict__ q4,
    const unsigned short* __restrict__ klb,
    const unsigned short* __restrict__ mtbh,
    const unsigned short* __restrict__ mtbl,
    const float* __restrict__ msum,
    unsigned short* __restrict__ outh) {
  int bh = blockIdx.y, tile = blockIdx.x;
  int b = bh >> 3, h = bh & 7;
  int tid = threadIdx.x, w = tid >> 6, lane = tid & 63;
  int lrow = lane & 15, lgrp = lane >> 4;
  int tok0 = tile * 256 + w * 64;
  __shared__ __align__(16) unsigned short Pl[4][64 * 72];
  unsigned short* myP = &Pl[w][0];

  f32x4 sacc[4][4] = {};
#pragma unroll
  for (int ks = 0; ks < 2; ++ks) {
    bf16x8 kb[4];
#pragma unroll
    for (int nf = 0; nf < 4; ++nf)
      kb[nf] = ld_bf8(klb + ((size_t)bh * 64 + nf * 16 + lrow) * 64 + ks * 32 + lgrp * 8);
#pragma unroll
    for (int mf = 0; mf < 4; ++mf) {
      bf16x8 qa = ld_bf8(q4 + ((size_t)bh * N_ + tok0 + mf * 16 + lrow) * 64 + ks * 32 + lgrp * 8);
#pragma unroll
      for (int nf = 0; nf < 4; ++nf)
        sacc[mf][nf] = __builtin_amdgcn_mfma_f32_16x16x32_bf16(qa, kb[nf], sacc[mf][nf], 0, 0, 0);
    }
  }
  f32x4 ssum[4] = {};
#pragma unroll
  for (int mf = 0; mf < 4; ++mf)
#pragma unroll
    for (int nf = 0; nf < 4; ++nf)
#pragma unroll
      for (int r = 0; r < 4; ++r) {
        sacc[mf][nf][r] = expf(sacc[mf][nf][r]);
        ssum[mf][r] += sacc[mf][nf][r];
      }
#pragma unroll
  for (int mf = 0; mf < 4; ++mf)
#pragma unroll
    for (int m = 1; m < 16; m <<= 1)
#pragma unroll
      for (int r = 0; r < 4; ++r) ssum[mf][r] += __shfl_xor(ssum[mf][r], m);
#pragma unroll
  for (int mf = 0; mf < 4; ++mf) {
    f32x4 inv;
#pragma unroll
    for (int r = 0; r < 4; ++r) inv[r] = 1.f / ssum[mf][r];
#pragma unroll
    for (int nf = 0; nf < 4; ++nf)
#pragma unroll
      for (int r = 0; r < 4; ++r) {
        float pdev = fmaf(sacc[mf][nf][r], inv[r], -0.015625f);
        myP[(mf * 16 + lgrp * 4 + r) * 72 + nf * 16 + lrow] = f2bf(pdev);
      }
  }

  f32x4 oacc[4][4] = {};
#pragma unroll
  for (int ks = 0; ks < 2; ++ks) {
    bf16x8 pa[4];
#pragma unroll
    for (int mf = 0; mf < 4; ++mf)
      pa[mf] = ld_bf8(myP + (mf * 16 + lrow) * 72 + ks * 32 + lgrp * 8);
#pragma unroll
    for (int nf = 0; nf < 4; ++nf) {
      bf16x8 mh = ld_bf8(mtbh + ((size_t)bh * 64 + nf * 16 + lrow) * 64 + ks * 32 + lgrp * 8);
      bf16x8 ml = ld_bf8(mtbl + ((size_t)bh * 64 + nf * 16 + lrow) * 64 + ks * 32 + lgrp * 8);
#pragma unroll
      for (int mf = 0; mf < 4; ++mf) {
        oacc[mf][nf] = __builtin_amdgcn_mfma_f32_16x16x32_bf16(pa[mf], mh, oacc[mf][nf], 0, 0, 0);
        oacc[mf][nf] = __builtin_amdgcn_mfma_f32_16x16x32_bf16(pa[mf], ml, oacc[mf][nf], 0, 0, 0);
      }
    }
  }
#pragma unroll
  for (int nf = 0; nf < 4; ++nf) {
    float ms = msum[(size_t)bh * 64 + nf * 16 + lrow];
#pragma unroll
    for (int mf = 0; mf < 4; ++mf)
#pragma unroll
      for (int r = 0; r < 4; ++r) {
        int tok = tok0 + mf * 16 + lgrp * 4 + r;
        int d = nf * 16 + lrow;
        outh[((size_t)b * N_ + tok) * C_ + h * HD_ + d] = f2bf(oacc[mf][nf][r] + ms);
      }
  }
}

// ---------------------------------------------------------------------------
// Final projection (serial tail): outh(bf16) @ wob^T(bf16) + bo -> f32 out.
__global__ __launch_bounds__(256) void oproj_kernel(const unsigned short* __restrict__ outh,
                                                    const unsigned short* __restrict__ wob,
                                                    const float* __restrict__ bo,
                                                    float* __restrict__ out) {
  __shared__ __align__(16) unsigned short Xs[128 * 32];
  __shared__ __align__(16) unsigned short Ws[128 * 32];
  int tid = threadIdx.x;
  int w = tid >> 6, lane = tid & 63;
  int wr = w >> 1, wc = w & 1;
  int row0 = blockIdx.x * 128, col0 = blockIdx.y * 128;
  f32x4 acc[4][4] = {};

  for (int k0 = 0; k0 < C_; k0 += 32) {
    __syncthreads();
#pragma unroll
    for (int i = 0; i < 2; ++i) {
      const unsigned short* gx = outh + (size_t)(row0 + w * 32 + i * 16 + (lane >> 2)) * C_ + k0 + (lane & 3) * 8;
      gload_lds16(gx, &Xs[(w * 32 + i * 16) * 32]);
      const unsigned short* gw = wob + (size_t)(col0 + w * 32 + i * 16 + (lane >> 2)) * C_ + k0 + (lane & 3) * 8;
      gload_lds16(gw, &Ws[(w * 32 + i * 16) * 32]);
    }
    __syncthreads();
    bf16x8 af[4], bfr[4];
#pragma unroll
    for (int m = 0; m < 4; ++m)
      af[m] = *(bf16x8*)&Xs[(wr * 64 + m * 16 + (lane & 15)) * 32 + (lane >> 4) * 8];
#pragma unroll
    for (int n = 0; n < 4; ++n)
      bfr[n] = *(bf16x8*)&Ws[(wc * 64 + n * 16 + (lane & 15)) * 32 + (lane >> 4) * 8];
#pragma unroll
    for (int m = 0; m < 4; ++m)
#pragma unroll
      for (int n = 0; n < 4; ++n)
        acc[m][n] = __builtin_amdgcn_mfma_f32_16x16x32_bf16(af[m], bfr[n], acc[m][n], 0, 0, 0);
  }

#pragma unroll
  for (int m = 0; m < 4; ++m) {
    int rbase = row0 + wr * 64 + m * 16 + (lane >> 4) * 4;
#pragma unroll
    for (int n = 0; n < 4; ++n) {
      int c = col0 + wc * 64 + n * 16 + (lane & 15);
      float bc = bo[c];
#pragma unroll
      for (int rg = 0; rg < 4; ++rg)
        out[(size_t)(rbase + rg) * C_ + c] = acc[m][n][rg] + bc;
    }
  }
}

// ---------------------------------------------------------------------------
extern "C" void kernel_launch(void* const* d_in, const int* in_sizes, int n_in,
                              void* d_out, int out_size, void* d_ws, size_t ws_size,
                              hipStream_t stream) {
  const float* x  = (const float*)d_in[0];
  const float* wq = (const float*)d_in[1];
  const float* bq = (const float*)d_in[2];
  const float* wk = (const float*)d_in[3];
  const float* bk = (const float*)d_in[4];
  const float* wv = (const float*)d_in[5];
  const float* bv = (const float*)d_in[6];
  const float* wo = (const float*)d_in[7];
  const float* bo = (const float*)d_in[8];
  float* out = (float*)d_out;

  char* base = (char*)d_ws;
  const size_t QKV = (size_t)BH_ * N_ * HD_;
  unsigned short* q4 = (unsigned short*)base;                 // 32MB
  unsigned short* k4 = (unsigned short*)(base + QKV * 2);     // 32MB
  unsigned short* vt = (unsigned short*)(base + QKV * 4);     // 32MB
  unsigned short* outh = (unsigned short*)(base + QKV * 2);   // alias k4 (dead after ker3kv)
  char* sp = base + QKV * 6;
  float* pacc  = (float*)sp; sp += (size_t)BH_ * NPART_ * 64 * 64 * 4;  // 16.78MB
  float* pacc0 = (float*)sp; sp += (size_t)BH_ * NPART_ * 64 * 4;
  float* ps    = (float*)sp; sp += (size_t)BH_ * NPART_ * 64 * 4;
  float* xbar  = (float*)sp; sp += (size_t)B_ * LM_ * C_ * 4;
  float* qland = (float*)sp; sp += (size_t)BH_ * LM_ * HD_ * 4;
  float* kland = (float*)sp; sp += (size_t)BH_ * LM_ * HD_ * 4;
  unsigned short* qlbh = (unsigned short*)sp; sp += (size_t)BH_ * LM_ * HD_ * 2;
  unsigned short* qlbl = (unsigned short*)sp; sp += (size_t)BH_ * LM_ * HD_ * 2;
  unsigned short* klb  = (unsigned short*)sp; sp += (size_t)BH_ * LM_ * HD_ * 2;
  float* pinv  = (float*)sp; sp += (size_t)BH_ * LM_ * LM_ * 4;
  float* kvb   = (float*)sp; sp += (size_t)BH_ * LM_ * HD_ * 4;
  unsigned short* mtbh = (unsigned short*)sp; sp += (size_t)BH_ * LM_ * HD_ * 2;
  unsigned short* mtbl = (unsigned short*)sp; sp += (size_t)BH_ * LM_ * HD_ * 2;
  float* msum  = (float*)sp; sp += (size_t)BH_ * HD_ * 4;
  float* asave = (float*)sp; sp += (size_t)BH_ * LM_ * LM_ * 4;   // 256KB
  float* vsave = (float*)sp; sp += (size_t)BH_ * LM_ * LM_ * 4;   // 256KB
  unsigned short* wob = (unsigned short*)sp; sp += (size_t)C_ * C_ * 2;  // 512KB

  const int W8 = (C_ * C_) / 8;

  // wo -> bf16 (needed only by the serial-tail oproj)
  cvt_bf16_kernel<<<W8 / 256, 256, 0, stream>>>(wo, wob, W8);

  // landmark path (f32-exact) + bf16 conversions in epilogue
  seg_mean_kernel<<<B_ * LM_, 256, 0, stream>>>(x, xbar);
  dim3 gl(4, 8);
  land_gemm_kernel<<<gl, 256, 0, stream>>>(xbar, wq, bq, wk, bk,
                                           qland, kland, qlbh, qlbl, klb);

  // fused 1: SVD phase 1 (blocks 0..15; computes ker2 in-LDS) + projections
  fused1_kernel<<<16 + 3 * 1024, 256, 0, stream>>>(
      x, wq, bq, wk, bk, wv, bv, q4, k4, vt, qland, kland, asave, vsave);

  // fused 2: SVD phase 2 + pinv (blocks 0..15) + ker3kv (256 blocks)
  fused2_kernel<<<16 + NCH_ * BH_, 256, 0, stream>>>(
      qlbh, qlbl, k4, vt, pacc, pacc0, ps, asave, vsave, pinv);

  // combine + M
  dim3 g7(4, BH_);
  kv_combine_kernel<<<g7, 256, 0, stream>>>(pacc, pacc0, ps, kvb);
  mmat_kernel<<<BH_, 256, 0, stream>>>(pinv, kvb, mtbh, mtbl, msum);

  // out_heads -> bf16 outh (aliases dead k4)
  dim3 g9(N_ / 256, BH_);
  ker1out_mfma_kernel<<<g9, 256, 0, stream>>>(q4, klb, mtbh, mtbl, msum, outh);

  // final projection (DMA-staged bf16 GEMM)
  dim3 g10(B_ * N_ / 128, C_ / 128);
  oproj_kernel<<<g10, 256, 0, stream>>>(outh, wob, bo, out);
}

// Round 14
// 480.401 us; speedup vs baseline: 7.2605x; 1.1853x over previous
//
#include <hip/hip_runtime.h>
#include <stdint.h>

// NystromAttention MI355X — Round 14: 6 Jacobi sweeps (SW1=4, SW2=2).
// R13 proved the R11/R12 failures were the staging-loop bug (fixed in R13),
// NOT sweep count — this is the clean single-variable test of 6 sweeps.
// Everything else byte-identical to R13 (passed, 569us, absmax 6.1e-5).

constexpr int B_   = 2;
constexpr int N_   = 16384;
constexpr int C_   = 512;
constexpr int H_   = 8;
constexpr int HD_  = 64;
constexpr int LM_  = 64;
constexpr int SEG_ = 256;
constexpr int BH_  = 16;
constexpr int NCH_ = 16;
constexpr int NPART_ = 64;
constexpr int SW1_ = 4;   // sweeps in phase 1
constexpr int SW2_ = 2;   // sweeps in phase 2  (total 6)

#define RCOND_ (640.0 * 1.1920928955078125e-07)

typedef unsigned short ushort4_t __attribute__((ext_vector_type(4)));
typedef unsigned short ushort8_t __attribute__((ext_vector_type(8)));
typedef __bf16 bf16x8 __attribute__((ext_vector_type(8)));
typedef float f32x4 __attribute__((ext_vector_type(4)));

__device__ inline float bf2f(unsigned short u) {
  union { unsigned int i; float f; } x; x.i = ((unsigned int)u) << 16; return x.f;
}
__device__ inline unsigned short f2bf(float f) {
  union { float f; unsigned int i; } x; x.f = f;
  unsigned int lsb = (x.i >> 16) & 1;
  return (unsigned short)((x.i + 0x7fffu + lsb) >> 16);
}
__device__ inline bf16x8 ld_bf8(const unsigned short* p) { return *(const bf16x8*)p; }

__device__ __forceinline__ void gload_lds16(const unsigned short* gsrc, unsigned short* ldst) {
  __builtin_amdgcn_global_load_lds((const __attribute__((address_space(1))) void*)gsrc,
                                   (__attribute__((address_space(3))) void*)ldst, 16, 0, 0);
}

// ---------------------------------------------------------------------------
__global__ __launch_bounds__(256) void cvt_bf16_kernel(const float* __restrict__ src,
                                                       unsigned short* __restrict__ dst,
                                                       int n8) {
  int i = (blockIdx.x * 256 + threadIdx.x);
  if (i >= n8) return;
  const float* s = src + (size_t)i * 8;
  float4 x0 = *(const float4*)(s);
  float4 x1 = *(const float4*)(s + 4);
  ushort8_t u;
  u[0] = f2bf(x0.x); u[1] = f2bf(x0.y); u[2] = f2bf(x0.z); u[3] = f2bf(x0.w);
  u[4] = f2bf(x1.x); u[5] = f2bf(x1.y); u[6] = f2bf(x1.z); u[7] = f2bf(x1.w);
  *(ushort8_t*)(dst + (size_t)i * 8) = u;
}

// ---------------------------------------------------------------------------
__global__ __launch_bounds__(256) void seg_mean_kernel(const float* __restrict__ x,
                                                       float* __restrict__ xbar) {
  int bl = blockIdx.x;
  int b = bl / LM_, l = bl % LM_;
  int t = threadIdx.x;
  int c4 = t & 127;
  int rh = t >> 7;
  const float* xp = x + ((size_t)b * N_ + (size_t)l * SEG_) * C_;
  float4 s = make_float4(0.f, 0.f, 0.f, 0.f);
  for (int r = rh * 128; r < rh * 128 + 128; ++r) {
    float4 v = *(const float4*)(xp + (size_t)r * C_ + c4 * 4);
    s.x += v.x; s.y += v.y; s.z += v.z; s.w += v.w;
  }
  __shared__ float red[2][512];
  *(float4*)&red[rh][c4 * 4] = s;
  __syncthreads();
  if (rh == 0) {
    float4 a = *(float4*)&red[0][c4 * 4];
    float4 c = *(float4*)&red[1][c4 * 4];
    const float invs = 1.0f / SEG_;
    float4 o;
    o.x = (a.x + c.x) * invs; o.y = (a.y + c.y) * invs;
    o.z = (a.z + c.z) * invs; o.w = (a.w + c.w) * invs;
    *(float4*)(xbar + (size_t)bl * C_ + c4 * 4) = o;
  }
}

// ---------------------------------------------------------------------------
// Merged landmark projections (f32 VALU GEMM, 128 rows) with bf16 epilogue:
// which==0 -> qland f32 + qlbh/qlbl;  which==1 -> kland f32 + klb.
__global__ __launch_bounds__(256) void land_gemm_kernel(const float* __restrict__ xbar,
                                                        const float* __restrict__ wq,
                                                        const float* __restrict__ bq,
                                                        const float* __restrict__ wk,
                                                        const float* __restrict__ bk,
                                                        float* __restrict__ qland,
                                                        float* __restrict__ kland,
                                                        unsigned short* __restrict__ qlbh,
                                                        unsigned short* __restrict__ qlbl,
                                                        unsigned short* __restrict__ klb) {
  __shared__ float As[32][68];
  __shared__ float Ws[32][68];
  int which = blockIdx.x >> 1;
  int row0 = (blockIdx.x & 1) * 64;
  int col0 = blockIdx.y * 64;
  const float* A = xbar;
  const float* W = which ? wk : wq;
  const float* bias = which ? bk : bq;
  float scale = which ? 1.0f : 0.125f;
  float* out = which ? kland : qland;
  int tid = threadIdx.x;
  int tm = tid >> 4, tn = tid & 15;
  float acc[4][4] = {};
  for (int k0 = 0; k0 < C_; k0 += 32) {
#pragma unroll
    for (int i = 0; i < 2; ++i) {
      int s = tid + i * 256;
      int r = s >> 3;
      int kg = (s & 7) << 2;
      float4 av = *(const float4*)(A + (size_t)(row0 + r) * C_ + k0 + kg);
      As[kg + 0][r] = av.x; As[kg + 1][r] = av.y;
      As[kg + 2][r] = av.z; As[kg + 3][r] = av.w;
      float4 wv = *(const float4*)(W + (size_t)(col0 + r) * C_ + k0 + kg);
      Ws[kg + 0][r] = wv.x; Ws[kg + 1][r] = wv.y;
      Ws[kg + 2][r] = wv.z; Ws[kg + 3][r] = wv.w;
    }
    __syncthreads();
#pragma unroll
    for (int kk = 0; kk < 32; ++kk) {
      float4 a = *(const float4*)&As[kk][tm * 4];
      float4 b = *(const float4*)&Ws[kk][tn * 4];
      float av[4] = {a.x, a.y, a.z, a.w};
      float bv[4] = {b.x, b.y, b.z, b.w};
#pragma unroll
      for (int i = 0; i < 4; ++i)
#pragma unroll
        for (int j = 0; j < 4; ++j) acc[i][j] += av[i] * bv[j];
    }
    __syncthreads();
  }
#pragma unroll
  for (int i = 0; i < 4; ++i) {
    int row = row0 + tm * 4 + i;
    int d0 = tn * 4;
    float o4[4];
#pragma unroll
    for (int j = 0; j < 4; ++j) o4[j] = (acc[i][j] + bias[col0 + d0 + j]) * scale;
    int b = row / LM_, n = row % LM_;
    int h = col0 >> 6;
    size_t idx = (((size_t)(b * H_ + h) * LM_) + n) * HD_ + d0;
    float4 o; o.x = o4[0]; o.y = o4[1]; o.z = o4[2]; o.w = o4[3];
    *(float4*)(out + idx) = o;
    if (which == 0) {
      ushort4_t uh, ul;
#pragma unroll
      for (int j = 0; j < 4; ++j) {
        unsigned short hbits = f2bf(o4[j]);
        uh[j] = hbits;
        ul[j] = f2bf(o4[j] - bf2f(hbits));
      }
      *(ushort4_t*)(qlbh + idx) = uh;
      *(ushort4_t*)(qlbl + idx) = ul;
    } else {
      ushort4_t uk;
#pragma unroll
      for (int j = 0; j < 4; ++j) uk[j] = f2bf(o4[j]);
      *(ushort4_t*)(klb + idx) = uk;
    }
  }
}

// ---------------------------------------------------------------------------
// Reg-staged MFMA GEMM body (A f32, W f32 converted in staging).
// omode 1: bf16 head-split; omode 2: bf16 vt.
__device__ __forceinline__ void mfma_gemm_body(const float* __restrict__ A,
                                               const float* __restrict__ W,
                                               const float* __restrict__ bias,
                                               unsigned short* __restrict__ out,
                                               float scale, int omode,
                                               int row0, int col0,
                                               unsigned short* Xs, unsigned short* Ws,
                                               int tid) {
  int wid = tid >> 6, lane = tid & 63;
  int wr = wid >> 1, wc = wid & 1;
  f32x4 acc[4][4] = {};
  int srow = tid >> 1;
  int sk = (tid & 1) * 16;
  const float* wpbase = W + (size_t)(col0 + srow) * C_ + sk;
  const float* apbase = A + (size_t)(row0 + srow) * C_ + sk;
  unsigned short* xdst = &Xs[srow * 32 + sk];
  unsigned short* wdst = &Ws[srow * 32 + sk];

  for (int k0 = 0; k0 < C_; k0 += 32) {
    __syncthreads();
    {
      float4 x0 = *(const float4*)(apbase + k0);
      float4 x1 = *(const float4*)(apbase + k0 + 4);
      float4 x2 = *(const float4*)(apbase + k0 + 8);
      float4 x3 = *(const float4*)(apbase + k0 + 12);
      ushort8_t u0, u1;
      u0[0] = f2bf(x0.x); u0[1] = f2bf(x0.y); u0[2] = f2bf(x0.z); u0[3] = f2bf(x0.w);
      u0[4] = f2bf(x1.x); u0[5] = f2bf(x1.y); u0[6] = f2bf(x1.z); u0[7] = f2bf(x1.w);
      u1[0] = f2bf(x2.x); u1[1] = f2bf(x2.y); u1[2] = f2bf(x2.z); u1[3] = f2bf(x2.w);
      u1[4] = f2bf(x3.x); u1[5] = f2bf(x3.y); u1[6] = f2bf(x3.z); u1[7] = f2bf(x3.w);
      *(ushort8_t*)(xdst) = u0;
      *(ushort8_t*)(xdst + 8) = u1;
    }
    {
      float4 w0 = *(const float4*)(wpbase + k0);
      float4 w1 = *(const float4*)(wpbase + k0 + 4);
      float4 w2 = *(const float4*)(wpbase + k0 + 8);
      float4 w3 = *(const float4*)(wpbase + k0 + 12);
      ushort8_t u0, u1;
      u0[0] = f2bf(w0.x); u0[1] = f2bf(w0.y); u0[2] = f2bf(w0.z); u0[3] = f2bf(w0.w);
      u0[4] = f2bf(w1.x); u0[5] = f2bf(w1.y); u0[6] = f2bf(w1.z); u0[7] = f2bf(w1.w);
      u1[0] = f2bf(w2.x); u1[1] = f2bf(w2.y); u1[2] = f2bf(w2.z); u1[3] = f2bf(w2.w);
      u1[4] = f2bf(w3.x); u1[5] = f2bf(w3.y); u1[6] = f2bf(w3.z); u1[7] = f2bf(w3.w);
      *(ushort8_t*)(wdst) = u0;
      *(ushort8_t*)(wdst + 8) = u1;
    }
    __syncthreads();
    bf16x8 af[4], bfr[4];
#pragma unroll
    for (int m = 0; m < 4; ++m)
      af[m] = *(bf16x8*)&Xs[(wr * 64 + m * 16 + (lane & 15)) * 32 + (lane >> 4) * 8];
#pragma unroll
    for (int n = 0; n < 4; ++n)
      bfr[n] = *(bf16x8*)&Ws[(wc * 64 + n * 16 + (lane & 15)) * 32 + (lane >> 4) * 8];
#pragma unroll
    for (int m = 0; m < 4; ++m)
#pragma unroll
      for (int n = 0; n < 4; ++n)
        acc[m][n] = __builtin_amdgcn_mfma_f32_16x16x32_bf16(af[m], bfr[n], acc[m][n], 0, 0, 0);
  }

#pragma unroll
  for (int m = 0; m < 4; ++m) {
    int rbase = row0 + wr * 64 + m * 16 + (lane >> 4) * 4;
#pragma unroll
    for (int n = 0; n < 4; ++n) {
      int c = col0 + wc * 64 + n * 16 + (lane & 15);
      float bc = bias[c];
      if (omode == 2) {
        int b = rbase >> 14, nn = rbase & 16383;
        int h = c >> 6, d = c & 63;
        ushort4_t u;
#pragma unroll
        for (int rg = 0; rg < 4; ++rg) u[rg] = f2bf((acc[m][n][rg] + bc) * scale);
        *(ushort4_t*)(out + ((size_t)(b * H_ + h) * HD_ + d) * N_ + nn) = u;
      } else {
#pragma unroll
        for (int rg = 0; rg < 4; ++rg) {
          float val = (acc[m][n][rg] + bc) * scale;
          int r = rbase + rg;
          int b = r >> 14, nn = r & 16383, h = c >> 6, d = c & 63;
          out[(((size_t)(b * H_ + h) * N_) + nn) * HD_ + d] = f2bf(val);
        }
      }
    }
  }
}

// ---------------------------------------------------------------------------
// SVD sweep loop (4-wave row-split, shared by both phases).
__device__ __forceinline__ void svd_sweeps(float a[16], float v[16], char* smemraw,
                                           int w, int lane, int nsweeps) {
  float (*pg)[4][64] = (float(*)[4][64])(smemraw);          // 2048 B
  float (*pa4)[64]   = (float(*)[64])(smemraw + 2048);      // 1024 B
  for (int sweep = 0; sweep < nsweeps; ++sweep) {
    float p0 = 0.f, p1 = 0.f;
#pragma unroll
    for (int k = 0; k < 16; k += 2) { p0 = fmaf(a[k], a[k], p0); p1 = fmaf(a[k + 1], a[k + 1], p1); }
    pa4[w][lane] = p0 + p1;
    __syncthreads();
    float alpha = (pa4[0][lane] + pa4[1][lane]) + (pa4[2][lane] + pa4[3][lane]);
    for (int mask = 1; mask < 64; ++mask) {
      int buf = mask & 1;
      bool lower = lane < (lane ^ mask);
      float beta = __shfl_xor(alpha, mask);
      float o[16];
#pragma unroll
      for (int k = 0; k < 16; ++k) o[k] = __shfl_xor(a[k], mask);
      float g0 = 0.f, g1 = 0.f;
#pragma unroll
      for (int k = 0; k < 16; k += 2) { g0 = fmaf(a[k], o[k], g0); g1 = fmaf(a[k + 1], o[k + 1], g1); }
      pg[buf][w][lane] = g0 + g1;
      __syncthreads();
      float gamma = (pg[buf][0][lane] + pg[buf][1][lane]) + (pg[buf][2][lane] + pg[buf][3][lane]);
      bool need = (gamma * gamma > 1e-12f * alpha * beta);
      if (__any(need)) {
        float ov[16];
#pragma unroll
        for (int k = 0; k < 16; ++k) ov[k] = __shfl_xor(v[k], mask);
        float ap = lower ? alpha : beta;
        float aq = lower ? beta : alpha;
        float c = 1.f, s = 0.f;
        if (need) {
          float tau = (aq - ap) / (2.f * gamma);
          float t = copysignf(1.f, tau) / (fabsf(tau) + sqrtf(fmaf(tau, tau, 1.f)));
          c = rsqrtf(fmaf(t, t, 1.f));
          s = t * c;
        }
        float sm = lower ? -s : s;
#pragma unroll
        for (int k = 0; k < 16; ++k) a[k] = fmaf(sm, o[k], c * a[k]);
#pragma unroll
        for (int k = 0; k < 16; ++k) v[k] = fmaf(sm, ov[k], c * v[k]);
        float twocsg = 2.f * c * s * gamma;
        alpha = fmaf(c * c, alpha, fmaf(s * s, beta, lower ? -twocsg : twocsg));
      }
    }
  }
}

// Phase 1: compute ker2 in-LDS from qland/kland, SW1_ sweeps, save state.
__device__ void svd_phase1(const float* __restrict__ qland, const float* __restrict__ kland,
                           float* __restrict__ asave, float* __restrict__ vsave,
                           int bh, char* smemraw, int tid) {
  __builtin_amdgcn_s_setprio(3);
  float (*qlS)[65] = (float(*)[65])(smemraw);             // 16640 B
  float (*klS)[65] = (float(*)[65])(smemraw + 16640);     // 16640 B -> 33280
  // 64 rows x 16 float4-groups = 1024 slots / 256 threads = 4 iterations.
  for (int i = 0; i < 4; ++i) {
    int s = tid + i * 256;
    int r = s >> 4, d4 = (s & 15) << 2;
    *(float4*)&qlS[r][d4] = *(const float4*)(qland + ((size_t)bh * 64 + r) * 64 + d4);
    *(float4*)&klS[r][d4] = *(const float4*)(kland + ((size_t)bh * 64 + r) * 64 + d4);
  }
  __syncthreads();
  int w = tid >> 6, lane = tid & 63;
  float a[16], v[16];
#pragma unroll
  for (int k = 0; k < 16; ++k) {
    int row = w * 16 + k;
    float acc = 0.f;
#pragma unroll
    for (int d4 = 0; d4 < 64; d4 += 4) {
      float4 qv = *(float4*)&qlS[row][d4];
      float4 kv = *(float4*)&klS[lane][d4];
      acc += qv.x * kv.x + qv.y * kv.y + qv.z * kv.z + qv.w * kv.w;
    }
    float e = expf(acc);
    float rs = e;
#pragma unroll
    for (int m = 1; m < 64; m <<= 1) rs += __shfl_xor(rs, m);
    a[k] = e * (1.f / rs);
  }
#pragma unroll
  for (int k = 0; k < 16; ++k) v[k] = (w * 16 + k == lane) ? 1.f : 0.f;
  __syncthreads();   // qlS/klS dead; pg/pa4 overlay safe
  svd_sweeps(a, v, smemraw, w, lane, SW1_);
#pragma unroll
  for (int k = 0; k < 16; ++k) {
    asave[((size_t)bh * 64 + w * 16 + k) * 64 + lane] = a[k];
    vsave[((size_t)bh * 64 + w * 16 + k) * 64 + lane] = v[k];
  }
  __builtin_amdgcn_s_setprio(0);
}

// Phase 2: load state, SW2_ sweeps, sigma/cutoff + pinv.
__device__ void svd_phase2(const float* __restrict__ asave, const float* __restrict__ vsave,
                           float* __restrict__ pinv, int bh, char* smemraw, int tid) {
  __builtin_amdgcn_s_setprio(3);
  double (*ps2)[64]  = (double(*)[64])(smemraw + 3072);     // 2048 B
  float (*vsL)[65]   = (float(*)[65])(smemraw + 5120);      // 16640 B
  float (*wasL)[65]  = (float(*)[65])(smemraw + 21760);     // 16640 B
  int w = tid >> 6, lane = tid & 63;
  float a[16], v[16];
#pragma unroll
  for (int k = 0; k < 16; ++k) {
    a[k] = asave[((size_t)bh * 64 + w * 16 + k) * 64 + lane];
    v[k] = vsave[((size_t)bh * 64 + w * 16 + k) * 64 + lane];
  }
  svd_sweeps(a, v, smemraw, w, lane, SW2_);

  double psig = 0.0;
#pragma unroll
  for (int k = 0; k < 16; ++k) psig += (double)a[k] * (double)a[k];
  ps2[w][lane] = psig;
  __syncthreads();
  double sig2 = (ps2[0][lane] + ps2[1][lane]) + (ps2[2][lane] + ps2[3][lane]);
  double smax = sig2;
#pragma unroll
  for (int m = 1; m < 64; m <<= 1) smax = fmax(smax, __shfl_xor(smax, m));
  double cutoff2 = smax * (RCOND_ * RCOND_);
  float wgt = (sig2 > cutoff2) ? (float)(1.0 / sig2) : 0.f;

#pragma unroll
  for (int k = 0; k < 16; ++k) {
    vsL[lane][w * 16 + k] = v[k];
    wasL[lane][w * 16 + k] = wgt * a[k];
  }
  __syncthreads();
  int i = tid >> 2;
  int j0 = (tid & 3) * 16;
  float acc[16] = {};
  for (int r = 0; r < 64; ++r) {
    float vv = vsL[r][i];
#pragma unroll
    for (int jj = 0; jj < 16; ++jj) acc[jj] = fmaf(vv, wasL[r][j0 + jj], acc[jj]);
  }
#pragma unroll
  for (int jj = 0; jj < 16; jj += 4) {
    float4 ovv = make_float4(acc[jj], acc[jj + 1], acc[jj + 2], acc[jj + 3]);
    *(float4*)(pinv + ((size_t)bh * 64 + i) * 64 + j0 + jj) = ovv;
  }
  __builtin_amdgcn_s_setprio(0);
}

// ---------------------------------------------------------------------------
// Fused 1: blocks 0..15 = SVD phase 1 (incl. ker2); 16..3087 = projections.
__global__ __launch_bounds__(256) void fused1_kernel(
    const float* __restrict__ x,
    const float* __restrict__ wq, const float* __restrict__ bq,
    const float* __restrict__ wk, const float* __restrict__ bk,
    const float* __restrict__ wv, const float* __restrict__ bv,
    unsigned short* __restrict__ q4, unsigned short* __restrict__ k4,
    unsigned short* __restrict__ vt,
    const float* __restrict__ qland, const float* __restrict__ kland,
    float* __restrict__ asave, float* __restrict__ vsave) {
  __shared__ __align__(16) char smem[33280];
  int tid = threadIdx.x;
  int blk = blockIdx.x;
  if (blk < 16) { svd_phase1(qland, kland, asave, vsave, blk, smem, tid); return; }
  int g = blk - 16;
  int which = g >> 10;
  int sub = g & 1023;
  int row0 = (sub >> 2) * 128;
  int col0 = (sub & 3) * 128;
  unsigned short* Xs = (unsigned short*)smem;
  unsigned short* Ws = Xs + 128 * 32;
  if (which == 0)
    mfma_gemm_body(x, wq, bq, q4, 0.125f, 1, row0, col0, Xs, Ws, tid);
  else if (which == 1)
    mfma_gemm_body(x, wk, bk, k4, 1.0f, 1, row0, col0, Xs, Ws, tid);
  else
    mfma_gemm_body(x, wv, bv, vt, 1.0f, 2, row0, col0, Xs, Ws, tid);
}

// ---------------------------------------------------------------------------
// ker3+kv body (deviation form, MFMA) — unchanged math.
__device__ void ker3kv_body(const unsigned short* __restrict__ qlh,
                            const unsigned short* __restrict__ qll,
                            const unsigned short* __restrict__ k4,
                            const unsigned short* __restrict__ vt,
                            float* __restrict__ pacc,
                            float* __restrict__ pacc0,
                            float* __restrict__ ps,
                            int bh, int ch, char* smemraw, int tid) {
  int w = tid >> 6, lane = tid & 63;
  int part = ch * 4 + w;
  int lrow = lane & 15, lgrp = lane >> 4;
  unsigned short* myP = (unsigned short*)smemraw + w * 64 * 72;

  bf16x8 qah[4][2], qal[4][2];
#pragma unroll
  for (int mf = 0; mf < 4; ++mf)
#pragma unroll
    for (int ks = 0; ks < 2; ++ks) {
      size_t off = ((size_t)bh * 64 + mf * 16 + lrow) * 64 + ks * 32 + lgrp * 8;
      qah[mf][ks] = ld_bf8(qlh + off);
      qal[mf][ks] = ld_bf8(qll + off);
    }
  bf16x8 onesf;
#pragma unroll
  for (int j = 0; j < 8; ++j) onesf[j] = (__bf16)1.0f;

  f32x4 kvacc[4][4] = {};
  f32x4 oneacc[4] = {};
  f32x4 ssum[4] = {};

  for (int sub = 0; sub < 4; ++sub) {
    int n0 = ch * 1024 + w * 256 + sub * 64;
    f32x4 sacc[4][4] = {};
#pragma unroll
    for (int ks = 0; ks < 2; ++ks) {
#pragma unroll
      for (int nf = 0; nf < 4; ++nf) {
        bf16x8 kb = ld_bf8(k4 + ((size_t)bh * N_ + n0 + nf * 16 + lrow) * 64 + ks * 32 + lgrp * 8);
#pragma unroll
        for (int mf = 0; mf < 4; ++mf) {
          sacc[mf][nf] = __builtin_amdgcn_mfma_f32_16x16x32_bf16(qah[mf][ks], kb, sacc[mf][nf], 0, 0, 0);
          sacc[mf][nf] = __builtin_amdgcn_mfma_f32_16x16x32_bf16(qal[mf][ks], kb, sacc[mf][nf], 0, 0, 0);
        }
      }
    }
#pragma unroll
    for (int mf = 0; mf < 4; ++mf) {
#pragma unroll
      for (int nf = 0; nf < 4; ++nf) {
#pragma unroll
        for (int r = 0; r < 4; ++r) {
          float pd = expf(sacc[mf][nf][r]) - 1.0f;
          ssum[mf][r] += pd;
          myP[(mf * 16 + lgrp * 4 + r) * 72 + nf * 16 + lrow] = f2bf(pd);
        }
      }
    }
#pragma unroll
    for (int ks = 0; ks < 2; ++ks) {
      bf16x8 pa[4];
#pragma unroll
      for (int mf = 0; mf < 4; ++mf)
        pa[mf] = ld_bf8(myP + (mf * 16 + lrow) * 72 + ks * 32 + lgrp * 8);
#pragma unroll
      for (int nf = 0; nf < 4; ++nf) {
        bf16x8 vb = ld_bf8(vt + ((size_t)bh * 64 + nf * 16 + lrow) * N_ + n0 + ks * 32 + lgrp * 8);
#pragma unroll
        for (int mf = 0; mf < 4; ++mf)
          kvacc[mf][nf] = __builtin_amdgcn_mfma_f32_16x16x32_bf16(pa[mf], vb, kvacc[mf][nf], 0, 0, 0);
        oneacc[nf] = __builtin_amdgcn_mfma_f32_16x16x32_bf16(onesf, vb, oneacc[nf], 0, 0, 0);
      }
    }
  }
#pragma unroll
  for (int mf = 0; mf < 4; ++mf)
#pragma unroll
    for (int m = 1; m < 16; m <<= 1)
#pragma unroll
      for (int r = 0; r < 4; ++r) ssum[mf][r] += __shfl_xor(ssum[mf][r], m);

  size_t pb = (((size_t)bh * NPART_ + part) * 64) * 64;
#pragma unroll
  for (int mf = 0; mf < 4; ++mf)
#pragma unroll
    for (int nf = 0; nf < 4; ++nf)
#pragma unroll
      for (int r = 0; r < 4; ++r)
        pacc[pb + (size_t)(mf * 16 + lgrp * 4 + r) * 64 + nf * 16 + lrow] = kvacc[mf][nf][r];
  if (lrow == 0) {
#pragma unroll
    for (int mf = 0; mf < 4; ++mf)
#pragma unroll
      for (int r = 0; r < 4; ++r)
        ps[((size_t)bh * NPART_ + part) * 64 + mf * 16 + lgrp * 4 + r] = ssum[mf][r];
  }
  if (lgrp == 0) {
#pragma unroll
    for (int nf = 0; nf < 4; ++nf)
      pacc0[((size_t)bh * NPART_ + part) * 64 + nf * 16 + lrow] = oneacc[nf][0];
  }
}

// Fused 2: blocks 0..15 = SVD phase 2 (+pinv); 16..271 = ker3kv.
__global__ __launch_bounds__(256, 1) void fused2_kernel(
    const unsigned short* __restrict__ qlh,
    const unsigned short* __restrict__ qll,
    const unsigned short* __restrict__ k4,
    const unsigned short* __restrict__ vt,
    float* __restrict__ pacc, float* __restrict__ pacc0, float* __restrict__ ps,
    const float* __restrict__ asave, const float* __restrict__ vsave,
    float* __restrict__ pinv) {
  __shared__ __align__(16) char smem[38400];
  int tid = threadIdx.x;
  int blk = blockIdx.x;
  if (blk < 16) { svd_phase2(asave, vsave, pinv, blk, smem, tid); return; }
  int g = blk - 16;
  int bh = g >> 4, ch = g & 15;
  ker3kv_body(qlh, qll, k4, vt, pacc, pacc0, ps, bh, ch, smem, tid);
}

// ---------------------------------------------------------------------------
__global__ __launch_bounds__(256) void kv_combine_kernel(const float* __restrict__ pacc,
                                                         const float* __restrict__ pacc0,
                                                         const float* __restrict__ ps,
                                                         float* __restrict__ kv) {
  int bh = blockIdx.y;
  int lm = blockIdx.x * 16 + (threadIdx.x >> 4);
  int d4 = (threadIdx.x & 15) * 4;
  float s = 16384.f;
  for (int part = 0; part < NPART_; ++part) s += ps[((size_t)bh * NPART_ + part) * 64 + lm];
  float4 a = make_float4(0.f, 0.f, 0.f, 0.f);
  for (int part = 0; part < NPART_; ++part) {
    float4 c0 = *(const float4*)&pacc0[((size_t)bh * NPART_ + part) * 64 + d4];
    float4 v = *(const float4*)&pacc[(((size_t)bh * NPART_ + part) * 64 + lm) * 64 + d4];
    a.x += c0.x + v.x; a.y += c0.y + v.y; a.z += c0.z + v.z; a.w += c0.w + v.w;
  }
  float inv = 1.f / s;
  float4 o = make_float4(a.x * inv, a.y * inv, a.z * inv, a.w * inv);
  *(float4*)(kv + ((size_t)bh * 64 + lm) * 64 + d4) = o;
}

// ---------------------------------------------------------------------------
__global__ __launch_bounds__(256) void mmat_kernel(const float* __restrict__ pinv,
                                                   const float* __restrict__ kv,
                                                   unsigned short* __restrict__ mtbh,
                                                   unsigned short* __restrict__ mtbl,
                                                   float* __restrict__ msum) {
  int bh = blockIdx.x;
  int tid = threadIdx.x;
  __shared__ float kvs[64][68];
  __shared__ double pcsd[64];
  for (int i = 0; i < 4; ++i) {
    int s = tid + i * 256;
    int r = s >> 4, d4 = (s & 15) << 2;
    *(float4*)&kvs[r][d4] = *(const float4*)(kv + ((size_t)bh * 64 + r) * 64 + d4);
  }
  if (tid < 64) {
    double s = 0.0;
    for (int l = 0; l < 64; ++l) s += (double)pinv[((size_t)bh * 64 + l) * 64 + tid];
    pcsd[tid] = s;
  }
  __syncthreads();
  int l = tid >> 2, t = tid & 3;
  double o[16] = {};
  for (int j = 0; j < 64; ++j) {
    double pv = (double)pinv[((size_t)bh * 64 + l) * 64 + j];
#pragma unroll
    for (int i = 0; i < 16; ++i) o[i] += pv * (double)kvs[j][t * 16 + i];
  }
#pragma unroll
  for (int i = 0; i < 16; ++i) {
    float f = (float)o[i];
    unsigned short hi = f2bf(f);
    float lo = f - bf2f(hi);
    int d = t * 16 + i;
    mtbh[((size_t)bh * 64 + d) * 64 + l] = hi;
    mtbl[((size_t)bh * 64 + d) * 64 + l] = f2bf(lo);
  }
  if (tid < 64) {
    double m = 0.0;
    for (int j = 0; j < 64; ++j) m += pcsd[j] * (double)kvs[j][tid];
    msum[(size_t)bh * 64 + tid] = (float)(m * (1.0 / 64.0));
  }
}

// ---------------------------------------------------------------------------
__global__ __launch_bounds__(256, 1) void ker1out_mfma_kernel(
    const unsigned short* __restrict__ q4,
    const unsigned short* __restrict__ klb,
    const unsigned short* __restrict__ mtbh,
    const unsigned short* __restrict__ mtbl,
    const float* __restrict__ msum,
    unsigned short* __restrict__ outh) {
  int bh = blockIdx.y, tile = blockIdx.x;
  int b = bh >> 3, h = bh & 7;
  int tid = threadIdx.x, w = tid >> 6, lane = tid & 63;
  int lrow = lane & 15, lgrp = lane >> 4;
  int tok0 = tile * 256 + w * 64;
  __shared__ __align__(16) unsigned short Pl[4][64 * 72];
  unsigned short* myP = &Pl[w][0];

  f32x4 sacc[4][4] = {};
#pragma unroll
  for (int ks = 0; ks < 2; ++ks) {
    bf16x8 kb[4];
#pragma unroll
    for (int nf = 0; nf < 4; ++nf)
      kb[nf] = ld_bf8(klb + ((size_t)bh * 64 + nf * 16 + lrow) * 64 + ks * 32 + lgrp * 8);
#pragma unroll
    for (int mf = 0; mf < 4; ++mf) {
      bf16x8 qa = ld_bf8(q4 + ((size_t)bh * N_ + tok0 + mf * 16 + lrow) * 64 + ks * 32 + lgrp * 8);
#pragma unroll
      for (int nf = 0; nf < 4; ++nf)
        sacc[mf][nf] = __builtin_amdgcn_mfma_f32_16x16x32_bf16(qa, kb[nf], sacc[mf][nf], 0, 0, 0);
    }
  }
  f32x4 ssum[4] = {};
#pragma unroll
  for (int mf = 0; mf < 4; ++mf)
#pragma unroll
    for (int nf = 0; nf < 4; ++nf)
#pragma unroll
      for (int r = 0; r < 4; ++r) {
        sacc[mf][nf][r] = expf(sacc[mf][nf][r]);
        ssum[mf][r] += sacc[mf][nf][r];
      }
#pragma unroll
  for (int mf = 0; mf < 4; ++mf)
#pragma unroll
    for (int m = 1; m < 16; m <<= 1)
#pragma unroll
      for (int r = 0; r < 4; ++r) ssum[mf][r] += __shfl_xor(ssum[mf][r], m);
#pragma unroll
  for (int mf = 0; mf < 4; ++mf) {
    f32x4 inv;
#pragma unroll
    for (int r = 0; r < 4; ++r) inv[r] = 1.f / ssum[mf][r];
#pragma unroll
    for (int nf = 0; nf < 4; ++nf)
#pragma unroll
      for (int r = 0; r < 4; ++r) {
        float pdev = fmaf(sacc[mf][nf][r], inv[r], -0.015625f);
        myP[(mf * 16 + lgrp * 4 + r) * 72 + nf * 16 + lrow] = f2bf(pdev);
      }
  }

  f32x4 oacc[4][4] = {};
#pragma unroll
  for (int ks = 0; ks < 2; ++ks) {
    bf16x8 pa[4];
#pragma unroll
    for (int mf = 0; mf < 4; ++mf)
      pa[mf] = ld_bf8(myP + (mf * 16 + lrow) * 72 + ks * 32 + lgrp * 8);
#pragma unroll
    for (int nf = 0; nf < 4; ++nf) {
      bf16x8 mh = ld_bf8(mtbh + ((size_t)bh * 64 + nf * 16 + lrow) * 64 + ks * 32 + lgrp * 8);
      bf16x8 ml = ld_bf8(mtbl + ((size_t)bh * 64 + nf * 16 + lrow) * 64 + ks * 32 + lgrp * 8);
#pragma unroll
      for (int mf = 0; mf < 4; ++mf) {
        oacc[mf][nf] = __builtin_amdgcn_mfma_f32_16x16x32_bf16(pa[mf], mh, oacc[mf][nf], 0, 0, 0);
        oacc[mf][nf] = __builtin_amdgcn_mfma_f32_16x16x32_bf16(pa[mf], ml, oacc[mf][nf], 0, 0, 0);
      }
    }
  }
#pragma unroll
  for (int nf = 0; nf < 4; ++nf) {
    float ms = msum[(size_t)bh * 64 + nf * 16 + lrow];
#pragma unroll
    for (int mf = 0; mf < 4; ++mf)
#pragma unroll
      for (int r = 0; r < 4; ++r) {
        int tok = tok0 + mf * 16 + lgrp * 4 + r;
        int d = nf * 16 + lrow;
        outh[((size_t)b * N_ + tok) * C_ + h * HD_ + d] = f2bf(oacc[mf][nf][r] + ms);
      }
  }
}

// ---------------------------------------------------------------------------
// Final projection (serial tail): outh(bf16) @ wob^T(bf16) + bo -> f32 out.
__global__ __launch_bounds__(256) void oproj_kernel(const unsigned short* __restrict__ outh,
                                                    const unsigned short* __restrict__ wob,
                                                    const float* __restrict__ bo,
                                                    float* __restrict__ out) {
  __shared__ __align__(16) unsigned short Xs[128 * 32];
  __shared__ __align__(16) unsigned short Ws[128 * 32];
  int tid = threadIdx.x;
  int w = tid >> 6, lane = tid & 63;
  int wr = w >> 1, wc = w & 1;
  int row0 = blockIdx.x * 128, col0 = blockIdx.y * 128;
  f32x4 acc[4][4] = {};

  for (int k0 = 0; k0 < C_; k0 += 32) {
    __syncthreads();
#pragma unroll
    for (int i = 0; i < 2; ++i) {
      const unsigned short* gx = outh + (size_t)(row0 + w * 32 + i * 16 + (lane >> 2)) * C_ + k0 + (lane & 3) * 8;
      gload_lds16(gx, &Xs[(w * 32 + i * 16) * 32]);
      const unsigned short* gw = wob + (size_t)(col0 + w * 32 + i * 16 + (lane >> 2)) * C_ + k0 + (lane & 3) * 8;
      gload_lds16(gw, &Ws[(w * 32 + i * 16) * 32]);
    }
    __syncthreads();
    bf16x8 af[4], bfr[4];
#pragma unroll
    for (int m = 0; m < 4; ++m)
      af[m] = *(bf16x8*)&Xs[(wr * 64 + m * 16 + (lane & 15)) * 32 + (lane >> 4) * 8];
#pragma unroll
    for (int n = 0; n < 4; ++n)
      bfr[n] = *(bf16x8*)&Ws[(wc * 64 + n * 16 + (lane & 15)) * 32 + (lane >> 4) * 8];
#pragma unroll
    for (int m = 0; m < 4; ++m)
#pragma unroll
      for (int n = 0; n < 4; ++n)
        acc[m][n] = __builtin_amdgcn_mfma_f32_16x16x32_bf16(af[m], bfr[n], acc[m][n], 0, 0, 0);
  }

#pragma unroll
  for (int m = 0; m < 4; ++m) {
    int rbase = row0 + wr * 64 + m * 16 + (lane >> 4) * 4;
#pragma unroll
    for (int n = 0; n < 4; ++n) {
      int c = col0 + wc * 64 + n * 16 + (lane & 15);
      float bc = bo[c];
#pragma unroll
      for (int rg = 0; rg < 4; ++rg)
        out[(size_t)(rbase + rg) * C_ + c] = acc[m][n][rg] + bc;
    }
  }
}

// ---------------------------------------------------------------------------
extern "C" void kernel_launch(void* const* d_in, const int* in_sizes, int n_in,
                              void* d_out, int out_size, void* d_ws, size_t ws_size,
                              hipStream_t stream) {
  const float* x  = (const float*)d_in[0];
  const float* wq = (const float*)d_in[1];
  const float* bq = (const float*)d_in[2];
  const float* wk = (const float*)d_in[3];
  const float* bk = (const float*)d_in[4];
  const float* wv = (const float*)d_in[5];
  const float* bv = (const float*)d_in[6];
  const float* wo = (const float*)d_in[7];
  const float* bo = (const float*)d_in[8];
  float* out = (float*)d_out;

  char* base = (char*)d_ws;
  const size_t QKV = (size_t)BH_ * N_ * HD_;
  unsigned short* q4 = (unsigned short*)base;                 // 32MB
  unsigned short* k4 = (unsigned short*)(base + QKV * 2);     // 32MB
  unsigned short* vt = (unsigned short*)(base + QKV * 4);     // 32MB
  unsigned short* outh = (unsigned short*)(base + QKV * 2);   // alias k4 (dead after ker3kv)
  char* sp = base + QKV * 6;
  float* pacc  = (float*)sp; sp += (size_t)BH_ * NPART_ * 64 * 64 * 4;  // 16.78MB
  float* pacc0 = (float*)sp; sp += (size_t)BH_ * NPART_ * 64 * 4;
  float* ps    = (float*)sp; sp += (size_t)BH_ * NPART_ * 64 * 4;
  float* xbar  = (float*)sp; sp += (size_t)B_ * LM_ * C_ * 4;
  float* qland = (float*)sp; sp += (size_t)BH_ * LM_ * HD_ * 4;
  float* kland = (float*)sp; sp += (size_t)BH_ * LM_ * HD_ * 4;
  unsigned short* qlbh = (unsigned short*)sp; sp += (size_t)BH_ * LM_ * HD_ * 2;
  unsigned short* qlbl = (unsigned short*)sp; sp += (size_t)BH_ * LM_ * HD_ * 2;
  unsigned short* klb  = (unsigned short*)sp; sp += (size_t)BH_ * LM_ * HD_ * 2;
  float* pinv  = (float*)sp; sp += (size_t)BH_ * LM_ * LM_ * 4;
  float* kvb   = (float*)sp; sp += (size_t)BH_ * LM_ * HD_ * 4;
  unsigned short* mtbh = (unsigned short*)sp; sp += (size_t)BH_ * LM_ * HD_ * 2;
  unsigned short* mtbl = (unsigned short*)sp; sp += (size_t)BH_ * LM_ * HD_ * 2;
  float* msum  = (float*)sp; sp += (size_t)BH_ * HD_ * 4;
  float* asave = (float*)sp; sp += (size_t)BH_ * LM_ * LM_ * 4;   // 256KB
  float* vsave = (float*)sp; sp += (size_t)BH_ * LM_ * LM_ * 4;   // 256KB
  unsigned short* wob = (unsigned short*)sp; sp += (size_t)C_ * C_ * 2;  // 512KB

  const int W8 = (C_ * C_) / 8;

  // wo -> bf16 (needed only by the serial-tail oproj)
  cvt_bf16_kernel<<<W8 / 256, 256, 0, stream>>>(wo, wob, W8);

  // landmark path (f32-exact) + bf16 conversions in epilogue
  seg_mean_kernel<<<B_ * LM_, 256, 0, stream>>>(x, xbar);
  dim3 gl(4, 8);
  land_gemm_kernel<<<gl, 256, 0, stream>>>(xbar, wq, bq, wk, bk,
                                           qland, kland, qlbh, qlbl, klb);

  // fused 1: SVD phase 1 (blocks 0..15; computes ker2 in-LDS) + projections
  fused1_kernel<<<16 + 3 * 1024, 256, 0, stream>>>(
      x, wq, bq, wk, bk, wv, bv, q4, k4, vt, qland, kland, asave, vsave);

  // fused 2: SVD phase 2 + pinv (blocks 0..15) + ker3kv (256 blocks)
  fused2_kernel<<<16 + NCH_ * BH_, 256, 0, stream>>>(
      qlbh, qlbl, k4, vt, pacc, pacc0, ps, asave, vsave, pinv);

  // combine + M
  dim3 g7(4, BH_);
  kv_combine_kernel<<<g7, 256, 0, stream>>>(pacc, pacc0, ps, kvb);
  mmat_kernel<<<BH_, 256, 0, stream>>>(pinv, kvb, mtbh, mtbl, msum);

  // out_heads -> bf16 outh (aliases dead k4)
  dim3 g9(N_ / 256, BH_);
  ker1out_mfma_kernel<<<g9, 256, 0, stream>>>(q4, klb, mtbh, mtbl, msum, outh);

  // final projection (DMA-staged bf16 GEMM)
  dim3 g10(B_ * N_ / 128, C_ / 128);
  oproj_kernel<<<g10, 256, 0, stream>>>(outh, wob, bo, out);
}

// Round 15
// 432.059 us; speedup vs baseline: 8.0729x; 1.1119x over previous
//
#include <hip/hip_runtime.h>
#include <stdint.h>

// NystromAttention MI355X — Round 15: 5 Jacobi sweeps (SW1=3, SW2=2).
// Single-constant change from R14 (passed, 480us, absmax 6.1e-5 identical to
// 8-sweep). With 3 sweeps, fused1 becomes projection-bound (~190us floor).

constexpr int B_   = 2;
constexpr int N_   = 16384;
constexpr int C_   = 512;
constexpr int H_   = 8;
constexpr int HD_  = 64;
constexpr int LM_  = 64;
constexpr int SEG_ = 256;
constexpr int BH_  = 16;
constexpr int NCH_ = 16;
constexpr int NPART_ = 64;
constexpr int SW1_ = 3;   // sweeps in phase 1
constexpr int SW2_ = 2;   // sweeps in phase 2  (total 5)

#define RCOND_ (640.0 * 1.1920928955078125e-07)

typedef unsigned short ushort4_t __attribute__((ext_vector_type(4)));
typedef unsigned short ushort8_t __attribute__((ext_vector_type(8)));
typedef __bf16 bf16x8 __attribute__((ext_vector_type(8)));
typedef float f32x4 __attribute__((ext_vector_type(4)));

__device__ inline float bf2f(unsigned short u) {
  union { unsigned int i; float f; } x; x.i = ((unsigned int)u) << 16; return x.f;
}
__device__ inline unsigned short f2bf(float f) {
  union { float f; unsigned int i; } x; x.f = f;
  unsigned int lsb = (x.i >> 16) & 1;
  return (unsigned short)((x.i + 0x7fffu + lsb) >> 16);
}
__device__ inline bf16x8 ld_bf8(const unsigned short* p) { return *(const bf16x8*)p; }

__device__ __forceinline__ void gload_lds16(const unsigned short* gsrc, unsigned short* ldst) {
  __builtin_amdgcn_global_load_lds((const __attribute__((address_space(1))) void*)gsrc,
                                   (__attribute__((address_space(3))) void*)ldst, 16, 0, 0);
}

// ---------------------------------------------------------------------------
__global__ __launch_bounds__(256) void cvt_bf16_kernel(const float* __restrict__ src,
                                                       unsigned short* __restrict__ dst,
                                                       int n8) {
  int i = (blockIdx.x * 256 + threadIdx.x);
  if (i >= n8) return;
  const float* s = src + (size_t)i * 8;
  float4 x0 = *(const float4*)(s);
  float4 x1 = *(const float4*)(s + 4);
  ushort8_t u;
  u[0] = f2bf(x0.x); u[1] = f2bf(x0.y); u[2] = f2bf(x0.z); u[3] = f2bf(x0.w);
  u[4] = f2bf(x1.x); u[5] = f2bf(x1.y); u[6] = f2bf(x1.z); u[7] = f2bf(x1.w);
  *(ushort8_t*)(dst + (size_t)i * 8) = u;
}

// ---------------------------------------------------------------------------
__global__ __launch_bounds__(256) void seg_mean_kernel(const float* __restrict__ x,
                                                       float* __restrict__ xbar) {
  int bl = blockIdx.x;
  int b = bl / LM_, l = bl % LM_;
  int t = threadIdx.x;
  int c4 = t & 127;
  int rh = t >> 7;
  const float* xp = x + ((size_t)b * N_ + (size_t)l * SEG_) * C_;
  float4 s = make_float4(0.f, 0.f, 0.f, 0.f);
  for (int r = rh * 128; r < rh * 128 + 128; ++r) {
    float4 v = *(const float4*)(xp + (size_t)r * C_ + c4 * 4);
    s.x += v.x; s.y += v.y; s.z += v.z; s.w += v.w;
  }
  __shared__ float red[2][512];
  *(float4*)&red[rh][c4 * 4] = s;
  __syncthreads();
  if (rh == 0) {
    float4 a = *(float4*)&red[0][c4 * 4];
    float4 c = *(float4*)&red[1][c4 * 4];
    const float invs = 1.0f / SEG_;
    float4 o;
    o.x = (a.x + c.x) * invs; o.y = (a.y + c.y) * invs;
    o.z = (a.z + c.z) * invs; o.w = (a.w + c.w) * invs;
    *(float4*)(xbar + (size_t)bl * C_ + c4 * 4) = o;
  }
}

// ---------------------------------------------------------------------------
// Merged landmark projections (f32 VALU GEMM, 128 rows) with bf16 epilogue:
// which==0 -> qland f32 + qlbh/qlbl;  which==1 -> kland f32 + klb.
__global__ __launch_bounds__(256) void land_gemm_kernel(const float* __restrict__ xbar,
                                                        const float* __restrict__ wq,
                                                        const float* __restrict__ bq,
                                                        const float* __restrict__ wk,
                                                        const float* __restrict__ bk,
                                                        float* __restrict__ qland,
                                                        float* __restrict__ kland,
                                                        unsigned short* __restrict__ qlbh,
                                                        unsigned short* __restrict__ qlbl,
                                                        unsigned short* __restrict__ klb) {
  __shared__ float As[32][68];
  __shared__ float Ws[32][68];
  int which = blockIdx.x >> 1;
  int row0 = (blockIdx.x & 1) * 64;
  int col0 = blockIdx.y * 64;
  const float* A = xbar;
  const float* W = which ? wk : wq;
  const float* bias = which ? bk : bq;
  float scale = which ? 1.0f : 0.125f;
  float* out = which ? kland : qland;
  int tid = threadIdx.x;
  int tm = tid >> 4, tn = tid & 15;
  float acc[4][4] = {};
  for (int k0 = 0; k0 < C_; k0 += 32) {
#pragma unroll
    for (int i = 0; i < 2; ++i) {
      int s = tid + i * 256;
      int r = s >> 3;
      int kg = (s & 7) << 2;
      float4 av = *(const float4*)(A + (size_t)(row0 + r) * C_ + k0 + kg);
      As[kg + 0][r] = av.x; As[kg + 1][r] = av.y;
      As[kg + 2][r] = av.z; As[kg + 3][r] = av.w;
      float4 wv = *(const float4*)(W + (size_t)(col0 + r) * C_ + k0 + kg);
      Ws[kg + 0][r] = wv.x; Ws[kg + 1][r] = wv.y;
      Ws[kg + 2][r] = wv.z; Ws[kg + 3][r] = wv.w;
    }
    __syncthreads();
#pragma unroll
    for (int kk = 0; kk < 32; ++kk) {
      float4 a = *(const float4*)&As[kk][tm * 4];
      float4 b = *(const float4*)&Ws[kk][tn * 4];
      float av[4] = {a.x, a.y, a.z, a.w};
      float bv[4] = {b.x, b.y, b.z, b.w};
#pragma unroll
      for (int i = 0; i < 4; ++i)
#pragma unroll
        for (int j = 0; j < 4; ++j) acc[i][j] += av[i] * bv[j];
    }
    __syncthreads();
  }
#pragma unroll
  for (int i = 0; i < 4; ++i) {
    int row = row0 + tm * 4 + i;
    int d0 = tn * 4;
    float o4[4];
#pragma unroll
    for (int j = 0; j < 4; ++j) o4[j] = (acc[i][j] + bias[col0 + d0 + j]) * scale;
    int b = row / LM_, n = row % LM_;
    int h = col0 >> 6;
    size_t idx = (((size_t)(b * H_ + h) * LM_) + n) * HD_ + d0;
    float4 o; o.x = o4[0]; o.y = o4[1]; o.z = o4[2]; o.w = o4[3];
    *(float4*)(out + idx) = o;
    if (which == 0) {
      ushort4_t uh, ul;
#pragma unroll
      for (int j = 0; j < 4; ++j) {
        unsigned short hbits = f2bf(o4[j]);
        uh[j] = hbits;
        ul[j] = f2bf(o4[j] - bf2f(hbits));
      }
      *(ushort4_t*)(qlbh + idx) = uh;
      *(ushort4_t*)(qlbl + idx) = ul;
    } else {
      ushort4_t uk;
#pragma unroll
      for (int j = 0; j < 4; ++j) uk[j] = f2bf(o4[j]);
      *(ushort4_t*)(klb + idx) = uk;
    }
  }
}

// ---------------------------------------------------------------------------
// Reg-staged MFMA GEMM body (A f32, W f32 converted in staging).
// omode 1: bf16 head-split; omode 2: bf16 vt.
__device__ __forceinline__ void mfma_gemm_body(const float* __restrict__ A,
                                               const float* __restrict__ W,
                                               const float* __restrict__ bias,
                                               unsigned short* __restrict__ out,
                                               float scale, int omode,
                                               int row0, int col0,
                                               unsigned short* Xs, unsigned short* Ws,
                                               int tid) {
  int wid = tid >> 6, lane = tid & 63;
  int wr = wid >> 1, wc = wid & 1;
  f32x4 acc[4][4] = {};
  int srow = tid >> 1;
  int sk = (tid & 1) * 16;
  const float* wpbase = W + (size_t)(col0 + srow) * C_ + sk;
  const float* apbase = A + (size_t)(row0 + srow) * C_ + sk;
  unsigned short* xdst = &Xs[srow * 32 + sk];
  unsigned short* wdst = &Ws[srow * 32 + sk];

  for (int k0 = 0; k0 < C_; k0 += 32) {
    __syncthreads();
    {
      float4 x0 = *(const float4*)(apbase + k0);
      float4 x1 = *(const float4*)(apbase + k0 + 4);
      float4 x2 = *(const float4*)(apbase + k0 + 8);
      float4 x3 = *(const float4*)(apbase + k0 + 12);
      ushort8_t u0, u1;
      u0[0] = f2bf(x0.x); u0[1] = f2bf(x0.y); u0[2] = f2bf(x0.z); u0[3] = f2bf(x0.w);
      u0[4] = f2bf(x1.x); u0[5] = f2bf(x1.y); u0[6] = f2bf(x1.z); u0[7] = f2bf(x1.w);
      u1[0] = f2bf(x2.x); u1[1] = f2bf(x2.y); u1[2] = f2bf(x2.z); u1[3] = f2bf(x2.w);
      u1[4] = f2bf(x3.x); u1[5] = f2bf(x3.y); u1[6] = f2bf(x3.z); u1[7] = f2bf(x3.w);
      *(ushort8_t*)(xdst) = u0;
      *(ushort8_t*)(xdst + 8) = u1;
    }
    {
      float4 w0 = *(const float4*)(wpbase + k0);
      float4 w1 = *(const float4*)(wpbase + k0 + 4);
      float4 w2 = *(const float4*)(wpbase + k0 + 8);
      float4 w3 = *(const float4*)(wpbase + k0 + 12);
      ushort8_t u0, u1;
      u0[0] = f2bf(w0.x); u0[1] = f2bf(w0.y); u0[2] = f2bf(w0.z); u0[3] = f2bf(w0.w);
      u0[4] = f2bf(w1.x); u0[5] = f2bf(w1.y); u0[6] = f2bf(w1.z); u0[7] = f2bf(w1.w);
      u1[0] = f2bf(w2.x); u1[1] = f2bf(w2.y); u1[2] = f2bf(w2.z); u1[3] = f2bf(w2.w);
      u1[4] = f2bf(w3.x); u1[5] = f2bf(w3.y); u1[6] = f2bf(w3.z); u1[7] = f2bf(w3.w);
      *(ushort8_t*)(wdst) = u0;
      *(ushort8_t*)(wdst + 8) = u1;
    }
    __syncthreads();
    bf16x8 af[4], bfr[4];
#pragma unroll
    for (int m = 0; m < 4; ++m)
      af[m] = *(bf16x8*)&Xs[(wr * 64 + m * 16 + (lane & 15)) * 32 + (lane >> 4) * 8];
#pragma unroll
    for (int n = 0; n < 4; ++n)
      bfr[n] = *(bf16x8*)&Ws[(wc * 64 + n * 16 + (lane & 15)) * 32 + (lane >> 4) * 8];
#pragma unroll
    for (int m = 0; m < 4; ++m)
#pragma unroll
      for (int n = 0; n < 4; ++n)
        acc[m][n] = __builtin_amdgcn_mfma_f32_16x16x32_bf16(af[m], bfr[n], acc[m][n], 0, 0, 0);
  }

#pragma unroll
  for (int m = 0; m < 4; ++m) {
    int rbase = row0 + wr * 64 + m * 16 + (lane >> 4) * 4;
#pragma unroll
    for (int n = 0; n < 4; ++n) {
      int c = col0 + wc * 64 + n * 16 + (lane & 15);
      float bc = bias[c];
      if (omode == 2) {
        int b = rbase >> 14, nn = rbase & 16383;
        int h = c >> 6, d = c & 63;
        ushort4_t u;
#pragma unroll
        for (int rg = 0; rg < 4; ++rg) u[rg] = f2bf((acc[m][n][rg] + bc) * scale);
        *(ushort4_t*)(out + ((size_t)(b * H_ + h) * HD_ + d) * N_ + nn) = u;
      } else {
#pragma unroll
        for (int rg = 0; rg < 4; ++rg) {
          float val = (acc[m][n][rg] + bc) * scale;
          int r = rbase + rg;
          int b = r >> 14, nn = r & 16383, h = c >> 6, d = c & 63;
          out[(((size_t)(b * H_ + h) * N_) + nn) * HD_ + d] = f2bf(val);
        }
      }
    }
  }
}

// ---------------------------------------------------------------------------
// SVD sweep loop (4-wave row-split, shared by both phases).
__device__ __forceinline__ void svd_sweeps(float a[16], float v[16], char* smemraw,
                                           int w, int lane, int nsweeps) {
  float (*pg)[4][64] = (float(*)[4][64])(smemraw);          // 2048 B
  float (*pa4)[64]   = (float(*)[64])(smemraw + 2048);      // 1024 B
  for (int sweep = 0; sweep < nsweeps; ++sweep) {
    float p0 = 0.f, p1 = 0.f;
#pragma unroll
    for (int k = 0; k < 16; k += 2) { p0 = fmaf(a[k], a[k], p0); p1 = fmaf(a[k + 1], a[k + 1], p1); }
    pa4[w][lane] = p0 + p1;
    __syncthreads();
    float alpha = (pa4[0][lane] + pa4[1][lane]) + (pa4[2][lane] + pa4[3][lane]);
    for (int mask = 1; mask < 64; ++mask) {
      int buf = mask & 1;
      bool lower = lane < (lane ^ mask);
      float beta = __shfl_xor(alpha, mask);
      float o[16];
#pragma unroll
      for (int k = 0; k < 16; ++k) o[k] = __shfl_xor(a[k], mask);
      float g0 = 0.f, g1 = 0.f;
#pragma unroll
      for (int k = 0; k < 16; k += 2) { g0 = fmaf(a[k], o[k], g0); g1 = fmaf(a[k + 1], o[k + 1], g1); }
      pg[buf][w][lane] = g0 + g1;
      __syncthreads();
      float gamma = (pg[buf][0][lane] + pg[buf][1][lane]) + (pg[buf][2][lane] + pg[buf][3][lane]);
      bool need = (gamma * gamma > 1e-12f * alpha * beta);
      if (__any(need)) {
        float ov[16];
#pragma unroll
        for (int k = 0; k < 16; ++k) ov[k] = __shfl_xor(v[k], mask);
        float ap = lower ? alpha : beta;
        float aq = lower ? beta : alpha;
        float c = 1.f, s = 0.f;
        if (need) {
          float tau = (aq - ap) / (2.f * gamma);
          float t = copysignf(1.f, tau) / (fabsf(tau) + sqrtf(fmaf(tau, tau, 1.f)));
          c = rsqrtf(fmaf(t, t, 1.f));
          s = t * c;
        }
        float sm = lower ? -s : s;
#pragma unroll
        for (int k = 0; k < 16; ++k) a[k] = fmaf(sm, o[k], c * a[k]);
#pragma unroll
        for (int k = 0; k < 16; ++k) v[k] = fmaf(sm, ov[k], c * v[k]);
        float twocsg = 2.f * c * s * gamma;
        alpha = fmaf(c * c, alpha, fmaf(s * s, beta, lower ? -twocsg : twocsg));
      }
    }
  }
}

// Phase 1: compute ker2 in-LDS from qland/kland, SW1_ sweeps, save state.
__device__ void svd_phase1(const float* __restrict__ qland, const float* __restrict__ kland,
                           float* __restrict__ asave, float* __restrict__ vsave,
                           int bh, char* smemraw, int tid) {
  __builtin_amdgcn_s_setprio(3);
  float (*qlS)[65] = (float(*)[65])(smemraw);             // 16640 B
  float (*klS)[65] = (float(*)[65])(smemraw + 16640);     // 16640 B -> 33280
  // 64 rows x 16 float4-groups = 1024 slots / 256 threads = 4 iterations.
  for (int i = 0; i < 4; ++i) {
    int s = tid + i * 256;
    int r = s >> 4, d4 = (s & 15) << 2;
    *(float4*)&qlS[r][d4] = *(const float4*)(qland + ((size_t)bh * 64 + r) * 64 + d4);
    *(float4*)&klS[r][d4] = *(const float4*)(kland + ((size_t)bh * 64 + r) * 64 + d4);
  }
  __syncthreads();
  int w = tid >> 6, lane = tid & 63;
  float a[16], v[16];
#pragma unroll
  for (int k = 0; k < 16; ++k) {
    int row = w * 16 + k;
    float acc = 0.f;
#pragma unroll
    for (int d4 = 0; d4 < 64; d4 += 4) {
      float4 qv = *(float4*)&qlS[row][d4];
      float4 kv = *(float4*)&klS[lane][d4];
      acc += qv.x * kv.x + qv.y * kv.y + qv.z * kv.z + qv.w * kv.w;
    }
    float e = expf(acc);
    float rs = e;
#pragma unroll
    for (int m = 1; m < 64; m <<= 1) rs += __shfl_xor(rs, m);
    a[k] = e * (1.f / rs);
  }
#pragma unroll
  for (int k = 0; k < 16; ++k) v[k] = (w * 16 + k == lane) ? 1.f : 0.f;
  __syncthreads();   // qlS/klS dead; pg/pa4 overlay safe
  svd_sweeps(a, v, smemraw, w, lane, SW1_);
#pragma unroll
  for (int k = 0; k < 16; ++k) {
    asave[((size_t)bh * 64 + w * 16 + k) * 64 + lane] = a[k];
    vsave[((size_t)bh * 64 + w * 16 + k) * 64 + lane] = v[k];
  }
  __builtin_amdgcn_s_setprio(0);
}

// Phase 2: load state, SW2_ sweeps, sigma/cutoff + pinv.
__device__ void svd_phase2(const float* __restrict__ asave, const float* __restrict__ vsave,
                           float* __restrict__ pinv, int bh, char* smemraw, int tid) {
  __builtin_amdgcn_s_setprio(3);
  double (*ps2)[64]  = (double(*)[64])(smemraw + 3072);     // 2048 B
  float (*vsL)[65]   = (float(*)[65])(smemraw + 5120);      // 16640 B
  float (*wasL)[65]  = (float(*)[65])(smemraw + 21760);     // 16640 B
  int w = tid >> 6, lane = tid & 63;
  float a[16], v[16];
#pragma unroll
  for (int k = 0; k < 16; ++k) {
    a[k] = asave[((size_t)bh * 64 + w * 16 + k) * 64 + lane];
    v[k] = vsave[((size_t)bh * 64 + w * 16 + k) * 64 + lane];
  }
  svd_sweeps(a, v, smemraw, w, lane, SW2_);

  double psig = 0.0;
#pragma unroll
  for (int k = 0; k < 16; ++k) psig += (double)a[k] * (double)a[k];
  ps2[w][lane] = psig;
  __syncthreads();
  double sig2 = (ps2[0][lane] + ps2[1][lane]) + (ps2[2][lane] + ps2[3][lane]);
  double smax = sig2;
#pragma unroll
  for (int m = 1; m < 64; m <<= 1) smax = fmax(smax, __shfl_xor(smax, m));
  double cutoff2 = smax * (RCOND_ * RCOND_);
  float wgt = (sig2 > cutoff2) ? (float)(1.0 / sig2) : 0.f;

#pragma unroll
  for (int k = 0; k < 16; ++k) {
    vsL[lane][w * 16 + k] = v[k];
    wasL[lane][w * 16 + k] = wgt * a[k];
  }
  __syncthreads();
  int i = tid >> 2;
  int j0 = (tid & 3) * 16;
  float acc[16] = {};
  for (int r = 0; r < 64; ++r) {
    float vv = vsL[r][i];
#pragma unroll
    for (int jj = 0; jj < 16; ++jj) acc[jj] = fmaf(vv, wasL[r][j0 + jj], acc[jj]);
  }
#pragma unroll
  for (int jj = 0; jj < 16; jj += 4) {
    float4 ovv = make_float4(acc[jj], acc[jj + 1], acc[jj + 2], acc[jj + 3]);
    *(float4*)(pinv + ((size_t)bh * 64 + i) * 64 + j0 + jj) = ovv;
  }
  __builtin_amdgcn_s_setprio(0);
}

// ---------------------------------------------------------------------------
// Fused 1: blocks 0..15 = SVD phase 1 (incl. ker2); 16..3087 = projections.
__global__ __launch_bounds__(256) void fused1_kernel(
    const float* __restrict__ x,
    const float* __restrict__ wq, const float* __restrict__ bq,
    const float* __restrict__ wk, const float* __restrict__ bk,
    const float* __restrict__ wv, const float* __restrict__ bv,
    unsigned short* __restrict__ q4, unsigned short* __restrict__ k4,
    unsigned short* __restrict__ vt,
    const float* __restrict__ qland, const float* __restrict__ kland,
    float* __restrict__ asave, float* __restrict__ vsave) {
  __shared__ __align__(16) char smem[33280];
  int tid = threadIdx.x;
  int blk = blockIdx.x;
  if (blk < 16) { svd_phase1(qland, kland, asave, vsave, blk, smem, tid); return; }
  int g = blk - 16;
  int which = g >> 10;
  int sub = g & 1023;
  int row0 = (sub >> 2) * 128;
  int col0 = (sub & 3) * 128;
  unsigned short* Xs = (unsigned short*)smem;
  unsigned short* Ws = Xs + 128 * 32;
  if (which == 0)
    mfma_gemm_body(x, wq, bq, q4, 0.125f, 1, row0, col0, Xs, Ws, tid);
  else if (which == 1)
    mfma_gemm_body(x, wk, bk, k4, 1.0f, 1, row0, col0, Xs, Ws, tid);
  else
    mfma_gemm_body(x, wv, bv, vt, 1.0f, 2, row0, col0, Xs, Ws, tid);
}

// ---------------------------------------------------------------------------
// ker3+kv body (deviation form, MFMA) — unchanged math.
__device__ void ker3kv_body(const unsigned short* __restrict__ qlh,
                            const unsigned short* __restrict__ qll,
                            const unsigned short* __restrict__ k4,
                            const unsigned short* __restrict__ vt,
                            float* __restrict__ pacc,
                            float* __restrict__ pacc0,
                            float* __restrict__ ps,
                            int bh, int ch, char* smemraw, int tid) {
  int w = tid >> 6, lane = tid & 63;
  int part = ch * 4 + w;
  int lrow = lane & 15, lgrp = lane >> 4;
  unsigned short* myP = (unsigned short*)smemraw + w * 64 * 72;

  bf16x8 qah[4][2], qal[4][2];
#pragma unroll
  for (int mf = 0; mf < 4; ++mf)
#pragma unroll
    for (int ks = 0; ks < 2; ++ks) {
      size_t off = ((size_t)bh * 64 + mf * 16 + lrow) * 64 + ks * 32 + lgrp * 8;
      qah[mf][ks] = ld_bf8(qlh + off);
      qal[mf][ks] = ld_bf8(qll + off);
    }
  bf16x8 onesf;
#pragma unroll
  for (int j = 0; j < 8; ++j) onesf[j] = (__bf16)1.0f;

  f32x4 kvacc[4][4] = {};
  f32x4 oneacc[4] = {};
  f32x4 ssum[4] = {};

  for (int sub = 0; sub < 4; ++sub) {
    int n0 = ch * 1024 + w * 256 + sub * 64;
    f32x4 sacc[4][4] = {};
#pragma unroll
    for (int ks = 0; ks < 2; ++ks) {
#pragma unroll
      for (int nf = 0; nf < 4; ++nf) {
        bf16x8 kb = ld_bf8(k4 + ((size_t)bh * N_ + n0 + nf * 16 + lrow) * 64 + ks * 32 + lgrp * 8);
#pragma unroll
        for (int mf = 0; mf < 4; ++mf) {
          sacc[mf][nf] = __builtin_amdgcn_mfma_f32_16x16x32_bf16(qah[mf][ks], kb, sacc[mf][nf], 0, 0, 0);
          sacc[mf][nf] = __builtin_amdgcn_mfma_f32_16x16x32_bf16(qal[mf][ks], kb, sacc[mf][nf], 0, 0, 0);
        }
      }
    }
#pragma unroll
    for (int mf = 0; mf < 4; ++mf) {
#pragma unroll
      for (int nf = 0; nf < 4; ++nf) {
#pragma unroll
        for (int r = 0; r < 4; ++r) {
          float pd = expf(sacc[mf][nf][r]) - 1.0f;
          ssum[mf][r] += pd;
          myP[(mf * 16 + lgrp * 4 + r) * 72 + nf * 16 + lrow] = f2bf(pd);
        }
      }
    }
#pragma unroll
    for (int ks = 0; ks < 2; ++ks) {
      bf16x8 pa[4];
#pragma unroll
      for (int mf = 0; mf < 4; ++mf)
        pa[mf] = ld_bf8(myP + (mf * 16 + lrow) * 72 + ks * 32 + lgrp * 8);
#pragma unroll
      for (int nf = 0; nf < 4; ++nf) {
        bf16x8 vb = ld_bf8(vt + ((size_t)bh * 64 + nf * 16 + lrow) * N_ + n0 + ks * 32 + lgrp * 8);
#pragma unroll
        for (int mf = 0; mf < 4; ++mf)
          kvacc[mf][nf] = __builtin_amdgcn_mfma_f32_16x16x32_bf16(pa[mf], vb, kvacc[mf][nf], 0, 0, 0);
        oneacc[nf] = __builtin_amdgcn_mfma_f32_16x16x32_bf16(onesf, vb, oneacc[nf], 0, 0, 0);
      }
    }
  }
#pragma unroll
  for (int mf = 0; mf < 4; ++mf)
#pragma unroll
    for (int m = 1; m < 16; m <<= 1)
#pragma unroll
      for (int r = 0; r < 4; ++r) ssum[mf][r] += __shfl_xor(ssum[mf][r], m);

  size_t pb = (((size_t)bh * NPART_ + part) * 64) * 64;
#pragma unroll
  for (int mf = 0; mf < 4; ++mf)
#pragma unroll
    for (int nf = 0; nf < 4; ++nf)
#pragma unroll
      for (int r = 0; r < 4; ++r)
        pacc[pb + (size_t)(mf * 16 + lgrp * 4 + r) * 64 + nf * 16 + lrow] = kvacc[mf][nf][r];
  if (lrow == 0) {
#pragma unroll
    for (int mf = 0; mf < 4; ++mf)
#pragma unroll
      for (int r = 0; r < 4; ++r)
        ps[((size_t)bh * NPART_ + part) * 64 + mf * 16 + lgrp * 4 + r] = ssum[mf][r];
  }
  if (lgrp == 0) {
#pragma unroll
    for (int nf = 0; nf < 4; ++nf)
      pacc0[((size_t)bh * NPART_ + part) * 64 + nf * 16 + lrow] = oneacc[nf][0];
  }
}

// Fused 2: blocks 0..15 = SVD phase 2 (+pinv); 16..271 = ker3kv.
__global__ __launch_bounds__(256, 1) void fused2_kernel(
    const unsigned short* __restrict__ qlh,
    const unsigned short* __restrict__ qll,
    const unsigned short* __restrict__ k4,
    const unsigned short* __restrict__ vt,
    float* __restrict__ pacc, float* __restrict__ pacc0, float* __restrict__ ps,
    const float* __restrict__ asave, const float* __restrict__ vsave,
    float* __restrict__ pinv) {
  __shared__ __align__(16) char smem[38400];
  int tid = threadIdx.x;
  int blk = blockIdx.x;
  if (blk < 16) { svd_phase2(asave, vsave, pinv, blk, smem, tid); return; }
  int g = blk - 16;
  int bh = g >> 4, ch = g & 15;
  ker3kv_body(qlh, qll, k4, vt, pacc, pacc0, ps, bh, ch, smem, tid);
}

// ---------------------------------------------------------------------------
__global__ __launch_bounds__(256) void kv_combine_kernel(const float* __restrict__ pacc,
                                                         const float* __restrict__ pacc0,
                                                         const float* __restrict__ ps,
                                                         float* __restrict__ kv) {
  int bh = blockIdx.y;
  int lm = blockIdx.x * 16 + (threadIdx.x >> 4);
  int d4 = (threadIdx.x & 15) * 4;
  float s = 16384.f;
  for (int part = 0; part < NPART_; ++part) s += ps[((size_t)bh * NPART_ + part) * 64 + lm];
  float4 a = make_float4(0.f, 0.f, 0.f, 0.f);
  for (int part = 0; part < NPART_; ++part) {
    float4 c0 = *(const float4*)&pacc0[((size_t)bh * NPART_ + part) * 64 + d4];
    float4 v = *(const float4*)&pacc[(((size_t)bh * NPART_ + part) * 64 + lm) * 64 + d4];
    a.x += c0.x + v.x; a.y += c0.y + v.y; a.z += c0.z + v.z; a.w += c0.w + v.w;
  }
  float inv = 1.f / s;
  float4 o = make_float4(a.x * inv, a.y * inv, a.z * inv, a.w * inv);
  *(float4*)(kv + ((size_t)bh * 64 + lm) * 64 + d4) = o;
}

// ---------------------------------------------------------------------------
__global__ __launch_bounds__(256) void mmat_kernel(const float* __restrict__ pinv,
                                                   const float* __restrict__ kv,
                                                   unsigned short* __restrict__ mtbh,
                                                   unsigned short* __restrict__ mtbl,
                                                   float* __restrict__ msum) {
  int bh = blockIdx.x;
  int tid = threadIdx.x;
  __shared__ float kvs[64][68];
  __shared__ double pcsd[64];
  for (int i = 0; i < 4; ++i) {
    int s = tid + i * 256;
    int r = s >> 4, d4 = (s & 15) << 2;
    *(float4*)&kvs[r][d4] = *(const float4*)(kv + ((size_t)bh * 64 + r) * 64 + d4);
  }
  if (tid < 64) {
    double s = 0.0;
    for (int l = 0; l < 64; ++l) s += (double)pinv[((size_t)bh * 64 + l) * 64 + tid];
    pcsd[tid] = s;
  }
  __syncthreads();
  int l = tid >> 2, t = tid & 3;
  double o[16] = {};
  for (int j = 0; j < 64; ++j) {
    double pv = (double)pinv[((size_t)bh * 64 + l) * 64 + j];
#pragma unroll
    for (int i = 0; i < 16; ++i) o[i] += pv * (double)kvs[j][t * 16 + i];
  }
#pragma unroll
  for (int i = 0; i < 16; ++i) {
    float f = (float)o[i];
    unsigned short hi = f2bf(f);
    float lo = f - bf2f(hi);
    int d = t * 16 + i;
    mtbh[((size_t)bh * 64 + d) * 64 + l] = hi;
    mtbl[((size_t)bh * 64 + d) * 64 + l] = f2bf(lo);
  }
  if (tid < 64) {
    double m = 0.0;
    for (int j = 0; j < 64; ++j) m += pcsd[j] * (double)kvs[j][tid];
    msum[(size_t)bh * 64 + tid] = (float)(m * (1.0 / 64.0));
  }
}

// ---------------------------------------------------------------------------
__global__ __launch_bounds__(256, 1) void ker1out_mfma_kernel(
    const unsigned short* __restrict__ q4,
    const unsigned short* __restrict__ klb,
    const unsigned short* __restrict__ mtbh,
    const unsigned short* __restrict__ mtbl,
    const float* __restrict__ msum,
    unsigned short* __restrict__ outh) {
  int bh = blockIdx.y, tile = blockIdx.x;
  int b = bh >> 3, h = bh & 7;
  int tid = threadIdx.x, w = tid >> 6, lane = tid & 63;
  int lrow = lane & 15, lgrp = lane >> 4;
  int tok0 = tile * 256 + w * 64;
  __shared__ __align__(16) unsigned short Pl[4][64 * 72];
  unsigned short* myP = &Pl[w][0];

  f32x4 sacc[4][4] = {};
#pragma unroll
  for (int ks = 0; ks < 2; ++ks) {
    bf16x8 kb[4];
#pragma unroll
    for (int nf = 0; nf < 4; ++nf)
      kb[nf] = ld_bf8(klb + ((size_t)bh * 64 + nf * 16 + lrow) * 64 + ks * 32 + lgrp * 8);
#pragma unroll
    for (int mf = 0; mf < 4; ++mf) {
      bf16x8 qa = ld_bf8(q4 + ((size_t)bh * N_ + tok0 + mf * 16 + lrow) * 64 + ks * 32 + lgrp * 8);
#pragma unroll
      for (int nf = 0; nf < 4; ++nf)
        sacc[mf][nf] = __builtin_amdgcn_mfma_f32_16x16x32_bf16(qa, kb[nf], sacc[mf][nf], 0, 0, 0);
    }
  }
  f32x4 ssum[4] = {};
#pragma unroll
  for (int mf = 0; mf < 4; ++mf)
#pragma unroll
    for (int nf = 0; nf < 4; ++nf)
#pragma unroll
      for (int r = 0; r < 4; ++r) {
        sacc[mf][nf][r] = expf(sacc[mf][nf][r]);
        ssum[mf][r] += sacc[mf][nf][r];
      }
#pragma unroll
  for (int mf = 0; mf < 4; ++mf)
#pragma unroll
    for (int m = 1; m < 16; m <<= 1)
#pragma unroll
      for (int r = 0; r < 4; ++r) ssum[mf][r] += __shfl_xor(ssum[mf][r], m);
#pragma unroll
  for (int mf = 0; mf < 4; ++mf) {
    f32x4 inv;
#pragma unroll
    for (int r = 0; r < 4; ++r) inv[r] = 1.f / ssum[mf][r];
#pragma unroll
    for (int nf = 0; nf < 4; ++nf)
#pragma unroll
      for (int r = 0; r < 4; ++r) {
        float pdev = fmaf(sacc[mf][nf][r], inv[r], -0.015625f);
        myP[(mf * 16 + lgrp * 4 + r) * 72 + nf * 16 + lrow] = f2bf(pdev);
      }
  }

  f32x4 oacc[4][4] = {};
#pragma unroll
  for (int ks = 0; ks < 2; ++ks) {
    bf16x8 pa[4];
#pragma unroll
    for (int mf = 0; mf < 4; ++mf)
      pa[mf] = ld_bf8(myP + (mf * 16 + lrow) * 72 + ks * 32 + lgrp * 8);
#pragma unroll
    for (int nf = 0; nf < 4; ++nf) {
      bf16x8 mh = ld_bf8(mtbh + ((size_t)bh * 64 + nf * 16 + lrow) * 64 + ks * 32 + lgrp * 8);
      bf16x8 ml = ld_bf8(mtbl + ((size_t)bh * 64 + nf * 16 + lrow) * 64 + ks * 32 + lgrp * 8);
#pragma unroll
      for (int mf = 0; mf < 4; ++mf) {
        oacc[mf][nf] = __builtin_amdgcn_mfma_f32_16x16x32_bf16(pa[mf], mh, oacc[mf][nf], 0, 0, 0);
        oacc[mf][nf] = __builtin_amdgcn_mfma_f32_16x16x32_bf16(pa[mf], ml, oacc[mf][nf], 0, 0, 0);
      }
    }
  }
#pragma unroll
  for (int nf = 0; nf < 4; ++nf) {
    float ms = msum[(size_t)bh * 64 + nf * 16 + lrow];
#pragma unroll
    for (int mf = 0; mf < 4; ++mf)
#pragma unroll
      for (int r = 0; r < 4; ++r) {
        int tok = tok0 + mf * 16 + lgrp * 4 + r;
        int d = nf * 16 + lrow;
        outh[((size_t)b * N_ + tok) * C_ + h * HD_ + d] = f2bf(oacc[mf][nf][r] + ms);
      }
  }
}

// ---------------------------------------------------------------------------
// Final projection (serial tail): outh(bf16) @ wob^T(bf16) + bo -> f32 out.
__global__ __launch_bounds__(256) void oproj_kernel(const unsigned short* __restrict__ outh,
                                                    const unsigned short* __restrict__ wob,
                                                    const float* __restrict__ bo,
                                                    float* __restrict__ out) {
  __shared__ __align__(16) unsigned short Xs[128 * 32];
  __shared__ __align__(16) unsigned short Ws[128 * 32];
  int tid = threadIdx.x;
  int w = tid >> 6, lane = tid & 63;
  int wr = w >> 1, wc = w & 1;
  int row0 = blockIdx.x * 128, col0 = blockIdx.y * 128;
  f32x4 acc[4][4] = {};

  for (int k0 = 0; k0 < C_; k0 += 32) {
    __syncthreads();
#pragma unroll
    for (int i = 0; i < 2; ++i) {
      const unsigned short* gx = outh + (size_t)(row0 + w * 32 + i * 16 + (lane >> 2)) * C_ + k0 + (lane & 3) * 8;
      gload_lds16(gx, &Xs[(w * 32 + i * 16) * 32]);
      const unsigned short* gw = wob + (size_t)(col0 + w * 32 + i * 16 + (lane >> 2)) * C_ + k0 + (lane & 3) * 8;
      gload_lds16(gw, &Ws[(w * 32 + i * 16) * 32]);
    }
    __syncthreads();
    bf16x8 af[4], bfr[4];
#pragma unroll
    for (int m = 0; m < 4; ++m)
      af[m] = *(bf16x8*)&Xs[(wr * 64 + m * 16 + (lane & 15)) * 32 + (lane >> 4) * 8];
#pragma unroll
    for (int n = 0; n < 4; ++n)
      bfr[n] = *(bf16x8*)&Ws[(wc * 64 + n * 16 + (lane & 15)) * 32 + (lane >> 4) * 8];
#pragma unroll
    for (int m = 0; m < 4; ++m)
#pragma unroll
      for (int n = 0; n < 4; ++n)
        acc[m][n] = __builtin_amdgcn_mfma_f32_16x16x32_bf16(af[m], bfr[n], acc[m][n], 0, 0, 0);
  }

#pragma unroll
  for (int m = 0; m < 4; ++m) {
    int rbase = row0 + wr * 64 + m * 16 + (lane >> 4) * 4;
#pragma unroll
    for (int n = 0; n < 4; ++n) {
      int c = col0 + wc * 64 + n * 16 + (lane & 15);
      float bc = bo[c];
#pragma unroll
      for (int rg = 0; rg < 4; ++rg)
        out[(size_t)(rbase + rg) * C_ + c] = acc[m][n][rg] + bc;
    }
  }
}

// ---------------------------------------------------------------------------
extern "C" void kernel_launch(void* const* d_in, const int* in_sizes, int n_in,
                              void* d_out, int out_size, void* d_ws, size_t ws_size,
                              hipStream_t stream) {
  const float* x  = (const float*)d_in[0];
  const float* wq = (const float*)d_in[1];
  const float* bq = (const float*)d_in[2];
  const float* wk = (const float*)d_in[3];
  const float* bk = (const float*)d_in[4];
  const float* wv = (const float*)d_in[5];
  const float* bv = (const float*)d_in[6];
  const float* wo = (const float*)d_in[7];
  const float* bo = (const float*)d_in[8];
  float* out = (float*)d_out;

  char* base = (char*)d_ws;
  const size_t QKV = (size_t)BH_ * N_ * HD_;
  unsigned short* q4 = (unsigned short*)base;                 // 32MB
  unsigned short* k4 = (unsigned short*)(base + QKV * 2);     // 32MB
  unsigned short* vt = (unsigned short*)(base + QKV * 4);     // 32MB
  unsigned short* outh = (unsigned short*)(base + QKV * 2);   // alias k4 (dead after ker3kv)
  char* sp = base + QKV * 6;
  float* pacc  = (float*)sp; sp += (size_t)BH_ * NPART_ * 64 * 64 * 4;  // 16.78MB
  float* pacc0 = (float*)sp; sp += (size_t)BH_ * NPART_ * 64 * 4;
  float* ps    = (float*)sp; sp += (size_t)BH_ * NPART_ * 64 * 4;
  float* xbar  = (float*)sp; sp += (size_t)B_ * LM_ * C_ * 4;
  float* qland = (float*)sp; sp += (size_t)BH_ * LM_ * HD_ * 4;
  float* kland = (float*)sp; sp += (size_t)BH_ * LM_ * HD_ * 4;
  unsigned short* qlbh = (unsigned short*)sp; sp += (size_t)BH_ * LM_ * HD_ * 2;
  unsigned short* qlbl = (unsigned short*)sp; sp += (size_t)BH_ * LM_ * HD_ * 2;
  unsigned short* klb  = (unsigned short*)sp; sp += (size_t)BH_ * LM_ * HD_ * 2;
  float* pinv  = (float*)sp; sp += (size_t)BH_ * LM_ * LM_ * 4;
  float* kvb   = (float*)sp; sp += (size_t)BH_ * LM_ * HD_ * 4;
  unsigned short* mtbh = (unsigned short*)sp; sp += (size_t)BH_ * LM_ * HD_ * 2;
  unsigned short* mtbl = (unsigned short*)sp; sp += (size_t)BH_ * LM_ * HD_ * 2;
  float* msum  = (float*)sp; sp += (size_t)BH_ * HD_ * 4;
  float* asave = (float*)sp; sp += (size_t)BH_ * LM_ * LM_ * 4;   // 256KB
  float* vsave = (float*)sp; sp += (size_t)BH_ * LM_ * LM_ * 4;   // 256KB
  unsigned short* wob = (unsigned short*)sp; sp += (size_t)C_ * C_ * 2;  // 512KB

  const int W8 = (C_ * C_) / 8;

  // wo -> bf16 (needed only by the serial-tail oproj)
  cvt_bf16_kernel<<<W8 / 256, 256, 0, stream>>>(wo, wob, W8);

  // landmark path (f32-exact) + bf16 conversions in epilogue
  seg_mean_kernel<<<B_ * LM_, 256, 0, stream>>>(x, xbar);
  dim3 gl(4, 8);
  land_gemm_kernel<<<gl, 256, 0, stream>>>(xbar, wq, bq, wk, bk,
                                           qland, kland, qlbh, qlbl, klb);

  // fused 1: SVD phase 1 (blocks 0..15; computes ker2 in-LDS) + projections
  fused1_kernel<<<16 + 3 * 1024, 256, 0, stream>>>(
      x, wq, bq, wk, bk, wv, bv, q4, k4, vt, qland, kland, asave, vsave);

  // fused 2: SVD phase 2 + pinv (blocks 0..15) + ker3kv (256 blocks)
  fused2_kernel<<<16 + NCH_ * BH_, 256, 0, stream>>>(
      qlbh, qlbl, k4, vt, pacc, pacc0, ps, asave, vsave, pinv);

  // combine + M
  dim3 g7(4, BH_);
  kv_combine_kernel<<<g7, 256, 0, stream>>>(pacc, pacc0, ps, kvb);
  mmat_kernel<<<BH_, 256, 0, stream>>>(pinv, kvb, mtbh, mtbl, msum);

  // out_heads -> bf16 outh (aliases dead k4)
  dim3 g9(N_ / 256, BH_);
  ker1out_mfma_kernel<<<g9, 256, 0, stream>>>(q4, klb, mtbh, mtbl, msum, outh);

  // final projection (DMA-staged bf16 GEMM)
  dim3 g10(B_ * N_ / 128, C_ / 128);
  oproj_kernel<<<g10, 256, 0, stream>>>(outh, wob, bo, out);
}

// Round 16
// 414.972 us; speedup vs baseline: 8.4053x; 1.0412x over previous
//
#include <hip/hip_runtime.h>
#include <stdint.h>

// NystromAttention MI355X — Round 16: SVD sweep transport via wide-LDS column
// mirror (Ac/Vc[64][68], ds_read/write_b128) instead of 32 ds_swizzle per
// round: 19 vs 35 DS ops/thread/round (DS-pipe-bound). Bit-identical values
// and op order -> absmax must stay exactly 1.220703e-4. Rest = R15 (432us).

constexpr int B_   = 2;
constexpr int N_   = 16384;
constexpr int C_   = 512;
constexpr int H_   = 8;
constexpr int HD_  = 64;
constexpr int LM_  = 64;
constexpr int SEG_ = 256;
constexpr int BH_  = 16;
constexpr int NCH_ = 16;
constexpr int NPART_ = 64;
constexpr int SW1_ = 3;   // sweeps in phase 1
constexpr int SW2_ = 2;   // sweeps in phase 2  (total 5 = R15-passing config)

#define RCOND_ (640.0 * 1.1920928955078125e-07)

typedef unsigned short ushort4_t __attribute__((ext_vector_type(4)));
typedef unsigned short ushort8_t __attribute__((ext_vector_type(8)));
typedef __bf16 bf16x8 __attribute__((ext_vector_type(8)));
typedef float f32x4 __attribute__((ext_vector_type(4)));

__device__ inline float bf2f(unsigned short u) {
  union { unsigned int i; float f; } x; x.i = ((unsigned int)u) << 16; return x.f;
}
__device__ inline unsigned short f2bf(float f) {
  union { float f; unsigned int i; } x; x.f = f;
  unsigned int lsb = (x.i >> 16) & 1;
  return (unsigned short)((x.i + 0x7fffu + lsb) >> 16);
}
__device__ inline bf16x8 ld_bf8(const unsigned short* p) { return *(const bf16x8*)p; }

__device__ __forceinline__ void gload_lds16(const unsigned short* gsrc, unsigned short* ldst) {
  __builtin_amdgcn_global_load_lds((const __attribute__((address_space(1))) void*)gsrc,
                                   (__attribute__((address_space(3))) void*)ldst, 16, 0, 0);
}

// ---------------------------------------------------------------------------
__global__ __launch_bounds__(256) void cvt_bf16_kernel(const float* __restrict__ src,
                                                       unsigned short* __restrict__ dst,
                                                       int n8) {
  int i = (blockIdx.x * 256 + threadIdx.x);
  if (i >= n8) return;
  const float* s = src + (size_t)i * 8;
  float4 x0 = *(const float4*)(s);
  float4 x1 = *(const float4*)(s + 4);
  ushort8_t u;
  u[0] = f2bf(x0.x); u[1] = f2bf(x0.y); u[2] = f2bf(x0.z); u[3] = f2bf(x0.w);
  u[4] = f2bf(x1.x); u[5] = f2bf(x1.y); u[6] = f2bf(x1.z); u[7] = f2bf(x1.w);
  *(ushort8_t*)(dst + (size_t)i * 8) = u;
}

// ---------------------------------------------------------------------------
__global__ __launch_bounds__(256) void seg_mean_kernel(const float* __restrict__ x,
                                                       float* __restrict__ xbar) {
  int bl = blockIdx.x;
  int b = bl / LM_, l = bl % LM_;
  int t = threadIdx.x;
  int c4 = t & 127;
  int rh = t >> 7;
  const float* xp = x + ((size_t)b * N_ + (size_t)l * SEG_) * C_;
  float4 s = make_float4(0.f, 0.f, 0.f, 0.f);
  for (int r = rh * 128; r < rh * 128 + 128; ++r) {
    float4 v = *(const float4*)(xp + (size_t)r * C_ + c4 * 4);
    s.x += v.x; s.y += v.y; s.z += v.z; s.w += v.w;
  }
  __shared__ float red[2][512];
  *(float4*)&red[rh][c4 * 4] = s;
  __syncthreads();
  if (rh == 0) {
    float4 a = *(float4*)&red[0][c4 * 4];
    float4 c = *(float4*)&red[1][c4 * 4];
    const float invs = 1.0f / SEG_;
    float4 o;
    o.x = (a.x + c.x) * invs; o.y = (a.y + c.y) * invs;
    o.z = (a.z + c.z) * invs; o.w = (a.w + c.w) * invs;
    *(float4*)(xbar + (size_t)bl * C_ + c4 * 4) = o;
  }
}

// ---------------------------------------------------------------------------
// Merged landmark projections (f32 VALU GEMM, 128 rows) with bf16 epilogue.
__global__ __launch_bounds__(256) void land_gemm_kernel(const float* __restrict__ xbar,
                                                        const float* __restrict__ wq,
                                                        const float* __restrict__ bq,
                                                        const float* __restrict__ wk,
                                                        const float* __restrict__ bk,
                                                        float* __restrict__ qland,
                                                        float* __restrict__ kland,
                                                        unsigned short* __restrict__ qlbh,
                                                        unsigned short* __restrict__ qlbl,
                                                        unsigned short* __restrict__ klb) {
  __shared__ float As[32][68];
  __shared__ float Ws[32][68];
  int which = blockIdx.x >> 1;
  int row0 = (blockIdx.x & 1) * 64;
  int col0 = blockIdx.y * 64;
  const float* A = xbar;
  const float* W = which ? wk : wq;
  const float* bias = which ? bk : bq;
  float scale = which ? 1.0f : 0.125f;
  float* out = which ? kland : qland;
  int tid = threadIdx.x;
  int tm = tid >> 4, tn = tid & 15;
  float acc[4][4] = {};
  for (int k0 = 0; k0 < C_; k0 += 32) {
#pragma unroll
    for (int i = 0; i < 2; ++i) {
      int s = tid + i * 256;
      int r = s >> 3;
      int kg = (s & 7) << 2;
      float4 av = *(const float4*)(A + (size_t)(row0 + r) * C_ + k0 + kg);
      As[kg + 0][r] = av.x; As[kg + 1][r] = av.y;
      As[kg + 2][r] = av.z; As[kg + 3][r] = av.w;
      float4 wv = *(const float4*)(W + (size_t)(col0 + r) * C_ + k0 + kg);
      Ws[kg + 0][r] = wv.x; Ws[kg + 1][r] = wv.y;
      Ws[kg + 2][r] = wv.z; Ws[kg + 3][r] = wv.w;
    }
    __syncthreads();
#pragma unroll
    for (int kk = 0; kk < 32; ++kk) {
      float4 a = *(const float4*)&As[kk][tm * 4];
      float4 b = *(const float4*)&Ws[kk][tn * 4];
      float av[4] = {a.x, a.y, a.z, a.w};
      float bv[4] = {b.x, b.y, b.z, b.w};
#pragma unroll
      for (int i = 0; i < 4; ++i)
#pragma unroll
        for (int j = 0; j < 4; ++j) acc[i][j] += av[i] * bv[j];
    }
    __syncthreads();
  }
#pragma unroll
  for (int i = 0; i < 4; ++i) {
    int row = row0 + tm * 4 + i;
    int d0 = tn * 4;
    float o4[4];
#pragma unroll
    for (int j = 0; j < 4; ++j) o4[j] = (acc[i][j] + bias[col0 + d0 + j]) * scale;
    int b = row / LM_, n = row % LM_;
    int h = col0 >> 6;
    size_t idx = (((size_t)(b * H_ + h) * LM_) + n) * HD_ + d0;
    float4 o; o.x = o4[0]; o.y = o4[1]; o.z = o4[2]; o.w = o4[3];
    *(float4*)(out + idx) = o;
    if (which == 0) {
      ushort4_t uh, ul;
#pragma unroll
      for (int j = 0; j < 4; ++j) {
        unsigned short hbits = f2bf(o4[j]);
        uh[j] = hbits;
        ul[j] = f2bf(o4[j] - bf2f(hbits));
      }
      *(ushort4_t*)(qlbh + idx) = uh;
      *(ushort4_t*)(qlbl + idx) = ul;
    } else {
      ushort4_t uk;
#pragma unroll
      for (int j = 0; j < 4; ++j) uk[j] = f2bf(o4[j]);
      *(ushort4_t*)(klb + idx) = uk;
    }
  }
}

// ---------------------------------------------------------------------------
// Reg-staged MFMA GEMM body (A f32, W f32 converted in staging).
// omode 1: bf16 head-split; omode 2: bf16 vt.
__device__ __forceinline__ void mfma_gemm_body(const float* __restrict__ A,
                                               const float* __restrict__ W,
                                               const float* __restrict__ bias,
                                               unsigned short* __restrict__ out,
                                               float scale, int omode,
                                               int row0, int col0,
                                               unsigned short* Xs, unsigned short* Ws,
                                               int tid) {
  int wid = tid >> 6, lane = tid & 63;
  int wr = wid >> 1, wc = wid & 1;
  f32x4 acc[4][4] = {};
  int srow = tid >> 1;
  int sk = (tid & 1) * 16;
  const float* wpbase = W + (size_t)(col0 + srow) * C_ + sk;
  const float* apbase = A + (size_t)(row0 + srow) * C_ + sk;
  unsigned short* xdst = &Xs[srow * 32 + sk];
  unsigned short* wdst = &Ws[srow * 32 + sk];

  for (int k0 = 0; k0 < C_; k0 += 32) {
    __syncthreads();
    {
      float4 x0 = *(const float4*)(apbase + k0);
      float4 x1 = *(const float4*)(apbase + k0 + 4);
      float4 x2 = *(const float4*)(apbase + k0 + 8);
      float4 x3 = *(const float4*)(apbase + k0 + 12);
      ushort8_t u0, u1;
      u0[0] = f2bf(x0.x); u0[1] = f2bf(x0.y); u0[2] = f2bf(x0.z); u0[3] = f2bf(x0.w);
      u0[4] = f2bf(x1.x); u0[5] = f2bf(x1.y); u0[6] = f2bf(x1.z); u0[7] = f2bf(x1.w);
      u1[0] = f2bf(x2.x); u1[1] = f2bf(x2.y); u1[2] = f2bf(x2.z); u1[3] = f2bf(x2.w);
      u1[4] = f2bf(x3.x); u1[5] = f2bf(x3.y); u1[6] = f2bf(x3.z); u1[7] = f2bf(x3.w);
      *(ushort8_t*)(xdst) = u0;
      *(ushort8_t*)(xdst + 8) = u1;
    }
    {
      float4 w0 = *(const float4*)(wpbase + k0);
      float4 w1 = *(const float4*)(wpbase + k0 + 4);
      float4 w2 = *(const float4*)(wpbase + k0 + 8);
      float4 w3 = *(const float4*)(wpbase + k0 + 12);
      ushort8_t u0, u1;
      u0[0] = f2bf(w0.x); u0[1] = f2bf(w0.y); u0[2] = f2bf(w0.z); u0[3] = f2bf(w0.w);
      u0[4] = f2bf(w1.x); u0[5] = f2bf(w1.y); u0[6] = f2bf(w1.z); u0[7] = f2bf(w1.w);
      u1[0] = f2bf(w2.x); u1[1] = f2bf(w2.y); u1[2] = f2bf(w2.z); u1[3] = f2bf(w2.w);
      u1[4] = f2bf(w3.x); u1[5] = f2bf(w3.y); u1[6] = f2bf(w3.z); u1[7] = f2bf(w3.w);
      *(ushort8_t*)(wdst) = u0;
      *(ushort8_t*)(wdst + 8) = u1;
    }
    __syncthreads();
    bf16x8 af[4], bfr[4];
#pragma unroll
    for (int m = 0; m < 4; ++m)
      af[m] = *(bf16x8*)&Xs[(wr * 64 + m * 16 + (lane & 15)) * 32 + (lane >> 4) * 8];
#pragma unroll
    for (int n = 0; n < 4; ++n)
      bfr[n] = *(bf16x8*)&Ws[(wc * 64 + n * 16 + (lane & 15)) * 32 + (lane >> 4) * 8];
#pragma unroll
    for (int m = 0; m < 4; ++m)
#pragma unroll
      for (int n = 0; n < 4; ++n)
        acc[m][n] = __builtin_amdgcn_mfma_f32_16x16x32_bf16(af[m], bfr[n], acc[m][n], 0, 0, 0);
  }

#pragma unroll
  for (int m = 0; m < 4; ++m) {
    int rbase = row0 + wr * 64 + m * 16 + (lane >> 4) * 4;
#pragma unroll
    for (int n = 0; n < 4; ++n) {
      int c = col0 + wc * 64 + n * 16 + (lane & 15);
      float bc = bias[c];
      if (omode == 2) {
        int b = rbase >> 14, nn = rbase & 16383;
        int h = c >> 6, d = c & 63;
        ushort4_t u;
#pragma unroll
        for (int rg = 0; rg < 4; ++rg) u[rg] = f2bf((acc[m][n][rg] + bc) * scale);
        *(ushort4_t*)(out + ((size_t)(b * H_ + h) * HD_ + d) * N_ + nn) = u;
      } else {
#pragma unroll
        for (int rg = 0; rg < 4; ++rg) {
          float val = (acc[m][n][rg] + bc) * scale;
          int r = rbase + rg;
          int b = r >> 14, nn = r & 16383, h = c >> 6, d = c & 63;
          out[(((size_t)(b * H_ + h) * N_) + nn) * HD_ + d] = f2bf(val);
        }
      }
    }
  }
}

// ---------------------------------------------------------------------------
// SVD sweep loop (4-wave row-split). Columns mirrored in LDS col-major with
// 68-float stride (16B-aligned b128 ops). Regs hold own column; partner column
// fetched via 4x ds_read_b128. Wave w touches only rows 16w..16w+15 of Ac/Vc
// -> no cross-wave hazard; single barrier per round (pg reduce), as before.
// LDS layout: Ac[64][68] @0 (17408), Vc @17408 (17408), pg @34816 (2048),
// pa4 @36864 (1024) -> 37888 total for sweeps.
__device__ __forceinline__ void svd_sweeps(float a[16], float v[16], char* smemraw,
                                           int w, int lane, int nsweeps) {
  float (*Ac)[68]    = (float(*)[68])(smemraw);
  float (*Vc)[68]    = (float(*)[68])(smemraw + 17408);
  float (*pg)[4][64] = (float(*)[4][64])(smemraw + 34816);
  float (*pa4)[64]   = (float(*)[64])(smemraw + 36864);
  const int r0 = w * 16;
  // mirror own column slices into LDS
  *(float4*)&Ac[lane][r0 + 0]  = make_float4(a[0], a[1], a[2], a[3]);
  *(float4*)&Ac[lane][r0 + 4]  = make_float4(a[4], a[5], a[6], a[7]);
  *(float4*)&Ac[lane][r0 + 8]  = make_float4(a[8], a[9], a[10], a[11]);
  *(float4*)&Ac[lane][r0 + 12] = make_float4(a[12], a[13], a[14], a[15]);
  *(float4*)&Vc[lane][r0 + 0]  = make_float4(v[0], v[1], v[2], v[3]);
  *(float4*)&Vc[lane][r0 + 4]  = make_float4(v[4], v[5], v[6], v[7]);
  *(float4*)&Vc[lane][r0 + 8]  = make_float4(v[8], v[9], v[10], v[11]);
  *(float4*)&Vc[lane][r0 + 12] = make_float4(v[12], v[13], v[14], v[15]);

  for (int sweep = 0; sweep < nsweeps; ++sweep) {
    float p0 = 0.f, p1 = 0.f;
#pragma unroll
    for (int k = 0; k < 16; k += 2) { p0 = fmaf(a[k], a[k], p0); p1 = fmaf(a[k + 1], a[k + 1], p1); }
    pa4[w][lane] = p0 + p1;
    __syncthreads();
    float alpha = (pa4[0][lane] + pa4[1][lane]) + (pa4[2][lane] + pa4[3][lane]);
    for (int mask = 1; mask < 64; ++mask) {
      int buf = mask & 1;
      int partner = lane ^ mask;
      bool lower = lane < partner;
      float beta = __shfl_xor(alpha, mask);
      float4 o0 = *(float4*)&Ac[partner][r0 + 0];
      float4 o1 = *(float4*)&Ac[partner][r0 + 4];
      float4 o2 = *(float4*)&Ac[partner][r0 + 8];
      float4 o3 = *(float4*)&Ac[partner][r0 + 12];
      float o[16] = {o0.x, o0.y, o0.z, o0.w, o1.x, o1.y, o1.z, o1.w,
                     o2.x, o2.y, o2.z, o2.w, o3.x, o3.y, o3.z, o3.w};
      float g0 = 0.f, g1 = 0.f;
#pragma unroll
      for (int k = 0; k < 16; k += 2) { g0 = fmaf(a[k], o[k], g0); g1 = fmaf(a[k + 1], o[k + 1], g1); }
      pg[buf][w][lane] = g0 + g1;
      __syncthreads();
      float gamma = (pg[buf][0][lane] + pg[buf][1][lane]) + (pg[buf][2][lane] + pg[buf][3][lane]);
      bool need = (gamma * gamma > 1e-12f * alpha * beta);
      if (__any(need)) {
        float4 q0 = *(float4*)&Vc[partner][r0 + 0];
        float4 q1 = *(float4*)&Vc[partner][r0 + 4];
        float4 q2 = *(float4*)&Vc[partner][r0 + 8];
        float4 q3 = *(float4*)&Vc[partner][r0 + 12];
        float ov[16] = {q0.x, q0.y, q0.z, q0.w, q1.x, q1.y, q1.z, q1.w,
                        q2.x, q2.y, q2.z, q2.w, q3.x, q3.y, q3.z, q3.w};
        float ap = lower ? alpha : beta;
        float aq = lower ? beta : alpha;
        float c = 1.f, s = 0.f;
        if (need) {
          float tau = (aq - ap) / (2.f * gamma);
          float t = copysignf(1.f, tau) / (fabsf(tau) + sqrtf(fmaf(tau, tau, 1.f)));
          c = rsqrtf(fmaf(t, t, 1.f));
          s = t * c;
        }
        float sm = lower ? -s : s;
#pragma unroll
        for (int k = 0; k < 16; ++k) a[k] = fmaf(sm, o[k], c * a[k]);
#pragma unroll
        for (int k = 0; k < 16; ++k) v[k] = fmaf(sm, ov[k], c * v[k]);
        float twocsg = 2.f * c * s * gamma;
        alpha = fmaf(c * c, alpha, fmaf(s * s, beta, lower ? -twocsg : twocsg));
        // write back own (updated) column slices
        *(float4*)&Ac[lane][r0 + 0]  = make_float4(a[0], a[1], a[2], a[3]);
        *(float4*)&Ac[lane][r0 + 4]  = make_float4(a[4], a[5], a[6], a[7]);
        *(float4*)&Ac[lane][r0 + 8]  = make_float4(a[8], a[9], a[10], a[11]);
        *(float4*)&Ac[lane][r0 + 12] = make_float4(a[12], a[13], a[14], a[15]);
        *(float4*)&Vc[lane][r0 + 0]  = make_float4(v[0], v[1], v[2], v[3]);
        *(float4*)&Vc[lane][r0 + 4]  = make_float4(v[4], v[5], v[6], v[7]);
        *(float4*)&Vc[lane][r0 + 8]  = make_float4(v[8], v[9], v[10], v[11]);
        *(float4*)&Vc[lane][r0 + 12] = make_float4(v[12], v[13], v[14], v[15]);
      }
    }
  }
}

// Phase 1: compute ker2 in-LDS from qland/kland, SW1_ sweeps, save state.
// smem: qlS[64][65]@0 (16640) + klS@16640 (16640) overlay Ac/Vc region.
__device__ void svd_phase1(const float* __restrict__ qland, const float* __restrict__ kland,
                           float* __restrict__ asave, float* __restrict__ vsave,
                           int bh, char* smemraw, int tid) {
  __builtin_amdgcn_s_setprio(3);
  float (*qlS)[65] = (float(*)[65])(smemraw);
  float (*klS)[65] = (float(*)[65])(smemraw + 16640);
  for (int i = 0; i < 4; ++i) {
    int s = tid + i * 256;
    int r = s >> 4, d4 = (s & 15) << 2;
    *(float4*)&qlS[r][d4] = *(const float4*)(qland + ((size_t)bh * 64 + r) * 64 + d4);
    *(float4*)&klS[r][d4] = *(const float4*)(kland + ((size_t)bh * 64 + r) * 64 + d4);
  }
  __syncthreads();
  int w = tid >> 6, lane = tid & 63;
  float a[16], v[16];
#pragma unroll
  for (int k = 0; k < 16; ++k) {
    int row = w * 16 + k;
    float acc = 0.f;
#pragma unroll
    for (int d4 = 0; d4 < 64; d4 += 4) {
      float4 qv = *(float4*)&qlS[row][d4];
      float4 kv = *(float4*)&klS[lane][d4];
      acc += qv.x * kv.x + qv.y * kv.y + qv.z * kv.z + qv.w * kv.w;
    }
    float e = expf(acc);
    float rs = e;
#pragma unroll
    for (int m = 1; m < 64; m <<= 1) rs += __shfl_xor(rs, m);
    a[k] = e * (1.f / rs);
  }
#pragma unroll
  for (int k = 0; k < 16; ++k) v[k] = (w * 16 + k == lane) ? 1.f : 0.f;
  __syncthreads();   // qlS/klS dead; Ac/Vc overlay safe
  svd_sweeps(a, v, smemraw, w, lane, SW1_);
#pragma unroll
  for (int k = 0; k < 16; ++k) {
    asave[((size_t)bh * 64 + w * 16 + k) * 64 + lane] = a[k];
    vsave[((size_t)bh * 64 + w * 16 + k) * 64 + lane] = v[k];
  }
  __builtin_amdgcn_s_setprio(0);
}

// Phase 2: load state, SW2_ sweeps, sigma/cutoff + pinv.
// Tail layout: ps2 @37888 (2048 -> 39936); vsL@0, wasL@16640 overlay Ac/Vc.
__device__ void svd_phase2(const float* __restrict__ asave, const float* __restrict__ vsave,
                           float* __restrict__ pinv, int bh, char* smemraw, int tid) {
  __builtin_amdgcn_s_setprio(3);
  double (*ps2)[64]  = (double(*)[64])(smemraw + 37888);
  float (*vsL)[65]   = (float(*)[65])(smemraw);
  float (*wasL)[65]  = (float(*)[65])(smemraw + 16640);
  int w = tid >> 6, lane = tid & 63;
  float a[16], v[16];
#pragma unroll
  for (int k = 0; k < 16; ++k) {
    a[k] = asave[((size_t)bh * 64 + w * 16 + k) * 64 + lane];
    v[k] = vsave[((size_t)bh * 64 + w * 16 + k) * 64 + lane];
  }
  svd_sweeps(a, v, smemraw, w, lane, SW2_);

  double psig = 0.0;
#pragma unroll
  for (int k = 0; k < 16; ++k) psig += (double)a[k] * (double)a[k];
  ps2[w][lane] = psig;
  __syncthreads();
  double sig2 = (ps2[0][lane] + ps2[1][lane]) + (ps2[2][lane] + ps2[3][lane]);
  double smax = sig2;
#pragma unroll
  for (int m = 1; m < 64; m <<= 1) smax = fmax(smax, __shfl_xor(smax, m));
  double cutoff2 = smax * (RCOND_ * RCOND_);
  float wgt = (sig2 > cutoff2) ? (float)(1.0 / sig2) : 0.f;

#pragma unroll
  for (int k = 0; k < 16; ++k) {
    vsL[lane][w * 16 + k] = v[k];
    wasL[lane][w * 16 + k] = wgt * a[k];
  }
  __syncthreads();
  int i = tid >> 2;
  int j0 = (tid & 3) * 16;
  float acc[16] = {};
  for (int r = 0; r < 64; ++r) {
    float vv = vsL[r][i];
#pragma unroll
    for (int jj = 0; jj < 16; ++jj) acc[jj] = fmaf(vv, wasL[r][j0 + jj], acc[jj]);
  }
#pragma unroll
  for (int jj = 0; jj < 16; jj += 4) {
    float4 ovv = make_float4(acc[jj], acc[jj + 1], acc[jj + 2], acc[jj + 3]);
    *(float4*)(pinv + ((size_t)bh * 64 + i) * 64 + j0 + jj) = ovv;
  }
  __builtin_amdgcn_s_setprio(0);
}

// ---------------------------------------------------------------------------
// Fused 1: blocks 0..15 = SVD phase 1 (incl. ker2); 16..3087 = projections.
__global__ __launch_bounds__(256) void fused1_kernel(
    const float* __restrict__ x,
    const float* __restrict__ wq, const float* __restrict__ bq,
    const float* __restrict__ wk, const float* __restrict__ bk,
    const float* __restrict__ wv, const float* __restrict__ bv,
    unsigned short* __restrict__ q4, unsigned short* __restrict__ k4,
    unsigned short* __restrict__ vt,
    const float* __restrict__ qland, const float* __restrict__ kland,
    float* __restrict__ asave, float* __restrict__ vsave) {
  __shared__ __align__(16) char smem[37888];
  int tid = threadIdx.x;
  int blk = blockIdx.x;
  if (blk < 16) { svd_phase1(qland, kland, asave, vsave, blk, smem, tid); return; }
  int g = blk - 16;
  int which = g >> 10;
  int sub = g & 1023;
  int row0 = (sub >> 2) * 128;
  int col0 = (sub & 3) * 128;
  unsigned short* Xs = (unsigned short*)smem;
  unsigned short* Ws = Xs + 128 * 32;
  if (which == 0)
    mfma_gemm_body(x, wq, bq, q4, 0.125f, 1, row0, col0, Xs, Ws, tid);
  else if (which == 1)
    mfma_gemm_body(x, wk, bk, k4, 1.0f, 1, row0, col0, Xs, Ws, tid);
  else
    mfma_gemm_body(x, wv, bv, vt, 1.0f, 2, row0, col0, Xs, Ws, tid);
}

// ---------------------------------------------------------------------------
// ker3+kv body (deviation form, MFMA) — unchanged math.
__device__ void ker3kv_body(const unsigned short* __restrict__ qlh,
                            const unsigned short* __restrict__ qll,
                            const unsigned short* __restrict__ k4,
                            const unsigned short* __restrict__ vt,
                            float* __restrict__ pacc,
                            float* __restrict__ pacc0,
                            float* __restrict__ ps,
                            int bh, int ch, char* smemraw, int tid) {
  int w = tid >> 6, lane = tid & 63;
  int part = ch * 4 + w;
  int lrow = lane & 15, lgrp = lane >> 4;
  unsigned short* myP = (unsigned short*)smemraw + w * 64 * 72;

  bf16x8 qah[4][2], qal[4][2];
#pragma unroll
  for (int mf = 0; mf < 4; ++mf)
#pragma unroll
    for (int ks = 0; ks < 2; ++ks) {
      size_t off = ((size_t)bh * 64 + mf * 16 + lrow) * 64 + ks * 32 + lgrp * 8;
      qah[mf][ks] = ld_bf8(qlh + off);
      qal[mf][ks] = ld_bf8(qll + off);
    }
  bf16x8 onesf;
#pragma unroll
  for (int j = 0; j < 8; ++j) onesf[j] = (__bf16)1.0f;

  f32x4 kvacc[4][4] = {};
  f32x4 oneacc[4] = {};
  f32x4 ssum[4] = {};

  for (int sub = 0; sub < 4; ++sub) {
    int n0 = ch * 1024 + w * 256 + sub * 64;
    f32x4 sacc[4][4] = {};
#pragma unroll
    for (int ks = 0; ks < 2; ++ks) {
#pragma unroll
      for (int nf = 0; nf < 4; ++nf) {
        bf16x8 kb = ld_bf8(k4 + ((size_t)bh * N_ + n0 + nf * 16 + lrow) * 64 + ks * 32 + lgrp * 8);
#pragma unroll
        for (int mf = 0; mf < 4; ++mf) {
          sacc[mf][nf] = __builtin_amdgcn_mfma_f32_16x16x32_bf16(qah[mf][ks], kb, sacc[mf][nf], 0, 0, 0);
          sacc[mf][nf] = __builtin_amdgcn_mfma_f32_16x16x32_bf16(qal[mf][ks], kb, sacc[mf][nf], 0, 0, 0);
        }
      }
    }
#pragma unroll
    for (int mf = 0; mf < 4; ++mf) {
#pragma unroll
      for (int nf = 0; nf < 4; ++nf) {
#pragma unroll
        for (int r = 0; r < 4; ++r) {
          float pd = expf(sacc[mf][nf][r]) - 1.0f;
          ssum[mf][r] += pd;
          myP[(mf * 16 + lgrp * 4 + r) * 72 + nf * 16 + lrow] = f2bf(pd);
        }
      }
    }
#pragma unroll
    for (int ks = 0; ks < 2; ++ks) {
      bf16x8 pa[4];
#pragma unroll
      for (int mf = 0; mf < 4; ++mf)
        pa[mf] = ld_bf8(myP + (mf * 16 + lrow) * 72 + ks * 32 + lgrp * 8);
#pragma unroll
      for (int nf = 0; nf < 4; ++nf) {
        bf16x8 vb = ld_bf8(vt + ((size_t)bh * 64 + nf * 16 + lrow) * N_ + n0 + ks * 32 + lgrp * 8);
#pragma unroll
        for (int mf = 0; mf < 4; ++mf)
          kvacc[mf][nf] = __builtin_amdgcn_mfma_f32_16x16x32_bf16(pa[mf], vb, kvacc[mf][nf], 0, 0, 0);
        oneacc[nf] = __builtin_amdgcn_mfma_f32_16x16x32_bf16(onesf, vb, oneacc[nf], 0, 0, 0);
      }
    }
  }
#pragma unroll
  for (int mf = 0; mf < 4; ++mf)
#pragma unroll
    for (int m = 1; m < 16; m <<= 1)
#pragma unroll
      for (int r = 0; r < 4; ++r) ssum[mf][r] += __shfl_xor(ssum[mf][r], m);

  size_t pb = (((size_t)bh * NPART_ + part) * 64) * 64;
#pragma unroll
  for (int mf = 0; mf < 4; ++mf)
#pragma unroll
    for (int nf = 0; nf < 4; ++nf)
#pragma unroll
      for (int r = 0; r < 4; ++r)
        pacc[pb + (size_t)(mf * 16 + lgrp * 4 + r) * 64 + nf * 16 + lrow] = kvacc[mf][nf][r];
  if (lrow == 0) {
#pragma unroll
    for (int mf = 0; mf < 4; ++mf)
#pragma unroll
      for (int r = 0; r < 4; ++r)
        ps[((size_t)bh * NPART_ + part) * 64 + mf * 16 + lgrp * 4 + r] = ssum[mf][r];
  }
  if (lgrp == 0) {
#pragma unroll
    for (int nf = 0; nf < 4; ++nf)
      pacc0[((size_t)bh * NPART_ + part) * 64 + nf * 16 + lrow] = oneacc[nf][0];
  }
}

// Fused 2: blocks 0..15 = SVD phase 2 (+pinv); 16..271 = ker3kv.
__global__ __launch_bounds__(256, 1) void fused2_kernel(
    const unsigned short* __restrict__ qlh,
    const unsigned short* __restrict__ qll,
    const unsigned short* __restrict__ k4,
    const unsigned short* __restrict__ vt,
    float* __restrict__ pacc, float* __restrict__ pacc0, float* __restrict__ ps,
    const float* __restrict__ asave, const float* __restrict__ vsave,
    float* __restrict__ pinv) {
  __shared__ __align__(16) char smem[39936];
  int tid = threadIdx.x;
  int blk = blockIdx.x;
  if (blk < 16) { svd_phase2(asave, vsave, pinv, blk, smem, tid); return; }
  int g = blk - 16;
  int bh = g >> 4, ch = g & 15;
  ker3kv_body(qlh, qll, k4, vt, pacc, pacc0, ps, bh, ch, smem, tid);
}

// ---------------------------------------------------------------------------
__global__ __launch_bounds__(256) void kv_combine_kernel(const float* __restrict__ pacc,
                                                         const float* __restrict__ pacc0,
                                                         const float* __restrict__ ps,
                                                         float* __restrict__ kv) {
  int bh = blockIdx.y;
  int lm = blockIdx.x * 16 + (threadIdx.x >> 4);
  int d4 = (threadIdx.x & 15) * 4;
  float s = 16384.f;
  for (int part = 0; part < NPART_; ++part) s += ps[((size_t)bh * NPART_ + part) * 64 + lm];
  float4 a = make_float4(0.f, 0.f, 0.f, 0.f);
  for (int part = 0; part < NPART_; ++part) {
    float4 c0 = *(const float4*)&pacc0[((size_t)bh * NPART_ + part) * 64 + d4];
    float4 v = *(const float4*)&pacc[(((size_t)bh * NPART_ + part) * 64 + lm) * 64 + d4];
    a.x += c0.x + v.x; a.y += c0.y + v.y; a.z += c0.z + v.z; a.w += c0.w + v.w;
  }
  float inv = 1.f / s;
  float4 o = make_float4(a.x * inv, a.y * inv, a.z * inv, a.w * inv);
  *(float4*)(kv + ((size_t)bh * 64 + lm) * 64 + d4) = o;
}

// ---------------------------------------------------------------------------
__global__ __launch_bounds__(256) void mmat_kernel(const float* __restrict__ pinv,
                                                   const float* __restrict__ kv,
                                                   unsigned short* __restrict__ mtbh,
                                                   unsigned short* __restrict__ mtbl,
                                                   float* __restrict__ msum) {
  int bh = blockIdx.x;
  int tid = threadIdx.x;
  __shared__ float kvs[64][68];
  __shared__ double pcsd[64];
  for (int i = 0; i < 4; ++i) {
    int s = tid + i * 256;
    int r = s >> 4, d4 = (s & 15) << 2;
    *(float4*)&kvs[r][d4] = *(const float4*)(kv + ((size_t)bh * 64 + r) * 64 + d4);
  }
  if (tid < 64) {
    double s = 0.0;
    for (int l = 0; l < 64; ++l) s += (double)pinv[((size_t)bh * 64 + l) * 64 + tid];
    pcsd[tid] = s;
  }
  __syncthreads();
  int l = tid >> 2, t = tid & 3;
  double o[16] = {};
  for (int j = 0; j < 64; ++j) {
    double pv = (double)pinv[((size_t)bh * 64 + l) * 64 + j];
#pragma unroll
    for (int i = 0; i < 16; ++i) o[i] += pv * (double)kvs[j][t * 16 + i];
  }
#pragma unroll
  for (int i = 0; i < 16; ++i) {
    float f = (float)o[i];
    unsigned short hi = f2bf(f);
    float lo = f - bf2f(hi);
    int d = t * 16 + i;
    mtbh[((size_t)bh * 64 + d) * 64 + l] = hi;
    mtbl[((size_t)bh * 64 + d) * 64 + l] = f2bf(lo);
  }
  if (tid < 64) {
    double m = 0.0;
    for (int j = 0; j < 64; ++j) m += pcsd[j] * (double)kvs[j][tid];
    msum[(size_t)bh * 64 + tid] = (float)(m * (1.0 / 64.0));
  }
}

// ---------------------------------------------------------------------------
__global__ __launch_bounds__(256, 1) void ker1out_mfma_kernel(
    const unsigned short* __restrict__ q4,
    const unsigned short* __restrict__ klb,
    const unsigned short* __restrict__ mtbh,
    const unsigned short* __restrict__ mtbl,
    const float* __restrict__ msum,
    unsigned short* __restrict__ outh) {
  int bh = blockIdx.y, tile = blockIdx.x;
  int b = bh >> 3, h = bh & 7;
  int tid = threadIdx.x, w = tid >> 6, lane = tid & 63;
  int lrow = lane & 15, lgrp = lane >> 4;
  int tok0 = tile * 256 + w * 64;
  __shared__ __align__(16) unsigned short Pl[4][64 * 72];
  unsigned short* myP = &Pl[w][0];

  f32x4 sacc[4][4] = {};
#pragma unroll
  for (int ks = 0; ks < 2; ++ks) {
    bf16x8 kb[4];
#pragma unroll
    for (int nf = 0; nf < 4; ++nf)
      kb[nf] = ld_bf8(klb + ((size_t)bh * 64 + nf * 16 + lrow) * 64 + ks * 32 + lgrp * 8);
#pragma unroll
    for (int mf = 0; mf < 4; ++mf) {
      bf16x8 qa = ld_bf8(q4 + ((size_t)bh * N_ + tok0 + mf * 16 + lrow) * 64 + ks * 32 + lgrp * 8);
#pragma unroll
      for (int nf = 0; nf < 4; ++nf)
        sacc[mf][nf] = __builtin_amdgcn_mfma_f32_16x16x32_bf16(qa, kb[nf], sacc[mf][nf], 0, 0, 0);
    }
  }
  f32x4 ssum[4] = {};
#pragma unroll
  for (int mf = 0; mf < 4; ++mf)
#pragma unroll
    for (int nf = 0; nf < 4; ++nf)
#pragma unroll
      for (int r = 0; r < 4; ++r) {
        sacc[mf][nf][r] = expf(sacc[mf][nf][r]);
        ssum[mf][r] += sacc[mf][nf][r];
      }
#pragma unroll
  for (int mf = 0; mf < 4; ++mf)
#pragma unroll
    for (int m = 1; m < 16; m <<= 1)
#pragma unroll
      for (int r = 0; r < 4; ++r) ssum[mf][r] += __shfl_xor(ssum[mf][r], m);
#pragma unroll
  for (int mf = 0; mf < 4; ++mf) {
    f32x4 inv;
#pragma unroll
    for (int r = 0; r < 4; ++r) inv[r] = 1.f / ssum[mf][r];
#pragma unroll
    for (int nf = 0; nf < 4; ++nf)
#pragma unroll
      for (int r = 0; r < 4; ++r) {
        float pdev = fmaf(sacc[mf][nf][r], inv[r], -0.015625f);
        myP[(mf * 16 + lgrp * 4 + r) * 72 + nf * 16 + lrow] = f2bf(pdev);
      }
  }

  f32x4 oacc[4][4] = {};
#pragma unroll
  for (int ks = 0; ks < 2; ++ks) {
    bf16x8 pa[4];
#pragma unroll
    for (int mf = 0; mf < 4; ++mf)
      pa[mf] = ld_bf8(myP + (mf * 16 + lrow) * 72 + ks * 32 + lgrp * 8);
#pragma unroll
    for (int nf = 0; nf < 4; ++nf) {
      bf16x8 mh = ld_bf8(mtbh + ((size_t)bh * 64 + nf * 16 + lrow) * 64 + ks * 32 + lgrp * 8);
      bf16x8 ml = ld_bf8(mtbl + ((size_t)bh * 64 + nf * 16 + lrow) * 64 + ks * 32 + lgrp * 8);
#pragma unroll
      for (int mf = 0; mf < 4; ++mf) {
        oacc[mf][nf] = __builtin_amdgcn_mfma_f32_16x16x32_bf16(pa[mf], mh, oacc[mf][nf], 0, 0, 0);
        oacc[mf][nf] = __builtin_amdgcn_mfma_f32_16x16x32_bf16(pa[mf], ml, oacc[mf][nf], 0, 0, 0);
      }
    }
  }
#pragma unroll
  for (int nf = 0; nf < 4; ++nf) {
    float ms = msum[(size_t)bh * 64 + nf * 16 + lrow];
#pragma unroll
    for (int mf = 0; mf < 4; ++mf)
#pragma unroll
      for (int r = 0; r < 4; ++r) {
        int tok = tok0 + mf * 16 + lgrp * 4 + r;
        int d = nf * 16 + lrow;
        outh[((size_t)b * N_ + tok) * C_ + h * HD_ + d] = f2bf(oacc[mf][nf][r] + ms);
      }
  }
}

// ---------------------------------------------------------------------------
// Final projection (serial tail): outh(bf16) @ wob^T(bf16) + bo -> f32 out.
__global__ __launch_bounds__(256) void oproj_kernel(const unsigned short* __restrict__ outh,
                                                    const unsigned short* __restrict__ wob,
                                                    const float* __restrict__ bo,
                                                    float* __restrict__ out) {
  __shared__ __align__(16) unsigned short Xs[128 * 32];
  __shared__ __align__(16) unsigned short Ws[128 * 32];
  int tid = threadIdx.x;
  int w = tid >> 6, lane = tid & 63;
  int wr = w >> 1, wc = w & 1;
  int row0 = blockIdx.x * 128, col0 = blockIdx.y * 128;
  f32x4 acc[4][4] = {};

  for (int k0 = 0; k0 < C_; k0 += 32) {
    __syncthreads();
#pragma unroll
    for (int i = 0; i < 2; ++i) {
      const unsigned short* gx = outh + (size_t)(row0 + w * 32 + i * 16 + (lane >> 2)) * C_ + k0 + (lane & 3) * 8;
      gload_lds16(gx, &Xs[(w * 32 + i * 16) * 32]);
      const unsigned short* gw = wob + (size_t)(col0 + w * 32 + i * 16 + (lane >> 2)) * C_ + k0 + (lane & 3) * 8;
      gload_lds16(gw, &Ws[(w * 32 + i * 16) * 32]);
    }
    __syncthreads();
    bf16x8 af[4], bfr[4];
#pragma unroll
    for (int m = 0; m < 4; ++m)
      af[m] = *(bf16x8*)&Xs[(wr * 64 + m * 16 + (lane & 15)) * 32 + (lane >> 4) * 8];
#pragma unroll
    for (int n = 0; n < 4; ++n)
      bfr[n] = *(bf16x8*)&Ws[(wc * 64 + n * 16 + (lane & 15)) * 32 + (lane >> 4) * 8];
#pragma unroll
    for (int m = 0; m < 4; ++m)
#pragma unroll
      for (int n = 0; n < 4; ++n)
        acc[m][n] = __builtin_amdgcn_mfma_f32_16x16x32_bf16(af[m], bfr[n], acc[m][n], 0, 0, 0);
  }

#pragma unroll
  for (int m = 0; m < 4; ++m) {
    int rbase = row0 + wr * 64 + m * 16 + (lane >> 4) * 4;
#pragma unroll
    for (int n = 0; n < 4; ++n) {
      int c = col0 + wc * 64 + n * 16 + (lane & 15);
      float bc = bo[c];
#pragma unroll
      for (int rg = 0; rg < 4; ++rg)
        out[(size_t)(rbase + rg) * C_ + c] = acc[m][n][rg] + bc;
    }
  }
}

// ---------------------------------------------------------------------------
extern "C" void kernel_launch(void* const* d_in, const int* in_sizes, int n_in,
                              void* d_out, int out_size, void* d_ws, size_t ws_size,
                              hipStream_t stream) {
  const float* x  = (const float*)d_in[0];
  const float* wq = (const float*)d_in[1];
  const float* bq = (const float*)d_in[2];
  const float* wk = (const float*)d_in[3];
  const float* bk = (const float*)d_in[4];
  const float* wv = (const float*)d_in[5];
  const float* bv = (const float*)d_in[6];
  const float* wo = (const float*)d_in[7];
  const float* bo = (const float*)d_in[8];
  float* out = (float*)d_out;

  char* base = (char*)d_ws;
  const size_t QKV = (size_t)BH_ * N_ * HD_;
  unsigned short* q4 = (unsigned short*)base;                 // 32MB
  unsigned short* k4 = (unsigned short*)(base + QKV * 2);     // 32MB
  unsigned short* vt = (unsigned short*)(base + QKV * 4);     // 32MB
  unsigned short* outh = (unsigned short*)(base + QKV * 2);   // alias k4 (dead after ker3kv)
  char* sp = base + QKV * 6;
  float* pacc  = (float*)sp; sp += (size_t)BH_ * NPART_ * 64 * 64 * 4;  // 16.78MB
  float* pacc0 = (float*)sp; sp += (size_t)BH_ * NPART_ * 64 * 4;
  float* ps    = (float*)sp; sp += (size_t)BH_ * NPART_ * 64 * 4;
  float* xbar  = (float*)sp; sp += (size_t)B_ * LM_ * C_ * 4;
  float* qland = (float*)sp; sp += (size_t)BH_ * LM_ * HD_ * 4;
  float* kland = (float*)sp; sp += (size_t)BH_ * LM_ * HD_ * 4;
  unsigned short* qlbh = (unsigned short*)sp; sp += (size_t)BH_ * LM_ * HD_ * 2;
  unsigned short* qlbl = (unsigned short*)sp; sp += (size_t)BH_ * LM_ * HD_ * 2;
  unsigned short* klb  = (unsigned short*)sp; sp += (size_t)BH_ * LM_ * HD_ * 2;
  float* pinv  = (float*)sp; sp += (size_t)BH_ * LM_ * LM_ * 4;
  float* kvb   = (float*)sp; sp += (size_t)BH_ * LM_ * HD_ * 4;
  unsigned short* mtbh = (unsigned short*)sp; sp += (size_t)BH_ * LM_ * HD_ * 2;
  unsigned short* mtbl = (unsigned short*)sp; sp += (size_t)BH_ * LM_ * HD_ * 2;
  float* msum  = (float*)sp; sp += (size_t)BH_ * HD_ * 4;
  float* asave = (float*)sp; sp += (size_t)BH_ * LM_ * LM_ * 4;   // 256KB
  float* vsave = (float*)sp; sp += (size_t)BH_ * LM_ * LM_ * 4;   // 256KB
  unsigned short* wob = (unsigned short*)sp; sp += (size_t)C_ * C_ * 2;  // 512KB

  const int W8 = (C_ * C_) / 8;

  // wo -> bf16 (needed only by the serial-tail oproj)
  cvt_bf16_kernel<<<W8 / 256, 256, 0, stream>>>(wo, wob, W8);

  // landmark path (f32-exact) + bf16 conversions in epilogue
  seg_mean_kernel<<<B_ * LM_, 256, 0, stream>>>(x, xbar);
  dim3 gl(4, 8);
  land_gemm_kernel<<<gl, 256, 0, stream>>>(xbar, wq, bq, wk, bk,
                                           qland, kland, qlbh, qlbl, klb);

  // fused 1: SVD phase 1 (blocks 0..15; computes ker2 in-LDS) + projections
  fused1_kernel<<<16 + 3 * 1024, 256, 0, stream>>>(
      x, wq, bq, wk, bk, wv, bv, q4, k4, vt, qland, kland, asave, vsave);

  // fused 2: SVD phase 2 + pinv (blocks 0..15) + ker3kv (256 blocks)
  fused2_kernel<<<16 + NCH_ * BH_, 256, 0, stream>>>(
      qlbh, qlbl, k4, vt, pacc, pacc0, ps, asave, vsave, pinv);

  // combine + M
  dim3 g7(4, BH_);
  kv_combine_kernel<<<g7, 256, 0, stream>>>(pacc, pacc0, ps, kvb);
  mmat_kernel<<<BH_, 256, 0, stream>>>(pinv, kvb, mtbh, mtbl, msum);

  // out_heads -> bf16 outh (aliases dead k4)
  dim3 g9(N_ / 256, BH_);
  ker1out_mfma_kernel<<<g9, 256, 0, stream>>>(q4, klb, mtbh, mtbl, msum, outh);

  // final projection (DMA-staged bf16 GEMM)
  dim3 g10(B_ * N_ / 128, C_ / 128);
  oproj_kernel<<<g10, 256, 0, stream>>>(outh, wob, bo, out);
}